// Round 4
// baseline (1873.628 us; speedup 1.0000x reference)
//
#include <hip/hip_runtime.h>
#include <hip/hip_bf16.h>

// ---- problem constants (match reference) ----
#define NP 100000
#define NA 50000
#define NTOT 150000          // NP+NA
#define E0 300000
#define E1 300000
#define E2 200000
#define ETOT 800000
#define NH 4
#define HD 16
#define HID 64
#define IN_DIM 128
#define KQV 192
#define LAYERS 2
#define NSRC 250000          // NA + 2*NP
#define JP 320               // fused paper cols: q | k_et1 | k_et2 | v_et1 | v_et2
#define JA 192               // fused author cols: q | k_et0 | v_et0
#define NCH 586              // ceil(NTOT/256)
#define PT 1563              // ceil(NP/64)
#define AT 782               // ceil(NA/64)

__device__ __forceinline__ float gelu_exact(float x) {
    return 0.5f * x * (1.0f + erff(x * 0.7071067811865475f));
}
// f32 -> bf16 bits, round-to-nearest-even (finite values)
__device__ __forceinline__ unsigned short f2bf(float f) {
    unsigned u = __float_as_uint(f);
    return (unsigned short)((u + 0x7fffu + ((u >> 16) & 1u)) >> 16);
}
__device__ __forceinline__ float bf2f(unsigned short b) {
    return __uint_as_float((unsigned)b << 16);
}

// decode global edge id -> (src in Ks/Vs space, dst in node space)
__device__ __forceinline__ void edge_decode(int e, const int* __restrict__ ei_ap,
                                            const int* __restrict__ ei_pa,
                                            const int* __restrict__ ei_pp,
                                            int& src, int& dst) {
    if (e < E0)            { src = ei_ap[e];                 dst = ei_ap[E0 + e]; }
    else if (e < E0 + E1)  { int le = e - E0;
                             src = NA + ei_pa[le];           dst = NP + ei_pa[E1 + le]; }
    else                   { int le = e - E0 - E1;
                             src = NA + NP + ei_pp[le];      dst = ei_pp[E2 + le]; }
}

// ---------------- CSR build ----------------
__global__ void zero_int_kernel(int* __restrict__ p, int n) {
    int i = blockIdx.x * blockDim.x + threadIdx.x;
    int st = gridDim.x * blockDim.x;
    for (int j = i; j < n; j += st) p[j] = 0;
}

__global__ void csr_count_kernel(const int* __restrict__ ei_ap, const int* __restrict__ ei_pa,
                                 const int* __restrict__ ei_pp, int* __restrict__ cnt) {
    int e = blockIdx.x * 256 + threadIdx.x;
    if (e >= ETOT) return;
    int src, dst; edge_decode(e, ei_ap, ei_pa, ei_pp, src, dst);
    atomicAdd(&cnt[dst], 1);
}

__global__ void scan_chunk_sums(const int* __restrict__ cnt, int* __restrict__ csum) {
    __shared__ int sd[256];
    int c = blockIdx.x, t = threadIdx.x;
    int i = c * 256 + t;
    sd[t] = (i < NTOT) ? cnt[i] : 0;
    __syncthreads();
    for (int o = 128; o > 0; o >>= 1) { if (t < o) sd[t] += sd[t + o]; __syncthreads(); }
    if (t == 0) csum[c] = sd[0];
}

__global__ void scan_offsets(const int* __restrict__ csum, int* __restrict__ coff, int nch) {
    __shared__ int sd[1024];
    int t = threadIdx.x;
    int v = (t < nch) ? csum[t] : 0;
    sd[t] = v;
    __syncthreads();
    for (int o = 1; o < 1024; o <<= 1) {
        int x = (t >= o) ? sd[t - o] : 0;
        __syncthreads();
        sd[t] += x;
        __syncthreads();
    }
    if (t < nch) coff[t] = sd[t] - v;   // exclusive
}

__global__ void scan_final(const int* __restrict__ cnt, const int* __restrict__ coff,
                           int* __restrict__ row_ptr, int* __restrict__ cursor) {
    __shared__ int sd[256];
    int c = blockIdx.x, t = threadIdx.x, i = c * 256 + t;
    int v = (i < NTOT) ? cnt[i] : 0;
    sd[t] = v;
    __syncthreads();
    for (int o = 1; o < 256; o <<= 1) {
        int x = (t >= o) ? sd[t - o] : 0;
        __syncthreads();
        sd[t] += x;
        __syncthreads();
    }
    if (i < NTOT) { int ex = coff[c] + sd[t] - v; row_ptr[i] = ex; cursor[i] = ex; }
    if (i == 0) row_ptr[NTOT] = ETOT;
}

__global__ void csr_fill_kernel(const int* __restrict__ ei_ap, const int* __restrict__ ei_pa,
                                const int* __restrict__ ei_pp, int* __restrict__ cursor,
                                int* __restrict__ edge_src) {
    int e = blockIdx.x * 256 + threadIdx.x;
    if (e >= ETOT) return;
    int src, dst; edge_decode(e, ei_ap, ei_pa, ei_pp, src, dst);
    int pos = atomicAdd(&cursor[dst], 1);
    edge_src[pos] = src;
}

// ---------------- fused-weight build (per layer) ----------------
__global__ void fuse_weights_kernel(const float* __restrict__ Wkqv, const float* __restrict__ bkqv,
                                    const float* __restrict__ Wkrel, const float* __restrict__ Wvrel,
                                    float* __restrict__ Wfp, float* __restrict__ bfp,
                                    float* __restrict__ Wfa, float* __restrict__ bfa) {
    int idx = blockIdx.x * 256 + threadIdx.x;
    int type, i, j;
    if (idx < 65 * JP) { type = 0; i = idx / JP; j = idx % JP; }
    else {
        int r = idx - 65 * JP;
        if (r >= 65 * JA) return;
        type = 1; i = r / JA; j = r % JA;
    }
    int c = j >> 6, jj = j & 63, h = jj >> 4, e = jj & 15;
    const float* Wk = Wkqv + (size_t)type * HID * KQV;
    const float* bk = bkqv + type * KQV;
    float val;
    if (c == 0) {
        val = (i < 64) ? Wk[i * KQV + 64 + jj] : bk[64 + jj];
    } else {
        int et, isV;
        if (type == 0) { et = (c == 1 || c == 3) ? 1 : 2; isV = (c >= 3); }
        else           { et = 0; isV = (c == 2); }
        const float* Wr = (isV ? Wvrel : Wkrel) + (size_t)(et * NH + h) * HD * HD;
        int sb = (isV ? 128 : 0) + h * HD;
        val = 0.0f;
        #pragma unroll
        for (int d = 0; d < HD; d++) {
            float a = (i < 64) ? Wk[i * KQV + sb + d] : bk[sb + d];
            val += a * Wr[d * HD + e];
        }
    }
    if (i < 64) (type ? Wfa : Wfp)[i * (type ? JA : JP) + j] = val;
    else        (type ? bfa : bfp)[j] = val;
}

// ---------------- shared GEMM core pieces ----------------
#define GEMM_CORE_64(ACCVAR, XS, WS, KOFF)                                         \
    {                                                                              \
        _Pragma("unroll")                                                          \
        for (int i = 0; i < 64; i += 4) {                                          \
            float4 A0 = *(const float4*)&XS[tr4 + 0][KOFF + i];                    \
            float4 A1 = *(const float4*)&XS[tr4 + 1][KOFF + i];                    \
            float4 A2 = *(const float4*)&XS[tr4 + 2][KOFF + i];                    \
            float4 A3 = *(const float4*)&XS[tr4 + 3][KOFF + i];                    \
            float4 W0 = *(const float4*)&WS[i + 0][tcj];                           \
            float4 W1 = *(const float4*)&WS[i + 1][tcj];                           \
            float4 W2 = *(const float4*)&WS[i + 2][tcj];                           \
            float4 W3 = *(const float4*)&WS[i + 3][tcj];                           \
            ACCVAR[0][0] += A0.x*W0.x + A0.y*W1.x + A0.z*W2.x + A0.w*W3.x;         \
            ACCVAR[0][1] += A0.x*W0.y + A0.y*W1.y + A0.z*W2.y + A0.w*W3.y;         \
            ACCVAR[0][2] += A0.x*W0.z + A0.y*W1.z + A0.z*W2.z + A0.w*W3.z;         \
            ACCVAR[0][3] += A0.x*W0.w + A0.y*W1.w + A0.z*W2.w + A0.w*W3.w;         \
            ACCVAR[1][0] += A1.x*W0.x + A1.y*W1.x + A1.z*W2.x + A1.w*W3.x;         \
            ACCVAR[1][1] += A1.x*W0.y + A1.y*W1.y + A1.z*W2.y + A1.w*W3.y;         \
            ACCVAR[1][2] += A1.x*W0.z + A1.y*W1.z + A1.z*W2.z + A1.w*W3.z;         \
            ACCVAR[1][3] += A1.x*W0.w + A1.y*W1.w + A1.z*W2.w + A1.w*W3.w;         \
            ACCVAR[2][0] += A2.x*W0.x + A2.y*W1.x + A2.z*W2.x + A2.w*W3.x;         \
            ACCVAR[2][1] += A2.x*W0.y + A2.y*W1.y + A2.z*W2.y + A2.w*W3.y;         \
            ACCVAR[2][2] += A2.x*W0.z + A2.y*W1.z + A2.z*W2.z + A2.w*W3.z;         \
            ACCVAR[2][3] += A2.x*W0.w + A2.y*W1.w + A2.z*W2.w + A2.w*W3.w;         \
            ACCVAR[3][0] += A3.x*W0.x + A3.y*W1.x + A3.z*W2.x + A3.w*W3.x;         \
            ACCVAR[3][1] += A3.x*W0.y + A3.y*W1.y + A3.z*W2.y + A3.w*W3.y;         \
            ACCVAR[3][2] += A3.x*W0.z + A3.y*W1.z + A3.z*W2.z + A3.w*W3.z;         \
            ACCVAR[3][3] += A3.x*W0.w + A3.y*W1.w + A3.z*W2.w + A3.w*W3.w;         \
        }                                                                          \
    }

// ---------------- input projection (K=128), paper+author merged ----------------
__global__ __launch_bounds__(256) void gemm_in(
    const float* __restrict__ xp, const float* __restrict__ xa,
    const float* __restrict__ W_in, const float* __restrict__ b_in,
    float* __restrict__ hbuf)
{
    __shared__ float xs[64][IN_DIM + 4];
    __shared__ float wsb[64][68];
    int b = blockIdx.x, tid = threadIdx.x;
    int type = (b >= PT);
    int tile = type ? (b - PT) : b;
    int N = type ? NA : NP;
    const float* X = type ? xa : xp;
    const float* W = W_in + (size_t)type * IN_DIM * HID;
    const float* bias = b_in + type * HID;
    float* H = hbuf + (type ? (size_t)NP * HID : 0);
    int nb = tile * 64;

    #pragma unroll
    for (int r = 0; r < 8; r++) {
        int f = tid + 256 * r;
        int row = f >> 5, col = (f & 31) * 4;
        int n = nb + row;
        float4 v = (n < N) ? *(const float4*)(X + (size_t)n * IN_DIM + col)
                           : make_float4(0.f, 0.f, 0.f, 0.f);
        *(float4*)&xs[row][col] = v;
    }
    const int tr = tid >> 4, tc = tid & 15;
    const int tr4 = tr * 4, tcj = tc * 4;
    float acc[4][4] = {};
    #pragma unroll
    for (int ks = 0; ks < IN_DIM; ks += 64) {
        __syncthreads();
        #pragma unroll
        for (int r = 0; r < 4; r++) {
            int f = tid + 256 * r;
            int row = f >> 4, col = (f & 15) * 4;
            *(float4*)&wsb[row][col] = *(const float4*)(W + (size_t)(ks + row) * HID + col);
        }
        __syncthreads();
        GEMM_CORE_64(acc, xs, wsb, ks)
    }
    float b0 = bias[tcj], b1 = bias[tcj+1], b2 = bias[tcj+2], b3 = bias[tcj+3];
    #pragma unroll
    for (int m = 0; m < 4; m++) {
        int n = nb + tr4 + m;
        if (n < N) {
            float* p = H + (size_t)n * HID + tcj;
            p[0] = acc[m][0] + b0; p[1] = acc[m][1] + b1;
            p[2] = acc[m][2] + b2; p[3] = acc[m][3] + b3;
        }
    }
}

// ---------------- KQV GEMM: one (row-tile, chunk) per block ----------------
// paper chunks: 0->Q f32 | 1->Ks@NA | 2->Ks@NA+NP | 3->Vs@NA | 4->Vs@NA+NP (bf16)
// author chunks: 0->Q@NP | 1->Ks@0 | 2->Vs@0
__global__ __launch_bounds__(256) void gemm_kqv(
    const float* __restrict__ hbuf,
    const float* __restrict__ Wfp, const float* __restrict__ bfp,
    const float* __restrict__ Wfa, const float* __restrict__ bfa,
    float* __restrict__ Q, unsigned short* __restrict__ Ksb, unsigned short* __restrict__ Vsb)
{
    __shared__ float xs[64][68];
    __shared__ float wsb[64][68];
    int b = blockIdx.x, tid = threadIdx.x;
    int type, tile, chunk;
    if (b < PT * 5) { type = 0; chunk = b / PT; tile = b % PT; }
    else            { int ab = b - PT * 5; type = 1; chunk = ab / AT; tile = ab % AT; }
    int N = type ? NA : NP;
    const float* X = hbuf + (type ? (size_t)NP * HID : 0);
    const float* W = type ? Wfa : Wfp;
    const float* bias = type ? bfa : bfp;
    int ldw = type ? JA : JP;
    int nb = tile * 64;

    #pragma unroll
    for (int r = 0; r < 4; r++) {
        int f = tid + 256 * r;
        int row = f >> 4, col = (f & 15) * 4;
        int n = nb + row;
        float4 v = (n < N) ? *(const float4*)(X + (size_t)n * HID + col)
                           : make_float4(0.f, 0.f, 0.f, 0.f);
        *(float4*)&xs[row][col] = v;
        *(float4*)&wsb[row][col] = *(const float4*)(W + (size_t)row * ldw + chunk * 64 + col);
    }
    __syncthreads();
    const int tr = tid >> 4, tc = tid & 15;
    const int tr4 = tr * 4, tcj = tc * 4;
    float acc[4][4] = {};
    GEMM_CORE_64(acc, xs, wsb, 0)

    const float* bp = bias + chunk * 64 + tcj;
    float b0 = bp[0], b1 = bp[1], b2 = bp[2], b3 = bp[3];
    // destination select
    if (chunk == 0) {
        int noff = type ? NP : 0;
        #pragma unroll
        for (int m = 0; m < 4; m++) {
            int n = nb + tr4 + m;
            if (n < N) {
                float* p = Q + (size_t)(noff + n) * HID + tcj;
                p[0] = acc[m][0] + b0; p[1] = acc[m][1] + b1;
                p[2] = acc[m][2] + b2; p[3] = acc[m][3] + b3;
            }
        }
    } else {
        unsigned short* base; int noff;
        if (type == 0) {
            base = (chunk <= 2) ? Ksb : Vsb;
            noff = ((chunk == 1 || chunk == 3) ? NA : NA + NP);
        } else {
            base = (chunk == 1) ? Ksb : Vsb;
            noff = 0;
        }
        #pragma unroll
        for (int m = 0; m < 4; m++) {
            int n = nb + tr4 + m;
            if (n < N) {
                ushort4 uv;
                uv.x = f2bf(acc[m][0] + b0); uv.y = f2bf(acc[m][1] + b1);
                uv.z = f2bf(acc[m][2] + b2); uv.w = f2bf(acc[m][3] + b3);
                *(ushort4*)(base + (size_t)(noff + n) * HID + tcj) = uv;
            }
        }
    }
}

// ---------------- fused attention: one wave per dst node, online softmax ----------------
__global__ __launch_bounds__(256) void attn_kernel(
    const float* Q, const unsigned short* __restrict__ Ksb,
    const unsigned short* __restrict__ Vsb,
    const float* __restrict__ p_rel, const int* __restrict__ row_ptr,
    const int* __restrict__ edge_src, float* attnout)
{
    int wid = threadIdx.x >> 6, lane = threadIdx.x & 63;
    int n = blockIdx.x * 4 + wid;
    if (n >= NTOT) return;
    int h = lane >> 4;
    float q = Q[(size_t)n * HID + lane];
    float pr0 = p_rel[h], pr1 = p_rel[4 + h], pr2 = p_rel[8 + h];
    int beg = row_ptr[n], end = row_ptr[n + 1];
    float m = -INFINITY, s = 0.0f, acc = 0.0f;
    int e = beg;
    for (; e + 1 < end; e += 2) {
        int s0 = edge_src[e], s1 = edge_src[e + 1];
        size_t r0 = (size_t)s0 * HID + lane, r1 = (size_t)s1 * HID + lane;
        float k0 = bf2f(Ksb[r0]), v0 = bf2f(Vsb[r0]);
        float k1 = bf2f(Ksb[r1]), v1 = bf2f(Vsb[r1]);
        float p0 = q * k0, p1 = q * k1;
        p0 += __shfl_xor(p0, 1, 64);  p1 += __shfl_xor(p1, 1, 64);
        p0 += __shfl_xor(p0, 2, 64);  p1 += __shfl_xor(p1, 2, 64);
        p0 += __shfl_xor(p0, 4, 64);  p1 += __shfl_xor(p1, 4, 64);
        p0 += __shfl_xor(p0, 8, 64);  p1 += __shfl_xor(p1, 8, 64);
        float a0 = p0 * ((s0 < NA) ? pr0 : ((s0 < NA + NP) ? pr1 : pr2)) * 0.25f;
        float a1 = p1 * ((s1 < NA) ? pr0 : ((s1 < NA + NP) ? pr1 : pr2)) * 0.25f;
        float mn = fmaxf(m, fmaxf(a0, a1));
        float cc = expf(m - mn);
        float e0 = expf(a0 - mn), e1 = expf(a1 - mn);
        s   = s * cc + e0 + e1;
        acc = acc * cc + e0 * v0 + e1 * v1;
        m = mn;
    }
    if (e < end) {
        int s0 = edge_src[e];
        size_t r0 = (size_t)s0 * HID + lane;
        float k0 = bf2f(Ksb[r0]), v0 = bf2f(Vsb[r0]);
        float p0 = q * k0;
        p0 += __shfl_xor(p0, 1, 64);
        p0 += __shfl_xor(p0, 2, 64);
        p0 += __shfl_xor(p0, 4, 64);
        p0 += __shfl_xor(p0, 8, 64);
        float a0 = p0 * ((s0 < NA) ? pr0 : ((s0 < NA + NP) ? pr1 : pr2)) * 0.25f;
        float mn = fmaxf(m, a0);
        float cc = expf(m - mn);
        float e0 = expf(a0 - mn);
        s   = s * cc + e0;
        acc = acc * cc + e0 * v0;
    }
    attnout[(size_t)n * HID + lane] = acc / (s + 1e-16f);
}

// ---------------- hout GEMM + skip + LN + gelu fused, paper+author merged ----------------
__global__ __launch_bounds__(256) void gemm_hout(
    const float* __restrict__ attnout, const float* __restrict__ Whout,
    const float* __restrict__ bhout, const float* __restrict__ skip_p,
    const float* __restrict__ lng, const float* __restrict__ lnb,
    float* __restrict__ hbuf)
{
    __shared__ float xs[64][68];
    __shared__ float wsb[64][68];
    int b = blockIdx.x, tid = threadIdx.x;
    int type = (b >= PT);
    int tile = type ? (b - PT) : b;
    int N = type ? NA : NP;
    size_t base_off = type ? (size_t)NP * HID : 0;
    const float* X = attnout + base_off;
    const float* W = Whout + (size_t)type * HID * HID;
    const float* bias = bhout + type * HID;
    float* H = hbuf + base_off;
    int nb = tile * 64;

    #pragma unroll
    for (int r = 0; r < 4; r++) {
        int f = tid + 256 * r;
        int row = f >> 4, col = (f & 15) * 4;
        int n = nb + row;
        float4 v = (n < N) ? *(const float4*)(X + (size_t)n * HID + col)
                           : make_float4(0.f, 0.f, 0.f, 0.f);
        v.x = gelu_exact(v.x); v.y = gelu_exact(v.y);
        v.z = gelu_exact(v.z); v.w = gelu_exact(v.w);
        *(float4*)&xs[row][col] = v;
        *(float4*)&wsb[row][col] = *(const float4*)(W + (size_t)row * HID + col);
    }
    __syncthreads();
    const int tr = tid >> 4, tc = tid & 15;
    const int tr4 = tr * 4, tcj = tc * 4;
    float acc[4][4] = {};
    GEMM_CORE_64(acc, xs, wsb, 0)

    float b0 = bias[tcj], b1 = bias[tcj+1], b2 = bias[tcj+2], b3 = bias[tcj+3];
    float a = 1.0f / (1.0f + expf(-skip_p[type]));
    float oma = 1.0f - a;
    float g0 = lng[type*HID+tcj], g1 = lng[type*HID+tcj+1],
          g2 = lng[type*HID+tcj+2], g3 = lng[type*HID+tcj+3];
    float l0 = lnb[type*HID+tcj], l1 = lnb[type*HID+tcj+1],
          l2 = lnb[type*HID+tcj+2], l3 = lnb[type*HID+tcj+3];
    #pragma unroll
    for (int m = 0; m < 4; m++) {
        int n = nb + tr4 + m;
        float v0 = 0.f, v1 = 0.f, v2 = 0.f, v3 = 0.f;
        if (n < N) {
            const float* hp = H + (size_t)n * HID + tcj;
            v0 = a * (acc[m][0] + b0) + oma * hp[0];
            v1 = a * (acc[m][1] + b1) + oma * hp[1];
            v2 = a * (acc[m][2] + b2) + oma * hp[2];
            v3 = a * (acc[m][3] + b3) + oma * hp[3];
        }
        // layernorm across the row (16 lanes x 4 vals)
        float sum = v0 + v1 + v2 + v3;
        sum += __shfl_xor(sum, 1, 64); sum += __shfl_xor(sum, 2, 64);
        sum += __shfl_xor(sum, 4, 64); sum += __shfl_xor(sum, 8, 64);
        float mean = sum * (1.0f / 64.0f);
        float d0 = v0 - mean, d1 = v1 - mean, d2 = v2 - mean, d3 = v3 - mean;
        float sq = d0*d0 + d1*d1 + d2*d2 + d3*d3;
        sq += __shfl_xor(sq, 1, 64); sq += __shfl_xor(sq, 2, 64);
        sq += __shfl_xor(sq, 4, 64); sq += __shfl_xor(sq, 8, 64);
        float rstd = rsqrtf(sq * (1.0f / 64.0f) + 1e-5f);
        if (n < N) {
            float* hp = H + (size_t)n * HID + tcj;
            hp[0] = gelu_exact(d0 * rstd * g0 + l0);
            hp[1] = gelu_exact(d1 * rstd * g1 + l1);
            hp[2] = gelu_exact(d2 * rstd * g2 + l2);
            hp[3] = gelu_exact(d3 * rstd * g3 + l3);
        }
    }
}

// ---------------- final linear, paper+author merged ----------------
__global__ __launch_bounds__(256) void gemm_out(
    const float* __restrict__ hbuf, const float* __restrict__ W_out,
    const float* __restrict__ b_out, float* __restrict__ out)
{
    __shared__ float xs[64][68];
    __shared__ float wsb[64][68];
    int b = blockIdx.x, tid = threadIdx.x;
    int type = (b >= PT);
    int tile = type ? (b - PT) : b;
    int N = type ? NA : NP;
    size_t base_off = type ? (size_t)NP * HID : 0;
    const float* X = hbuf + base_off;
    const float* W = W_out + (size_t)type * HID * HID;
    const float* bias = b_out + type * HID;
    float* O = out + base_off;
    int nb = tile * 64;

    #pragma unroll
    for (int r = 0; r < 4; r++) {
        int f = tid + 256 * r;
        int row = f >> 4, col = (f & 15) * 4;
        int n = nb + row;
        float4 v = (n < N) ? *(const float4*)(X + (size_t)n * HID + col)
                           : make_float4(0.f, 0.f, 0.f, 0.f);
        *(float4*)&xs[row][col] = v;
        *(float4*)&wsb[row][col] = *(const float4*)(W + (size_t)row * HID + col);
    }
    __syncthreads();
    const int tr = tid >> 4, tc = tid & 15;
    const int tr4 = tr * 4, tcj = tc * 4;
    float acc[4][4] = {};
    GEMM_CORE_64(acc, xs, wsb, 0)

    float b0 = bias[tcj], b1 = bias[tcj+1], b2 = bias[tcj+2], b3 = bias[tcj+3];
    #pragma unroll
    for (int m = 0; m < 4; m++) {
        int n = nb + tr4 + m;
        if (n < N) {
            float* p = O + (size_t)n * HID + tcj;
            p[0] = acc[m][0] + b0; p[1] = acc[m][1] + b1;
            p[2] = acc[m][2] + b2; p[3] = acc[m][3] + b3;
        }
    }
}

extern "C" void kernel_launch(void* const* d_in, const int* in_sizes, int n_in,
                              void* d_out, int out_size, void* d_ws, size_t ws_size,
                              hipStream_t stream) {
    const float* x_paper  = (const float*)d_in[0];
    const float* x_author = (const float*)d_in[1];
    const int*   ei_ap    = (const int*)d_in[2];
    const int*   ei_pa    = (const int*)d_in[3];
    const int*   ei_pp    = (const int*)d_in[4];
    const float* W_in     = (const float*)d_in[5];
    const float* b_in     = (const float*)d_in[6];
    const float* W_kqv    = (const float*)d_in[7];
    const float* b_kqv    = (const float*)d_in[8];
    const float* W_krel   = (const float*)d_in[9];
    const float* W_vrel   = (const float*)d_in[10];
    const float* p_rel    = (const float*)d_in[11];
    const float* W_hout   = (const float*)d_in[12];
    const float* b_hout   = (const float*)d_in[13];
    const float* skip     = (const float*)d_in[14];
    const float* ln_g     = (const float*)d_in[15];
    const float* ln_b     = (const float*)d_in[16];
    const float* W_out    = (const float*)d_in[17];
    const float* b_out    = (const float*)d_in[18];
    float* out            = (float*)d_out;

    // ---- workspace layout (~146 MB) ----
    float* ws   = (float*)d_ws;
    float* hbuf = ws;                                   // NTOT*64 f32
    float* Q    = hbuf + (size_t)NTOT * HID;            // NTOT*64 f32 (attn out aliases Q)
    unsigned short* Ksb = (unsigned short*)(Q + (size_t)NTOT * HID);  // NSRC*64 bf16
    unsigned short* Vsb = Ksb + (size_t)NSRC * HID;                   // NSRC*64 bf16
    float* Wfp  = (float*)(Vsb + (size_t)NSRC * HID);   // 64*320
    float* bfp  = Wfp  + 64 * JP;                       // 320
    float* Wfa  = bfp  + JP;                            // 64*192
    float* bfa  = Wfa  + 64 * JA;                       // 192
    int* cnt      = (int*)(bfa + JA);                   // NTOT
    int* row_ptr  = cnt + NTOT;                         // NTOT+1 (pad 16)
    int* cursor   = row_ptr + NTOT + 16;                // NTOT
    int* edge_src = cursor + NTOT;                      // ETOT
    int* csum     = edge_src + ETOT;                    // 1024
    int* coff     = csum + 1024;                        // 1024

    dim3 blk(256);
    const int EB = (ETOT + 255) / 256;

    // ---- CSR build (edges are layer-invariant) ----
    zero_int_kernel<<<256, blk, 0, stream>>>(cnt, NTOT);
    csr_count_kernel<<<EB, blk, 0, stream>>>(ei_ap, ei_pa, ei_pp, cnt);
    scan_chunk_sums<<<NCH, blk, 0, stream>>>(cnt, csum);
    scan_offsets<<<1, 1024, 0, stream>>>(csum, coff, NCH);
    scan_final<<<NCH, blk, 0, stream>>>(cnt, coff, row_ptr, cursor);
    csr_fill_kernel<<<EB, blk, 0, stream>>>(ei_ap, ei_pa, ei_pp, cursor, edge_src);

    // ---- input projection ----
    gemm_in<<<PT + AT, blk, 0, stream>>>(x_paper, x_author, W_in, b_in, hbuf);

    for (int l = 0; l < LAYERS; l++) {
        fuse_weights_kernel<<<(65 * JP + 65 * JA + 255) / 256, blk, 0, stream>>>(
            W_kqv + (size_t)l * 2 * HID * KQV, b_kqv + (size_t)l * 2 * KQV,
            W_krel + (size_t)l * 3 * NH * HD * HD, W_vrel + (size_t)l * 3 * NH * HD * HD,
            Wfp, bfp, Wfa, bfa);
        gemm_kqv<<<PT * 5 + AT * 3, blk, 0, stream>>>(
            hbuf, Wfp, bfp, Wfa, bfa, Q, Ksb, Vsb);
        attn_kernel<<<(NTOT + 3) / 4, blk, 0, stream>>>(
            Q, Ksb, Vsb, p_rel + l * 3 * NH, row_ptr, edge_src, Q);
        gemm_hout<<<PT + AT, blk, 0, stream>>>(
            Q, W_hout + (size_t)l * 2 * HID * HID, b_hout + l * 2 * HID,
            skip + l * 2, ln_g + l * 2 * HID, ln_b + l * 2 * HID, hbuf);
    }

    gemm_out<<<PT + AT, blk, 0, stream>>>(hbuf, W_out, b_out, out);
}

// Round 5
// 934.111 us; speedup vs baseline: 2.0058x; 2.0058x over previous
//
#include <hip/hip_runtime.h>
#include <hip/hip_bf16.h>

// ---- problem constants (match reference) ----
#define NP 100000
#define NA 50000
#define NTOT 150000          // NP+NA
#define E0 300000
#define E1 300000
#define E2 200000
#define ETOT 800000
#define NH 4
#define HD 16
#define HID 64
#define IN_DIM 128
#define KQV 192
#define LAYERS 2
#define NSRC 250000          // NA + 2*NP
#define JP 320               // fused paper cols: q | k_et1 | k_et2 | v_et1 | v_et2
#define JA 192               // fused author cols: q | k_et0 | v_et0
#define NCH 586              // ceil(NTOT/256)
#define PT 1563              // ceil(NP/64)
#define AT 782               // ceil(NA/64)

__device__ __forceinline__ float gelu_exact(float x) {
    return 0.5f * x * (1.0f + erff(x * 0.7071067811865475f));
}
// f32 -> bf16 bits, round-to-nearest-even (finite values)
__device__ __forceinline__ unsigned short f2bf(float f) {
    unsigned u = __float_as_uint(f);
    return (unsigned short)((u + 0x7fffu + ((u >> 16) & 1u)) >> 16);
}
__device__ __forceinline__ float bf2f(unsigned short b) {
    return __uint_as_float((unsigned)b << 16);
}

// decode global edge id -> (src in Ks/Vs space, dst in node space)
__device__ __forceinline__ void edge_decode(int e, const int* __restrict__ ei_ap,
                                            const int* __restrict__ ei_pa,
                                            const int* __restrict__ ei_pp,
                                            int& src, int& dst) {
    if (e < E0)            { src = ei_ap[e];                 dst = ei_ap[E0 + e]; }
    else if (e < E0 + E1)  { int le = e - E0;
                             src = NA + ei_pa[le];           dst = NP + ei_pa[E1 + le]; }
    else                   { int le = e - E0 - E1;
                             src = NA + NP + ei_pp[le];      dst = ei_pp[E2 + le]; }
}

// ---------------- CSR build ----------------
__global__ void zero_int_kernel(int* __restrict__ p, int n) {
    int i = blockIdx.x * blockDim.x + threadIdx.x;
    int st = gridDim.x * blockDim.x;
    for (int j = i; j < n; j += st) p[j] = 0;
}

__global__ void csr_count_kernel(const int* __restrict__ ei_ap, const int* __restrict__ ei_pa,
                                 const int* __restrict__ ei_pp, int* __restrict__ cnt) {
    int e = blockIdx.x * 256 + threadIdx.x;
    if (e >= ETOT) return;
    int src, dst; edge_decode(e, ei_ap, ei_pa, ei_pp, src, dst);
    atomicAdd(&cnt[dst], 1);
}

__global__ void scan_chunk_sums(const int* __restrict__ cnt, int* __restrict__ csum) {
    __shared__ int sd[256];
    int c = blockIdx.x, t = threadIdx.x;
    int i = c * 256 + t;
    sd[t] = (i < NTOT) ? cnt[i] : 0;
    __syncthreads();
    for (int o = 128; o > 0; o >>= 1) { if (t < o) sd[t] += sd[t + o]; __syncthreads(); }
    if (t == 0) csum[c] = sd[0];
}

__global__ void scan_offsets(const int* __restrict__ csum, int* __restrict__ coff, int nch) {
    __shared__ int sd[1024];
    int t = threadIdx.x;
    int v = (t < nch) ? csum[t] : 0;
    sd[t] = v;
    __syncthreads();
    for (int o = 1; o < 1024; o <<= 1) {
        int x = (t >= o) ? sd[t - o] : 0;
        __syncthreads();
        sd[t] += x;
        __syncthreads();
    }
    if (t < nch) coff[t] = sd[t] - v;   // exclusive
}

__global__ void scan_final(const int* __restrict__ cnt, const int* __restrict__ coff,
                           int* __restrict__ row_ptr, int* __restrict__ cursor) {
    __shared__ int sd[256];
    int c = blockIdx.x, t = threadIdx.x, i = c * 256 + t;
    int v = (i < NTOT) ? cnt[i] : 0;
    sd[t] = v;
    __syncthreads();
    for (int o = 1; o < 256; o <<= 1) {
        int x = (t >= o) ? sd[t - o] : 0;
        __syncthreads();
        sd[t] += x;
        __syncthreads();
    }
    if (i < NTOT) { int ex = coff[c] + sd[t] - v; row_ptr[i] = ex; cursor[i] = ex; }
    if (i == 0) row_ptr[NTOT] = ETOT;
}

__global__ void csr_fill_kernel(const int* __restrict__ ei_ap, const int* __restrict__ ei_pa,
                                const int* __restrict__ ei_pp, int* __restrict__ cursor,
                                int* __restrict__ edge_src) {
    int e = blockIdx.x * 256 + threadIdx.x;
    if (e >= ETOT) return;
    int src, dst; edge_decode(e, ei_ap, ei_pa, ei_pp, src, dst);
    int pos = atomicAdd(&cursor[dst], 1);
    edge_src[pos] = src;
}

// ---------------- fused-weight build (per layer) ----------------
__global__ void fuse_weights_kernel(const float* __restrict__ Wkqv, const float* __restrict__ bkqv,
                                    const float* __restrict__ Wkrel, const float* __restrict__ Wvrel,
                                    float* __restrict__ Wfp, float* __restrict__ bfp,
                                    float* __restrict__ Wfa, float* __restrict__ bfa) {
    int idx = blockIdx.x * 256 + threadIdx.x;
    int type, i, j;
    if (idx < 65 * JP) { type = 0; i = idx / JP; j = idx % JP; }
    else {
        int r = idx - 65 * JP;
        if (r >= 65 * JA) return;
        type = 1; i = r / JA; j = r % JA;
    }
    int c = j >> 6, jj = j & 63, h = jj >> 4, e = jj & 15;
    const float* Wk = Wkqv + (size_t)type * HID * KQV;
    const float* bk = bkqv + type * KQV;
    float val;
    if (c == 0) {
        val = (i < 64) ? Wk[i * KQV + 64 + jj] : bk[64 + jj];
    } else {
        int et, isV;
        if (type == 0) { et = (c == 1 || c == 3) ? 1 : 2; isV = (c >= 3); }
        else           { et = 0; isV = (c == 2); }
        const float* Wr = (isV ? Wvrel : Wkrel) + (size_t)(et * NH + h) * HD * HD;
        int sb = (isV ? 128 : 0) + h * HD;
        val = 0.0f;
        #pragma unroll
        for (int d = 0; d < HD; d++) {
            float a = (i < 64) ? Wk[i * KQV + sb + d] : bk[sb + d];
            val += a * Wr[d * HD + e];
        }
    }
    if (i < 64) (type ? Wfa : Wfp)[i * (type ? JA : JP) + j] = val;
    else        (type ? bfa : bfp)[j] = val;
}

// ---------------- shared GEMM core pieces ----------------
#define GEMM_CORE_64(ACCVAR, XS, WS, KOFF)                                         \
    {                                                                              \
        _Pragma("unroll")                                                          \
        for (int i = 0; i < 64; i += 4) {                                          \
            float4 A0 = *(const float4*)&XS[tr4 + 0][KOFF + i];                    \
            float4 A1 = *(const float4*)&XS[tr4 + 1][KOFF + i];                    \
            float4 A2 = *(const float4*)&XS[tr4 + 2][KOFF + i];                    \
            float4 A3 = *(const float4*)&XS[tr4 + 3][KOFF + i];                    \
            float4 W0 = *(const float4*)&WS[i + 0][tcj];                           \
            float4 W1 = *(const float4*)&WS[i + 1][tcj];                           \
            float4 W2 = *(const float4*)&WS[i + 2][tcj];                           \
            float4 W3 = *(const float4*)&WS[i + 3][tcj];                           \
            ACCVAR[0][0] += A0.x*W0.x + A0.y*W1.x + A0.z*W2.x + A0.w*W3.x;         \
            ACCVAR[0][1] += A0.x*W0.y + A0.y*W1.y + A0.z*W2.y + A0.w*W3.y;         \
            ACCVAR[0][2] += A0.x*W0.z + A0.y*W1.z + A0.z*W2.z + A0.w*W3.z;         \
            ACCVAR[0][3] += A0.x*W0.w + A0.y*W1.w + A0.z*W2.w + A0.w*W3.w;         \
            ACCVAR[1][0] += A1.x*W0.x + A1.y*W1.x + A1.z*W2.x + A1.w*W3.x;         \
            ACCVAR[1][1] += A1.x*W0.y + A1.y*W1.y + A1.z*W2.y + A1.w*W3.y;         \
            ACCVAR[1][2] += A1.x*W0.z + A1.y*W1.z + A1.z*W2.z + A1.w*W3.z;         \
            ACCVAR[1][3] += A1.x*W0.w + A1.y*W1.w + A1.z*W2.w + A1.w*W3.w;         \
            ACCVAR[2][0] += A2.x*W0.x + A2.y*W1.x + A2.z*W2.x + A2.w*W3.x;         \
            ACCVAR[2][1] += A2.x*W0.y + A2.y*W1.y + A2.z*W2.y + A2.w*W3.y;         \
            ACCVAR[2][2] += A2.x*W0.z + A2.y*W1.z + A2.z*W2.z + A2.w*W3.z;         \
            ACCVAR[2][3] += A2.x*W0.w + A2.y*W1.w + A2.z*W2.w + A2.w*W3.w;         \
            ACCVAR[3][0] += A3.x*W0.x + A3.y*W1.x + A3.z*W2.x + A3.w*W3.x;         \
            ACCVAR[3][1] += A3.x*W0.y + A3.y*W1.y + A3.z*W2.y + A3.w*W3.y;         \
            ACCVAR[3][2] += A3.x*W0.z + A3.y*W1.z + A3.z*W2.z + A3.w*W3.z;         \
            ACCVAR[3][3] += A3.x*W0.w + A3.y*W1.w + A3.z*W2.w + A3.w*W3.w;         \
        }                                                                          \
    }

// ---------------- input projection (K=128), paper+author merged ----------------
// K staged in 64-col chunks; #pragma unroll 1 on the ks loop keeps VGPR ~140
// (full unroll here spilled at 256 VGPR -> 3 GB scratch traffic in R4).
__global__ __launch_bounds__(256) void gemm_in(
    const float* __restrict__ xp, const float* __restrict__ xa,
    const float* __restrict__ W_in, const float* __restrict__ b_in,
    float* __restrict__ hbuf)
{
    __shared__ float xs[64][68];
    __shared__ float wsb[64][68];
    int b = blockIdx.x, tid = threadIdx.x;
    int type = (b >= PT);
    int tile = type ? (b - PT) : b;
    int N = type ? NA : NP;
    const float* X = type ? xa : xp;
    const float* W = W_in + (size_t)type * IN_DIM * HID;
    const float* bias = b_in + type * HID;
    float* H = hbuf + (type ? (size_t)NP * HID : 0);
    int nb = tile * 64;

    const int tr = tid >> 4, tc = tid & 15;
    const int tr4 = tr * 4, tcj = tc * 4;
    float acc[4][4] = {};

    #pragma unroll 1
    for (int ks = 0; ks < IN_DIM; ks += 64) {
        __syncthreads();
        #pragma unroll
        for (int r = 0; r < 4; r++) {
            int f = tid + 256 * r;
            int row = f >> 4, col = (f & 15) * 4;
            int n = nb + row;
            float4 v = (n < N) ? *(const float4*)(X + (size_t)n * IN_DIM + ks + col)
                               : make_float4(0.f, 0.f, 0.f, 0.f);
            *(float4*)&xs[row][col] = v;
            *(float4*)&wsb[row][col] = *(const float4*)(W + (size_t)(ks + row) * HID + col);
        }
        __syncthreads();
        GEMM_CORE_64(acc, xs, wsb, 0)
    }
    float b0 = bias[tcj], b1 = bias[tcj+1], b2 = bias[tcj+2], b3 = bias[tcj+3];
    #pragma unroll
    for (int m = 0; m < 4; m++) {
        int n = nb + tr4 + m;
        if (n < N) {
            float* p = H + (size_t)n * HID + tcj;
            p[0] = acc[m][0] + b0; p[1] = acc[m][1] + b1;
            p[2] = acc[m][2] + b2; p[3] = acc[m][3] + b3;
        }
    }
}

// ---------------- KQV GEMM: one (row-tile, chunk) per block ----------------
// paper chunks: 0->Q f32 | 1->Ks@NA | 2->Ks@NA+NP | 3->Vs@NA | 4->Vs@NA+NP (bf16)
// author chunks: 0->Q@NP | 1->Ks@0 | 2->Vs@0
__global__ __launch_bounds__(256) void gemm_kqv(
    const float* __restrict__ hbuf,
    const float* __restrict__ Wfp, const float* __restrict__ bfp,
    const float* __restrict__ Wfa, const float* __restrict__ bfa,
    float* __restrict__ Q, unsigned short* __restrict__ Ksb, unsigned short* __restrict__ Vsb)
{
    __shared__ float xs[64][68];
    __shared__ float wsb[64][68];
    int b = blockIdx.x, tid = threadIdx.x;
    int type, tile, chunk;
    if (b < PT * 5) { type = 0; chunk = b / PT; tile = b % PT; }
    else            { int ab = b - PT * 5; type = 1; chunk = ab / AT; tile = ab % AT; }
    int N = type ? NA : NP;
    const float* X = hbuf + (type ? (size_t)NP * HID : 0);
    const float* W = type ? Wfa : Wfp;
    const float* bias = type ? bfa : bfp;
    int ldw = type ? JA : JP;
    int nb = tile * 64;

    #pragma unroll
    for (int r = 0; r < 4; r++) {
        int f = tid + 256 * r;
        int row = f >> 4, col = (f & 15) * 4;
        int n = nb + row;
        float4 v = (n < N) ? *(const float4*)(X + (size_t)n * HID + col)
                           : make_float4(0.f, 0.f, 0.f, 0.f);
        *(float4*)&xs[row][col] = v;
        *(float4*)&wsb[row][col] = *(const float4*)(W + (size_t)row * ldw + chunk * 64 + col);
    }
    __syncthreads();
    const int tr = tid >> 4, tc = tid & 15;
    const int tr4 = tr * 4, tcj = tc * 4;
    float acc[4][4] = {};
    GEMM_CORE_64(acc, xs, wsb, 0)

    const float* bp = bias + chunk * 64 + tcj;
    float b0 = bp[0], b1 = bp[1], b2 = bp[2], b3 = bp[3];
    // destination select
    if (chunk == 0) {
        int noff = type ? NP : 0;
        #pragma unroll
        for (int m = 0; m < 4; m++) {
            int n = nb + tr4 + m;
            if (n < N) {
                float* p = Q + (size_t)(noff + n) * HID + tcj;
                p[0] = acc[m][0] + b0; p[1] = acc[m][1] + b1;
                p[2] = acc[m][2] + b2; p[3] = acc[m][3] + b3;
            }
        }
    } else {
        unsigned short* base; int noff;
        if (type == 0) {
            base = (chunk <= 2) ? Ksb : Vsb;
            noff = ((chunk == 1 || chunk == 3) ? NA : NA + NP);
        } else {
            base = (chunk == 1) ? Ksb : Vsb;
            noff = 0;
        }
        #pragma unroll
        for (int m = 0; m < 4; m++) {
            int n = nb + tr4 + m;
            if (n < N) {
                ushort4 uv;
                uv.x = f2bf(acc[m][0] + b0); uv.y = f2bf(acc[m][1] + b1);
                uv.z = f2bf(acc[m][2] + b2); uv.w = f2bf(acc[m][3] + b3);
                *(ushort4*)(base + (size_t)(noff + n) * HID + tcj) = uv;
            }
        }
    }
}

// ---------------- fused attention: one wave per dst node, online softmax ----------------
__global__ __launch_bounds__(256) void attn_kernel(
    const float* Q, const unsigned short* __restrict__ Ksb,
    const unsigned short* __restrict__ Vsb,
    const float* __restrict__ p_rel, const int* __restrict__ row_ptr,
    const int* __restrict__ edge_src, float* attnout)
{
    int wid = threadIdx.x >> 6, lane = threadIdx.x & 63;
    int n = blockIdx.x * 4 + wid;
    if (n >= NTOT) return;
    int h = lane >> 4;
    float q = Q[(size_t)n * HID + lane];
    float pr0 = p_rel[h], pr1 = p_rel[4 + h], pr2 = p_rel[8 + h];
    int beg = row_ptr[n], end = row_ptr[n + 1];
    float m = -INFINITY, s = 0.0f, acc = 0.0f;
    int e = beg;
    for (; e + 1 < end; e += 2) {
        int s0 = edge_src[e], s1 = edge_src[e + 1];
        size_t r0 = (size_t)s0 * HID + lane, r1 = (size_t)s1 * HID + lane;
        float k0 = bf2f(Ksb[r0]), v0 = bf2f(Vsb[r0]);
        float k1 = bf2f(Ksb[r1]), v1 = bf2f(Vsb[r1]);
        float p0 = q * k0, p1 = q * k1;
        p0 += __shfl_xor(p0, 1, 64);  p1 += __shfl_xor(p1, 1, 64);
        p0 += __shfl_xor(p0, 2, 64);  p1 += __shfl_xor(p1, 2, 64);
        p0 += __shfl_xor(p0, 4, 64);  p1 += __shfl_xor(p1, 4, 64);
        p0 += __shfl_xor(p0, 8, 64);  p1 += __shfl_xor(p1, 8, 64);
        float a0 = p0 * ((s0 < NA) ? pr0 : ((s0 < NA + NP) ? pr1 : pr2)) * 0.25f;
        float a1 = p1 * ((s1 < NA) ? pr0 : ((s1 < NA + NP) ? pr1 : pr2)) * 0.25f;
        float mn = fmaxf(m, fmaxf(a0, a1));
        float cc = expf(m - mn);
        float e0 = expf(a0 - mn), e1 = expf(a1 - mn);
        s   = s * cc + e0 + e1;
        acc = acc * cc + e0 * v0 + e1 * v1;
        m = mn;
    }
    if (e < end) {
        int s0 = edge_src[e];
        size_t r0 = (size_t)s0 * HID + lane;
        float k0 = bf2f(Ksb[r0]), v0 = bf2f(Vsb[r0]);
        float p0 = q * k0;
        p0 += __shfl_xor(p0, 1, 64);
        p0 += __shfl_xor(p0, 2, 64);
        p0 += __shfl_xor(p0, 4, 64);
        p0 += __shfl_xor(p0, 8, 64);
        float a0 = p0 * ((s0 < NA) ? pr0 : ((s0 < NA + NP) ? pr1 : pr2)) * 0.25f;
        float mn = fmaxf(m, a0);
        float cc = expf(m - mn);
        float e0 = expf(a0 - mn);
        s   = s * cc + e0;
        acc = acc * cc + e0 * v0;
    }
    attnout[(size_t)n * HID + lane] = acc / (s + 1e-16f);
}

// ---------------- hout GEMM + skip + LN + gelu fused, paper+author merged ----------------
__global__ __launch_bounds__(256) void gemm_hout(
    const float* __restrict__ attnout, const float* __restrict__ Whout,
    const float* __restrict__ bhout, const float* __restrict__ skip_p,
    const float* __restrict__ lng, const float* __restrict__ lnb,
    float* __restrict__ hbuf)
{
    __shared__ float xs[64][68];
    __shared__ float wsb[64][68];
    int b = blockIdx.x, tid = threadIdx.x;
    int type = (b >= PT);
    int tile = type ? (b - PT) : b;
    int N = type ? NA : NP;
    size_t base_off = type ? (size_t)NP * HID : 0;
    const float* X = attnout + base_off;
    const float* W = Whout + (size_t)type * HID * HID;
    const float* bias = bhout + type * HID;
    float* H = hbuf + base_off;
    int nb = tile * 64;

    #pragma unroll
    for (int r = 0; r < 4; r++) {
        int f = tid + 256 * r;
        int row = f >> 4, col = (f & 15) * 4;
        int n = nb + row;
        float4 v = (n < N) ? *(const float4*)(X + (size_t)n * HID + col)
                           : make_float4(0.f, 0.f, 0.f, 0.f);
        v.x = gelu_exact(v.x); v.y = gelu_exact(v.y);
        v.z = gelu_exact(v.z); v.w = gelu_exact(v.w);
        *(float4*)&xs[row][col] = v;
        *(float4*)&wsb[row][col] = *(const float4*)(W + (size_t)row * HID + col);
    }
    __syncthreads();
    const int tr = tid >> 4, tc = tid & 15;
    const int tr4 = tr * 4, tcj = tc * 4;
    float acc[4][4] = {};
    GEMM_CORE_64(acc, xs, wsb, 0)

    float b0 = bias[tcj], b1 = bias[tcj+1], b2 = bias[tcj+2], b3 = bias[tcj+3];
    float a = 1.0f / (1.0f + expf(-skip_p[type]));
    float oma = 1.0f - a;
    float g0 = lng[type*HID+tcj], g1 = lng[type*HID+tcj+1],
          g2 = lng[type*HID+tcj+2], g3 = lng[type*HID+tcj+3];
    float l0 = lnb[type*HID+tcj], l1 = lnb[type*HID+tcj+1],
          l2 = lnb[type*HID+tcj+2], l3 = lnb[type*HID+tcj+3];
    #pragma unroll
    for (int m = 0; m < 4; m++) {
        int n = nb + tr4 + m;
        float v0 = 0.f, v1 = 0.f, v2 = 0.f, v3 = 0.f;
        if (n < N) {
            const float* hp = H + (size_t)n * HID + tcj;
            v0 = a * (acc[m][0] + b0) + oma * hp[0];
            v1 = a * (acc[m][1] + b1) + oma * hp[1];
            v2 = a * (acc[m][2] + b2) + oma * hp[2];
            v3 = a * (acc[m][3] + b3) + oma * hp[3];
        }
        // layernorm across the row (16 lanes x 4 vals)
        float sum = v0 + v1 + v2 + v3;
        sum += __shfl_xor(sum, 1, 64); sum += __shfl_xor(sum, 2, 64);
        sum += __shfl_xor(sum, 4, 64); sum += __shfl_xor(sum, 8, 64);
        float mean = sum * (1.0f / 64.0f);
        float d0 = v0 - mean, d1 = v1 - mean, d2 = v2 - mean, d3 = v3 - mean;
        float sq = d0*d0 + d1*d1 + d2*d2 + d3*d3;
        sq += __shfl_xor(sq, 1, 64); sq += __shfl_xor(sq, 2, 64);
        sq += __shfl_xor(sq, 4, 64); sq += __shfl_xor(sq, 8, 64);
        float rstd = rsqrtf(sq * (1.0f / 64.0f) + 1e-5f);
        if (n < N) {
            float* hp = H + (size_t)n * HID + tcj;
            hp[0] = gelu_exact(d0 * rstd * g0 + l0);
            hp[1] = gelu_exact(d1 * rstd * g1 + l1);
            hp[2] = gelu_exact(d2 * rstd * g2 + l2);
            hp[3] = gelu_exact(d3 * rstd * g3 + l3);
        }
    }
}

// ---------------- final linear, paper+author merged ----------------
__global__ __launch_bounds__(256) void gemm_out(
    const float* __restrict__ hbuf, const float* __restrict__ W_out,
    const float* __restrict__ b_out, float* __restrict__ out)
{
    __shared__ float xs[64][68];
    __shared__ float wsb[64][68];
    int b = blockIdx.x, tid = threadIdx.x;
    int type = (b >= PT);
    int tile = type ? (b - PT) : b;
    int N = type ? NA : NP;
    size_t base_off = type ? (size_t)NP * HID : 0;
    const float* X = hbuf + base_off;
    const float* W = W_out + (size_t)type * HID * HID;
    const float* bias = b_out + type * HID;
    float* O = out + base_off;
    int nb = tile * 64;

    #pragma unroll
    for (int r = 0; r < 4; r++) {
        int f = tid + 256 * r;
        int row = f >> 4, col = (f & 15) * 4;
        int n = nb + row;
        float4 v = (n < N) ? *(const float4*)(X + (size_t)n * HID + col)
                           : make_float4(0.f, 0.f, 0.f, 0.f);
        *(float4*)&xs[row][col] = v;
        *(float4*)&wsb[row][col] = *(const float4*)(W + (size_t)row * HID + col);
    }
    __syncthreads();
    const int tr = tid >> 4, tc = tid & 15;
    const int tr4 = tr * 4, tcj = tc * 4;
    float acc[4][4] = {};
    GEMM_CORE_64(acc, xs, wsb, 0)

    float b0 = bias[tcj], b1 = bias[tcj+1], b2 = bias[tcj+2], b3 = bias[tcj+3];
    #pragma unroll
    for (int m = 0; m < 4; m++) {
        int n = nb + tr4 + m;
        if (n < N) {
            float* p = O + (size_t)n * HID + tcj;
            p[0] = acc[m][0] + b0; p[1] = acc[m][1] + b1;
            p[2] = acc[m][2] + b2; p[3] = acc[m][3] + b3;
        }
    }
}

extern "C" void kernel_launch(void* const* d_in, const int* in_sizes, int n_in,
                              void* d_out, int out_size, void* d_ws, size_t ws_size,
                              hipStream_t stream) {
    const float* x_paper  = (const float*)d_in[0];
    const float* x_author = (const float*)d_in[1];
    const int*   ei_ap    = (const int*)d_in[2];
    const int*   ei_pa    = (const int*)d_in[3];
    const int*   ei_pp    = (const int*)d_in[4];
    const float* W_in     = (const float*)d_in[5];
    const float* b_in     = (const float*)d_in[6];
    const float* W_kqv    = (const float*)d_in[7];
    const float* b_kqv    = (const float*)d_in[8];
    const float* W_krel   = (const float*)d_in[9];
    const float* W_vrel   = (const float*)d_in[10];
    const float* p_rel    = (const float*)d_in[11];
    const float* W_hout   = (const float*)d_in[12];
    const float* b_hout   = (const float*)d_in[13];
    const float* skip     = (const float*)d_in[14];
    const float* ln_g     = (const float*)d_in[15];
    const float* ln_b     = (const float*)d_in[16];
    const float* W_out    = (const float*)d_in[17];
    const float* b_out    = (const float*)d_in[18];
    float* out            = (float*)d_out;

    // ---- workspace layout (~146 MB) ----
    float* ws   = (float*)d_ws;
    float* hbuf = ws;                                   // NTOT*64 f32
    float* Q    = hbuf + (size_t)NTOT * HID;            // NTOT*64 f32 (attn out aliases Q)
    unsigned short* Ksb = (unsigned short*)(Q + (size_t)NTOT * HID);  // NSRC*64 bf16
    unsigned short* Vsb = Ksb + (size_t)NSRC * HID;                   // NSRC*64 bf16
    float* Wfp  = (float*)(Vsb + (size_t)NSRC * HID);   // 64*320
    float* bfp  = Wfp  + 64 * JP;                       // 320
    float* Wfa  = bfp  + JP;                            // 64*192
    float* bfa  = Wfa  + 64 * JA;                       // 192
    int* cnt      = (int*)(bfa + JA);                   // NTOT
    int* row_ptr  = cnt + NTOT;                         // NTOT+1 (pad 16)
    int* cursor   = row_ptr + NTOT + 16;                // NTOT
    int* edge_src = cursor + NTOT;                      // ETOT
    int* csum     = edge_src + ETOT;                    // 1024
    int* coff     = csum + 1024;                        // 1024

    dim3 blk(256);
    const int EB = (ETOT + 255) / 256;

    // ---- CSR build (edges are layer-invariant) ----
    zero_int_kernel<<<256, blk, 0, stream>>>(cnt, NTOT);
    csr_count_kernel<<<EB, blk, 0, stream>>>(ei_ap, ei_pa, ei_pp, cnt);
    scan_chunk_sums<<<NCH, blk, 0, stream>>>(cnt, csum);
    scan_offsets<<<1, 1024, 0, stream>>>(csum, coff, NCH);
    scan_final<<<NCH, blk, 0, stream>>>(cnt, coff, row_ptr, cursor);
    csr_fill_kernel<<<EB, blk, 0, stream>>>(ei_ap, ei_pa, ei_pp, cursor, edge_src);

    // ---- input projection ----
    gemm_in<<<PT + AT, blk, 0, stream>>>(x_paper, x_author, W_in, b_in, hbuf);

    for (int l = 0; l < LAYERS; l++) {
        fuse_weights_kernel<<<(65 * JP + 65 * JA + 255) / 256, blk, 0, stream>>>(
            W_kqv + (size_t)l * 2 * HID * KQV, b_kqv + (size_t)l * 2 * KQV,
            W_krel + (size_t)l * 3 * NH * HD * HD, W_vrel + (size_t)l * 3 * NH * HD * HD,
            Wfp, bfp, Wfa, bfa);
        gemm_kqv<<<PT * 5 + AT * 3, blk, 0, stream>>>(
            hbuf, Wfp, bfp, Wfa, bfa, Q, Ksb, Vsb);
        attn_kernel<<<(NTOT + 3) / 4, blk, 0, stream>>>(
            Q, Ksb, Vsb, p_rel + l * 3 * NH, row_ptr, edge_src, Q);
        gemm_hout<<<PT + AT, blk, 0, stream>>>(
            Q, W_hout + (size_t)l * 2 * HID * HID, b_hout + l * 2 * HID,
            skip + l * 2, ln_g + l * 2 * HID, ln_b + l * 2 * HID, hbuf);
    }

    gemm_out<<<PT + AT, blk, 0, stream>>>(hbuf, W_out, b_out, out);
}

// Round 6
// 757.559 us; speedup vs baseline: 2.4732x; 1.2331x over previous
//
#include <hip/hip_runtime.h>
#include <hip/hip_bf16.h>

// ---- problem constants (match reference) ----
#define NP 100000
#define NA 50000
#define NTOT 150000          // NP+NA
#define E0 300000
#define E1 300000
#define E2 200000
#define ETOT 800000
#define NH 4
#define HD 16
#define HID 64
#define IN_DIM 128
#define KQV 192
#define LAYERS 2
#define NSRC 250000          // NA + 2*NP
#define JP 320               // fused paper cols: q | k_et1 | k_et2 | v_et1 | v_et2
#define JA 192               // fused author cols: q | k_et0 | v_et0
#define NCH 586              // ceil(NTOT/256)
#define PT 1563              // ceil(NP/64)
#define AT 782               // ceil(NA/64)

__device__ __forceinline__ float gelu_exact(float x) {
    return 0.5f * x * (1.0f + erff(x * 0.7071067811865475f));
}
// f32 -> bf16 bits, round-to-nearest-even (finite values)
__device__ __forceinline__ unsigned short f2bf(float f) {
    unsigned u = __float_as_uint(f);
    return (unsigned short)((u + 0x7fffu + ((u >> 16) & 1u)) >> 16);
}
__device__ __forceinline__ float bf2f(unsigned short b) {
    return __uint_as_float((unsigned)b << 16);
}

// decode global edge id -> (src in Ks/Vs space, dst in node space)
__device__ __forceinline__ void edge_decode(int e, const int* __restrict__ ei_ap,
                                            const int* __restrict__ ei_pa,
                                            const int* __restrict__ ei_pp,
                                            int& src, int& dst) {
    if (e < E0)            { src = ei_ap[e];                 dst = ei_ap[E0 + e]; }
    else if (e < E0 + E1)  { int le = e - E0;
                             src = NA + ei_pa[le];           dst = NP + ei_pa[E1 + le]; }
    else                   { int le = e - E0 - E1;
                             src = NA + NP + ei_pp[le];      dst = ei_pp[E2 + le]; }
}

// ---------------- CSR build ----------------
__global__ void zero_int_kernel(int* __restrict__ p, int n) {
    int i = blockIdx.x * blockDim.x + threadIdx.x;
    int st = gridDim.x * blockDim.x;
    for (int j = i; j < n; j += st) p[j] = 0;
}

__global__ void csr_count_kernel(const int* __restrict__ ei_ap, const int* __restrict__ ei_pa,
                                 const int* __restrict__ ei_pp, int* __restrict__ cnt) {
    int e = blockIdx.x * 256 + threadIdx.x;
    if (e >= ETOT) return;
    int src, dst; edge_decode(e, ei_ap, ei_pa, ei_pp, src, dst);
    atomicAdd(&cnt[dst], 1);
}

__global__ void scan_chunk_sums(const int* __restrict__ cnt, int* __restrict__ csum) {
    __shared__ int sd[256];
    int c = blockIdx.x, t = threadIdx.x;
    int i = c * 256 + t;
    sd[t] = (i < NTOT) ? cnt[i] : 0;
    __syncthreads();
    for (int o = 128; o > 0; o >>= 1) { if (t < o) sd[t] += sd[t + o]; __syncthreads(); }
    if (t == 0) csum[c] = sd[0];
}

__global__ void scan_offsets(const int* __restrict__ csum, int* __restrict__ coff, int nch) {
    __shared__ int sd[1024];
    int t = threadIdx.x;
    int v = (t < nch) ? csum[t] : 0;
    sd[t] = v;
    __syncthreads();
    for (int o = 1; o < 1024; o <<= 1) {
        int x = (t >= o) ? sd[t - o] : 0;
        __syncthreads();
        sd[t] += x;
        __syncthreads();
    }
    if (t < nch) coff[t] = sd[t] - v;   // exclusive
}

__global__ void scan_final(const int* __restrict__ cnt, const int* __restrict__ coff,
                           int* __restrict__ row_ptr, int* __restrict__ cursor) {
    __shared__ int sd[256];
    int c = blockIdx.x, t = threadIdx.x, i = c * 256 + t;
    int v = (i < NTOT) ? cnt[i] : 0;
    sd[t] = v;
    __syncthreads();
    for (int o = 1; o < 256; o <<= 1) {
        int x = (t >= o) ? sd[t - o] : 0;
        __syncthreads();
        sd[t] += x;
        __syncthreads();
    }
    if (i < NTOT) { int ex = coff[c] + sd[t] - v; row_ptr[i] = ex; cursor[i] = ex; }
    if (i == 0) row_ptr[NTOT] = ETOT;
}

__global__ void csr_fill_kernel(const int* __restrict__ ei_ap, const int* __restrict__ ei_pa,
                                const int* __restrict__ ei_pp, int* __restrict__ cursor,
                                int* __restrict__ edge_src) {
    int e = blockIdx.x * 256 + threadIdx.x;
    if (e >= ETOT) return;
    int src, dst; edge_decode(e, ei_ap, ei_pa, ei_pp, src, dst);
    int pos = atomicAdd(&cursor[dst], 1);
    edge_src[pos] = src;
}

// ---------------- fused-weight build (per layer) ----------------
__global__ void fuse_weights_kernel(const float* __restrict__ Wkqv, const float* __restrict__ bkqv,
                                    const float* __restrict__ Wkrel, const float* __restrict__ Wvrel,
                                    float* __restrict__ Wfp, float* __restrict__ bfp,
                                    float* __restrict__ Wfa, float* __restrict__ bfa) {
    int idx = blockIdx.x * 256 + threadIdx.x;
    int type, i, j;
    if (idx < 65 * JP) { type = 0; i = idx / JP; j = idx % JP; }
    else {
        int r = idx - 65 * JP;
        if (r >= 65 * JA) return;
        type = 1; i = r / JA; j = r % JA;
    }
    int c = j >> 6, jj = j & 63, h = jj >> 4, e = jj & 15;
    const float* Wk = Wkqv + (size_t)type * HID * KQV;
    const float* bk = bkqv + type * KQV;
    float val;
    if (c == 0) {
        val = (i < 64) ? Wk[i * KQV + 64 + jj] : bk[64 + jj];
    } else {
        int et, isV;
        if (type == 0) { et = (c == 1 || c == 3) ? 1 : 2; isV = (c >= 3); }
        else           { et = 0; isV = (c == 2); }
        const float* Wr = (isV ? Wvrel : Wkrel) + (size_t)(et * NH + h) * HD * HD;
        int sb = (isV ? 128 : 0) + h * HD;
        val = 0.0f;
        #pragma unroll
        for (int d = 0; d < HD; d++) {
            float a = (i < 64) ? Wk[i * KQV + sb + d] : bk[sb + d];
            val += a * Wr[d * HD + e];
        }
    }
    if (i < 64) (type ? Wfa : Wfp)[i * (type ? JA : JP) + j] = val;
    else        (type ? bfa : bfp)[j] = val;
}

// ---------------- shared GEMM core pieces ----------------
#define GEMM_CORE_64(ACCVAR, XS, WS, KOFF)                                         \
    {                                                                              \
        _Pragma("unroll")                                                          \
        for (int i = 0; i < 64; i += 4) {                                          \
            float4 A0 = *(const float4*)&XS[tr4 + 0][KOFF + i];                    \
            float4 A1 = *(const float4*)&XS[tr4 + 1][KOFF + i];                    \
            float4 A2 = *(const float4*)&XS[tr4 + 2][KOFF + i];                    \
            float4 A3 = *(const float4*)&XS[tr4 + 3][KOFF + i];                    \
            float4 W0 = *(const float4*)&WS[i + 0][tcj];                           \
            float4 W1 = *(const float4*)&WS[i + 1][tcj];                           \
            float4 W2 = *(const float4*)&WS[i + 2][tcj];                           \
            float4 W3 = *(const float4*)&WS[i + 3][tcj];                           \
            ACCVAR[0][0] += A0.x*W0.x + A0.y*W1.x + A0.z*W2.x + A0.w*W3.x;         \
            ACCVAR[0][1] += A0.x*W0.y + A0.y*W1.y + A0.z*W2.y + A0.w*W3.y;         \
            ACCVAR[0][2] += A0.x*W0.z + A0.y*W1.z + A0.z*W2.z + A0.w*W3.z;         \
            ACCVAR[0][3] += A0.x*W0.w + A0.y*W1.w + A0.z*W2.w + A0.w*W3.w;         \
            ACCVAR[1][0] += A1.x*W0.x + A1.y*W1.x + A1.z*W2.x + A1.w*W3.x;         \
            ACCVAR[1][1] += A1.x*W0.y + A1.y*W1.y + A1.z*W2.y + A1.w*W3.y;         \
            ACCVAR[1][2] += A1.x*W0.z + A1.y*W1.z + A1.z*W2.z + A1.w*W3.z;         \
            ACCVAR[1][3] += A1.x*W0.w + A1.y*W1.w + A1.z*W2.w + A1.w*W3.w;         \
            ACCVAR[2][0] += A2.x*W0.x + A2.y*W1.x + A2.z*W2.x + A2.w*W3.x;         \
            ACCVAR[2][1] += A2.x*W0.y + A2.y*W1.y + A2.z*W2.y + A2.w*W3.y;         \
            ACCVAR[2][2] += A2.x*W0.z + A2.y*W1.z + A2.z*W2.z + A2.w*W3.z;         \
            ACCVAR[2][3] += A2.x*W0.w + A2.y*W1.w + A2.z*W2.w + A2.w*W3.w;         \
            ACCVAR[3][0] += A3.x*W0.x + A3.y*W1.x + A3.z*W2.x + A3.w*W3.x;         \
            ACCVAR[3][1] += A3.x*W0.y + A3.y*W1.y + A3.z*W2.y + A3.w*W3.y;         \
            ACCVAR[3][2] += A3.x*W0.z + A3.y*W1.z + A3.z*W2.z + A3.w*W3.z;         \
            ACCVAR[3][3] += A3.x*W0.w + A3.y*W1.w + A3.z*W2.w + A3.w*W3.w;         \
        }                                                                          \
    }

// ---------------- input projection (K=128), paper+author merged ----------------
// K staged in 64-col chunks; #pragma unroll 1 on the ks loop keeps VGPR ~140
// (full unroll here spilled at 256 VGPR -> 3 GB scratch traffic in R4).
__global__ __launch_bounds__(256) void gemm_in(
    const float* __restrict__ xp, const float* __restrict__ xa,
    const float* __restrict__ W_in, const float* __restrict__ b_in,
    float* __restrict__ hbuf)
{
    __shared__ float xs[64][68];
    __shared__ float wsb[64][68];
    int b = blockIdx.x, tid = threadIdx.x;
    int type = (b >= PT);
    int tile = type ? (b - PT) : b;
    int N = type ? NA : NP;
    const float* X = type ? xa : xp;
    const float* W = W_in + (size_t)type * IN_DIM * HID;
    const float* bias = b_in + type * HID;
    float* H = hbuf + (type ? (size_t)NP * HID : 0);
    int nb = tile * 64;

    const int tr = tid >> 4, tc = tid & 15;
    const int tr4 = tr * 4, tcj = tc * 4;
    float acc[4][4] = {};

    #pragma unroll 1
    for (int ks = 0; ks < IN_DIM; ks += 64) {
        __syncthreads();
        #pragma unroll
        for (int r = 0; r < 4; r++) {
            int f = tid + 256 * r;
            int row = f >> 4, col = (f & 15) * 4;
            int n = nb + row;
            float4 v = (n < N) ? *(const float4*)(X + (size_t)n * IN_DIM + ks + col)
                               : make_float4(0.f, 0.f, 0.f, 0.f);
            *(float4*)&xs[row][col] = v;
            *(float4*)&wsb[row][col] = *(const float4*)(W + (size_t)(ks + row) * HID + col);
        }
        __syncthreads();
        GEMM_CORE_64(acc, xs, wsb, 0)
    }
    float b0 = bias[tcj], b1 = bias[tcj+1], b2 = bias[tcj+2], b3 = bias[tcj+3];
    #pragma unroll
    for (int m = 0; m < 4; m++) {
        int n = nb + tr4 + m;
        if (n < N) {
            float* p = H + (size_t)n * HID + tcj;
            p[0] = acc[m][0] + b0; p[1] = acc[m][1] + b1;
            p[2] = acc[m][2] + b2; p[3] = acc[m][3] + b3;
        }
    }
}

// ---------------- KQV GEMM: one (row-tile, chunk) per block ----------------
// paper chunks: 0->Q f32 | 1->Ks@NA | 2->Ks@NA+NP | 3->Vs@NA | 4->Vs@NA+NP (bf16)
// author chunks: 0->Q@NP | 1->Ks@0 | 2->Vs@0
__global__ __launch_bounds__(256) void gemm_kqv(
    const float* __restrict__ hbuf,
    const float* __restrict__ Wfp, const float* __restrict__ bfp,
    const float* __restrict__ Wfa, const float* __restrict__ bfa,
    float* __restrict__ Q, unsigned short* __restrict__ Ksb, unsigned short* __restrict__ Vsb)
{
    __shared__ float xs[64][68];
    __shared__ float wsb[64][68];
    int b = blockIdx.x, tid = threadIdx.x;
    int type, tile, chunk;
    if (b < PT * 5) { type = 0; chunk = b / PT; tile = b % PT; }
    else            { int ab = b - PT * 5; type = 1; chunk = ab / AT; tile = ab % AT; }
    int N = type ? NA : NP;
    const float* X = hbuf + (type ? (size_t)NP * HID : 0);
    const float* W = type ? Wfa : Wfp;
    const float* bias = type ? bfa : bfp;
    int ldw = type ? JA : JP;
    int nb = tile * 64;

    #pragma unroll
    for (int r = 0; r < 4; r++) {
        int f = tid + 256 * r;
        int row = f >> 4, col = (f & 15) * 4;
        int n = nb + row;
        float4 v = (n < N) ? *(const float4*)(X + (size_t)n * HID + col)
                           : make_float4(0.f, 0.f, 0.f, 0.f);
        *(float4*)&xs[row][col] = v;
        *(float4*)&wsb[row][col] = *(const float4*)(W + (size_t)row * ldw + chunk * 64 + col);
    }
    __syncthreads();
    const int tr = tid >> 4, tc = tid & 15;
    const int tr4 = tr * 4, tcj = tc * 4;
    float acc[4][4] = {};
    GEMM_CORE_64(acc, xs, wsb, 0)

    const float* bp = bias + chunk * 64 + tcj;
    float b0 = bp[0], b1 = bp[1], b2 = bp[2], b3 = bp[3];
    // destination select
    if (chunk == 0) {
        int noff = type ? NP : 0;
        #pragma unroll
        for (int m = 0; m < 4; m++) {
            int n = nb + tr4 + m;
            if (n < N) {
                float* p = Q + (size_t)(noff + n) * HID + tcj;
                p[0] = acc[m][0] + b0; p[1] = acc[m][1] + b1;
                p[2] = acc[m][2] + b2; p[3] = acc[m][3] + b3;
            }
        }
    } else {
        unsigned short* base; int noff;
        if (type == 0) {
            base = (chunk <= 2) ? Ksb : Vsb;
            noff = ((chunk == 1 || chunk == 3) ? NA : NA + NP);
        } else {
            base = (chunk == 1) ? Ksb : Vsb;
            noff = 0;
        }
        #pragma unroll
        for (int m = 0; m < 4; m++) {
            int n = nb + tr4 + m;
            if (n < N) {
                ushort4 uv;
                uv.x = f2bf(acc[m][0] + b0); uv.y = f2bf(acc[m][1] + b1);
                uv.z = f2bf(acc[m][2] + b2); uv.w = f2bf(acc[m][3] + b3);
                *(ushort4*)(base + (size_t)(noff + n) * HID + tcj) = uv;
            }
        }
    }
}

// ---------------- fused attention: one wave per dst node, online softmax ----------------
__global__ __launch_bounds__(256) void attn_kernel(
    const float* Q, const unsigned short* __restrict__ Ksb,
    const unsigned short* __restrict__ Vsb,
    const float* __restrict__ p_rel, const int* __restrict__ row_ptr,
    const int* __restrict__ edge_src, float* attnout)
{
    int wid = threadIdx.x >> 6, lane = threadIdx.x & 63;
    int n = blockIdx.x * 4 + wid;
    if (n >= NTOT) return;
    int h = lane >> 4;
    float q = Q[(size_t)n * HID + lane];
    float pr0 = p_rel[h], pr1 = p_rel[4 + h], pr2 = p_rel[8 + h];
    int beg = row_ptr[n], end = row_ptr[n + 1];
    float m = -INFINITY, s = 0.0f, acc = 0.0f;
    int e = beg;
    for (; e + 1 < end; e += 2) {
        int s0 = edge_src[e], s1 = edge_src[e + 1];
        size_t r0 = (size_t)s0 * HID + lane, r1 = (size_t)s1 * HID + lane;
        float k0 = bf2f(Ksb[r0]), v0 = bf2f(Vsb[r0]);
        float k1 = bf2f(Ksb[r1]), v1 = bf2f(Vsb[r1]);
        float p0 = q * k0, p1 = q * k1;
        p0 += __shfl_xor(p0, 1, 64);  p1 += __shfl_xor(p1, 1, 64);
        p0 += __shfl_xor(p0, 2, 64);  p1 += __shfl_xor(p1, 2, 64);
        p0 += __shfl_xor(p0, 4, 64);  p1 += __shfl_xor(p1, 4, 64);
        p0 += __shfl_xor(p0, 8, 64);  p1 += __shfl_xor(p1, 8, 64);
        float a0 = p0 * ((s0 < NA) ? pr0 : ((s0 < NA + NP) ? pr1 : pr2)) * 0.25f;
        float a1 = p1 * ((s1 < NA) ? pr0 : ((s1 < NA + NP) ? pr1 : pr2)) * 0.25f;
        float mn = fmaxf(m, fmaxf(a0, a1));
        float cc = expf(m - mn);
        float e0 = expf(a0 - mn), e1 = expf(a1 - mn);
        s   = s * cc + e0 + e1;
        acc = acc * cc + e0 * v0 + e1 * v1;
        m = mn;
    }
    if (e < end) {
        int s0 = edge_src[e];
        size_t r0 = (size_t)s0 * HID + lane;
        float k0 = bf2f(Ksb[r0]), v0 = bf2f(Vsb[r0]);
        float p0 = q * k0;
        p0 += __shfl_xor(p0, 1, 64);
        p0 += __shfl_xor(p0, 2, 64);
        p0 += __shfl_xor(p0, 4, 64);
        p0 += __shfl_xor(p0, 8, 64);
        float a0 = p0 * ((s0 < NA) ? pr0 : ((s0 < NA + NP) ? pr1 : pr2)) * 0.25f;
        float mn = fmaxf(m, a0);
        float cc = expf(m - mn);
        float e0 = expf(a0 - mn);
        s   = s * cc + e0;
        acc = acc * cc + e0 * v0;
    }
    attnout[(size_t)n * HID + lane] = acc / (s + 1e-16f);
}

// ---------------- hout GEMM + skip + LN + gelu fused, paper+author merged ----------------
// Epilogue m-loop is #pragma unroll 1: full unroll kept 4 rows of LN state live
// over acc[4][4] -> 256 VGPR spill (R5: 192us, 94MB scratch writes).
__global__ __launch_bounds__(256) void gemm_hout(
    const float* __restrict__ attnout, const float* __restrict__ Whout,
    const float* __restrict__ bhout, const float* __restrict__ skip_p,
    const float* __restrict__ lng, const float* __restrict__ lnb,
    float* __restrict__ hbuf)
{
    __shared__ float xs[64][68];
    __shared__ float wsb[64][68];
    int b = blockIdx.x, tid = threadIdx.x;
    int type = (b >= PT);
    int tile = type ? (b - PT) : b;
    int N = type ? NA : NP;
    size_t base_off = type ? (size_t)NP * HID : 0;
    const float* X = attnout + base_off;
    const float* W = Whout + (size_t)type * HID * HID;
    const float* bias = bhout + type * HID;
    float* H = hbuf + base_off;
    int nb = tile * 64;

    #pragma unroll
    for (int r = 0; r < 4; r++) {
        int f = tid + 256 * r;
        int row = f >> 4, col = (f & 15) * 4;
        int n = nb + row;
        float4 v = (n < N) ? *(const float4*)(X + (size_t)n * HID + col)
                           : make_float4(0.f, 0.f, 0.f, 0.f);
        v.x = gelu_exact(v.x); v.y = gelu_exact(v.y);
        v.z = gelu_exact(v.z); v.w = gelu_exact(v.w);
        *(float4*)&xs[row][col] = v;
        *(float4*)&wsb[row][col] = *(const float4*)(W + (size_t)row * HID + col);
    }
    __syncthreads();
    const int tr = tid >> 4, tc = tid & 15;
    const int tr4 = tr * 4, tcj = tc * 4;
    float acc[4][4] = {};
    GEMM_CORE_64(acc, xs, wsb, 0)

    float b0 = bias[tcj], b1 = bias[tcj+1], b2 = bias[tcj+2], b3 = bias[tcj+3];
    float a = 1.0f / (1.0f + expf(-skip_p[type]));
    float oma = 1.0f - a;
    float g0 = lng[type*HID+tcj], g1 = lng[type*HID+tcj+1],
          g2 = lng[type*HID+tcj+2], g3 = lng[type*HID+tcj+3];
    float l0 = lnb[type*HID+tcj], l1 = lnb[type*HID+tcj+1],
          l2 = lnb[type*HID+tcj+2], l3 = lnb[type*HID+tcj+3];
    #pragma unroll 1
    for (int m = 0; m < 4; m++) {
        int n = nb + tr4 + m;
        float v0 = 0.f, v1 = 0.f, v2 = 0.f, v3 = 0.f;
        if (n < N) {
            const float* hp = H + (size_t)n * HID + tcj;
            v0 = a * (acc[m][0] + b0) + oma * hp[0];
            v1 = a * (acc[m][1] + b1) + oma * hp[1];
            v2 = a * (acc[m][2] + b2) + oma * hp[2];
            v3 = a * (acc[m][3] + b3) + oma * hp[3];
        }
        // layernorm across the row (16 lanes x 4 vals)
        float sum = v0 + v1 + v2 + v3;
        sum += __shfl_xor(sum, 1, 64); sum += __shfl_xor(sum, 2, 64);
        sum += __shfl_xor(sum, 4, 64); sum += __shfl_xor(sum, 8, 64);
        float mean = sum * (1.0f / 64.0f);
        float d0 = v0 - mean, d1 = v1 - mean, d2 = v2 - mean, d3 = v3 - mean;
        float sq = d0*d0 + d1*d1 + d2*d2 + d3*d3;
        sq += __shfl_xor(sq, 1, 64); sq += __shfl_xor(sq, 2, 64);
        sq += __shfl_xor(sq, 4, 64); sq += __shfl_xor(sq, 8, 64);
        float rstd = rsqrtf(sq * (1.0f / 64.0f) + 1e-5f);
        if (n < N) {
            float* hp = H + (size_t)n * HID + tcj;
            hp[0] = gelu_exact(d0 * rstd * g0 + l0);
            hp[1] = gelu_exact(d1 * rstd * g1 + l1);
            hp[2] = gelu_exact(d2 * rstd * g2 + l2);
            hp[3] = gelu_exact(d3 * rstd * g3 + l3);
        }
    }
}

// ---------------- final linear, paper+author merged ----------------
__global__ __launch_bounds__(256) void gemm_out(
    const float* __restrict__ hbuf, const float* __restrict__ W_out,
    const float* __restrict__ b_out, float* __restrict__ out)
{
    __shared__ float xs[64][68];
    __shared__ float wsb[64][68];
    int b = blockIdx.x, tid = threadIdx.x;
    int type = (b >= PT);
    int tile = type ? (b - PT) : b;
    int N = type ? NA : NP;
    size_t base_off = type ? (size_t)NP * HID : 0;
    const float* X = hbuf + base_off;
    const float* W = W_out + (size_t)type * HID * HID;
    const float* bias = b_out + type * HID;
    float* O = out + base_off;
    int nb = tile * 64;

    #pragma unroll
    for (int r = 0; r < 4; r++) {
        int f = tid + 256 * r;
        int row = f >> 4, col = (f & 15) * 4;
        int n = nb + row;
        float4 v = (n < N) ? *(const float4*)(X + (size_t)n * HID + col)
                           : make_float4(0.f, 0.f, 0.f, 0.f);
        *(float4*)&xs[row][col] = v;
        *(float4*)&wsb[row][col] = *(const float4*)(W + (size_t)row * HID + col);
    }
    __syncthreads();
    const int tr = tid >> 4, tc = tid & 15;
    const int tr4 = tr * 4, tcj = tc * 4;
    float acc[4][4] = {};
    GEMM_CORE_64(acc, xs, wsb, 0)

    float b0 = bias[tcj], b1 = bias[tcj+1], b2 = bias[tcj+2], b3 = bias[tcj+3];
    #pragma unroll
    for (int m = 0; m < 4; m++) {
        int n = nb + tr4 + m;
        if (n < N) {
            float* p = O + (size_t)n * HID + tcj;
            p[0] = acc[m][0] + b0; p[1] = acc[m][1] + b1;
            p[2] = acc[m][2] + b2; p[3] = acc[m][3] + b3;
        }
    }
}

extern "C" void kernel_launch(void* const* d_in, const int* in_sizes, int n_in,
                              void* d_out, int out_size, void* d_ws, size_t ws_size,
                              hipStream_t stream) {
    const float* x_paper  = (const float*)d_in[0];
    const float* x_author = (const float*)d_in[1];
    const int*   ei_ap    = (const int*)d_in[2];
    const int*   ei_pa    = (const int*)d_in[3];
    const int*   ei_pp    = (const int*)d_in[4];
    const float* W_in     = (const float*)d_in[5];
    const float* b_in     = (const float*)d_in[6];
    const float* W_kqv    = (const float*)d_in[7];
    const float* b_kqv    = (const float*)d_in[8];
    const float* W_krel   = (const float*)d_in[9];
    const float* W_vrel   = (const float*)d_in[10];
    const float* p_rel    = (const float*)d_in[11];
    const float* W_hout   = (const float*)d_in[12];
    const float* b_hout   = (const float*)d_in[13];
    const float* skip     = (const float*)d_in[14];
    const float* ln_g     = (const float*)d_in[15];
    const float* ln_b     = (const float*)d_in[16];
    const float* W_out    = (const float*)d_in[17];
    const float* b_out    = (const float*)d_in[18];
    float* out            = (float*)d_out;

    // ---- workspace layout (~146 MB) ----
    float* ws   = (float*)d_ws;
    float* hbuf = ws;                                   // NTOT*64 f32
    float* Q    = hbuf + (size_t)NTOT * HID;            // NTOT*64 f32 (attn out aliases Q)
    unsigned short* Ksb = (unsigned short*)(Q + (size_t)NTOT * HID);  // NSRC*64 bf16
    unsigned short* Vsb = Ksb + (size_t)NSRC * HID;                   // NSRC*64 bf16
    float* Wfp  = (float*)(Vsb + (size_t)NSRC * HID);   // 64*320
    float* bfp  = Wfp  + 64 * JP;                       // 320
    float* Wfa  = bfp  + JP;                            // 64*192
    float* bfa  = Wfa  + 64 * JA;                       // 192
    int* cnt      = (int*)(bfa + JA);                   // NTOT
    int* row_ptr  = cnt + NTOT;                         // NTOT+1 (pad 16)
    int* cursor   = row_ptr + NTOT + 16;                // NTOT
    int* edge_src = cursor + NTOT;                      // ETOT
    int* csum     = edge_src + ETOT;                    // 1024
    int* coff     = csum + 1024;                        // 1024

    dim3 blk(256);
    const int EB = (ETOT + 255) / 256;

    // ---- CSR build (edges are layer-invariant) ----
    zero_int_kernel<<<256, blk, 0, stream>>>(cnt, NTOT);
    csr_count_kernel<<<EB, blk, 0, stream>>>(ei_ap, ei_pa, ei_pp, cnt);
    scan_chunk_sums<<<NCH, blk, 0, stream>>>(cnt, csum);
    scan_offsets<<<1, 1024, 0, stream>>>(csum, coff, NCH);
    scan_final<<<NCH, blk, 0, stream>>>(cnt, coff, row_ptr, cursor);
    csr_fill_kernel<<<EB, blk, 0, stream>>>(ei_ap, ei_pa, ei_pp, cursor, edge_src);

    // ---- input projection ----
    gemm_in<<<PT + AT, blk, 0, stream>>>(x_paper, x_author, W_in, b_in, hbuf);

    for (int l = 0; l < LAYERS; l++) {
        fuse_weights_kernel<<<(65 * JP + 65 * JA + 255) / 256, blk, 0, stream>>>(
            W_kqv + (size_t)l * 2 * HID * KQV, b_kqv + (size_t)l * 2 * KQV,
            W_krel + (size_t)l * 3 * NH * HD * HD, W_vrel + (size_t)l * 3 * NH * HD * HD,
            Wfp, bfp, Wfa, bfa);
        gemm_kqv<<<PT * 5 + AT * 3, blk, 0, stream>>>(
            hbuf, Wfp, bfp, Wfa, bfa, Q, Ksb, Vsb);
        attn_kernel<<<(NTOT + 3) / 4, blk, 0, stream>>>(
            Q, Ksb, Vsb, p_rel + l * 3 * NH, row_ptr, edge_src, Q);
        gemm_hout<<<PT + AT, blk, 0, stream>>>(
            Q, W_hout + (size_t)l * 2 * HID * HID, b_hout + l * 2 * HID,
            skip + l * 2, ln_g + l * 2 * HID, ln_b + l * 2 * HID, hbuf);
    }

    gemm_out<<<PT + AT, blk, 0, stream>>>(hbuf, W_out, b_out, out);
}

// Round 7
// 669.742 us; speedup vs baseline: 2.7975x; 1.1311x over previous
//
#include <hip/hip_runtime.h>
#include <hip/hip_bf16.h>

// ---- problem constants (match reference) ----
#define NP 100000
#define NA 50000
#define NTOT 150000          // NP+NA
#define E0 300000
#define E1 300000
#define E2 200000
#define ETOT 800000
#define NH 4
#define HD 16
#define HID 64
#define IN_DIM 128
#define KQV 192
#define LAYERS 2
#define NSRC 250000          // NA + 2*NP
#define JP 320               // fused paper cols: q | k_et1 | k_et2 | v_et1 | v_et2
#define JA 192               // fused author cols: q | k_et0 | v_et0
#define NCH 586              // ceil(NTOT/256)
#define PT 1563              // ceil(NP/64)
#define AT 782               // ceil(NA/64)

typedef __attribute__((ext_vector_type(8))) short bf16x8;   // 8 bf16 (4 VGPRs)
typedef __attribute__((ext_vector_type(4))) float f32x4;    // MFMA C/D

__device__ __forceinline__ float gelu_exact(float x) {
    return 0.5f * x * (1.0f + erff(x * 0.7071067811865475f));
}
// f32 -> bf16 bits, round-to-nearest-even (finite values)
__device__ __forceinline__ unsigned short f2bf(float f) {
    unsigned u = __float_as_uint(f);
    return (unsigned short)((u + 0x7fffu + ((u >> 16) & 1u)) >> 16);
}
__device__ __forceinline__ float bf2f(unsigned short b) {
    return __uint_as_float((unsigned)b << 16);
}

// decode global edge id -> (src in Ks/Vs space, dst in node space)
__device__ __forceinline__ void edge_decode(int e, const int* __restrict__ ei_ap,
                                            const int* __restrict__ ei_pa,
                                            const int* __restrict__ ei_pp,
                                            int& src, int& dst) {
    if (e < E0)            { src = ei_ap[e];                 dst = ei_ap[E0 + e]; }
    else if (e < E0 + E1)  { int le = e - E0;
                             src = NA + ei_pa[le];           dst = NP + ei_pa[E1 + le]; }
    else                   { int le = e - E0 - E1;
                             src = NA + NP + ei_pp[le];      dst = ei_pp[E2 + le]; }
}

// ---------------- CSR build ----------------
__global__ void zero_int_kernel(int* __restrict__ p, int n) {
    int i = blockIdx.x * blockDim.x + threadIdx.x;
    int st = gridDim.x * blockDim.x;
    for (int j = i; j < n; j += st) p[j] = 0;
}

__global__ void csr_count_kernel(const int* __restrict__ ei_ap, const int* __restrict__ ei_pa,
                                 const int* __restrict__ ei_pp, int* __restrict__ cnt) {
    int e = blockIdx.x * 256 + threadIdx.x;
    if (e >= ETOT) return;
    int src, dst; edge_decode(e, ei_ap, ei_pa, ei_pp, src, dst);
    atomicAdd(&cnt[dst], 1);
}

__global__ void scan_chunk_sums(const int* __restrict__ cnt, int* __restrict__ csum) {
    __shared__ int sd[256];
    int c = blockIdx.x, t = threadIdx.x;
    int i = c * 256 + t;
    sd[t] = (i < NTOT) ? cnt[i] : 0;
    __syncthreads();
    for (int o = 128; o > 0; o >>= 1) { if (t < o) sd[t] += sd[t + o]; __syncthreads(); }
    if (t == 0) csum[c] = sd[0];
}

__global__ void scan_offsets(const int* __restrict__ csum, int* __restrict__ coff, int nch) {
    __shared__ int sd[1024];
    int t = threadIdx.x;
    int v = (t < nch) ? csum[t] : 0;
    sd[t] = v;
    __syncthreads();
    for (int o = 1; o < 1024; o <<= 1) {
        int x = (t >= o) ? sd[t - o] : 0;
        __syncthreads();
        sd[t] += x;
        __syncthreads();
    }
    if (t < nch) coff[t] = sd[t] - v;   // exclusive
}

__global__ void scan_final(const int* __restrict__ cnt, const int* __restrict__ coff,
                           int* __restrict__ row_ptr, int* __restrict__ cursor) {
    __shared__ int sd[256];
    int c = blockIdx.x, t = threadIdx.x, i = c * 256 + t;
    int v = (i < NTOT) ? cnt[i] : 0;
    sd[t] = v;
    __syncthreads();
    for (int o = 1; o < 256; o <<= 1) {
        int x = (t >= o) ? sd[t - o] : 0;
        __syncthreads();
        sd[t] += x;
        __syncthreads();
    }
    if (i < NTOT) { int ex = coff[c] + sd[t] - v; row_ptr[i] = ex; cursor[i] = ex; }
    if (i == 0) row_ptr[NTOT] = ETOT;
}

__global__ void csr_fill_kernel(const int* __restrict__ ei_ap, const int* __restrict__ ei_pa,
                                const int* __restrict__ ei_pp, int* __restrict__ cursor,
                                int* __restrict__ edge_src) {
    int e = blockIdx.x * 256 + threadIdx.x;
    if (e >= ETOT) return;
    int src, dst; edge_decode(e, ei_ap, ei_pa, ei_pp, src, dst);
    int pos = atomicAdd(&cursor[dst], 1);
    edge_src[pos] = src;
}

// ---------------- fused-weight build (per layer) ----------------
__global__ void fuse_weights_kernel(const float* __restrict__ Wkqv, const float* __restrict__ bkqv,
                                    const float* __restrict__ Wkrel, const float* __restrict__ Wvrel,
                                    float* __restrict__ Wfp, float* __restrict__ bfp,
                                    float* __restrict__ Wfa, float* __restrict__ bfa) {
    int idx = blockIdx.x * 256 + threadIdx.x;
    int type, i, j;
    if (idx < 65 * JP) { type = 0; i = idx / JP; j = idx % JP; }
    else {
        int r = idx - 65 * JP;
        if (r >= 65 * JA) return;
        type = 1; i = r / JA; j = r % JA;
    }
    int c = j >> 6, jj = j & 63, h = jj >> 4, e = jj & 15;
    const float* Wk = Wkqv + (size_t)type * HID * KQV;
    const float* bk = bkqv + type * KQV;
    float val;
    if (c == 0) {
        val = (i < 64) ? Wk[i * KQV + 64 + jj] : bk[64 + jj];
    } else {
        int et, isV;
        if (type == 0) { et = (c == 1 || c == 3) ? 1 : 2; isV = (c >= 3); }
        else           { et = 0; isV = (c == 2); }
        const float* Wr = (isV ? Wvrel : Wkrel) + (size_t)(et * NH + h) * HD * HD;
        int sb = (isV ? 128 : 0) + h * HD;
        val = 0.0f;
        #pragma unroll
        for (int d = 0; d < HD; d++) {
            float a = (i < 64) ? Wk[i * KQV + sb + d] : bk[sb + d];
            val += a * Wr[d * HD + e];
        }
    }
    if (i < 64) (type ? Wfa : Wfp)[i * (type ? JA : JP) + j] = val;
    else        (type ? bfa : bfp)[j] = val;
}

// ---------------- shared GEMM core pieces ----------------
#define GEMM_CORE_64(ACCVAR, XS, WS, KOFF)                                         \
    {                                                                              \
        _Pragma("unroll")                                                          \
        for (int i = 0; i < 64; i += 4) {                                          \
            float4 A0 = *(const float4*)&XS[tr4 + 0][KOFF + i];                    \
            float4 A1 = *(const float4*)&XS[tr4 + 1][KOFF + i];                    \
            float4 A2 = *(const float4*)&XS[tr4 + 2][KOFF + i];                    \
            float4 A3 = *(const float4*)&XS[tr4 + 3][KOFF + i];                    \
            float4 W0 = *(const float4*)&WS[i + 0][tcj];                           \
            float4 W1 = *(const float4*)&WS[i + 1][tcj];                           \
            float4 W2 = *(const float4*)&WS[i + 2][tcj];                           \
            float4 W3 = *(const float4*)&WS[i + 3][tcj];                           \
            ACCVAR[0][0] += A0.x*W0.x + A0.y*W1.x + A0.z*W2.x + A0.w*W3.x;         \
            ACCVAR[0][1] += A0.x*W0.y + A0.y*W1.y + A0.z*W2.y + A0.w*W3.y;         \
            ACCVAR[0][2] += A0.x*W0.z + A0.y*W1.z + A0.z*W2.z + A0.w*W3.z;         \
            ACCVAR[0][3] += A0.x*W0.w + A0.y*W1.w + A0.z*W2.w + A0.w*W3.w;         \
            ACCVAR[1][0] += A1.x*W0.x + A1.y*W1.x + A1.z*W2.x + A1.w*W3.x;         \
            ACCVAR[1][1] += A1.x*W0.y + A1.y*W1.y + A1.z*W2.y + A1.w*W3.y;         \
            ACCVAR[1][2] += A1.x*W0.z + A1.y*W1.z + A1.z*W2.z + A1.w*W3.z;         \
            ACCVAR[1][3] += A1.x*W0.w + A1.y*W1.w + A1.z*W2.w + A1.w*W3.w;         \
            ACCVAR[2][0] += A2.x*W0.x + A2.y*W1.x + A2.z*W2.x + A2.w*W3.x;         \
            ACCVAR[2][1] += A2.x*W0.y + A2.y*W1.y + A2.z*W2.y + A2.w*W3.y;         \
            ACCVAR[2][2] += A2.x*W0.z + A2.y*W1.z + A2.z*W2.z + A2.w*W3.z;         \
            ACCVAR[2][3] += A2.x*W0.w + A2.y*W1.w + A2.z*W2.w + A2.w*W3.w;         \
            ACCVAR[3][0] += A3.x*W0.x + A3.y*W1.x + A3.z*W2.x + A3.w*W3.x;         \
            ACCVAR[3][1] += A3.x*W0.y + A3.y*W1.y + A3.z*W2.y + A3.w*W3.y;         \
            ACCVAR[3][2] += A3.x*W0.z + A3.y*W1.z + A3.z*W2.z + A3.w*W3.z;         \
            ACCVAR[3][3] += A3.x*W0.w + A3.y*W1.w + A3.z*W2.w + A3.w*W3.w;         \
        }                                                                          \
    }

// ---------------- input projection (K=128), paper+author merged ----------------
// K staged in 64-col chunks; #pragma unroll 1 on the ks loop keeps VGPR ~140
// (full unroll here spilled at 256 VGPR -> 3 GB scratch traffic in R4).
__global__ __launch_bounds__(256) void gemm_in(
    const float* __restrict__ xp, const float* __restrict__ xa,
    const float* __restrict__ W_in, const float* __restrict__ b_in,
    float* __restrict__ hbuf)
{
    __shared__ float xs[64][68];
    __shared__ float wsb[64][68];
    int b = blockIdx.x, tid = threadIdx.x;
    int type = (b >= PT);
    int tile = type ? (b - PT) : b;
    int N = type ? NA : NP;
    const float* X = type ? xa : xp;
    const float* W = W_in + (size_t)type * IN_DIM * HID;
    const float* bias = b_in + type * HID;
    float* H = hbuf + (type ? (size_t)NP * HID : 0);
    int nb = tile * 64;

    const int tr = tid >> 4, tc = tid & 15;
    const int tr4 = tr * 4, tcj = tc * 4;
    float acc[4][4] = {};

    #pragma unroll 1
    for (int ks = 0; ks < IN_DIM; ks += 64) {
        __syncthreads();
        #pragma unroll
        for (int r = 0; r < 4; r++) {
            int f = tid + 256 * r;
            int row = f >> 4, col = (f & 15) * 4;
            int n = nb + row;
            float4 v = (n < N) ? *(const float4*)(X + (size_t)n * IN_DIM + ks + col)
                               : make_float4(0.f, 0.f, 0.f, 0.f);
            *(float4*)&xs[row][col] = v;
            *(float4*)&wsb[row][col] = *(const float4*)(W + (size_t)(ks + row) * HID + col);
        }
        __syncthreads();
        GEMM_CORE_64(acc, xs, wsb, 0)
    }
    float b0 = bias[tcj], b1 = bias[tcj+1], b2 = bias[tcj+2], b3 = bias[tcj+3];
    #pragma unroll
    for (int m = 0; m < 4; m++) {
        int n = nb + tr4 + m;
        if (n < N) {
            float* p = H + (size_t)n * HID + tcj;
            p[0] = acc[m][0] + b0; p[1] = acc[m][1] + b1;
            p[2] = acc[m][2] + b2; p[3] = acc[m][3] + b3;
        }
    }
}

// ---------------- KQV GEMM via MFMA bf16: one (row-tile, chunk) per block ----------------
// X[64x64] f32 -> bf16 LDS; W[64xldw] f32 -> transposed bf16 LDS Wt[col][k].
// 4 waves: wave w owns 32x32 quadrant (wr=(w>>1)*32, wc=(w&1)*32), 2x2 frags of
// mfma_f32_16x16x32_bf16 over 2 K-steps. Fragment layouts (guide §3, m89-verified):
//   A: row=lane&15, k=(lane>>4)*8+j (one ds_read_b128)
//   B: col=lane&15, k=(lane>>4)*8+j (from transposed Wt)
//   D: col=lane&15, row=(lane>>4)*4+reg
// paper chunks: 0->Q f32 | 1->Ks@NA | 2->Ks@NA+NP | 3->Vs@NA | 4->Vs@NA+NP (bf16)
// author chunks: 0->Q@NP | 1->Ks@0 | 2->Vs@0
__global__ __launch_bounds__(256) void gemm_kqv(
    const float* __restrict__ hbuf,
    const float* __restrict__ Wfp, const float* __restrict__ bfp,
    const float* __restrict__ Wfa, const float* __restrict__ bfa,
    float* __restrict__ Q, unsigned short* __restrict__ Ksb, unsigned short* __restrict__ Vsb)
{
    __shared__ unsigned short Xb[64][72];   // stride 72 shorts = 144B (16B-aligned rows)
    __shared__ unsigned short Wt[64][72];   // Wt[col][k]
    int b = blockIdx.x, tid = threadIdx.x;
    int type, tile, chunk;
    if (b < PT * 5) { type = 0; chunk = b / PT; tile = b % PT; }
    else            { int ab = b - PT * 5; type = 1; chunk = ab / AT; tile = ab % AT; }
    int N = type ? NA : NP;
    const float* X = hbuf + (type ? (size_t)NP * HID : 0);
    const float* W = type ? Wfa : Wfp;
    const float* bias = type ? bfa : bfp;
    int ldw = type ? JA : JP;
    int nb = tile * 64;

    // stage X tile as bf16 (4 threads/row, 16 cols each)
    {
        int row = tid >> 2, c0 = (tid & 3) * 16;
        int n = nb + row;
        unsigned short tmp[16];
        if (n < N) {
            const float* xr = X + (size_t)n * HID + c0;
            #pragma unroll
            for (int i = 0; i < 16; i += 4) {
                float4 v = *(const float4*)(xr + i);
                tmp[i] = f2bf(v.x); tmp[i+1] = f2bf(v.y);
                tmp[i+2] = f2bf(v.z); tmp[i+3] = f2bf(v.w);
            }
        } else {
            #pragma unroll
            for (int i = 0; i < 16; i++) tmp[i] = 0;
        }
        #pragma unroll
        for (int i = 0; i < 16; i += 4)
            *(ushort4*)&Xb[row][c0 + i] = make_ushort4(tmp[i], tmp[i+1], tmp[i+2], tmp[i+3]);
    }
    // stage W transposed as bf16: Wt[col][k] = W[k][chunk*64+col]
    #pragma unroll
    for (int it = 0; it < 4; it++) {
        int idx = it * 256 + tid;           // 0..1023
        int k = idx & 63, c = (idx >> 6) * 4;
        float4 v = *(const float4*)(W + (size_t)k * ldw + chunk * 64 + c);
        Wt[c + 0][k] = f2bf(v.x); Wt[c + 1][k] = f2bf(v.y);
        Wt[c + 2][k] = f2bf(v.z); Wt[c + 3][k] = f2bf(v.w);
    }
    __syncthreads();

    int w = tid >> 6, lane = tid & 63;
    int wr = (w >> 1) * 32, wc = (w & 1) * 32;
    int lrow = lane & 15, lgrp = lane >> 4;

    f32x4 acc00 = {0.f, 0.f, 0.f, 0.f};
    f32x4 acc01 = {0.f, 0.f, 0.f, 0.f};
    f32x4 acc10 = {0.f, 0.f, 0.f, 0.f};
    f32x4 acc11 = {0.f, 0.f, 0.f, 0.f};
    #pragma unroll
    for (int ks = 0; ks < 2; ks++) {
        int ko = ks * 32 + lgrp * 8;
        bf16x8 a0 = *(const bf16x8*)&Xb[wr + lrow][ko];
        bf16x8 a1 = *(const bf16x8*)&Xb[wr + 16 + lrow][ko];
        bf16x8 b0 = *(const bf16x8*)&Wt[wc + lrow][ko];
        bf16x8 b1 = *(const bf16x8*)&Wt[wc + 16 + lrow][ko];
        acc00 = __builtin_amdgcn_mfma_f32_16x16x32_bf16(a0, b0, acc00, 0, 0, 0);
        acc01 = __builtin_amdgcn_mfma_f32_16x16x32_bf16(a0, b1, acc01, 0, 0, 0);
        acc10 = __builtin_amdgcn_mfma_f32_16x16x32_bf16(a1, b0, acc10, 0, 0, 0);
        acc11 = __builtin_amdgcn_mfma_f32_16x16x32_bf16(a1, b1, acc11, 0, 0, 0);
    }

    // epilogue: D col=lane&15, row=(lane>>4)*4+reg
    float bias0 = bias[chunk * 64 + wc + lrow];         // frag col n=0
    float bias1 = bias[chunk * 64 + wc + 16 + lrow];    // frag col n=1
    float* qbase = nullptr;
    unsigned short* usbase = nullptr;
    int noff;
    if (chunk == 0) {
        qbase = Q; noff = type ? NP : 0;
    } else if (type == 0) {
        usbase = (chunk <= 2) ? Ksb : Vsb;
        noff = ((chunk == 1 || chunk == 3) ? NA : NA + NP);
    } else {
        usbase = (chunk == 1) ? Ksb : Vsb;
        noff = 0;
    }
    #pragma unroll
    for (int mi = 0; mi < 2; mi++) {
        const f32x4 accn0 = mi ? acc10 : acc00;
        const f32x4 accn1 = mi ? acc11 : acc01;
        int rbase = wr + mi * 16 + lgrp * 4;
        #pragma unroll
        for (int r = 0; r < 4; r++) {
            int n = nb + rbase + r;
            if (n >= N) continue;
            float v0 = accn0[r] + bias0;
            float v1 = accn1[r] + bias1;
            int c0 = wc + lrow, c1 = wc + 16 + lrow;
            if (qbase) {
                qbase[(size_t)(noff + n) * HID + c0] = v0;
                qbase[(size_t)(noff + n) * HID + c1] = v1;
            } else {
                usbase[(size_t)(noff + n) * HID + c0] = f2bf(v0);
                usbase[(size_t)(noff + n) * HID + c1] = f2bf(v1);
            }
        }
    }
}

// ---------------- fused attention: one wave per dst node, online softmax ----------------
__global__ __launch_bounds__(256) void attn_kernel(
    const float* Q, const unsigned short* __restrict__ Ksb,
    const unsigned short* __restrict__ Vsb,
    const float* __restrict__ p_rel, const int* __restrict__ row_ptr,
    const int* __restrict__ edge_src, float* attnout)
{
    int wid = threadIdx.x >> 6, lane = threadIdx.x & 63;
    int n = blockIdx.x * 4 + wid;
    if (n >= NTOT) return;
    int h = lane >> 4;
    float q = Q[(size_t)n * HID + lane];
    float pr0 = p_rel[h], pr1 = p_rel[4 + h], pr2 = p_rel[8 + h];
    int beg = row_ptr[n], end = row_ptr[n + 1];
    float m = -INFINITY, s = 0.0f, acc = 0.0f;
    int e = beg;
    for (; e + 1 < end; e += 2) {
        int s0 = edge_src[e], s1 = edge_src[e + 1];
        size_t r0 = (size_t)s0 * HID + lane, r1 = (size_t)s1 * HID + lane;
        float k0 = bf2f(Ksb[r0]), v0 = bf2f(Vsb[r0]);
        float k1 = bf2f(Ksb[r1]), v1 = bf2f(Vsb[r1]);
        float p0 = q * k0, p1 = q * k1;
        p0 += __shfl_xor(p0, 1, 64);  p1 += __shfl_xor(p1, 1, 64);
        p0 += __shfl_xor(p0, 2, 64);  p1 += __shfl_xor(p1, 2, 64);
        p0 += __shfl_xor(p0, 4, 64);  p1 += __shfl_xor(p1, 4, 64);
        p0 += __shfl_xor(p0, 8, 64);  p1 += __shfl_xor(p1, 8, 64);
        float a0 = p0 * ((s0 < NA) ? pr0 : ((s0 < NA + NP) ? pr1 : pr2)) * 0.25f;
        float a1 = p1 * ((s1 < NA) ? pr0 : ((s1 < NA + NP) ? pr1 : pr2)) * 0.25f;
        float mn = fmaxf(m, fmaxf(a0, a1));
        float cc = expf(m - mn);
        float e0 = expf(a0 - mn), e1 = expf(a1 - mn);
        s   = s * cc + e0 + e1;
        acc = acc * cc + e0 * v0 + e1 * v1;
        m = mn;
    }
    if (e < end) {
        int s0 = edge_src[e];
        size_t r0 = (size_t)s0 * HID + lane;
        float k0 = bf2f(Ksb[r0]), v0 = bf2f(Vsb[r0]);
        float p0 = q * k0;
        p0 += __shfl_xor(p0, 1, 64);
        p0 += __shfl_xor(p0, 2, 64);
        p0 += __shfl_xor(p0, 4, 64);
        p0 += __shfl_xor(p0, 8, 64);
        float a0 = p0 * ((s0 < NA) ? pr0 : ((s0 < NA + NP) ? pr1 : pr2)) * 0.25f;
        float mn = fmaxf(m, a0);
        float cc = expf(m - mn);
        float e0 = expf(a0 - mn);
        s   = s * cc + e0;
        acc = acc * cc + e0 * v0;
    }
    attnout[(size_t)n * HID + lane] = acc / (s + 1e-16f);
}

// ---------------- hout GEMM + skip + LN + gelu fused, paper+author merged ----------------
// Epilogue m-loop is #pragma unroll 1: full unroll kept 4 rows of LN state live
// over acc[4][4] -> 256 VGPR spill (R5: 192us, 94MB scratch writes).
__global__ __launch_bounds__(256) void gemm_hout(
    const float* __restrict__ attnout, const float* __restrict__ Whout,
    const float* __restrict__ bhout, const float* __restrict__ skip_p,
    const float* __restrict__ lng, const float* __restrict__ lnb,
    float* __restrict__ hbuf)
{
    __shared__ float xs[64][68];
    __shared__ float wsb[64][68];
    int b = blockIdx.x, tid = threadIdx.x;
    int type = (b >= PT);
    int tile = type ? (b - PT) : b;
    int N = type ? NA : NP;
    size_t base_off = type ? (size_t)NP * HID : 0;
    const float* X = attnout + base_off;
    const float* W = Whout + (size_t)type * HID * HID;
    const float* bias = bhout + type * HID;
    float* H = hbuf + base_off;
    int nb = tile * 64;

    #pragma unroll
    for (int r = 0; r < 4; r++) {
        int f = tid + 256 * r;
        int row = f >> 4, col = (f & 15) * 4;
        int n = nb + row;
        float4 v = (n < N) ? *(const float4*)(X + (size_t)n * HID + col)
                           : make_float4(0.f, 0.f, 0.f, 0.f);
        v.x = gelu_exact(v.x); v.y = gelu_exact(v.y);
        v.z = gelu_exact(v.z); v.w = gelu_exact(v.w);
        *(float4*)&xs[row][col] = v;
        *(float4*)&wsb[row][col] = *(const float4*)(W + (size_t)row * HID + col);
    }
    __syncthreads();
    const int tr = tid >> 4, tc = tid & 15;
    const int tr4 = tr * 4, tcj = tc * 4;
    float acc[4][4] = {};
    GEMM_CORE_64(acc, xs, wsb, 0)

    float b0 = bias[tcj], b1 = bias[tcj+1], b2 = bias[tcj+2], b3 = bias[tcj+3];
    float a = 1.0f / (1.0f + expf(-skip_p[type]));
    float oma = 1.0f - a;
    float g0 = lng[type*HID+tcj], g1 = lng[type*HID+tcj+1],
          g2 = lng[type*HID+tcj+2], g3 = lng[type*HID+tcj+3];
    float l0 = lnb[type*HID+tcj], l1 = lnb[type*HID+tcj+1],
          l2 = lnb[type*HID+tcj+2], l3 = lnb[type*HID+tcj+3];
    #pragma unroll 1
    for (int m = 0; m < 4; m++) {
        int n = nb + tr4 + m;
        float v0 = 0.f, v1 = 0.f, v2 = 0.f, v3 = 0.f;
        if (n < N) {
            const float* hp = H + (size_t)n * HID + tcj;
            v0 = a * (acc[m][0] + b0) + oma * hp[0];
            v1 = a * (acc[m][1] + b1) + oma * hp[1];
            v2 = a * (acc[m][2] + b2) + oma * hp[2];
            v3 = a * (acc[m][3] + b3) + oma * hp[3];
        }
        // layernorm across the row (16 lanes x 4 vals)
        float sum = v0 + v1 + v2 + v3;
        sum += __shfl_xor(sum, 1, 64); sum += __shfl_xor(sum, 2, 64);
        sum += __shfl_xor(sum, 4, 64); sum += __shfl_xor(sum, 8, 64);
        float mean = sum * (1.0f / 64.0f);
        float d0 = v0 - mean, d1 = v1 - mean, d2 = v2 - mean, d3 = v3 - mean;
        float sq = d0*d0 + d1*d1 + d2*d2 + d3*d3;
        sq += __shfl_xor(sq, 1, 64); sq += __shfl_xor(sq, 2, 64);
        sq += __shfl_xor(sq, 4, 64); sq += __shfl_xor(sq, 8, 64);
        float rstd = rsqrtf(sq * (1.0f / 64.0f) + 1e-5f);
        if (n < N) {
            float* hp = H + (size_t)n * HID + tcj;
            hp[0] = gelu_exact(d0 * rstd * g0 + l0);
            hp[1] = gelu_exact(d1 * rstd * g1 + l1);
            hp[2] = gelu_exact(d2 * rstd * g2 + l2);
            hp[3] = gelu_exact(d3 * rstd * g3 + l3);
        }
    }
}

// ---------------- final linear, paper+author merged ----------------
__global__ __launch_bounds__(256) void gemm_out(
    const float* __restrict__ hbuf, const float* __restrict__ W_out,
    const float* __restrict__ b_out, float* __restrict__ out)
{
    __shared__ float xs[64][68];
    __shared__ float wsb[64][68];
    int b = blockIdx.x, tid = threadIdx.x;
    int type = (b >= PT);
    int tile = type ? (b - PT) : b;
    int N = type ? NA : NP;
    size_t base_off = type ? (size_t)NP * HID : 0;
    const float* X = hbuf + base_off;
    const float* W = W_out + (size_t)type * HID * HID;
    const float* bias = b_out + type * HID;
    float* O = out + base_off;
    int nb = tile * 64;

    #pragma unroll
    for (int r = 0; r < 4; r++) {
        int f = tid + 256 * r;
        int row = f >> 4, col = (f & 15) * 4;
        int n = nb + row;
        float4 v = (n < N) ? *(const float4*)(X + (size_t)n * HID + col)
                           : make_float4(0.f, 0.f, 0.f, 0.f);
        *(float4*)&xs[row][col] = v;
        *(float4*)&wsb[row][col] = *(const float4*)(W + (size_t)row * HID + col);
    }
    __syncthreads();
    const int tr = tid >> 4, tc = tid & 15;
    const int tr4 = tr * 4, tcj = tc * 4;
    float acc[4][4] = {};
    GEMM_CORE_64(acc, xs, wsb, 0)

    float b0 = bias[tcj], b1 = bias[tcj+1], b2 = bias[tcj+2], b3 = bias[tcj+3];
    #pragma unroll
    for (int m = 0; m < 4; m++) {
        int n = nb + tr4 + m;
        if (n < N) {
            float* p = O + (size_t)n * HID + tcj;
            p[0] = acc[m][0] + b0; p[1] = acc[m][1] + b1;
            p[2] = acc[m][2] + b2; p[3] = acc[m][3] + b3;
        }
    }
}

extern "C" void kernel_launch(void* const* d_in, const int* in_sizes, int n_in,
                              void* d_out, int out_size, void* d_ws, size_t ws_size,
                              hipStream_t stream) {
    const float* x_paper  = (const float*)d_in[0];
    const float* x_author = (const float*)d_in[1];
    const int*   ei_ap    = (const int*)d_in[2];
    const int*   ei_pa    = (const int*)d_in[3];
    const int*   ei_pp    = (const int*)d_in[4];
    const float* W_in     = (const float*)d_in[5];
    const float* b_in     = (const float*)d_in[6];
    const float* W_kqv    = (const float*)d_in[7];
    const float* b_kqv    = (const float*)d_in[8];
    const float* W_krel   = (const float*)d_in[9];
    const float* W_vrel   = (const float*)d_in[10];
    const float* p_rel    = (const float*)d_in[11];
    const float* W_hout   = (const float*)d_in[12];
    const float* b_hout   = (const float*)d_in[13];
    const float* skip     = (const float*)d_in[14];
    const float* ln_g     = (const float*)d_in[15];
    const float* ln_b     = (const float*)d_in[16];
    const float* W_out    = (const float*)d_in[17];
    const float* b_out    = (const float*)d_in[18];
    float* out            = (float*)d_out;

    // ---- workspace layout (~146 MB) ----
    float* ws   = (float*)d_ws;
    float* hbuf = ws;                                   // NTOT*64 f32
    float* Q    = hbuf + (size_t)NTOT * HID;            // NTOT*64 f32 (attn out aliases Q)
    unsigned short* Ksb = (unsigned short*)(Q + (size_t)NTOT * HID);  // NSRC*64 bf16
    unsigned short* Vsb = Ksb + (size_t)NSRC * HID;                   // NSRC*64 bf16
    float* Wfp  = (float*)(Vsb + (size_t)NSRC * HID);   // 64*320
    float* bfp  = Wfp  + 64 * JP;                       // 320
    float* Wfa  = bfp  + JP;                            // 64*192
    float* bfa  = Wfa  + 64 * JA;                       // 192
    int* cnt      = (int*)(bfa + JA);                   // NTOT
    int* row_ptr  = cnt + NTOT;                         // NTOT+1 (pad 16)
    int* cursor   = row_ptr + NTOT + 16;                // NTOT
    int* edge_src = cursor + NTOT;                      // ETOT
    int* csum     = edge_src + ETOT;                    // 1024
    int* coff     = csum + 1024;                        // 1024

    dim3 blk(256);
    const int EB = (ETOT + 255) / 256;

    // ---- CSR build (edges are layer-invariant) ----
    zero_int_kernel<<<256, blk, 0, stream>>>(cnt, NTOT);
    csr_count_kernel<<<EB, blk, 0, stream>>>(ei_ap, ei_pa, ei_pp, cnt);
    scan_chunk_sums<<<NCH, blk, 0, stream>>>(cnt, csum);
    scan_offsets<<<1, 1024, 0, stream>>>(csum, coff, NCH);
    scan_final<<<NCH, blk, 0, stream>>>(cnt, coff, row_ptr, cursor);
    csr_fill_kernel<<<EB, blk, 0, stream>>>(ei_ap, ei_pa, ei_pp, cursor, edge_src);

    // ---- input projection ----
    gemm_in<<<PT + AT, blk, 0, stream>>>(x_paper, x_author, W_in, b_in, hbuf);

    for (int l = 0; l < LAYERS; l++) {
        fuse_weights_kernel<<<(65 * JP + 65 * JA + 255) / 256, blk, 0, stream>>>(
            W_kqv + (size_t)l * 2 * HID * KQV, b_kqv + (size_t)l * 2 * KQV,
            W_krel + (size_t)l * 3 * NH * HD * HD, W_vrel + (size_t)l * 3 * NH * HD * HD,
            Wfp, bfp, Wfa, bfa);
        gemm_kqv<<<PT * 5 + AT * 3, blk, 0, stream>>>(
            hbuf, Wfp, bfp, Wfa, bfa, Q, Ksb, Vsb);
        attn_kernel<<<(NTOT + 3) / 4, blk, 0, stream>>>(
            Q, Ksb, Vsb, p_rel + l * 3 * NH, row_ptr, edge_src, Q);
        gemm_hout<<<PT + AT, blk, 0, stream>>>(
            Q, W_hout + (size_t)l * 2 * HID * HID, b_hout + l * 2 * HID,
            skip + l * 2, ln_g + l * 2 * HID, ln_b + l * 2 * HID, hbuf);
    }

    gemm_out<<<PT + AT, blk, 0, stream>>>(hbuf, W_out, b_out, out);
}

// Round 8
// 540.546 us; speedup vs baseline: 3.4662x; 1.2390x over previous
//
#include <hip/hip_runtime.h>
#include <hip/hip_bf16.h>

// ---- problem constants (match reference) ----
#define NP 100000
#define NA 50000
#define NTOT 150000          // NP+NA
#define E0 300000
#define E1 300000
#define E2 200000
#define ETOT 800000
#define NH 4
#define HD 16
#define HID 64
#define IN_DIM 128
#define KQV 192
#define LAYERS 2
#define NSRC 250000          // NA + 2*NP
#define JP 320               // fused paper cols: q | k_et1 | k_et2 | v_et1 | v_et2
#define JA 192               // fused author cols: q | k_et0 | v_et0
#define NCH 586              // ceil(NTOT/256)
#define PT 1563              // ceil(NP/64)
#define AT 782               // ceil(NA/64)

typedef __attribute__((ext_vector_type(8))) short bf16x8;   // 8 bf16 (4 VGPRs)
typedef __attribute__((ext_vector_type(4))) float f32x4;    // MFMA C/D

__device__ __forceinline__ float gelu_exact(float x) {
    return 0.5f * x * (1.0f + erff(x * 0.7071067811865475f));
}
// f32 -> bf16 bits, round-to-nearest-even (finite values)
__device__ __forceinline__ unsigned short f2bf(float f) {
    unsigned u = __float_as_uint(f);
    return (unsigned short)((u + 0x7fffu + ((u >> 16) & 1u)) >> 16);
}
__device__ __forceinline__ float bf2f(unsigned short b) {
    return __uint_as_float((unsigned)b << 16);
}

// decode global edge id -> (src in Ks/Vs space, dst in node space)
__device__ __forceinline__ void edge_decode(int e, const int* __restrict__ ei_ap,
                                            const int* __restrict__ ei_pa,
                                            const int* __restrict__ ei_pp,
                                            int& src, int& dst) {
    if (e < E0)            { src = ei_ap[e];                 dst = ei_ap[E0 + e]; }
    else if (e < E0 + E1)  { int le = e - E0;
                             src = NA + ei_pa[le];           dst = NP + ei_pa[E1 + le]; }
    else                   { int le = e - E0 - E1;
                             src = NA + NP + ei_pp[le];      dst = ei_pp[E2 + le]; }
}

// ---------------- CSR build ----------------
__global__ void zero_int_kernel(int* __restrict__ p, int n) {
    int i = blockIdx.x * blockDim.x + threadIdx.x;
    int st = gridDim.x * blockDim.x;
    for (int j = i; j < n; j += st) p[j] = 0;
}

__global__ void csr_count_kernel(const int* __restrict__ ei_ap, const int* __restrict__ ei_pa,
                                 const int* __restrict__ ei_pp, int* __restrict__ cnt) {
    int e = blockIdx.x * 256 + threadIdx.x;
    if (e >= ETOT) return;
    int src, dst; edge_decode(e, ei_ap, ei_pa, ei_pp, src, dst);
    atomicAdd(&cnt[dst], 1);
}

__global__ void scan_chunk_sums(const int* __restrict__ cnt, int* __restrict__ csum) {
    __shared__ int sd[256];
    int c = blockIdx.x, t = threadIdx.x;
    int i = c * 256 + t;
    sd[t] = (i < NTOT) ? cnt[i] : 0;
    __syncthreads();
    for (int o = 128; o > 0; o >>= 1) { if (t < o) sd[t] += sd[t + o]; __syncthreads(); }
    if (t == 0) csum[c] = sd[0];
}

__global__ void scan_offsets(const int* __restrict__ csum, int* __restrict__ coff, int nch) {
    __shared__ int sd[1024];
    int t = threadIdx.x;
    int v = (t < nch) ? csum[t] : 0;
    sd[t] = v;
    __syncthreads();
    for (int o = 1; o < 1024; o <<= 1) {
        int x = (t >= o) ? sd[t - o] : 0;
        __syncthreads();
        sd[t] += x;
        __syncthreads();
    }
    if (t < nch) coff[t] = sd[t] - v;   // exclusive
}

__global__ void scan_final(const int* __restrict__ cnt, const int* __restrict__ coff,
                           int* __restrict__ row_ptr, int* __restrict__ cursor) {
    __shared__ int sd[256];
    int c = blockIdx.x, t = threadIdx.x, i = c * 256 + t;
    int v = (i < NTOT) ? cnt[i] : 0;
    sd[t] = v;
    __syncthreads();
    for (int o = 1; o < 256; o <<= 1) {
        int x = (t >= o) ? sd[t - o] : 0;
        __syncthreads();
        sd[t] += x;
        __syncthreads();
    }
    if (i < NTOT) { int ex = coff[c] + sd[t] - v; row_ptr[i] = ex; cursor[i] = ex; }
    if (i == 0) row_ptr[NTOT] = ETOT;
}

__global__ void csr_fill_kernel(const int* __restrict__ ei_ap, const int* __restrict__ ei_pa,
                                const int* __restrict__ ei_pp, int* __restrict__ cursor,
                                int* __restrict__ edge_src) {
    int e = blockIdx.x * 256 + threadIdx.x;
    if (e >= ETOT) return;
    int src, dst; edge_decode(e, ei_ap, ei_pa, ei_pp, src, dst);
    int pos = atomicAdd(&cursor[dst], 1);
    edge_src[pos] = src;
}

// ---------------- fused-weight build (per layer) ----------------
__global__ void fuse_weights_kernel(const float* __restrict__ Wkqv, const float* __restrict__ bkqv,
                                    const float* __restrict__ Wkrel, const float* __restrict__ Wvrel,
                                    float* __restrict__ Wfp, float* __restrict__ bfp,
                                    float* __restrict__ Wfa, float* __restrict__ bfa) {
    int idx = blockIdx.x * 256 + threadIdx.x;
    int type, i, j;
    if (idx < 65 * JP) { type = 0; i = idx / JP; j = idx % JP; }
    else {
        int r = idx - 65 * JP;
        if (r >= 65 * JA) return;
        type = 1; i = r / JA; j = r % JA;
    }
    int c = j >> 6, jj = j & 63, h = jj >> 4, e = jj & 15;
    const float* Wk = Wkqv + (size_t)type * HID * KQV;
    const float* bk = bkqv + type * KQV;
    float val;
    if (c == 0) {
        val = (i < 64) ? Wk[i * KQV + 64 + jj] : bk[64 + jj];
    } else {
        int et, isV;
        if (type == 0) { et = (c == 1 || c == 3) ? 1 : 2; isV = (c >= 3); }
        else           { et = 0; isV = (c == 2); }
        const float* Wr = (isV ? Wvrel : Wkrel) + (size_t)(et * NH + h) * HD * HD;
        int sb = (isV ? 128 : 0) + h * HD;
        val = 0.0f;
        #pragma unroll
        for (int d = 0; d < HD; d++) {
            float a = (i < 64) ? Wk[i * KQV + sb + d] : bk[sb + d];
            val += a * Wr[d * HD + e];
        }
    }
    if (i < 64) (type ? Wfa : Wfp)[i * (type ? JA : JP) + j] = val;
    else        (type ? bfa : bfp)[j] = val;
}

// ---------------- shared GEMM core pieces (f32 VALU, used by gemm_hout) ----------------
#define GEMM_CORE_64(ACCVAR, XS, WS, KOFF)                                         \
    {                                                                              \
        _Pragma("unroll")                                                          \
        for (int i = 0; i < 64; i += 4) {                                          \
            float4 A0 = *(const float4*)&XS[tr4 + 0][KOFF + i];                    \
            float4 A1 = *(const float4*)&XS[tr4 + 1][KOFF + i];                    \
            float4 A2 = *(const float4*)&XS[tr4 + 2][KOFF + i];                    \
            float4 A3 = *(const float4*)&XS[tr4 + 3][KOFF + i];                    \
            float4 W0 = *(const float4*)&WS[i + 0][tcj];                           \
            float4 W1 = *(const float4*)&WS[i + 1][tcj];                           \
            float4 W2 = *(const float4*)&WS[i + 2][tcj];                           \
            float4 W3 = *(const float4*)&WS[i + 3][tcj];                           \
            ACCVAR[0][0] += A0.x*W0.x + A0.y*W1.x + A0.z*W2.x + A0.w*W3.x;         \
            ACCVAR[0][1] += A0.x*W0.y + A0.y*W1.y + A0.z*W2.y + A0.w*W3.y;         \
            ACCVAR[0][2] += A0.x*W0.z + A0.y*W1.z + A0.z*W2.z + A0.w*W3.z;         \
            ACCVAR[0][3] += A0.x*W0.w + A0.y*W1.w + A0.z*W2.w + A0.w*W3.w;         \
            ACCVAR[1][0] += A1.x*W0.x + A1.y*W1.x + A1.z*W2.x + A1.w*W3.x;         \
            ACCVAR[1][1] += A1.x*W0.y + A1.y*W1.y + A1.z*W2.y + A1.w*W3.y;         \
            ACCVAR[1][2] += A1.x*W0.z + A1.y*W1.z + A1.z*W2.z + A1.w*W3.z;         \
            ACCVAR[1][3] += A1.x*W0.w + A1.y*W1.w + A1.z*W2.w + A1.w*W3.w;         \
            ACCVAR[2][0] += A2.x*W0.x + A2.y*W1.x + A2.z*W2.x + A2.w*W3.x;         \
            ACCVAR[2][1] += A2.x*W0.y + A2.y*W1.y + A2.z*W2.y + A2.w*W3.y;         \
            ACCVAR[2][2] += A2.x*W0.z + A2.y*W1.z + A2.z*W2.z + A2.w*W3.z;         \
            ACCVAR[2][3] += A2.x*W0.w + A2.y*W1.w + A2.z*W2.w + A2.w*W3.w;         \
            ACCVAR[3][0] += A3.x*W0.x + A3.y*W1.x + A3.z*W2.x + A3.w*W3.x;         \
            ACCVAR[3][1] += A3.x*W0.y + A3.y*W1.y + A3.z*W2.y + A3.w*W3.y;         \
            ACCVAR[3][2] += A3.x*W0.z + A3.y*W1.z + A3.z*W2.z + A3.w*W3.z;         \
            ACCVAR[3][3] += A3.x*W0.w + A3.y*W1.w + A3.z*W2.w + A3.w*W3.w;         \
        }                                                                          \
    }

// ---------------- input projection via MFMA bf16 (K=128), paper+author merged ----------------
// Same verified MFMA structure as gemm_kqv: 4 waves x 32x32 quadrant, 2x2 frags,
// 4 K-steps of mfma_f32_16x16x32_bf16. Replaces the latency-bound f32 core
// (R7: 128us @ 600GB/s, 10.5% occupancy).
__global__ __launch_bounds__(256) void gemm_in(
    const float* __restrict__ xp, const float* __restrict__ xa,
    const float* __restrict__ W_in, const float* __restrict__ b_in,
    float* __restrict__ hbuf)
{
    __shared__ unsigned short Xb[64][136];   // 272B rows (16B-aligned)
    __shared__ unsigned short Wt[64][136];   // Wt[col][k]
    int b = blockIdx.x, tid = threadIdx.x;
    int type = (b >= PT);
    int tile = type ? (b - PT) : b;
    int N = type ? NA : NP;
    const float* X = type ? xa : xp;
    const float* W = W_in + (size_t)type * IN_DIM * HID;
    const float* bias = b_in + type * HID;
    float* H = hbuf + (type ? (size_t)NP * HID : 0);
    int nb = tile * 64;

    // stage X[64][128] -> bf16 (4 threads/row, 32 cols each)
    {
        int row = tid >> 2, c0 = (tid & 3) * 32;
        int n = nb + row;
        if (n < N) {
            const float* xr = X + (size_t)n * IN_DIM + c0;
            #pragma unroll
            for (int i = 0; i < 32; i += 4) {
                float4 v = *(const float4*)(xr + i);
                *(ushort4*)&Xb[row][c0 + i] =
                    make_ushort4(f2bf(v.x), f2bf(v.y), f2bf(v.z), f2bf(v.w));
            }
        } else {
            #pragma unroll
            for (int i = 0; i < 32; i += 4)
                *(ushort4*)&Xb[row][c0 + i] = make_ushort4(0, 0, 0, 0);
        }
    }
    // stage W transposed: Wt[col][k] = W[k][col], k 0..127, col 0..63
    #pragma unroll
    for (int it = 0; it < 8; it++) {
        int idx = it * 256 + tid;            // 0..2047 = 128k x 16 col-groups
        int k = idx & 127, c = (idx >> 7) * 4;
        float4 v = *(const float4*)(W + (size_t)k * HID + c);
        Wt[c + 0][k] = f2bf(v.x); Wt[c + 1][k] = f2bf(v.y);
        Wt[c + 2][k] = f2bf(v.z); Wt[c + 3][k] = f2bf(v.w);
    }
    __syncthreads();

    int w = tid >> 6, lane = tid & 63;
    int wr = (w >> 1) * 32, wc = (w & 1) * 32;
    int lrow = lane & 15, lgrp = lane >> 4;

    f32x4 acc00 = {0.f, 0.f, 0.f, 0.f};
    f32x4 acc01 = {0.f, 0.f, 0.f, 0.f};
    f32x4 acc10 = {0.f, 0.f, 0.f, 0.f};
    f32x4 acc11 = {0.f, 0.f, 0.f, 0.f};
    #pragma unroll
    for (int ks = 0; ks < 4; ks++) {
        int ko = ks * 32 + lgrp * 8;
        bf16x8 a0 = *(const bf16x8*)&Xb[wr + lrow][ko];
        bf16x8 a1 = *(const bf16x8*)&Xb[wr + 16 + lrow][ko];
        bf16x8 b0 = *(const bf16x8*)&Wt[wc + lrow][ko];
        bf16x8 b1 = *(const bf16x8*)&Wt[wc + 16 + lrow][ko];
        acc00 = __builtin_amdgcn_mfma_f32_16x16x32_bf16(a0, b0, acc00, 0, 0, 0);
        acc01 = __builtin_amdgcn_mfma_f32_16x16x32_bf16(a0, b1, acc01, 0, 0, 0);
        acc10 = __builtin_amdgcn_mfma_f32_16x16x32_bf16(a1, b0, acc10, 0, 0, 0);
        acc11 = __builtin_amdgcn_mfma_f32_16x16x32_bf16(a1, b1, acc11, 0, 0, 0);
    }

    float bias0 = bias[wc + lrow], bias1 = bias[wc + 16 + lrow];
    #pragma unroll
    for (int mi = 0; mi < 2; mi++) {
        const f32x4 accn0 = mi ? acc10 : acc00;
        const f32x4 accn1 = mi ? acc11 : acc01;
        int rbase = wr + mi * 16 + lgrp * 4;
        #pragma unroll
        for (int r = 0; r < 4; r++) {
            int n = nb + rbase + r;
            if (n >= N) continue;
            H[(size_t)n * HID + wc + lrow]      = accn0[r] + bias0;
            H[(size_t)n * HID + wc + 16 + lrow] = accn1[r] + bias1;
        }
    }
}

// ---------------- KQV GEMM via MFMA bf16: one (row-tile, chunk) per block ----------------
// Fragment layouts (guide §3, m89-verified):
//   A: row=lane&15, k=(lane>>4)*8+j (one ds_read_b128)
//   B: col=lane&15, k=(lane>>4)*8+j (from transposed Wt)
//   D: col=lane&15, row=(lane>>4)*4+reg
// paper chunks: 0->Q f32 | 1->Ks@NA | 2->Ks@NA+NP | 3->Vs@NA | 4->Vs@NA+NP (bf16)
// author chunks: 0->Q@NP | 1->Ks@0 | 2->Vs@0
__global__ __launch_bounds__(256) void gemm_kqv(
    const float* __restrict__ hbuf,
    const float* __restrict__ Wfp, const float* __restrict__ bfp,
    const float* __restrict__ Wfa, const float* __restrict__ bfa,
    float* __restrict__ Q, unsigned short* __restrict__ Ksb, unsigned short* __restrict__ Vsb)
{
    __shared__ unsigned short Xb[64][72];   // stride 72 shorts = 144B (16B-aligned rows)
    __shared__ unsigned short Wt[64][72];   // Wt[col][k]
    int b = blockIdx.x, tid = threadIdx.x;
    int type, tile, chunk;
    if (b < PT * 5) { type = 0; chunk = b / PT; tile = b % PT; }
    else            { int ab = b - PT * 5; type = 1; chunk = ab / AT; tile = ab % AT; }
    int N = type ? NA : NP;
    const float* X = hbuf + (type ? (size_t)NP * HID : 0);
    const float* W = type ? Wfa : Wfp;
    const float* bias = type ? bfa : bfp;
    int ldw = type ? JA : JP;
    int nb = tile * 64;

    // stage X tile as bf16 (4 threads/row, 16 cols each)
    {
        int row = tid >> 2, c0 = (tid & 3) * 16;
        int n = nb + row;
        unsigned short tmp[16];
        if (n < N) {
            const float* xr = X + (size_t)n * HID + c0;
            #pragma unroll
            for (int i = 0; i < 16; i += 4) {
                float4 v = *(const float4*)(xr + i);
                tmp[i] = f2bf(v.x); tmp[i+1] = f2bf(v.y);
                tmp[i+2] = f2bf(v.z); tmp[i+3] = f2bf(v.w);
            }
        } else {
            #pragma unroll
            for (int i = 0; i < 16; i++) tmp[i] = 0;
        }
        #pragma unroll
        for (int i = 0; i < 16; i += 4)
            *(ushort4*)&Xb[row][c0 + i] = make_ushort4(tmp[i], tmp[i+1], tmp[i+2], tmp[i+3]);
    }
    // stage W transposed as bf16: Wt[col][k] = W[k][chunk*64+col]
    #pragma unroll
    for (int it = 0; it < 4; it++) {
        int idx = it * 256 + tid;           // 0..1023
        int k = idx & 63, c = (idx >> 6) * 4;
        float4 v = *(const float4*)(W + (size_t)k * ldw + chunk * 64 + c);
        Wt[c + 0][k] = f2bf(v.x); Wt[c + 1][k] = f2bf(v.y);
        Wt[c + 2][k] = f2bf(v.z); Wt[c + 3][k] = f2bf(v.w);
    }
    __syncthreads();

    int w = tid >> 6, lane = tid & 63;
    int wr = (w >> 1) * 32, wc = (w & 1) * 32;
    int lrow = lane & 15, lgrp = lane >> 4;

    f32x4 acc00 = {0.f, 0.f, 0.f, 0.f};
    f32x4 acc01 = {0.f, 0.f, 0.f, 0.f};
    f32x4 acc10 = {0.f, 0.f, 0.f, 0.f};
    f32x4 acc11 = {0.f, 0.f, 0.f, 0.f};
    #pragma unroll
    for (int ks = 0; ks < 2; ks++) {
        int ko = ks * 32 + lgrp * 8;
        bf16x8 a0 = *(const bf16x8*)&Xb[wr + lrow][ko];
        bf16x8 a1 = *(const bf16x8*)&Xb[wr + 16 + lrow][ko];
        bf16x8 b0 = *(const bf16x8*)&Wt[wc + lrow][ko];
        bf16x8 b1 = *(const bf16x8*)&Wt[wc + 16 + lrow][ko];
        acc00 = __builtin_amdgcn_mfma_f32_16x16x32_bf16(a0, b0, acc00, 0, 0, 0);
        acc01 = __builtin_amdgcn_mfma_f32_16x16x32_bf16(a0, b1, acc01, 0, 0, 0);
        acc10 = __builtin_amdgcn_mfma_f32_16x16x32_bf16(a1, b0, acc10, 0, 0, 0);
        acc11 = __builtin_amdgcn_mfma_f32_16x16x32_bf16(a1, b1, acc11, 0, 0, 0);
    }

    // epilogue: D col=lane&15, row=(lane>>4)*4+reg
    float bias0 = bias[chunk * 64 + wc + lrow];         // frag col n=0
    float bias1 = bias[chunk * 64 + wc + 16 + lrow];    // frag col n=1
    float* qbase = nullptr;
    unsigned short* usbase = nullptr;
    int noff;
    if (chunk == 0) {
        qbase = Q; noff = type ? NP : 0;
    } else if (type == 0) {
        usbase = (chunk <= 2) ? Ksb : Vsb;
        noff = ((chunk == 1 || chunk == 3) ? NA : NA + NP);
    } else {
        usbase = (chunk == 1) ? Ksb : Vsb;
        noff = 0;
    }
    #pragma unroll
    for (int mi = 0; mi < 2; mi++) {
        const f32x4 accn0 = mi ? acc10 : acc00;
        const f32x4 accn1 = mi ? acc11 : acc01;
        int rbase = wr + mi * 16 + lgrp * 4;
        #pragma unroll
        for (int r = 0; r < 4; r++) {
            int n = nb + rbase + r;
            if (n >= N) continue;
            float v0 = accn0[r] + bias0;
            float v1 = accn1[r] + bias1;
            int c0 = wc + lrow, c1 = wc + 16 + lrow;
            if (qbase) {
                qbase[(size_t)(noff + n) * HID + c0] = v0;
                qbase[(size_t)(noff + n) * HID + c1] = v1;
            } else {
                usbase[(size_t)(noff + n) * HID + c0] = f2bf(v0);
                usbase[(size_t)(noff + n) * HID + c1] = f2bf(v1);
            }
        }
    }
}

// ---------------- fused attention: one wave per dst node, online softmax ----------------
__global__ __launch_bounds__(256) void attn_kernel(
    const float* Q, const unsigned short* __restrict__ Ksb,
    const unsigned short* __restrict__ Vsb,
    const float* __restrict__ p_rel, const int* __restrict__ row_ptr,
    const int* __restrict__ edge_src, float* attnout)
{
    int wid = threadIdx.x >> 6, lane = threadIdx.x & 63;
    int n = blockIdx.x * 4 + wid;
    if (n >= NTOT) return;
    int h = lane >> 4;
    float q = Q[(size_t)n * HID + lane];
    float pr0 = p_rel[h], pr1 = p_rel[4 + h], pr2 = p_rel[8 + h];
    int beg = row_ptr[n], end = row_ptr[n + 1];
    float m = -INFINITY, s = 0.0f, acc = 0.0f;
    int e = beg;
    for (; e + 1 < end; e += 2) {
        int s0 = edge_src[e], s1 = edge_src[e + 1];
        size_t r0 = (size_t)s0 * HID + lane, r1 = (size_t)s1 * HID + lane;
        float k0 = bf2f(Ksb[r0]), v0 = bf2f(Vsb[r0]);
        float k1 = bf2f(Ksb[r1]), v1 = bf2f(Vsb[r1]);
        float p0 = q * k0, p1 = q * k1;
        p0 += __shfl_xor(p0, 1, 64);  p1 += __shfl_xor(p1, 1, 64);
        p0 += __shfl_xor(p0, 2, 64);  p1 += __shfl_xor(p1, 2, 64);
        p0 += __shfl_xor(p0, 4, 64);  p1 += __shfl_xor(p1, 4, 64);
        p0 += __shfl_xor(p0, 8, 64);  p1 += __shfl_xor(p1, 8, 64);
        float a0 = p0 * ((s0 < NA) ? pr0 : ((s0 < NA + NP) ? pr1 : pr2)) * 0.25f;
        float a1 = p1 * ((s1 < NA) ? pr0 : ((s1 < NA + NP) ? pr1 : pr2)) * 0.25f;
        float mn = fmaxf(m, fmaxf(a0, a1));
        float cc = expf(m - mn);
        float e0 = expf(a0 - mn), e1 = expf(a1 - mn);
        s   = s * cc + e0 + e1;
        acc = acc * cc + e0 * v0 + e1 * v1;
        m = mn;
    }
    if (e < end) {
        int s0 = edge_src[e];
        size_t r0 = (size_t)s0 * HID + lane;
        float k0 = bf2f(Ksb[r0]), v0 = bf2f(Vsb[r0]);
        float p0 = q * k0;
        p0 += __shfl_xor(p0, 1, 64);
        p0 += __shfl_xor(p0, 2, 64);
        p0 += __shfl_xor(p0, 4, 64);
        p0 += __shfl_xor(p0, 8, 64);
        float a0 = p0 * ((s0 < NA) ? pr0 : ((s0 < NA + NP) ? pr1 : pr2)) * 0.25f;
        float mn = fmaxf(m, a0);
        float cc = expf(m - mn);
        float e0 = expf(a0 - mn);
        s   = s * cc + e0;
        acc = acc * cc + e0 * v0;
    }
    attnout[(size_t)n * HID + lane] = acc / (s + 1e-16f);
}

// ---------------- hout GEMM + skip + LN + gelu fused, paper+author merged ----------------
// Epilogue m-loop is #pragma unroll 1: full unroll kept 4 rows of LN state live
// over acc[4][4] -> 256 VGPR spill (R5: 192us, 94MB scratch writes).
__global__ __launch_bounds__(256) void gemm_hout(
    const float* __restrict__ attnout, const float* __restrict__ Whout,
    const float* __restrict__ bhout, const float* __restrict__ skip_p,
    const float* __restrict__ lng, const float* __restrict__ lnb,
    float* __restrict__ hbuf)
{
    __shared__ float xs[64][68];
    __shared__ float wsb[64][68];
    int b = blockIdx.x, tid = threadIdx.x;
    int type = (b >= PT);
    int tile = type ? (b - PT) : b;
    int N = type ? NA : NP;
    size_t base_off = type ? (size_t)NP * HID : 0;
    const float* X = attnout + base_off;
    const float* W = Whout + (size_t)type * HID * HID;
    const float* bias = bhout + type * HID;
    float* H = hbuf + base_off;
    int nb = tile * 64;

    #pragma unroll
    for (int r = 0; r < 4; r++) {
        int f = tid + 256 * r;
        int row = f >> 4, col = (f & 15) * 4;
        int n = nb + row;
        float4 v = (n < N) ? *(const float4*)(X + (size_t)n * HID + col)
                           : make_float4(0.f, 0.f, 0.f, 0.f);
        v.x = gelu_exact(v.x); v.y = gelu_exact(v.y);
        v.z = gelu_exact(v.z); v.w = gelu_exact(v.w);
        *(float4*)&xs[row][col] = v;
        *(float4*)&wsb[row][col] = *(const float4*)(W + (size_t)row * HID + col);
    }
    __syncthreads();
    const int tr = tid >> 4, tc = tid & 15;
    const int tr4 = tr * 4, tcj = tc * 4;
    float acc[4][4] = {};
    GEMM_CORE_64(acc, xs, wsb, 0)

    float b0 = bias[tcj], b1 = bias[tcj+1], b2 = bias[tcj+2], b3 = bias[tcj+3];
    float a = 1.0f / (1.0f + expf(-skip_p[type]));
    float oma = 1.0f - a;
    float g0 = lng[type*HID+tcj], g1 = lng[type*HID+tcj+1],
          g2 = lng[type*HID+tcj+2], g3 = lng[type*HID+tcj+3];
    float l0 = lnb[type*HID+tcj], l1 = lnb[type*HID+tcj+1],
          l2 = lnb[type*HID+tcj+2], l3 = lnb[type*HID+tcj+3];
    #pragma unroll 1
    for (int m = 0; m < 4; m++) {
        int n = nb + tr4 + m;
        float v0 = 0.f, v1 = 0.f, v2 = 0.f, v3 = 0.f;
        if (n < N) {
            const float* hp = H + (size_t)n * HID + tcj;
            v0 = a * (acc[m][0] + b0) + oma * hp[0];
            v1 = a * (acc[m][1] + b1) + oma * hp[1];
            v2 = a * (acc[m][2] + b2) + oma * hp[2];
            v3 = a * (acc[m][3] + b3) + oma * hp[3];
        }
        // layernorm across the row (16 lanes x 4 vals)
        float sum = v0 + v1 + v2 + v3;
        sum += __shfl_xor(sum, 1, 64); sum += __shfl_xor(sum, 2, 64);
        sum += __shfl_xor(sum, 4, 64); sum += __shfl_xor(sum, 8, 64);
        float mean = sum * (1.0f / 64.0f);
        float d0 = v0 - mean, d1 = v1 - mean, d2 = v2 - mean, d3 = v3 - mean;
        float sq = d0*d0 + d1*d1 + d2*d2 + d3*d3;
        sq += __shfl_xor(sq, 1, 64); sq += __shfl_xor(sq, 2, 64);
        sq += __shfl_xor(sq, 4, 64); sq += __shfl_xor(sq, 8, 64);
        float rstd = rsqrtf(sq * (1.0f / 64.0f) + 1e-5f);
        if (n < N) {
            float* hp = H + (size_t)n * HID + tcj;
            hp[0] = gelu_exact(d0 * rstd * g0 + l0);
            hp[1] = gelu_exact(d1 * rstd * g1 + l1);
            hp[2] = gelu_exact(d2 * rstd * g2 + l2);
            hp[3] = gelu_exact(d3 * rstd * g3 + l3);
        }
    }
}

// ---------------- final linear via MFMA bf16 (K=64), paper+author merged ----------------
// Replaces the spilled f32 version (R7: 256 VGPR, 109MB scratch writes, 127us).
__global__ __launch_bounds__(256) void gemm_out(
    const float* __restrict__ hbuf, const float* __restrict__ W_out,
    const float* __restrict__ b_out, float* __restrict__ out)
{
    __shared__ unsigned short Xb[64][72];
    __shared__ unsigned short Wt[64][72];
    int b = blockIdx.x, tid = threadIdx.x;
    int type = (b >= PT);
    int tile = type ? (b - PT) : b;
    int N = type ? NA : NP;
    size_t base_off = type ? (size_t)NP * HID : 0;
    const float* X = hbuf + base_off;
    const float* W = W_out + (size_t)type * HID * HID;
    const float* bias = b_out + type * HID;
    float* O = out + base_off;
    int nb = tile * 64;

    {
        int row = tid >> 2, c0 = (tid & 3) * 16;
        int n = nb + row;
        unsigned short tmp[16];
        if (n < N) {
            const float* xr = X + (size_t)n * HID + c0;
            #pragma unroll
            for (int i = 0; i < 16; i += 4) {
                float4 v = *(const float4*)(xr + i);
                tmp[i] = f2bf(v.x); tmp[i+1] = f2bf(v.y);
                tmp[i+2] = f2bf(v.z); tmp[i+3] = f2bf(v.w);
            }
        } else {
            #pragma unroll
            for (int i = 0; i < 16; i++) tmp[i] = 0;
        }
        #pragma unroll
        for (int i = 0; i < 16; i += 4)
            *(ushort4*)&Xb[row][c0 + i] = make_ushort4(tmp[i], tmp[i+1], tmp[i+2], tmp[i+3]);
    }
    #pragma unroll
    for (int it = 0; it < 4; it++) {
        int idx = it * 256 + tid;           // 0..1023
        int k = idx & 63, c = (idx >> 6) * 4;
        float4 v = *(const float4*)(W + (size_t)k * HID + c);
        Wt[c + 0][k] = f2bf(v.x); Wt[c + 1][k] = f2bf(v.y);
        Wt[c + 2][k] = f2bf(v.z); Wt[c + 3][k] = f2bf(v.w);
    }
    __syncthreads();

    int w = tid >> 6, lane = tid & 63;
    int wr = (w >> 1) * 32, wc = (w & 1) * 32;
    int lrow = lane & 15, lgrp = lane >> 4;

    f32x4 acc00 = {0.f, 0.f, 0.f, 0.f};
    f32x4 acc01 = {0.f, 0.f, 0.f, 0.f};
    f32x4 acc10 = {0.f, 0.f, 0.f, 0.f};
    f32x4 acc11 = {0.f, 0.f, 0.f, 0.f};
    #pragma unroll
    for (int ks = 0; ks < 2; ks++) {
        int ko = ks * 32 + lgrp * 8;
        bf16x8 a0 = *(const bf16x8*)&Xb[wr + lrow][ko];
        bf16x8 a1 = *(const bf16x8*)&Xb[wr + 16 + lrow][ko];
        bf16x8 b0 = *(const bf16x8*)&Wt[wc + lrow][ko];
        bf16x8 b1 = *(const bf16x8*)&Wt[wc + 16 + lrow][ko];
        acc00 = __builtin_amdgcn_mfma_f32_16x16x32_bf16(a0, b0, acc00, 0, 0, 0);
        acc01 = __builtin_amdgcn_mfma_f32_16x16x32_bf16(a0, b1, acc01, 0, 0, 0);
        acc10 = __builtin_amdgcn_mfma_f32_16x16x32_bf16(a1, b0, acc10, 0, 0, 0);
        acc11 = __builtin_amdgcn_mfma_f32_16x16x32_bf16(a1, b1, acc11, 0, 0, 0);
    }

    float bias0 = bias[wc + lrow], bias1 = bias[wc + 16 + lrow];
    #pragma unroll
    for (int mi = 0; mi < 2; mi++) {
        const f32x4 accn0 = mi ? acc10 : acc00;
        const f32x4 accn1 = mi ? acc11 : acc01;
        int rbase = wr + mi * 16 + lgrp * 4;
        #pragma unroll
        for (int r = 0; r < 4; r++) {
            int n = nb + rbase + r;
            if (n >= N) continue;
            O[(size_t)n * HID + wc + lrow]      = accn0[r] + bias0;
            O[(size_t)n * HID + wc + 16 + lrow] = accn1[r] + bias1;
        }
    }
}

extern "C" void kernel_launch(void* const* d_in, const int* in_sizes, int n_in,
                              void* d_out, int out_size, void* d_ws, size_t ws_size,
                              hipStream_t stream) {
    const float* x_paper  = (const float*)d_in[0];
    const float* x_author = (const float*)d_in[1];
    const int*   ei_ap    = (const int*)d_in[2];
    const int*   ei_pa    = (const int*)d_in[3];
    const int*   ei_pp    = (const int*)d_in[4];
    const float* W_in     = (const float*)d_in[5];
    const float* b_in     = (const float*)d_in[6];
    const float* W_kqv    = (const float*)d_in[7];
    const float* b_kqv    = (const float*)d_in[8];
    const float* W_krel   = (const float*)d_in[9];
    const float* W_vrel   = (const float*)d_in[10];
    const float* p_rel    = (const float*)d_in[11];
    const float* W_hout   = (const float*)d_in[12];
    const float* b_hout   = (const float*)d_in[13];
    const float* skip     = (const float*)d_in[14];
    const float* ln_g     = (const float*)d_in[15];
    const float* ln_b     = (const float*)d_in[16];
    const float* W_out    = (const float*)d_in[17];
    const float* b_out    = (const float*)d_in[18];
    float* out            = (float*)d_out;

    // ---- workspace layout (~146 MB) ----
    float* ws   = (float*)d_ws;
    float* hbuf = ws;                                   // NTOT*64 f32
    float* Q    = hbuf + (size_t)NTOT * HID;            // NTOT*64 f32 (attn out aliases Q)
    unsigned short* Ksb = (unsigned short*)(Q + (size_t)NTOT * HID);  // NSRC*64 bf16
    unsigned short* Vsb = Ksb + (size_t)NSRC * HID;                   // NSRC*64 bf16
    float* Wfp  = (float*)(Vsb + (size_t)NSRC * HID);   // 64*320
    float* bfp  = Wfp  + 64 * JP;                       // 320
    float* Wfa  = bfp  + JP;                            // 64*192
    float* bfa  = Wfa  + 64 * JA;                       // 192
    int* cnt      = (int*)(bfa + JA);                   // NTOT
    int* row_ptr  = cnt + NTOT;                         // NTOT+1 (pad 16)
    int* cursor   = row_ptr + NTOT + 16;                // NTOT
    int* edge_src = cursor + NTOT;                      // ETOT
    int* csum     = edge_src + ETOT;                    // 1024
    int* coff     = csum + 1024;                        // 1024

    dim3 blk(256);
    const int EB = (ETOT + 255) / 256;

    // ---- CSR build (edges are layer-invariant) ----
    zero_int_kernel<<<256, blk, 0, stream>>>(cnt, NTOT);
    csr_count_kernel<<<EB, blk, 0, stream>>>(ei_ap, ei_pa, ei_pp, cnt);
    scan_chunk_sums<<<NCH, blk, 0, stream>>>(cnt, csum);
    scan_offsets<<<1, 1024, 0, stream>>>(csum, coff, NCH);
    scan_final<<<NCH, blk, 0, stream>>>(cnt, coff, row_ptr, cursor);
    csr_fill_kernel<<<EB, blk, 0, stream>>>(ei_ap, ei_pa, ei_pp, cursor, edge_src);

    // ---- input projection ----
    gemm_in<<<PT + AT, blk, 0, stream>>>(x_paper, x_author, W_in, b_in, hbuf);

    for (int l = 0; l < LAYERS; l++) {
        fuse_weights_kernel<<<(65 * JP + 65 * JA + 255) / 256, blk, 0, stream>>>(
            W_kqv + (size_t)l * 2 * HID * KQV, b_kqv + (size_t)l * 2 * KQV,
            W_krel + (size_t)l * 3 * NH * HD * HD, W_vrel + (size_t)l * 3 * NH * HD * HD,
            Wfp, bfp, Wfa, bfa);
        gemm_kqv<<<PT * 5 + AT * 3, blk, 0, stream>>>(
            hbuf, Wfp, bfp, Wfa, bfa, Q, Ksb, Vsb);
        attn_kernel<<<(NTOT + 3) / 4, blk, 0, stream>>>(
            Q, Ksb, Vsb, p_rel + l * 3 * NH, row_ptr, edge_src, Q);
        gemm_hout<<<PT + AT, blk, 0, stream>>>(
            Q, W_hout + (size_t)l * 2 * HID * HID, b_hout + l * 2 * HID,
            skip + l * 2, ln_g + l * 2 * HID, ln_b + l * 2 * HID, hbuf);
    }

    gemm_out<<<PT + AT, blk, 0, stream>>>(hbuf, W_out, b_out, out);
}

// Round 9
// 500.261 us; speedup vs baseline: 3.7453x; 1.0805x over previous
//
#include <hip/hip_runtime.h>
#include <hip/hip_bf16.h>

// ---- problem constants (match reference) ----
#define NP 100000
#define NA 50000
#define NTOT 150000          // NP+NA
#define E0 300000
#define E1 300000
#define E2 200000
#define ETOT 800000
#define NH 4
#define HD 16
#define HID 64
#define IN_DIM 128
#define KQV 192
#define LAYERS 2
#define NSRC 250000          // NA + 2*NP
#define JP 320               // fused paper cols: q | k_et1 | k_et2 | v_et1 | v_et2
#define JA 192               // fused author cols: q | k_et0 | v_et0
#define NCH 586              // ceil(NTOT/256)
#define PT 1563              // ceil(NP/64)
#define AT 782               // ceil(NA/64)

typedef __attribute__((ext_vector_type(8))) short bf16x8;   // 8 bf16 (4 VGPRs)
typedef __attribute__((ext_vector_type(4))) float f32x4;    // MFMA C/D

__device__ __forceinline__ float gelu_exact(float x) {
    return 0.5f * x * (1.0f + erff(x * 0.7071067811865475f));
}
// f32 -> bf16 bits, round-to-nearest-even (finite values)
__device__ __forceinline__ unsigned short f2bf(float f) {
    unsigned u = __float_as_uint(f);
    return (unsigned short)((u + 0x7fffu + ((u >> 16) & 1u)) >> 16);
}
__device__ __forceinline__ float bf2f(unsigned short b) {
    return __uint_as_float((unsigned)b << 16);
}

// decode global edge id -> (src in KV space, dst in node space)
__device__ __forceinline__ void edge_decode(int e, const int* __restrict__ ei_ap,
                                            const int* __restrict__ ei_pa,
                                            const int* __restrict__ ei_pp,
                                            int& src, int& dst) {
    if (e < E0)            { src = ei_ap[e];                 dst = ei_ap[E0 + e]; }
    else if (e < E0 + E1)  { int le = e - E0;
                             src = NA + ei_pa[le];           dst = NP + ei_pa[E1 + le]; }
    else                   { int le = e - E0 - E1;
                             src = NA + NP + ei_pp[le];      dst = ei_pp[E2 + le]; }
}

// ---------------- CSR build ----------------
__global__ void zero_int_kernel(int* __restrict__ p, int n) {
    int i = blockIdx.x * blockDim.x + threadIdx.x;
    int st = gridDim.x * blockDim.x;
    for (int j = i; j < n; j += st) p[j] = 0;
}

__global__ void csr_count_kernel(const int* __restrict__ ei_ap, const int* __restrict__ ei_pa,
                                 const int* __restrict__ ei_pp, int* __restrict__ cnt) {
    int e = blockIdx.x * 256 + threadIdx.x;
    if (e >= ETOT) return;
    int src, dst; edge_decode(e, ei_ap, ei_pa, ei_pp, src, dst);
    atomicAdd(&cnt[dst], 1);
}

__global__ void scan_chunk_sums(const int* __restrict__ cnt, int* __restrict__ csum) {
    __shared__ int sd[256];
    int c = blockIdx.x, t = threadIdx.x;
    int i = c * 256 + t;
    sd[t] = (i < NTOT) ? cnt[i] : 0;
    __syncthreads();
    for (int o = 128; o > 0; o >>= 1) { if (t < o) sd[t] += sd[t + o]; __syncthreads(); }
    if (t == 0) csum[c] = sd[0];
}

__global__ void scan_offsets(const int* __restrict__ csum, int* __restrict__ coff, int nch) {
    __shared__ int sd[1024];
    int t = threadIdx.x;
    int v = (t < nch) ? csum[t] : 0;
    sd[t] = v;
    __syncthreads();
    for (int o = 1; o < 1024; o <<= 1) {
        int x = (t >= o) ? sd[t - o] : 0;
        __syncthreads();
        sd[t] += x;
        __syncthreads();
    }
    if (t < nch) coff[t] = sd[t] - v;   // exclusive
}

__global__ void scan_final(const int* __restrict__ cnt, const int* __restrict__ coff,
                           int* __restrict__ row_ptr, int* __restrict__ cursor) {
    __shared__ int sd[256];
    int c = blockIdx.x, t = threadIdx.x, i = c * 256 + t;
    int v = (i < NTOT) ? cnt[i] : 0;
    sd[t] = v;
    __syncthreads();
    for (int o = 1; o < 256; o <<= 1) {
        int x = (t >= o) ? sd[t - o] : 0;
        __syncthreads();
        sd[t] += x;
        __syncthreads();
    }
    if (i < NTOT) { int ex = coff[c] + sd[t] - v; row_ptr[i] = ex; cursor[i] = ex; }
    if (i == 0) row_ptr[NTOT] = ETOT;
}

__global__ void csr_fill_kernel(const int* __restrict__ ei_ap, const int* __restrict__ ei_pa,
                                const int* __restrict__ ei_pp, int* __restrict__ cursor,
                                int* __restrict__ edge_src) {
    int e = blockIdx.x * 256 + threadIdx.x;
    if (e >= ETOT) return;
    int src, dst; edge_decode(e, ei_ap, ei_pa, ei_pp, src, dst);
    int pos = atomicAdd(&cursor[dst], 1);
    edge_src[pos] = src;
}

// ---------------- fused-weight build (per layer) ----------------
__global__ void fuse_weights_kernel(const float* __restrict__ Wkqv, const float* __restrict__ bkqv,
                                    const float* __restrict__ Wkrel, const float* __restrict__ Wvrel,
                                    float* __restrict__ Wfp, float* __restrict__ bfp,
                                    float* __restrict__ Wfa, float* __restrict__ bfa) {
    int idx = blockIdx.x * 256 + threadIdx.x;
    int type, i, j;
    if (idx < 65 * JP) { type = 0; i = idx / JP; j = idx % JP; }
    else {
        int r = idx - 65 * JP;
        if (r >= 65 * JA) return;
        type = 1; i = r / JA; j = r % JA;
    }
    int c = j >> 6, jj = j & 63, h = jj >> 4, e = jj & 15;
    const float* Wk = Wkqv + (size_t)type * HID * KQV;
    const float* bk = bkqv + type * KQV;
    float val;
    if (c == 0) {
        val = (i < 64) ? Wk[i * KQV + 64 + jj] : bk[64 + jj];
    } else {
        int et, isV;
        if (type == 0) { et = (c == 1 || c == 3) ? 1 : 2; isV = (c >= 3); }
        else           { et = 0; isV = (c == 2); }
        const float* Wr = (isV ? Wvrel : Wkrel) + (size_t)(et * NH + h) * HD * HD;
        int sb = (isV ? 128 : 0) + h * HD;
        val = 0.0f;
        #pragma unroll
        for (int d = 0; d < HD; d++) {
            float a = (i < 64) ? Wk[i * KQV + sb + d] : bk[sb + d];
            val += a * Wr[d * HD + e];
        }
    }
    if (i < 64) (type ? Wfa : Wfp)[i * (type ? JA : JP) + j] = val;
    else        (type ? bfa : bfp)[j] = val;
}

// ---------------- input projection via MFMA bf16 (K=128), paper+author merged ----------------
__global__ __launch_bounds__(256) void gemm_in(
    const float* __restrict__ xp, const float* __restrict__ xa,
    const float* __restrict__ W_in, const float* __restrict__ b_in,
    float* __restrict__ hbuf)
{
    __shared__ unsigned short Xb[64][136];   // 272B rows (16B-aligned)
    __shared__ unsigned short Wt[64][136];   // Wt[col][k]
    int b = blockIdx.x, tid = threadIdx.x;
    int type = (b >= PT);
    int tile = type ? (b - PT) : b;
    int N = type ? NA : NP;
    const float* X = type ? xa : xp;
    const float* W = W_in + (size_t)type * IN_DIM * HID;
    const float* bias = b_in + type * HID;
    float* H = hbuf + (type ? (size_t)NP * HID : 0);
    int nb = tile * 64;

    {
        int row = tid >> 2, c0 = (tid & 3) * 32;
        int n = nb + row;
        if (n < N) {
            const float* xr = X + (size_t)n * IN_DIM + c0;
            #pragma unroll
            for (int i = 0; i < 32; i += 4) {
                float4 v = *(const float4*)(xr + i);
                *(ushort4*)&Xb[row][c0 + i] =
                    make_ushort4(f2bf(v.x), f2bf(v.y), f2bf(v.z), f2bf(v.w));
            }
        } else {
            #pragma unroll
            for (int i = 0; i < 32; i += 4)
                *(ushort4*)&Xb[row][c0 + i] = make_ushort4(0, 0, 0, 0);
        }
    }
    #pragma unroll
    for (int it = 0; it < 8; it++) {
        int idx = it * 256 + tid;            // 0..2047
        int k = idx & 127, c = (idx >> 7) * 4;
        float4 v = *(const float4*)(W + (size_t)k * HID + c);
        Wt[c + 0][k] = f2bf(v.x); Wt[c + 1][k] = f2bf(v.y);
        Wt[c + 2][k] = f2bf(v.z); Wt[c + 3][k] = f2bf(v.w);
    }
    __syncthreads();

    int w = tid >> 6, lane = tid & 63;
    int wr = (w >> 1) * 32, wc = (w & 1) * 32;
    int lrow = lane & 15, lgrp = lane >> 4;

    f32x4 acc00 = {0.f, 0.f, 0.f, 0.f};
    f32x4 acc01 = {0.f, 0.f, 0.f, 0.f};
    f32x4 acc10 = {0.f, 0.f, 0.f, 0.f};
    f32x4 acc11 = {0.f, 0.f, 0.f, 0.f};
    #pragma unroll
    for (int ks = 0; ks < 4; ks++) {
        int ko = ks * 32 + lgrp * 8;
        bf16x8 a0 = *(const bf16x8*)&Xb[wr + lrow][ko];
        bf16x8 a1 = *(const bf16x8*)&Xb[wr + 16 + lrow][ko];
        bf16x8 b0 = *(const bf16x8*)&Wt[wc + lrow][ko];
        bf16x8 b1 = *(const bf16x8*)&Wt[wc + 16 + lrow][ko];
        acc00 = __builtin_amdgcn_mfma_f32_16x16x32_bf16(a0, b0, acc00, 0, 0, 0);
        acc01 = __builtin_amdgcn_mfma_f32_16x16x32_bf16(a0, b1, acc01, 0, 0, 0);
        acc10 = __builtin_amdgcn_mfma_f32_16x16x32_bf16(a1, b0, acc10, 0, 0, 0);
        acc11 = __builtin_amdgcn_mfma_f32_16x16x32_bf16(a1, b1, acc11, 0, 0, 0);
    }

    float bias0 = bias[wc + lrow], bias1 = bias[wc + 16 + lrow];
    #pragma unroll
    for (int mi = 0; mi < 2; mi++) {
        const f32x4 accn0 = mi ? acc10 : acc00;
        const f32x4 accn1 = mi ? acc11 : acc01;
        int rbase = wr + mi * 16 + lgrp * 4;
        #pragma unroll
        for (int r = 0; r < 4; r++) {
            int n = nb + rbase + r;
            if (n >= N) continue;
            H[(size_t)n * HID + wc + lrow]      = accn0[r] + bias0;
            H[(size_t)n * HID + wc + 16 + lrow] = accn1[r] + bias1;
        }
    }
}

// ---------------- KQV GEMM via MFMA bf16: one (row-tile, chunk) per block ----------------
// K/V outputs go into packed KV rows: KVb[src][lane] = (V_bf16 << 16) | K_bf16,
// written as disjoint ushort halves (K blocks write even halves, V blocks odd).
// paper chunks: 0->Q f32 | 1->K@NA | 2->K@NA+NP | 3->V@NA | 4->V@NA+NP
// author chunks: 0->Q@NP | 1->K@0 | 2->V@0
__global__ __launch_bounds__(256) void gemm_kqv(
    const float* __restrict__ hbuf,
    const float* __restrict__ Wfp, const float* __restrict__ bfp,
    const float* __restrict__ Wfa, const float* __restrict__ bfa,
    float* __restrict__ Q, unsigned* __restrict__ KVb)
{
    __shared__ unsigned short Xb[64][72];
    __shared__ unsigned short Wt[64][72];
    int b = blockIdx.x, tid = threadIdx.x;
    int type, tile, chunk;
    if (b < PT * 5) { type = 0; chunk = b / PT; tile = b % PT; }
    else            { int ab = b - PT * 5; type = 1; chunk = ab / AT; tile = ab % AT; }
    int N = type ? NA : NP;
    const float* X = hbuf + (type ? (size_t)NP * HID : 0);
    const float* W = type ? Wfa : Wfp;
    const float* bias = type ? bfa : bfp;
    int ldw = type ? JA : JP;
    int nb = tile * 64;

    {
        int row = tid >> 2, c0 = (tid & 3) * 16;
        int n = nb + row;
        unsigned short tmp[16];
        if (n < N) {
            const float* xr = X + (size_t)n * HID + c0;
            #pragma unroll
            for (int i = 0; i < 16; i += 4) {
                float4 v = *(const float4*)(xr + i);
                tmp[i] = f2bf(v.x); tmp[i+1] = f2bf(v.y);
                tmp[i+2] = f2bf(v.z); tmp[i+3] = f2bf(v.w);
            }
        } else {
            #pragma unroll
            for (int i = 0; i < 16; i++) tmp[i] = 0;
        }
        #pragma unroll
        for (int i = 0; i < 16; i += 4)
            *(ushort4*)&Xb[row][c0 + i] = make_ushort4(tmp[i], tmp[i+1], tmp[i+2], tmp[i+3]);
    }
    #pragma unroll
    for (int it = 0; it < 4; it++) {
        int idx = it * 256 + tid;           // 0..1023
        int k = idx & 63, c = (idx >> 6) * 4;
        float4 v = *(const float4*)(W + (size_t)k * ldw + chunk * 64 + c);
        Wt[c + 0][k] = f2bf(v.x); Wt[c + 1][k] = f2bf(v.y);
        Wt[c + 2][k] = f2bf(v.z); Wt[c + 3][k] = f2bf(v.w);
    }
    __syncthreads();

    int w = tid >> 6, lane = tid & 63;
    int wr = (w >> 1) * 32, wc = (w & 1) * 32;
    int lrow = lane & 15, lgrp = lane >> 4;

    f32x4 acc00 = {0.f, 0.f, 0.f, 0.f};
    f32x4 acc01 = {0.f, 0.f, 0.f, 0.f};
    f32x4 acc10 = {0.f, 0.f, 0.f, 0.f};
    f32x4 acc11 = {0.f, 0.f, 0.f, 0.f};
    #pragma unroll
    for (int ks = 0; ks < 2; ks++) {
        int ko = ks * 32 + lgrp * 8;
        bf16x8 a0 = *(const bf16x8*)&Xb[wr + lrow][ko];
        bf16x8 a1 = *(const bf16x8*)&Xb[wr + 16 + lrow][ko];
        bf16x8 b0 = *(const bf16x8*)&Wt[wc + lrow][ko];
        bf16x8 b1 = *(const bf16x8*)&Wt[wc + 16 + lrow][ko];
        acc00 = __builtin_amdgcn_mfma_f32_16x16x32_bf16(a0, b0, acc00, 0, 0, 0);
        acc01 = __builtin_amdgcn_mfma_f32_16x16x32_bf16(a0, b1, acc01, 0, 0, 0);
        acc10 = __builtin_amdgcn_mfma_f32_16x16x32_bf16(a1, b0, acc10, 0, 0, 0);
        acc11 = __builtin_amdgcn_mfma_f32_16x16x32_bf16(a1, b1, acc11, 0, 0, 0);
    }

    float bias0 = bias[chunk * 64 + wc + lrow];
    float bias1 = bias[chunk * 64 + wc + 16 + lrow];
    int noff, isV = 0;
    bool isQ = (chunk == 0);
    if (isQ) {
        noff = type ? NP : 0;
    } else if (type == 0) {
        isV = (chunk >= 3);
        noff = ((chunk == 1 || chunk == 3) ? NA : NA + NP);
    } else {
        isV = (chunk == 2);
        noff = 0;
    }
    unsigned short* kvh = (unsigned short*)KVb;
    #pragma unroll
    for (int mi = 0; mi < 2; mi++) {
        const f32x4 accn0 = mi ? acc10 : acc00;
        const f32x4 accn1 = mi ? acc11 : acc01;
        int rbase = wr + mi * 16 + lgrp * 4;
        #pragma unroll
        for (int r = 0; r < 4; r++) {
            int n = nb + rbase + r;
            if (n >= N) continue;
            float v0 = accn0[r] + bias0;
            float v1 = accn1[r] + bias1;
            int c0 = wc + lrow, c1 = wc + 16 + lrow;
            if (isQ) {
                Q[(size_t)(noff + n) * HID + c0] = v0;
                Q[(size_t)(noff + n) * HID + c1] = v1;
            } else {
                kvh[((((size_t)(noff + n)) * HID + c0) << 1) | isV] = f2bf(v0);
                kvh[((((size_t)(noff + n)) * HID + c1) << 1) | isV] = f2bf(v1);
            }
        }
    }
}

// ---------------- fused attention: one wave per dst node, online softmax ----------------
// Packed KV: one dword gather/edge; __expf (R8: libm expf + dual gathers = 140 inst/edge,
// VALUBusy 90%).
__global__ __launch_bounds__(256) void attn_kernel(
    const float* Q, const unsigned* __restrict__ KVb,
    const float* __restrict__ p_rel, const int* __restrict__ row_ptr,
    const int* __restrict__ edge_src, float* attnout)
{
    int wid = threadIdx.x >> 6, lane = threadIdx.x & 63;
    int n = blockIdx.x * 4 + wid;
    if (n >= NTOT) return;
    int h = lane >> 4;
    float q = Q[(size_t)n * HID + lane];
    float pr0 = p_rel[h] * 0.25f, pr1 = p_rel[4 + h] * 0.25f, pr2 = p_rel[8 + h] * 0.25f;
    int beg = row_ptr[n], end = row_ptr[n + 1];
    float m = -INFINITY, s = 0.0f, acc = 0.0f;
    int e = beg;
    for (; e + 1 < end; e += 2) {
        int s0 = edge_src[e], s1 = edge_src[e + 1];
        unsigned kv0 = KVb[((unsigned)s0 << 6) + lane];
        unsigned kv1 = KVb[((unsigned)s1 << 6) + lane];
        float k0 = __uint_as_float(kv0 << 16);
        float v0 = __uint_as_float(kv0 & 0xffff0000u);
        float k1 = __uint_as_float(kv1 << 16);
        float v1 = __uint_as_float(kv1 & 0xffff0000u);
        float p0 = q * k0, p1 = q * k1;
        p0 += __shfl_xor(p0, 1, 64);  p1 += __shfl_xor(p1, 1, 64);
        p0 += __shfl_xor(p0, 2, 64);  p1 += __shfl_xor(p1, 2, 64);
        p0 += __shfl_xor(p0, 4, 64);  p1 += __shfl_xor(p1, 4, 64);
        p0 += __shfl_xor(p0, 8, 64);  p1 += __shfl_xor(p1, 8, 64);
        float a0 = p0 * ((s0 < NA) ? pr0 : ((s0 < NA + NP) ? pr1 : pr2));
        float a1 = p1 * ((s1 < NA) ? pr0 : ((s1 < NA + NP) ? pr1 : pr2));
        float mn = fmaxf(m, fmaxf(a0, a1));
        float cc = __expf(m - mn);
        float e0 = __expf(a0 - mn), e1 = __expf(a1 - mn);
        s   = s * cc + e0 + e1;
        acc = acc * cc + e0 * v0 + e1 * v1;
        m = mn;
    }
    if (e < end) {
        int s0 = edge_src[e];
        unsigned kv0 = KVb[((unsigned)s0 << 6) + lane];
        float k0 = __uint_as_float(kv0 << 16);
        float v0 = __uint_as_float(kv0 & 0xffff0000u);
        float p0 = q * k0;
        p0 += __shfl_xor(p0, 1, 64);
        p0 += __shfl_xor(p0, 2, 64);
        p0 += __shfl_xor(p0, 4, 64);
        p0 += __shfl_xor(p0, 8, 64);
        float a0 = p0 * ((s0 < NA) ? pr0 : ((s0 < NA + NP) ? pr1 : pr2));
        float mn = fmaxf(m, a0);
        float cc = __expf(m - mn);
        float e0 = __expf(a0 - mn);
        s   = s * cc + e0;
        acc = acc * cc + e0 * v0;
    }
    attnout[(size_t)n * HID + lane] = acc / (s + 1e-16f);
}

// ---------------- hout via MFMA bf16 + skip + LN + gelu, paper+author merged ----------------
// gelu applied during bf16 staging; skip-blend lands in LDS f32; shfl-LN pass follows.
__global__ __launch_bounds__(256) void gemm_hout(
    const float* __restrict__ attnout, const float* __restrict__ Whout,
    const float* __restrict__ bhout, const float* __restrict__ skip_p,
    const float* __restrict__ lng, const float* __restrict__ lnb,
    float* __restrict__ hbuf)
{
    __shared__ unsigned short Xb[64][72];
    __shared__ unsigned short Wt[64][72];
    __shared__ float hs[64][68];
    int b = blockIdx.x, tid = threadIdx.x;
    int type = (b >= PT);
    int tile = type ? (b - PT) : b;
    int N = type ? NA : NP;
    size_t base_off = type ? (size_t)NP * HID : 0;
    const float* X = attnout + base_off;
    const float* W = Whout + (size_t)type * HID * HID;
    const float* bias = bhout + type * HID;
    float* H = hbuf + base_off;
    int nb = tile * 64;

    {
        int row = tid >> 2, c0 = (tid & 3) * 16;
        int n = nb + row;
        unsigned short tmp[16];
        if (n < N) {
            const float* xr = X + (size_t)n * HID + c0;
            #pragma unroll
            for (int i = 0; i < 16; i += 4) {
                float4 v = *(const float4*)(xr + i);
                tmp[i]   = f2bf(gelu_exact(v.x)); tmp[i+1] = f2bf(gelu_exact(v.y));
                tmp[i+2] = f2bf(gelu_exact(v.z)); tmp[i+3] = f2bf(gelu_exact(v.w));
            }
        } else {
            #pragma unroll
            for (int i = 0; i < 16; i++) tmp[i] = 0;
        }
        #pragma unroll
        for (int i = 0; i < 16; i += 4)
            *(ushort4*)&Xb[row][c0 + i] = make_ushort4(tmp[i], tmp[i+1], tmp[i+2], tmp[i+3]);
    }
    #pragma unroll
    for (int it = 0; it < 4; it++) {
        int idx = it * 256 + tid;
        int k = idx & 63, c = (idx >> 6) * 4;
        float4 v = *(const float4*)(W + (size_t)k * HID + c);
        Wt[c + 0][k] = f2bf(v.x); Wt[c + 1][k] = f2bf(v.y);
        Wt[c + 2][k] = f2bf(v.z); Wt[c + 3][k] = f2bf(v.w);
    }
    __syncthreads();

    int w = tid >> 6, lane = tid & 63;
    int wr = (w >> 1) * 32, wc = (w & 1) * 32;
    int lrow = lane & 15, lgrp = lane >> 4;

    f32x4 acc00 = {0.f, 0.f, 0.f, 0.f};
    f32x4 acc01 = {0.f, 0.f, 0.f, 0.f};
    f32x4 acc10 = {0.f, 0.f, 0.f, 0.f};
    f32x4 acc11 = {0.f, 0.f, 0.f, 0.f};
    #pragma unroll
    for (int ks = 0; ks < 2; ks++) {
        int ko = ks * 32 + lgrp * 8;
        bf16x8 a0 = *(const bf16x8*)&Xb[wr + lrow][ko];
        bf16x8 a1 = *(const bf16x8*)&Xb[wr + 16 + lrow][ko];
        bf16x8 b0 = *(const bf16x8*)&Wt[wc + lrow][ko];
        bf16x8 b1 = *(const bf16x8*)&Wt[wc + 16 + lrow][ko];
        acc00 = __builtin_amdgcn_mfma_f32_16x16x32_bf16(a0, b0, acc00, 0, 0, 0);
        acc01 = __builtin_amdgcn_mfma_f32_16x16x32_bf16(a0, b1, acc01, 0, 0, 0);
        acc10 = __builtin_amdgcn_mfma_f32_16x16x32_bf16(a1, b0, acc10, 0, 0, 0);
        acc11 = __builtin_amdgcn_mfma_f32_16x16x32_bf16(a1, b1, acc11, 0, 0, 0);
    }

    float a = 1.0f / (1.0f + __expf(-skip_p[type]));
    float oma = 1.0f - a;
    float bias0 = bias[wc + lrow], bias1 = bias[wc + 16 + lrow];
    #pragma unroll
    for (int mi = 0; mi < 2; mi++) {
        const f32x4 accn0 = mi ? acc10 : acc00;
        const f32x4 accn1 = mi ? acc11 : acc01;
        int rbase = wr + mi * 16 + lgrp * 4;
        #pragma unroll
        for (int r = 0; r < 4; r++) {
            int row = rbase + r;
            int n = nb + row;
            if (n < N) {
                const float* hp = H + (size_t)n * HID;
                hs[row][wc + lrow]      = a * (accn0[r] + bias0) + oma * hp[wc + lrow];
                hs[row][wc + 16 + lrow] = a * (accn1[r] + bias1) + oma * hp[wc + 16 + lrow];
            } else {
                hs[row][wc + lrow] = 0.f;
                hs[row][wc + 16 + lrow] = 0.f;
            }
        }
    }
    __syncthreads();

    const int tr = tid >> 4, tc = tid & 15;
    const int tcj = tc * 4;
    float g0 = lng[type*HID+tcj], g1 = lng[type*HID+tcj+1],
          g2 = lng[type*HID+tcj+2], g3 = lng[type*HID+tcj+3];
    float l0 = lnb[type*HID+tcj], l1 = lnb[type*HID+tcj+1],
          l2 = lnb[type*HID+tcj+2], l3 = lnb[type*HID+tcj+3];
    #pragma unroll 1
    for (int m = 0; m < 4; m++) {
        int row = tr * 4 + m;
        int n = nb + row;
        float v0 = hs[row][tcj], v1 = hs[row][tcj+1], v2 = hs[row][tcj+2], v3 = hs[row][tcj+3];
        float sum = v0 + v1 + v2 + v3;
        sum += __shfl_xor(sum, 1, 64); sum += __shfl_xor(sum, 2, 64);
        sum += __shfl_xor(sum, 4, 64); sum += __shfl_xor(sum, 8, 64);
        float mean = sum * (1.0f / 64.0f);
        float d0 = v0 - mean, d1 = v1 - mean, d2 = v2 - mean, d3 = v3 - mean;
        float sq = d0*d0 + d1*d1 + d2*d2 + d3*d3;
        sq += __shfl_xor(sq, 1, 64); sq += __shfl_xor(sq, 2, 64);
        sq += __shfl_xor(sq, 4, 64); sq += __shfl_xor(sq, 8, 64);
        float rstd = rsqrtf(sq * (1.0f / 64.0f) + 1e-5f);
        if (n < N) {
            float* hp = H + (size_t)n * HID + tcj;
            hp[0] = gelu_exact(d0 * rstd * g0 + l0);
            hp[1] = gelu_exact(d1 * rstd * g1 + l1);
            hp[2] = gelu_exact(d2 * rstd * g2 + l2);
            hp[3] = gelu_exact(d3 * rstd * g3 + l3);
        }
    }
}

// ---------------- final linear via MFMA bf16 (K=64), paper+author merged ----------------
__global__ __launch_bounds__(256) void gemm_out(
    const float* __restrict__ hbuf, const float* __restrict__ W_out,
    const float* __restrict__ b_out, float* __restrict__ out)
{
    __shared__ unsigned short Xb[64][72];
    __shared__ unsigned short Wt[64][72];
    int b = blockIdx.x, tid = threadIdx.x;
    int type = (b >= PT);
    int tile = type ? (b - PT) : b;
    int N = type ? NA : NP;
    size_t base_off = type ? (size_t)NP * HID : 0;
    const float* X = hbuf + base_off;
    const float* W = W_out + (size_t)type * HID * HID;
    const float* bias = b_out + type * HID;
    float* O = out + base_off;
    int nb = tile * 64;

    {
        int row = tid >> 2, c0 = (tid & 3) * 16;
        int n = nb + row;
        unsigned short tmp[16];
        if (n < N) {
            const float* xr = X + (size_t)n * HID + c0;
            #pragma unroll
            for (int i = 0; i < 16; i += 4) {
                float4 v = *(const float4*)(xr + i);
                tmp[i] = f2bf(v.x); tmp[i+1] = f2bf(v.y);
                tmp[i+2] = f2bf(v.z); tmp[i+3] = f2bf(v.w);
            }
        } else {
            #pragma unroll
            for (int i = 0; i < 16; i++) tmp[i] = 0;
        }
        #pragma unroll
        for (int i = 0; i < 16; i += 4)
            *(ushort4*)&Xb[row][c0 + i] = make_ushort4(tmp[i], tmp[i+1], tmp[i+2], tmp[i+3]);
    }
    #pragma unroll
    for (int it = 0; it < 4; it++) {
        int idx = it * 256 + tid;
        int k = idx & 63, c = (idx >> 6) * 4;
        float4 v = *(const float4*)(W + (size_t)k * HID + c);
        Wt[c + 0][k] = f2bf(v.x); Wt[c + 1][k] = f2bf(v.y);
        Wt[c + 2][k] = f2bf(v.z); Wt[c + 3][k] = f2bf(v.w);
    }
    __syncthreads();

    int w = tid >> 6, lane = tid & 63;
    int wr = (w >> 1) * 32, wc = (w & 1) * 32;
    int lrow = lane & 15, lgrp = lane >> 4;

    f32x4 acc00 = {0.f, 0.f, 0.f, 0.f};
    f32x4 acc01 = {0.f, 0.f, 0.f, 0.f};
    f32x4 acc10 = {0.f, 0.f, 0.f, 0.f};
    f32x4 acc11 = {0.f, 0.f, 0.f, 0.f};
    #pragma unroll
    for (int ks = 0; ks < 2; ks++) {
        int ko = ks * 32 + lgrp * 8;
        bf16x8 a0 = *(const bf16x8*)&Xb[wr + lrow][ko];
        bf16x8 a1 = *(const bf16x8*)&Xb[wr + 16 + lrow][ko];
        bf16x8 b0 = *(const bf16x8*)&Wt[wc + lrow][ko];
        bf16x8 b1 = *(const bf16x8*)&Wt[wc + 16 + lrow][ko];
        acc00 = __builtin_amdgcn_mfma_f32_16x16x32_bf16(a0, b0, acc00, 0, 0, 0);
        acc01 = __builtin_amdgcn_mfma_f32_16x16x32_bf16(a0, b1, acc01, 0, 0, 0);
        acc10 = __builtin_amdgcn_mfma_f32_16x16x32_bf16(a1, b0, acc10, 0, 0, 0);
        acc11 = __builtin_amdgcn_mfma_f32_16x16x32_bf16(a1, b1, acc11, 0, 0, 0);
    }

    float bias0 = bias[wc + lrow], bias1 = bias[wc + 16 + lrow];
    #pragma unroll
    for (int mi = 0; mi < 2; mi++) {
        const f32x4 accn0 = mi ? acc10 : acc00;
        const f32x4 accn1 = mi ? acc11 : acc01;
        int rbase = wr + mi * 16 + lgrp * 4;
        #pragma unroll
        for (int r = 0; r < 4; r++) {
            int n = nb + rbase + r;
            if (n >= N) continue;
            O[(size_t)n * HID + wc + lrow]      = accn0[r] + bias0;
            O[(size_t)n * HID + wc + 16 + lrow] = accn1[r] + bias1;
        }
    }
}

extern "C" void kernel_launch(void* const* d_in, const int* in_sizes, int n_in,
                              void* d_out, int out_size, void* d_ws, size_t ws_size,
                              hipStream_t stream) {
    const float* x_paper  = (const float*)d_in[0];
    const float* x_author = (const float*)d_in[1];
    const int*   ei_ap    = (const int*)d_in[2];
    const int*   ei_pa    = (const int*)d_in[3];
    const int*   ei_pp    = (const int*)d_in[4];
    const float* W_in     = (const float*)d_in[5];
    const float* b_in     = (const float*)d_in[6];
    const float* W_kqv    = (const float*)d_in[7];
    const float* b_kqv    = (const float*)d_in[8];
    const float* W_krel   = (const float*)d_in[9];
    const float* W_vrel   = (const float*)d_in[10];
    const float* p_rel    = (const float*)d_in[11];
    const float* W_hout   = (const float*)d_in[12];
    const float* b_hout   = (const float*)d_in[13];
    const float* skip     = (const float*)d_in[14];
    const float* ln_g     = (const float*)d_in[15];
    const float* ln_b     = (const float*)d_in[16];
    const float* W_out    = (const float*)d_in[17];
    const float* b_out    = (const float*)d_in[18];
    float* out            = (float*)d_out;

    // ---- workspace layout (~146 MB) ----
    float* ws   = (float*)d_ws;
    float* hbuf = ws;                                   // NTOT*64 f32
    float* Q    = hbuf + (size_t)NTOT * HID;            // NTOT*64 f32 (attn out aliases Q)
    unsigned* KVb = (unsigned*)(Q + (size_t)NTOT * HID); // NSRC*64 packed (K lo | V hi)
    float* Wfp  = (float*)(KVb + (size_t)NSRC * HID);   // 64*320
    float* bfp  = Wfp  + 64 * JP;                       // 320
    float* Wfa  = bfp  + JP;                            // 64*192
    float* bfa  = Wfa  + 64 * JA;                       // 192
    int* cnt      = (int*)(bfa + JA);                   // NTOT
    int* row_ptr  = cnt + NTOT;                         // NTOT+1 (pad 16)
    int* cursor   = row_ptr + NTOT + 16;                // NTOT
    int* edge_src = cursor + NTOT;                      // ETOT
    int* csum     = edge_src + ETOT;                    // 1024
    int* coff     = csum + 1024;                        // 1024

    dim3 blk(256);
    const int EB = (ETOT + 255) / 256;

    // ---- CSR build (edges are layer-invariant) ----
    zero_int_kernel<<<256, blk, 0, stream>>>(cnt, NTOT);
    csr_count_kernel<<<EB, blk, 0, stream>>>(ei_ap, ei_pa, ei_pp, cnt);
    scan_chunk_sums<<<NCH, blk, 0, stream>>>(cnt, csum);
    scan_offsets<<<1, 1024, 0, stream>>>(csum, coff, NCH);
    scan_final<<<NCH, blk, 0, stream>>>(cnt, coff, row_ptr, cursor);
    csr_fill_kernel<<<EB, blk, 0, stream>>>(ei_ap, ei_pa, ei_pp, cursor, edge_src);

    // ---- input projection ----
    gemm_in<<<PT + AT, blk, 0, stream>>>(x_paper, x_author, W_in, b_in, hbuf);

    for (int l = 0; l < LAYERS; l++) {
        fuse_weights_kernel<<<(65 * JP + 65 * JA + 255) / 256, blk, 0, stream>>>(
            W_kqv + (size_t)l * 2 * HID * KQV, b_kqv + (size_t)l * 2 * KQV,
            W_krel + (size_t)l * 3 * NH * HD * HD, W_vrel + (size_t)l * 3 * NH * HD * HD,
            Wfp, bfp, Wfa, bfa);
        gemm_kqv<<<PT * 5 + AT * 3, blk, 0, stream>>>(
            hbuf, Wfp, bfp, Wfa, bfa, Q, KVb);
        attn_kernel<<<(NTOT + 3) / 4, blk, 0, stream>>>(
            Q, KVb, p_rel + l * 3 * NH, row_ptr, edge_src, Q);
        gemm_hout<<<PT + AT, blk, 0, stream>>>(
            Q, W_hout + (size_t)l * 2 * HID * HID, b_hout + l * 2 * HID,
            skip + l * 2, ln_g + l * 2 * HID, ln_b + l * 2 * HID, hbuf);
    }

    gemm_out<<<PT + AT, blk, 0, stream>>>(hbuf, W_out, b_out, out);
}

// Round 10
// 498.516 us; speedup vs baseline: 3.7584x; 1.0035x over previous
//
#include <hip/hip_runtime.h>
#include <hip/hip_bf16.h>

// ---- problem constants (match reference) ----
#define NP 100000
#define NA 50000
#define NTOT 150000          // NP+NA
#define E0 300000
#define E1 300000
#define E2 200000
#define ETOT 800000
#define NH 4
#define HD 16
#define HID 64
#define IN_DIM 128
#define KQV 192
#define LAYERS 2
#define NSRC 250000          // NA + 2*NP
#define JP 320               // fused paper cols: q | k_et1 | k_et2 | v_et1 | v_et2
#define JA 192               // fused author cols: q | k_et0 | v_et0
#define NCH 586              // ceil(NTOT/256)
#define PT 1563              // ceil(NP/64)
#define AT 782               // ceil(NA/64)

typedef __attribute__((ext_vector_type(8))) short bf16x8;   // 8 bf16 (4 VGPRs)
typedef __attribute__((ext_vector_type(4))) float f32x4;    // MFMA C/D
typedef _Float16 h16x2 __attribute__((ext_vector_type(2)));

__device__ __forceinline__ float gelu_exact(float x) {
    return 0.5f * x * (1.0f + erff(x * 0.7071067811865475f));
}
// f32 -> bf16 bits, round-to-nearest-even (finite values)
__device__ __forceinline__ unsigned short f2bf(float f) {
    unsigned u = __float_as_uint(f);
    return (unsigned short)((u + 0x7fffu + ((u >> 16) & 1u)) >> 16);
}
// f32 -> f16 bits (RNE via hardware cvt)
__device__ __forceinline__ unsigned short f2h(float f) {
    union { _Float16 h; unsigned short u; } c;
    c.h = (_Float16)f;
    return c.u;
}

// decode global edge id -> (src in KV space, dst in node space)
__device__ __forceinline__ void edge_decode(int e, const int* __restrict__ ei_ap,
                                            const int* __restrict__ ei_pa,
                                            const int* __restrict__ ei_pp,
                                            int& src, int& dst) {
    if (e < E0)            { src = ei_ap[e];                 dst = ei_ap[E0 + e]; }
    else if (e < E0 + E1)  { int le = e - E0;
                             src = NA + ei_pa[le];           dst = NP + ei_pa[E1 + le]; }
    else                   { int le = e - E0 - E1;
                             src = NA + NP + ei_pp[le];      dst = ei_pp[E2 + le]; }
}

// ---------------- CSR build ----------------
__global__ void zero_int_kernel(int* __restrict__ p, int n) {
    int i = blockIdx.x * blockDim.x + threadIdx.x;
    int st = gridDim.x * blockDim.x;
    for (int j = i; j < n; j += st) p[j] = 0;
}

__global__ void csr_count_kernel(const int* __restrict__ ei_ap, const int* __restrict__ ei_pa,
                                 const int* __restrict__ ei_pp, int* __restrict__ cnt) {
    int e = blockIdx.x * 256 + threadIdx.x;
    if (e >= ETOT) return;
    int src, dst; edge_decode(e, ei_ap, ei_pa, ei_pp, src, dst);
    atomicAdd(&cnt[dst], 1);
}

__global__ void scan_chunk_sums(const int* __restrict__ cnt, int* __restrict__ csum) {
    __shared__ int sd[256];
    int c = blockIdx.x, t = threadIdx.x;
    int i = c * 256 + t;
    sd[t] = (i < NTOT) ? cnt[i] : 0;
    __syncthreads();
    for (int o = 128; o > 0; o >>= 1) { if (t < o) sd[t] += sd[t + o]; __syncthreads(); }
    if (t == 0) csum[c] = sd[0];
}

__global__ void scan_offsets(const int* __restrict__ csum, int* __restrict__ coff, int nch) {
    __shared__ int sd[1024];
    int t = threadIdx.x;
    int v = (t < nch) ? csum[t] : 0;
    sd[t] = v;
    __syncthreads();
    for (int o = 1; o < 1024; o <<= 1) {
        int x = (t >= o) ? sd[t - o] : 0;
        __syncthreads();
        sd[t] += x;
        __syncthreads();
    }
    if (t < nch) coff[t] = sd[t] - v;   // exclusive
}

__global__ void scan_final(const int* __restrict__ cnt, const int* __restrict__ coff,
                           int* __restrict__ row_ptr, int* __restrict__ cursor) {
    __shared__ int sd[256];
    int c = blockIdx.x, t = threadIdx.x, i = c * 256 + t;
    int v = (i < NTOT) ? cnt[i] : 0;
    sd[t] = v;
    __syncthreads();
    for (int o = 1; o < 256; o <<= 1) {
        int x = (t >= o) ? sd[t - o] : 0;
        __syncthreads();
        sd[t] += x;
        __syncthreads();
    }
    if (i < NTOT) { int ex = coff[c] + sd[t] - v; row_ptr[i] = ex; cursor[i] = ex; }
    if (i == 0) row_ptr[NTOT] = ETOT;
}

__global__ void csr_fill_kernel(const int* __restrict__ ei_ap, const int* __restrict__ ei_pa,
                                const int* __restrict__ ei_pp, int* __restrict__ cursor,
                                int* __restrict__ edge_src) {
    int e = blockIdx.x * 256 + threadIdx.x;
    if (e >= ETOT) return;
    int src, dst; edge_decode(e, ei_ap, ei_pa, ei_pp, src, dst);
    int pos = atomicAdd(&cursor[dst], 1);
    edge_src[pos] = src;
}

// ---------------- fused-weight build (per layer) ----------------
__global__ void fuse_weights_kernel(const float* __restrict__ Wkqv, const float* __restrict__ bkqv,
                                    const float* __restrict__ Wkrel, const float* __restrict__ Wvrel,
                                    float* __restrict__ Wfp, float* __restrict__ bfp,
                                    float* __restrict__ Wfa, float* __restrict__ bfa) {
    int idx = blockIdx.x * 256 + threadIdx.x;
    int type, i, j;
    if (idx < 65 * JP) { type = 0; i = idx / JP; j = idx % JP; }
    else {
        int r = idx - 65 * JP;
        if (r >= 65 * JA) return;
        type = 1; i = r / JA; j = r % JA;
    }
    int c = j >> 6, jj = j & 63, h = jj >> 4, e = jj & 15;
    const float* Wk = Wkqv + (size_t)type * HID * KQV;
    const float* bk = bkqv + type * KQV;
    float val;
    if (c == 0) {
        val = (i < 64) ? Wk[i * KQV + 64 + jj] : bk[64 + jj];
    } else {
        int et, isV;
        if (type == 0) { et = (c == 1 || c == 3) ? 1 : 2; isV = (c >= 3); }
        else           { et = 0; isV = (c == 2); }
        const float* Wr = (isV ? Wvrel : Wkrel) + (size_t)(et * NH + h) * HD * HD;
        int sb = (isV ? 128 : 0) + h * HD;
        val = 0.0f;
        #pragma unroll
        for (int d = 0; d < HD; d++) {
            float a = (i < 64) ? Wk[i * KQV + sb + d] : bk[sb + d];
            val += a * Wr[d * HD + e];
        }
    }
    if (i < 64) (type ? Wfa : Wfp)[i * (type ? JA : JP) + j] = val;
    else        (type ? bfa : bfp)[j] = val;
}

// ---------------- input projection via MFMA bf16 (K=128), paper+author merged ----------------
__global__ __launch_bounds__(256) void gemm_in(
    const float* __restrict__ xp, const float* __restrict__ xa,
    const float* __restrict__ W_in, const float* __restrict__ b_in,
    float* __restrict__ hbuf)
{
    __shared__ unsigned short Xb[64][136];   // 272B rows (16B-aligned)
    __shared__ unsigned short Wt[64][136];   // Wt[col][k]
    int b = blockIdx.x, tid = threadIdx.x;
    int type = (b >= PT);
    int tile = type ? (b - PT) : b;
    int N = type ? NA : NP;
    const float* X = type ? xa : xp;
    const float* W = W_in + (size_t)type * IN_DIM * HID;
    const float* bias = b_in + type * HID;
    float* H = hbuf + (type ? (size_t)NP * HID : 0);
    int nb = tile * 64;

    {
        int row = tid >> 2, c0 = (tid & 3) * 32;
        int n = nb + row;
        if (n < N) {
            const float* xr = X + (size_t)n * IN_DIM + c0;
            #pragma unroll
            for (int i = 0; i < 32; i += 4) {
                float4 v = *(const float4*)(xr + i);
                *(ushort4*)&Xb[row][c0 + i] =
                    make_ushort4(f2bf(v.x), f2bf(v.y), f2bf(v.z), f2bf(v.w));
            }
        } else {
            #pragma unroll
            for (int i = 0; i < 32; i += 4)
                *(ushort4*)&Xb[row][c0 + i] = make_ushort4(0, 0, 0, 0);
        }
    }
    #pragma unroll
    for (int it = 0; it < 8; it++) {
        int idx = it * 256 + tid;            // 0..2047
        int k = idx & 127, c = (idx >> 7) * 4;
        float4 v = *(const float4*)(W + (size_t)k * HID + c);
        Wt[c + 0][k] = f2bf(v.x); Wt[c + 1][k] = f2bf(v.y);
        Wt[c + 2][k] = f2bf(v.z); Wt[c + 3][k] = f2bf(v.w);
    }
    __syncthreads();

    int w = tid >> 6, lane = tid & 63;
    int wr = (w >> 1) * 32, wc = (w & 1) * 32;
    int lrow = lane & 15, lgrp = lane >> 4;

    f32x4 acc00 = {0.f, 0.f, 0.f, 0.f};
    f32x4 acc01 = {0.f, 0.f, 0.f, 0.f};
    f32x4 acc10 = {0.f, 0.f, 0.f, 0.f};
    f32x4 acc11 = {0.f, 0.f, 0.f, 0.f};
    #pragma unroll
    for (int ks = 0; ks < 4; ks++) {
        int ko = ks * 32 + lgrp * 8;
        bf16x8 a0 = *(const bf16x8*)&Xb[wr + lrow][ko];
        bf16x8 a1 = *(const bf16x8*)&Xb[wr + 16 + lrow][ko];
        bf16x8 b0 = *(const bf16x8*)&Wt[wc + lrow][ko];
        bf16x8 b1 = *(const bf16x8*)&Wt[wc + 16 + lrow][ko];
        acc00 = __builtin_amdgcn_mfma_f32_16x16x32_bf16(a0, b0, acc00, 0, 0, 0);
        acc01 = __builtin_amdgcn_mfma_f32_16x16x32_bf16(a0, b1, acc01, 0, 0, 0);
        acc10 = __builtin_amdgcn_mfma_f32_16x16x32_bf16(a1, b0, acc10, 0, 0, 0);
        acc11 = __builtin_amdgcn_mfma_f32_16x16x32_bf16(a1, b1, acc11, 0, 0, 0);
    }

    float bias0 = bias[wc + lrow], bias1 = bias[wc + 16 + lrow];
    #pragma unroll
    for (int mi = 0; mi < 2; mi++) {
        const f32x4 accn0 = mi ? acc10 : acc00;
        const f32x4 accn1 = mi ? acc11 : acc01;
        int rbase = wr + mi * 16 + lgrp * 4;
        #pragma unroll
        for (int r = 0; r < 4; r++) {
            int n = nb + rbase + r;
            if (n >= N) continue;
            H[(size_t)n * HID + wc + lrow]      = accn0[r] + bias0;
            H[(size_t)n * HID + wc + 16 + lrow] = accn1[r] + bias1;
        }
    }
}

// ---------------- KQV GEMM via MFMA bf16: one (row-tile, chunk) per block ----------------
// K/V outputs -> f16 pair layout: row of 64 dwords per src;
// dword[2p] = (k[2p] | k[2p+1]<<16), dword[2p+1] = (v[2p] | v[2p+1]<<16), f16 bits.
// ushort index in 128-ushort row: k at 4*(c>>1)+(c&1), v at +2.
// paper chunks: 0->Q f32 | 1->K@NA | 2->K@NA+NP | 3->V@NA | 4->V@NA+NP
// author chunks: 0->Q@NP | 1->K@0 | 2->V@0
__global__ __launch_bounds__(256) void gemm_kqv(
    const float* __restrict__ hbuf,
    const float* __restrict__ Wfp, const float* __restrict__ bfp,
    const float* __restrict__ Wfa, const float* __restrict__ bfa,
    float* __restrict__ Q, unsigned* __restrict__ KVb)
{
    __shared__ unsigned short Xb[64][72];
    __shared__ unsigned short Wt[64][72];
    int b = blockIdx.x, tid = threadIdx.x;
    int type, tile, chunk;
    if (b < PT * 5) { type = 0; chunk = b / PT; tile = b % PT; }
    else            { int ab = b - PT * 5; type = 1; chunk = ab / AT; tile = ab % AT; }
    int N = type ? NA : NP;
    const float* X = hbuf + (type ? (size_t)NP * HID : 0);
    const float* W = type ? Wfa : Wfp;
    const float* bias = type ? bfa : bfp;
    int ldw = type ? JA : JP;
    int nb = tile * 64;

    {
        int row = tid >> 2, c0 = (tid & 3) * 16;
        int n = nb + row;
        unsigned short tmp[16];
        if (n < N) {
            const float* xr = X + (size_t)n * HID + c0;
            #pragma unroll
            for (int i = 0; i < 16; i += 4) {
                float4 v = *(const float4*)(xr + i);
                tmp[i] = f2bf(v.x); tmp[i+1] = f2bf(v.y);
                tmp[i+2] = f2bf(v.z); tmp[i+3] = f2bf(v.w);
            }
        } else {
            #pragma unroll
            for (int i = 0; i < 16; i++) tmp[i] = 0;
        }
        #pragma unroll
        for (int i = 0; i < 16; i += 4)
            *(ushort4*)&Xb[row][c0 + i] = make_ushort4(tmp[i], tmp[i+1], tmp[i+2], tmp[i+3]);
    }
    #pragma unroll
    for (int it = 0; it < 4; it++) {
        int idx = it * 256 + tid;           // 0..1023
        int k = idx & 63, c = (idx >> 6) * 4;
        float4 v = *(const float4*)(W + (size_t)k * ldw + chunk * 64 + c);
        Wt[c + 0][k] = f2bf(v.x); Wt[c + 1][k] = f2bf(v.y);
        Wt[c + 2][k] = f2bf(v.z); Wt[c + 3][k] = f2bf(v.w);
    }
    __syncthreads();

    int w = tid >> 6, lane = tid & 63;
    int wr = (w >> 1) * 32, wc = (w & 1) * 32;
    int lrow = lane & 15, lgrp = lane >> 4;

    f32x4 acc00 = {0.f, 0.f, 0.f, 0.f};
    f32x4 acc01 = {0.f, 0.f, 0.f, 0.f};
    f32x4 acc10 = {0.f, 0.f, 0.f, 0.f};
    f32x4 acc11 = {0.f, 0.f, 0.f, 0.f};
    #pragma unroll
    for (int ks = 0; ks < 2; ks++) {
        int ko = ks * 32 + lgrp * 8;
        bf16x8 a0 = *(const bf16x8*)&Xb[wr + lrow][ko];
        bf16x8 a1 = *(const bf16x8*)&Xb[wr + 16 + lrow][ko];
        bf16x8 b0 = *(const bf16x8*)&Wt[wc + lrow][ko];
        bf16x8 b1 = *(const bf16x8*)&Wt[wc + 16 + lrow][ko];
        acc00 = __builtin_amdgcn_mfma_f32_16x16x32_bf16(a0, b0, acc00, 0, 0, 0);
        acc01 = __builtin_amdgcn_mfma_f32_16x16x32_bf16(a0, b1, acc01, 0, 0, 0);
        acc10 = __builtin_amdgcn_mfma_f32_16x16x32_bf16(a1, b0, acc10, 0, 0, 0);
        acc11 = __builtin_amdgcn_mfma_f32_16x16x32_bf16(a1, b1, acc11, 0, 0, 0);
    }

    float bias0 = bias[chunk * 64 + wc + lrow];
    float bias1 = bias[chunk * 64 + wc + 16 + lrow];
    int noff, isV = 0;
    bool isQ = (chunk == 0);
    if (isQ) {
        noff = type ? NP : 0;
    } else if (type == 0) {
        isV = (chunk >= 3);
        noff = ((chunk == 1 || chunk == 3) ? NA : NA + NP);
    } else {
        isV = (chunk == 2);
        noff = 0;
    }
    unsigned short* kvh = (unsigned short*)KVb;
    #pragma unroll
    for (int mi = 0; mi < 2; mi++) {
        const f32x4 accn0 = mi ? acc10 : acc00;
        const f32x4 accn1 = mi ? acc11 : acc01;
        int rbase = wr + mi * 16 + lgrp * 4;
        #pragma unroll
        for (int r = 0; r < 4; r++) {
            int n = nb + rbase + r;
            if (n >= N) continue;
            float v0 = accn0[r] + bias0;
            float v1 = accn1[r] + bias1;
            int c0 = wc + lrow, c1 = wc + 16 + lrow;
            if (isQ) {
                Q[(size_t)(noff + n) * HID + c0] = v0;
                Q[(size_t)(noff + n) * HID + c1] = v1;
            } else {
                size_t rowb = ((size_t)(noff + n)) << 7;   // 128 ushorts/row
                kvh[rowb + ((c0 & ~1) << 1) + (c0 & 1) + (isV << 1)] = f2h(v0);
                kvh[rowb + ((c1 & ~1) << 1) + (c1 & 1) + (isV << 1)] = f2h(v1);
            }
        }
    }
}

// ---------------- fused attention: one wave per dst node, 2 edges/iter ----------------
// f16 pair KV: lane p=lane&31 owns dims (2p,2p+1); half-wave 0 takes edge e,
// half 1 takes e+1. One uint2 gather + fdot2 + 3-step shfl reduce per edge.
// Shared (m,s) via cross-half alpha swap; per-half acc merged at the end.
__global__ __launch_bounds__(256) void attn_kernel(
    const float* Q, const unsigned* __restrict__ KVb,
    const float* __restrict__ p_rel, const int* __restrict__ row_ptr,
    const int* __restrict__ edge_src, float* attnout)
{
    int wid = threadIdx.x >> 6, lane = threadIdx.x & 63;
    int n = blockIdx.x * 4 + wid;
    if (n >= NTOT) return;
    int half = lane >> 5;
    int p = lane & 31;           // pair index: dims 2p, 2p+1
    int h = p >> 3;              // head
    float2 qp = *(const float2*)(Q + (size_t)n * HID + 2 * p);
    h16x2 qh; qh[0] = (_Float16)qp.x; qh[1] = (_Float16)qp.y;
    float pr0 = p_rel[h] * 0.25f, pr1 = p_rel[4 + h] * 0.25f, pr2 = p_rel[8 + h] * 0.25f;
    int beg = row_ptr[n], end = row_ptr[n + 1];
    float m = -INFINITY, s = 0.0f;
    float acc0 = 0.f, acc1 = 0.f;
    for (int e = beg; e < end; e += 2) {
        int ee = e + half;
        bool valid = (ee < end);
        int src = valid ? edge_src[ee] : 0;
        uint2 kv = *(const uint2*)(KVb + (((size_t)src) << 6) + 2 * p);
        float dot;
#if __has_builtin(__builtin_amdgcn_fdot2)
        {
            union { unsigned u; h16x2 v; } ck; ck.u = kv.x;
            dot = __builtin_amdgcn_fdot2(qh, ck.v, 0.0f, false);
        }
#else
        {
            union { unsigned u; _Float16 f[2]; } ck; ck.u = kv.x;
            dot = qp.x * (float)ck.f[0] + qp.y * (float)ck.f[1];
        }
#endif
        dot += __shfl_xor(dot, 1, 64);
        dot += __shfl_xor(dot, 2, 64);
        dot += __shfl_xor(dot, 4, 64);
        float prsc = (src < NA) ? pr0 : ((src < NA + NP) ? pr1 : pr2);
        float a_own = valid ? dot * prsc : -INFINITY;
        float a_oth = __shfl_xor(a_own, 32, 64);
        float mn = fmaxf(m, fmaxf(a_own, a_oth));
        float cc = __expf(m - mn);
        float e_own = __expf(a_own - mn);
        float e_oth = __expf(a_oth - mn);
        s = s * cc + e_own + e_oth;
        union { unsigned u; _Float16 f[2]; } cv; cv.u = kv.y;
        acc0 = acc0 * cc + e_own * (float)cv.f[0];
        acc1 = acc1 * cc + e_own * (float)cv.f[1];
        m = mn;
    }
    acc0 += __shfl_xor(acc0, 32, 64);
    acc1 += __shfl_xor(acc1, 32, 64);
    if (half == 0) {
        float inv = 1.0f / (s + 1e-16f);
        float2 o; o.x = acc0 * inv; o.y = acc1 * inv;
        *(float2*)(attnout + (size_t)n * HID + 2 * p) = o;
    }
}

// ---------------- hout via MFMA bf16 + skip + LN + gelu, paper+author merged ----------------
__global__ __launch_bounds__(256) void gemm_hout(
    const float* __restrict__ attnout, const float* __restrict__ Whout,
    const float* __restrict__ bhout, const float* __restrict__ skip_p,
    const float* __restrict__ lng, const float* __restrict__ lnb,
    float* __restrict__ hbuf)
{
    __shared__ unsigned short Xb[64][72];
    __shared__ unsigned short Wt[64][72];
    __shared__ float hs[64][68];
    int b = blockIdx.x, tid = threadIdx.x;
    int type = (b >= PT);
    int tile = type ? (b - PT) : b;
    int N = type ? NA : NP;
    size_t base_off = type ? (size_t)NP * HID : 0;
    const float* X = attnout + base_off;
    const float* W = Whout + (size_t)type * HID * HID;
    const float* bias = bhout + type * HID;
    float* H = hbuf + base_off;
    int nb = tile * 64;

    {
        int row = tid >> 2, c0 = (tid & 3) * 16;
        int n = nb + row;
        unsigned short tmp[16];
        if (n < N) {
            const float* xr = X + (size_t)n * HID + c0;
            #pragma unroll
            for (int i = 0; i < 16; i += 4) {
                float4 v = *(const float4*)(xr + i);
                tmp[i]   = f2bf(gelu_exact(v.x)); tmp[i+1] = f2bf(gelu_exact(v.y));
                tmp[i+2] = f2bf(gelu_exact(v.z)); tmp[i+3] = f2bf(gelu_exact(v.w));
            }
        } else {
            #pragma unroll
            for (int i = 0; i < 16; i++) tmp[i] = 0;
        }
        #pragma unroll
        for (int i = 0; i < 16; i += 4)
            *(ushort4*)&Xb[row][c0 + i] = make_ushort4(tmp[i], tmp[i+1], tmp[i+2], tmp[i+3]);
    }
    #pragma unroll
    for (int it = 0; it < 4; it++) {
        int idx = it * 256 + tid;
        int k = idx & 63, c = (idx >> 6) * 4;
        float4 v = *(const float4*)(W + (size_t)k * HID + c);
        Wt[c + 0][k] = f2bf(v.x); Wt[c + 1][k] = f2bf(v.y);
        Wt[c + 2][k] = f2bf(v.z); Wt[c + 3][k] = f2bf(v.w);
    }
    __syncthreads();

    int w = tid >> 6, lane = tid & 63;
    int wr = (w >> 1) * 32, wc = (w & 1) * 32;
    int lrow = lane & 15, lgrp = lane >> 4;

    f32x4 acc00 = {0.f, 0.f, 0.f, 0.f};
    f32x4 acc01 = {0.f, 0.f, 0.f, 0.f};
    f32x4 acc10 = {0.f, 0.f, 0.f, 0.f};
    f32x4 acc11 = {0.f, 0.f, 0.f, 0.f};
    #pragma unroll
    for (int ks = 0; ks < 2; ks++) {
        int ko = ks * 32 + lgrp * 8;
        bf16x8 a0 = *(const bf16x8*)&Xb[wr + lrow][ko];
        bf16x8 a1 = *(const bf16x8*)&Xb[wr + 16 + lrow][ko];
        bf16x8 b0 = *(const bf16x8*)&Wt[wc + lrow][ko];
        bf16x8 b1 = *(const bf16x8*)&Wt[wc + 16 + lrow][ko];
        acc00 = __builtin_amdgcn_mfma_f32_16x16x32_bf16(a0, b0, acc00, 0, 0, 0);
        acc01 = __builtin_amdgcn_mfma_f32_16x16x32_bf16(a0, b1, acc01, 0, 0, 0);
        acc10 = __builtin_amdgcn_mfma_f32_16x16x32_bf16(a1, b0, acc10, 0, 0, 0);
        acc11 = __builtin_amdgcn_mfma_f32_16x16x32_bf16(a1, b1, acc11, 0, 0, 0);
    }

    float a = 1.0f / (1.0f + __expf(-skip_p[type]));
    float oma = 1.0f - a;
    float bias0 = bias[wc + lrow], bias1 = bias[wc + 16 + lrow];
    #pragma unroll
    for (int mi = 0; mi < 2; mi++) {
        const f32x4 accn0 = mi ? acc10 : acc00;
        const f32x4 accn1 = mi ? acc11 : acc01;
        int rbase = wr + mi * 16 + lgrp * 4;
        #pragma unroll
        for (int r = 0; r < 4; r++) {
            int row = rbase + r;
            int n = nb + row;
            if (n < N) {
                const float* hp = H + (size_t)n * HID;
                hs[row][wc + lrow]      = a * (accn0[r] + bias0) + oma * hp[wc + lrow];
                hs[row][wc + 16 + lrow] = a * (accn1[r] + bias1) + oma * hp[wc + 16 + lrow];
            } else {
                hs[row][wc + lrow] = 0.f;
                hs[row][wc + 16 + lrow] = 0.f;
            }
        }
    }
    __syncthreads();

    const int tr = tid >> 4, tc = tid & 15;
    const int tcj = tc * 4;
    float g0 = lng[type*HID+tcj], g1 = lng[type*HID+tcj+1],
          g2 = lng[type*HID+tcj+2], g3 = lng[type*HID+tcj+3];
    float l0 = lnb[type*HID+tcj], l1 = lnb[type*HID+tcj+1],
          l2 = lnb[type*HID+tcj+2], l3 = lnb[type*HID+tcj+3];
    #pragma unroll 1
    for (int m = 0; m < 4; m++) {
        int row = tr * 4 + m;
        int n = nb + row;
        float v0 = hs[row][tcj], v1 = hs[row][tcj+1], v2 = hs[row][tcj+2], v3 = hs[row][tcj+3];
        float sum = v0 + v1 + v2 + v3;
        sum += __shfl_xor(sum, 1, 64); sum += __shfl_xor(sum, 2, 64);
        sum += __shfl_xor(sum, 4, 64); sum += __shfl_xor(sum, 8, 64);
        float mean = sum * (1.0f / 64.0f);
        float d0 = v0 - mean, d1 = v1 - mean, d2 = v2 - mean, d3 = v3 - mean;
        float sq = d0*d0 + d1*d1 + d2*d2 + d3*d3;
        sq += __shfl_xor(sq, 1, 64); sq += __shfl_xor(sq, 2, 64);
        sq += __shfl_xor(sq, 4, 64); sq += __shfl_xor(sq, 8, 64);
        float rstd = rsqrtf(sq * (1.0f / 64.0f) + 1e-5f);
        if (n < N) {
            float* hp = H + (size_t)n * HID + tcj;
            hp[0] = gelu_exact(d0 * rstd * g0 + l0);
            hp[1] = gelu_exact(d1 * rstd * g1 + l1);
            hp[2] = gelu_exact(d2 * rstd * g2 + l2);
            hp[3] = gelu_exact(d3 * rstd * g3 + l3);
        }
    }
}

// ---------------- final linear via MFMA bf16 (K=64), paper+author merged ----------------
__global__ __launch_bounds__(256) void gemm_out(
    const float* __restrict__ hbuf, const float* __restrict__ W_out,
    const float* __restrict__ b_out, float* __restrict__ out)
{
    __shared__ unsigned short Xb[64][72];
    __shared__ unsigned short Wt[64][72];
    int b = blockIdx.x, tid = threadIdx.x;
    int type = (b >= PT);
    int tile = type ? (b - PT) : b;
    int N = type ? NA : NP;
    size_t base_off = type ? (size_t)NP * HID : 0;
    const float* X = hbuf + base_off;
    const float* W = W_out + (size_t)type * HID * HID;
    const float* bias = b_out + type * HID;
    float* O = out + base_off;
    int nb = tile * 64;

    {
        int row = tid >> 2, c0 = (tid & 3) * 16;
        int n = nb + row;
        unsigned short tmp[16];
        if (n < N) {
            const float* xr = X + (size_t)n * HID + c0;
            #pragma unroll
            for (int i = 0; i < 16; i += 4) {
                float4 v = *(const float4*)(xr + i);
                tmp[i] = f2bf(v.x); tmp[i+1] = f2bf(v.y);
                tmp[i+2] = f2bf(v.z); tmp[i+3] = f2bf(v.w);
            }
        } else {
            #pragma unroll
            for (int i = 0; i < 16; i++) tmp[i] = 0;
        }
        #pragma unroll
        for (int i = 0; i < 16; i += 4)
            *(ushort4*)&Xb[row][c0 + i] = make_ushort4(tmp[i], tmp[i+1], tmp[i+2], tmp[i+3]);
    }
    #pragma unroll
    for (int it = 0; it < 4; it++) {
        int idx = it * 256 + tid;
        int k = idx & 63, c = (idx >> 6) * 4;
        float4 v = *(const float4*)(W + (size_t)k * HID + c);
        Wt[c + 0][k] = f2bf(v.x); Wt[c + 1][k] = f2bf(v.y);
        Wt[c + 2][k] = f2bf(v.z); Wt[c + 3][k] = f2bf(v.w);
    }
    __syncthreads();

    int w = tid >> 6, lane = tid & 63;
    int wr = (w >> 1) * 32, wc = (w & 1) * 32;
    int lrow = lane & 15, lgrp = lane >> 4;

    f32x4 acc00 = {0.f, 0.f, 0.f, 0.f};
    f32x4 acc01 = {0.f, 0.f, 0.f, 0.f};
    f32x4 acc10 = {0.f, 0.f, 0.f, 0.f};
    f32x4 acc11 = {0.f, 0.f, 0.f, 0.f};
    #pragma unroll
    for (int ks = 0; ks < 2; ks++) {
        int ko = ks * 32 + lgrp * 8;
        bf16x8 a0 = *(const bf16x8*)&Xb[wr + lrow][ko];
        bf16x8 a1 = *(const bf16x8*)&Xb[wr + 16 + lrow][ko];
        bf16x8 b0 = *(const bf16x8*)&Wt[wc + lrow][ko];
        bf16x8 b1 = *(const bf16x8*)&Wt[wc + 16 + lrow][ko];
        acc00 = __builtin_amdgcn_mfma_f32_16x16x32_bf16(a0, b0, acc00, 0, 0, 0);
        acc01 = __builtin_amdgcn_mfma_f32_16x16x32_bf16(a0, b1, acc01, 0, 0, 0);
        acc10 = __builtin_amdgcn_mfma_f32_16x16x32_bf16(a1, b0, acc10, 0, 0, 0);
        acc11 = __builtin_amdgcn_mfma_f32_16x16x32_bf16(a1, b1, acc11, 0, 0, 0);
    }

    float bias0 = bias[wc + lrow], bias1 = bias[wc + 16 + lrow];
    #pragma unroll
    for (int mi = 0; mi < 2; mi++) {
        const f32x4 accn0 = mi ? acc10 : acc00;
        const f32x4 accn1 = mi ? acc11 : acc01;
        int rbase = wr + mi * 16 + lgrp * 4;
        #pragma unroll
        for (int r = 0; r < 4; r++) {
            int n = nb + rbase + r;
            if (n >= N) continue;
            O[(size_t)n * HID + wc + lrow]      = accn0[r] + bias0;
            O[(size_t)n * HID + wc + 16 + lrow] = accn1[r] + bias1;
        }
    }
}

extern "C" void kernel_launch(void* const* d_in, const int* in_sizes, int n_in,
                              void* d_out, int out_size, void* d_ws, size_t ws_size,
                              hipStream_t stream) {
    const float* x_paper  = (const float*)d_in[0];
    const float* x_author = (const float*)d_in[1];
    const int*   ei_ap    = (const int*)d_in[2];
    const int*   ei_pa    = (const int*)d_in[3];
    const int*   ei_pp    = (const int*)d_in[4];
    const float* W_in     = (const float*)d_in[5];
    const float* b_in     = (const float*)d_in[6];
    const float* W_kqv    = (const float*)d_in[7];
    const float* b_kqv    = (const float*)d_in[8];
    const float* W_krel   = (const float*)d_in[9];
    const float* W_vrel   = (const float*)d_in[10];
    const float* p_rel    = (const float*)d_in[11];
    const float* W_hout   = (const float*)d_in[12];
    const float* b_hout   = (const float*)d_in[13];
    const float* skip     = (const float*)d_in[14];
    const float* ln_g     = (const float*)d_in[15];
    const float* ln_b     = (const float*)d_in[16];
    const float* W_out    = (const float*)d_in[17];
    const float* b_out    = (const float*)d_in[18];
    float* out            = (float*)d_out;

    // ---- workspace layout (~146 MB) ----
    float* ws   = (float*)d_ws;
    float* hbuf = ws;                                   // NTOT*64 f32
    float* Q    = hbuf + (size_t)NTOT * HID;            // NTOT*64 f32 (attn out aliases Q)
    unsigned* KVb = (unsigned*)(Q + (size_t)NTOT * HID); // NSRC*64 dwords (f16 k/v pairs)
    float* Wfp  = (float*)(KVb + (size_t)NSRC * HID);   // 64*320
    float* bfp  = Wfp  + 64 * JP;                       // 320
    float* Wfa  = bfp  + JP;                            // 64*192
    float* bfa  = Wfa  + 64 * JA;                       // 192
    int* cnt      = (int*)(bfa + JA);                   // NTOT
    int* row_ptr  = cnt + NTOT;                         // NTOT+1 (pad 16)
    int* cursor   = row_ptr + NTOT + 16;                // NTOT
    int* edge_src = cursor + NTOT;                      // ETOT
    int* csum     = edge_src + ETOT;                    // 1024
    int* coff     = csum + 1024;                        // 1024

    dim3 blk(256);
    const int EB = (ETOT + 255) / 256;

    // ---- CSR build (edges are layer-invariant) ----
    zero_int_kernel<<<256, blk, 0, stream>>>(cnt, NTOT);
    csr_count_kernel<<<EB, blk, 0, stream>>>(ei_ap, ei_pa, ei_pp, cnt);
    scan_chunk_sums<<<NCH, blk, 0, stream>>>(cnt, csum);
    scan_offsets<<<1, 1024, 0, stream>>>(csum, coff, NCH);
    scan_final<<<NCH, blk, 0, stream>>>(cnt, coff, row_ptr, cursor);
    csr_fill_kernel<<<EB, blk, 0, stream>>>(ei_ap, ei_pa, ei_pp, cursor, edge_src);

    // ---- input projection ----
    gemm_in<<<PT + AT, blk, 0, stream>>>(x_paper, x_author, W_in, b_in, hbuf);

    for (int l = 0; l < LAYERS; l++) {
        fuse_weights_kernel<<<(65 * JP + 65 * JA + 255) / 256, blk, 0, stream>>>(
            W_kqv + (size_t)l * 2 * HID * KQV, b_kqv + (size_t)l * 2 * KQV,
            W_krel + (size_t)l * 3 * NH * HD * HD, W_vrel + (size_t)l * 3 * NH * HD * HD,
            Wfp, bfp, Wfa, bfa);
        gemm_kqv<<<PT * 5 + AT * 3, blk, 0, stream>>>(
            hbuf, Wfp, bfp, Wfa, bfa, Q, KVb);
        attn_kernel<<<(NTOT + 3) / 4, blk, 0, stream>>>(
            Q, KVb, p_rel + l * 3 * NH, row_ptr, edge_src, Q);
        gemm_hout<<<PT + AT, blk, 0, stream>>>(
            Q, W_hout + (size_t)l * 2 * HID * HID, b_hout + l * 2 * HID,
            skip + l * 2, ln_g + l * 2 * HID, ln_b + l * 2 * HID, hbuf);
    }

    gemm_out<<<PT + AT, blk, 0, stream>>>(hbuf, W_out, b_out, out);
}

// Round 11
// 482.768 us; speedup vs baseline: 3.8810x; 1.0326x over previous
//
#include <hip/hip_runtime.h>
#include <hip/hip_bf16.h>

// ---- problem constants (match reference) ----
#define NP 100000
#define NA 50000
#define NTOT 150000          // NP+NA
#define E0 300000
#define E1 300000
#define E2 200000
#define ETOT 800000
#define NH 4
#define HD 16
#define HID 64
#define IN_DIM 128
#define KQV 192
#define LAYERS 2
#define NSRC 250000          // NA + 2*NP
#define JP 320               // fused paper cols: q | k_et1 | k_et2 | v_et1 | v_et2
#define JA 192               // fused author cols: q | k_et0 | v_et0
#define NCH 586              // ceil(NTOT/256)
#define PT 1563              // ceil(NP/64)
#define AT 782               // ceil(NA/64)

typedef __attribute__((ext_vector_type(8))) short bf16x8;   // 8 bf16 (4 VGPRs)
typedef __attribute__((ext_vector_type(4))) float f32x4;    // MFMA C/D
typedef _Float16 h16x2 __attribute__((ext_vector_type(2)));

__device__ __forceinline__ float gelu_exact(float x) {
    return 0.5f * x * (1.0f + erff(x * 0.7071067811865475f));
}
// f32 -> bf16 bits, round-to-nearest-even (finite values)
__device__ __forceinline__ unsigned short f2bf(float f) {
    unsigned u = __float_as_uint(f);
    return (unsigned short)((u + 0x7fffu + ((u >> 16) & 1u)) >> 16);
}
// f32 -> f16 bits (RNE via hardware cvt)
__device__ __forceinline__ unsigned short f2h(float f) {
    union { _Float16 h; unsigned short u; } c;
    c.h = (_Float16)f;
    return c.u;
}

// decode global edge id -> (src in KV space, dst in node space)
__device__ __forceinline__ void edge_decode(int e, const int* __restrict__ ei_ap,
                                            const int* __restrict__ ei_pa,
                                            const int* __restrict__ ei_pp,
                                            int& src, int& dst) {
    if (e < E0)            { src = ei_ap[e];                 dst = ei_ap[E0 + e]; }
    else if (e < E0 + E1)  { int le = e - E0;
                             src = NA + ei_pa[le];           dst = NP + ei_pa[E1 + le]; }
    else                   { int le = e - E0 - E1;
                             src = NA + NP + ei_pp[le];      dst = ei_pp[E2 + le]; }
}

// ---------------- CSR build ----------------
__global__ void zero_int_kernel(int* __restrict__ p, int n) {
    int i = blockIdx.x * blockDim.x + threadIdx.x;
    int st = gridDim.x * blockDim.x;
    for (int j = i; j < n; j += st) p[j] = 0;
}

__global__ void csr_count_kernel(const int* __restrict__ ei_ap, const int* __restrict__ ei_pa,
                                 const int* __restrict__ ei_pp, int* __restrict__ cnt) {
    int e = blockIdx.x * 256 + threadIdx.x;
    if (e >= ETOT) return;
    int src, dst; edge_decode(e, ei_ap, ei_pa, ei_pp, src, dst);
    atomicAdd(&cnt[dst], 1);
}

__global__ void scan_chunk_sums(const int* __restrict__ cnt, int* __restrict__ csum) {
    __shared__ int sd[256];
    int c = blockIdx.x, t = threadIdx.x;
    int i = c * 256 + t;
    sd[t] = (i < NTOT) ? cnt[i] : 0;
    __syncthreads();
    for (int o = 128; o > 0; o >>= 1) { if (t < o) sd[t] += sd[t + o]; __syncthreads(); }
    if (t == 0) csum[c] = sd[0];
}

__global__ void scan_offsets(const int* __restrict__ csum, int* __restrict__ coff, int nch) {
    __shared__ int sd[1024];
    int t = threadIdx.x;
    int v = (t < nch) ? csum[t] : 0;
    sd[t] = v;
    __syncthreads();
    for (int o = 1; o < 1024; o <<= 1) {
        int x = (t >= o) ? sd[t - o] : 0;
        __syncthreads();
        sd[t] += x;
        __syncthreads();
    }
    if (t < nch) coff[t] = sd[t] - v;   // exclusive
}

__global__ void scan_final(const int* __restrict__ cnt, const int* __restrict__ coff,
                           int* __restrict__ row_ptr, int* __restrict__ cursor) {
    __shared__ int sd[256];
    int c = blockIdx.x, t = threadIdx.x, i = c * 256 + t;
    int v = (i < NTOT) ? cnt[i] : 0;
    sd[t] = v;
    __syncthreads();
    for (int o = 1; o < 256; o <<= 1) {
        int x = (t >= o) ? sd[t - o] : 0;
        __syncthreads();
        sd[t] += x;
        __syncthreads();
    }
    if (i < NTOT) { int ex = coff[c] + sd[t] - v; row_ptr[i] = ex; cursor[i] = ex; }
    if (i == 0) row_ptr[NTOT] = ETOT;
}

__global__ void csr_fill_kernel(const int* __restrict__ ei_ap, const int* __restrict__ ei_pa,
                                const int* __restrict__ ei_pp, int* __restrict__ cursor,
                                int* __restrict__ edge_src) {
    int e = blockIdx.x * 256 + threadIdx.x;
    if (e >= ETOT) return;
    int src, dst; edge_decode(e, ei_ap, ei_pa, ei_pp, src, dst);
    int pos = atomicAdd(&cursor[dst], 1);
    edge_src[pos] = src;
}

// ---------------- fused-weight build (per layer) ----------------
__global__ void fuse_weights_kernel(const float* __restrict__ Wkqv, const float* __restrict__ bkqv,
                                    const float* __restrict__ Wkrel, const float* __restrict__ Wvrel,
                                    float* __restrict__ Wfp, float* __restrict__ bfp,
                                    float* __restrict__ Wfa, float* __restrict__ bfa) {
    int idx = blockIdx.x * 256 + threadIdx.x;
    int type, i, j;
    if (idx < 65 * JP) { type = 0; i = idx / JP; j = idx % JP; }
    else {
        int r = idx - 65 * JP;
        if (r >= 65 * JA) return;
        type = 1; i = r / JA; j = r % JA;
    }
    int c = j >> 6, jj = j & 63, h = jj >> 4, e = jj & 15;
    const float* Wk = Wkqv + (size_t)type * HID * KQV;
    const float* bk = bkqv + type * KQV;
    float val;
    if (c == 0) {
        val = (i < 64) ? Wk[i * KQV + 64 + jj] : bk[64 + jj];
    } else {
        int et, isV;
        if (type == 0) { et = (c == 1 || c == 3) ? 1 : 2; isV = (c >= 3); }
        else           { et = 0; isV = (c == 2); }
        const float* Wr = (isV ? Wvrel : Wkrel) + (size_t)(et * NH + h) * HD * HD;
        int sb = (isV ? 128 : 0) + h * HD;
        val = 0.0f;
        #pragma unroll
        for (int d = 0; d < HD; d++) {
            float a = (i < 64) ? Wk[i * KQV + sb + d] : bk[sb + d];
            val += a * Wr[d * HD + e];
        }
    }
    if (i < 64) (type ? Wfa : Wfp)[i * (type ? JA : JP) + j] = val;
    else        (type ? bfa : bfp)[j] = val;
}

// ---------------- input projection via MFMA bf16 (K=128), paper+author merged ----------------
__global__ __launch_bounds__(256) void gemm_in(
    const float* __restrict__ xp, const float* __restrict__ xa,
    const float* __restrict__ W_in, const float* __restrict__ b_in,
    float* __restrict__ hbuf)
{
    __shared__ unsigned short Xb[64][136];   // 272B rows (16B-aligned)
    __shared__ unsigned short Wt[64][136];   // Wt[col][k]
    int b = blockIdx.x, tid = threadIdx.x;
    int type = (b >= PT);
    int tile = type ? (b - PT) : b;
    int N = type ? NA : NP;
    const float* X = type ? xa : xp;
    const float* W = W_in + (size_t)type * IN_DIM * HID;
    const float* bias = b_in + type * HID;
    float* H = hbuf + (type ? (size_t)NP * HID : 0);
    int nb = tile * 64;

    {
        int row = tid >> 2, c0 = (tid & 3) * 32;
        int n = nb + row;
        if (n < N) {
            const float* xr = X + (size_t)n * IN_DIM + c0;
            #pragma unroll
            for (int i = 0; i < 32; i += 4) {
                float4 v = *(const float4*)(xr + i);
                *(ushort4*)&Xb[row][c0 + i] =
                    make_ushort4(f2bf(v.x), f2bf(v.y), f2bf(v.z), f2bf(v.w));
            }
        } else {
            #pragma unroll
            for (int i = 0; i < 32; i += 4)
                *(ushort4*)&Xb[row][c0 + i] = make_ushort4(0, 0, 0, 0);
        }
    }
    #pragma unroll
    for (int it = 0; it < 8; it++) {
        int idx = it * 256 + tid;            // 0..2047
        int k = idx & 127, c = (idx >> 7) * 4;
        float4 v = *(const float4*)(W + (size_t)k * HID + c);
        Wt[c + 0][k] = f2bf(v.x); Wt[c + 1][k] = f2bf(v.y);
        Wt[c + 2][k] = f2bf(v.z); Wt[c + 3][k] = f2bf(v.w);
    }
    __syncthreads();

    int w = tid >> 6, lane = tid & 63;
    int wr = (w >> 1) * 32, wc = (w & 1) * 32;
    int lrow = lane & 15, lgrp = lane >> 4;

    f32x4 acc00 = {0.f, 0.f, 0.f, 0.f};
    f32x4 acc01 = {0.f, 0.f, 0.f, 0.f};
    f32x4 acc10 = {0.f, 0.f, 0.f, 0.f};
    f32x4 acc11 = {0.f, 0.f, 0.f, 0.f};
    #pragma unroll
    for (int ks = 0; ks < 4; ks++) {
        int ko = ks * 32 + lgrp * 8;
        bf16x8 a0 = *(const bf16x8*)&Xb[wr + lrow][ko];
        bf16x8 a1 = *(const bf16x8*)&Xb[wr + 16 + lrow][ko];
        bf16x8 b0 = *(const bf16x8*)&Wt[wc + lrow][ko];
        bf16x8 b1 = *(const bf16x8*)&Wt[wc + 16 + lrow][ko];
        acc00 = __builtin_amdgcn_mfma_f32_16x16x32_bf16(a0, b0, acc00, 0, 0, 0);
        acc01 = __builtin_amdgcn_mfma_f32_16x16x32_bf16(a0, b1, acc01, 0, 0, 0);
        acc10 = __builtin_amdgcn_mfma_f32_16x16x32_bf16(a1, b0, acc10, 0, 0, 0);
        acc11 = __builtin_amdgcn_mfma_f32_16x16x32_bf16(a1, b1, acc11, 0, 0, 0);
    }

    float bias0 = bias[wc + lrow], bias1 = bias[wc + 16 + lrow];
    #pragma unroll
    for (int mi = 0; mi < 2; mi++) {
        const f32x4 accn0 = mi ? acc10 : acc00;
        const f32x4 accn1 = mi ? acc11 : acc01;
        int rbase = wr + mi * 16 + lgrp * 4;
        #pragma unroll
        for (int r = 0; r < 4; r++) {
            int n = nb + rbase + r;
            if (n >= N) continue;
            H[(size_t)n * HID + wc + lrow]      = accn0[r] + bias0;
            H[(size_t)n * HID + wc + 16 + lrow] = accn1[r] + bias1;
        }
    }
}

// ---------------- KQV GEMM via MFMA bf16: one (row-tile, chunk) per block ----------------
// K/V outputs -> f16 pair layout: row of 64 dwords per src;
// dword[2p] = (k[2p] | k[2p+1]<<16), dword[2p+1] = (v[2p] | v[2p+1]<<16), f16 bits.
// paper chunks: 0->Q f32 | 1->K@NA | 2->K@NA+NP | 3->V@NA | 4->V@NA+NP
// author chunks: 0->Q@NP | 1->K@0 | 2->V@0
__global__ __launch_bounds__(256) void gemm_kqv(
    const float* __restrict__ hbuf,
    const float* __restrict__ Wfp, const float* __restrict__ bfp,
    const float* __restrict__ Wfa, const float* __restrict__ bfa,
    float* __restrict__ Q, unsigned* __restrict__ KVb)
{
    __shared__ unsigned short Xb[64][72];
    __shared__ unsigned short Wt[64][72];
    int b = blockIdx.x, tid = threadIdx.x;
    int type, tile, chunk;
    if (b < PT * 5) { type = 0; chunk = b / PT; tile = b % PT; }
    else            { int ab = b - PT * 5; type = 1; chunk = ab / AT; tile = ab % AT; }
    int N = type ? NA : NP;
    const float* X = hbuf + (type ? (size_t)NP * HID : 0);
    const float* W = type ? Wfa : Wfp;
    const float* bias = type ? bfa : bfp;
    int ldw = type ? JA : JP;
    int nb = tile * 64;

    {
        int row = tid >> 2, c0 = (tid & 3) * 16;
        int n = nb + row;
        unsigned short tmp[16];
        if (n < N) {
            const float* xr = X + (size_t)n * HID + c0;
            #pragma unroll
            for (int i = 0; i < 16; i += 4) {
                float4 v = *(const float4*)(xr + i);
                tmp[i] = f2bf(v.x); tmp[i+1] = f2bf(v.y);
                tmp[i+2] = f2bf(v.z); tmp[i+3] = f2bf(v.w);
            }
        } else {
            #pragma unroll
            for (int i = 0; i < 16; i++) tmp[i] = 0;
        }
        #pragma unroll
        for (int i = 0; i < 16; i += 4)
            *(ushort4*)&Xb[row][c0 + i] = make_ushort4(tmp[i], tmp[i+1], tmp[i+2], tmp[i+3]);
    }
    #pragma unroll
    for (int it = 0; it < 4; it++) {
        int idx = it * 256 + tid;           // 0..1023
        int k = idx & 63, c = (idx >> 6) * 4;
        float4 v = *(const float4*)(W + (size_t)k * ldw + chunk * 64 + c);
        Wt[c + 0][k] = f2bf(v.x); Wt[c + 1][k] = f2bf(v.y);
        Wt[c + 2][k] = f2bf(v.z); Wt[c + 3][k] = f2bf(v.w);
    }
    __syncthreads();

    int w = tid >> 6, lane = tid & 63;
    int wr = (w >> 1) * 32, wc = (w & 1) * 32;
    int lrow = lane & 15, lgrp = lane >> 4;

    f32x4 acc00 = {0.f, 0.f, 0.f, 0.f};
    f32x4 acc01 = {0.f, 0.f, 0.f, 0.f};
    f32x4 acc10 = {0.f, 0.f, 0.f, 0.f};
    f32x4 acc11 = {0.f, 0.f, 0.f, 0.f};
    #pragma unroll
    for (int ks = 0; ks < 2; ks++) {
        int ko = ks * 32 + lgrp * 8;
        bf16x8 a0 = *(const bf16x8*)&Xb[wr + lrow][ko];
        bf16x8 a1 = *(const bf16x8*)&Xb[wr + 16 + lrow][ko];
        bf16x8 b0 = *(const bf16x8*)&Wt[wc + lrow][ko];
        bf16x8 b1 = *(const bf16x8*)&Wt[wc + 16 + lrow][ko];
        acc00 = __builtin_amdgcn_mfma_f32_16x16x32_bf16(a0, b0, acc00, 0, 0, 0);
        acc01 = __builtin_amdgcn_mfma_f32_16x16x32_bf16(a0, b1, acc01, 0, 0, 0);
        acc10 = __builtin_amdgcn_mfma_f32_16x16x32_bf16(a1, b0, acc10, 0, 0, 0);
        acc11 = __builtin_amdgcn_mfma_f32_16x16x32_bf16(a1, b1, acc11, 0, 0, 0);
    }

    float bias0 = bias[chunk * 64 + wc + lrow];
    float bias1 = bias[chunk * 64 + wc + 16 + lrow];
    int noff, isV = 0;
    bool isQ = (chunk == 0);
    if (isQ) {
        noff = type ? NP : 0;
    } else if (type == 0) {
        isV = (chunk >= 3);
        noff = ((chunk == 1 || chunk == 3) ? NA : NA + NP);
    } else {
        isV = (chunk == 2);
        noff = 0;
    }
    unsigned short* kvh = (unsigned short*)KVb;
    #pragma unroll
    for (int mi = 0; mi < 2; mi++) {
        const f32x4 accn0 = mi ? acc10 : acc00;
        const f32x4 accn1 = mi ? acc11 : acc01;
        int rbase = wr + mi * 16 + lgrp * 4;
        #pragma unroll
        for (int r = 0; r < 4; r++) {
            int n = nb + rbase + r;
            if (n >= N) continue;
            float v0 = accn0[r] + bias0;
            float v1 = accn1[r] + bias1;
            int c0 = wc + lrow, c1 = wc + 16 + lrow;
            if (isQ) {
                Q[(size_t)(noff + n) * HID + c0] = v0;
                Q[(size_t)(noff + n) * HID + c1] = v1;
            } else {
                size_t rowb = ((size_t)(noff + n)) << 7;   // 128 ushorts/row
                kvh[rowb + ((c0 & ~1) << 1) + (c0 & 1) + (isV << 1)] = f2h(v0);
                kvh[rowb + ((c1 & ~1) << 1) + (c1 & 1) + (isV << 1)] = f2h(v1);
            }
        }
    }
}

// ---------------- fused attention: one wave per dst node, 4 edges/iter ----------------
// MLP-bound fix (R10 post-mortem): 2 independent uint2 gathers in flight per
// iteration (4 edges via half-waves), exp2-domain softmax (1/ln2 folded into
// p_rel), cross-half exp values via shfl instead of recompute, clamped
// unconditional loads (invalid edges contribute alpha=-inf -> p=0).
__global__ __launch_bounds__(256) void attn_kernel(
    const float* Q, const unsigned* __restrict__ KVb,
    const float* __restrict__ p_rel, const int* __restrict__ row_ptr,
    const int* __restrict__ edge_src, float* attnout)
{
    int wid = threadIdx.x >> 6, lane = threadIdx.x & 63;
    int n = blockIdx.x * 4 + wid;
    if (n >= NTOT) return;
    int half = lane >> 5;
    int p = lane & 31;           // pair index: dims 2p, 2p+1
    int h = p >> 3;              // head
    float2 qp = *(const float2*)(Q + (size_t)n * HID + 2 * p);
    h16x2 qh; qh[0] = (_Float16)qp.x; qh[1] = (_Float16)qp.y;
    const float INV_LN2 = 1.4426950408889634f;
    float pr0 = p_rel[h] * 0.25f * INV_LN2;
    float pr1 = p_rel[4 + h] * 0.25f * INV_LN2;
    float pr2 = p_rel[8 + h] * 0.25f * INV_LN2;
    int beg = row_ptr[n], end = row_ptr[n + 1];
    float m = -INFINITY, s = 0.0f;
    float acc0 = 0.f, acc1 = 0.f;
    for (int e = beg; e < end; e += 4) {
        int e0 = e + half;           // edges e, e+1
        int e1 = e + 2 + half;       // edges e+2, e+3
        bool v0 = (e0 < end), v1 = (e1 < end);
        int s0 = edge_src[v0 ? e0 : beg];
        int s1 = edge_src[v1 ? e1 : beg];
        uint2 kv0 = *(const uint2*)(KVb + (((size_t)s0) << 6) + 2 * p);
        uint2 kv1 = *(const uint2*)(KVb + (((size_t)s1) << 6) + 2 * p);
        float d0, d1;
#if __has_builtin(__builtin_amdgcn_fdot2)
        {
            union { unsigned u; h16x2 v; } ck;
            ck.u = kv0.x; d0 = __builtin_amdgcn_fdot2(qh, ck.v, 0.0f, false);
            ck.u = kv1.x; d1 = __builtin_amdgcn_fdot2(qh, ck.v, 0.0f, false);
        }
#else
        {
            union { unsigned u; _Float16 f[2]; } ck;
            ck.u = kv0.x; d0 = qp.x * (float)ck.f[0] + qp.y * (float)ck.f[1];
            ck.u = kv1.x; d1 = qp.x * (float)ck.f[0] + qp.y * (float)ck.f[1];
        }
#endif
        d0 += __shfl_xor(d0, 1, 64);  d1 += __shfl_xor(d1, 1, 64);
        d0 += __shfl_xor(d0, 2, 64);  d1 += __shfl_xor(d1, 2, 64);
        d0 += __shfl_xor(d0, 4, 64);  d1 += __shfl_xor(d1, 4, 64);
        float pa = (s0 < NA) ? pr0 : ((s0 < NA + NP) ? pr1 : pr2);
        float pb = (s1 < NA) ? pr0 : ((s1 < NA + NP) ? pr1 : pr2);
        float a0 = v0 ? d0 * pa : -INFINITY;
        float a1 = v1 ? d1 * pb : -INFINITY;
        float a0x = __shfl_xor(a0, 32, 64);
        float a1x = __shfl_xor(a1, 32, 64);
        float mn = fmaxf(m, fmaxf(fmaxf(a0, a0x), fmaxf(a1, a1x)));
        float cc = exp2f(m - mn);
        float p0 = exp2f(a0 - mn);
        float p1 = exp2f(a1 - mn);
        float p0x = __shfl_xor(p0, 32, 64);
        float p1x = __shfl_xor(p1, 32, 64);
        s = s * cc + p0 + p1 + p0x + p1x;
        union { unsigned u; _Float16 f[2]; } cv0, cv1;
        cv0.u = kv0.y; cv1.u = kv1.y;
        acc0 = acc0 * cc + p0 * (float)cv0.f[0] + p1 * (float)cv1.f[0];
        acc1 = acc1 * cc + p0 * (float)cv0.f[1] + p1 * (float)cv1.f[1];
        m = mn;
    }
    acc0 += __shfl_xor(acc0, 32, 64);
    acc1 += __shfl_xor(acc1, 32, 64);
    if (half == 0) {
        float inv = 1.0f / (s + 1e-16f);
        float2 o; o.x = acc0 * inv; o.y = acc1 * inv;
        *(float2*)(attnout + (size_t)n * HID + 2 * p) = o;
    }
}

// ---------------- hout via MFMA bf16 + skip + LN + gelu, paper+author merged ----------------
__global__ __launch_bounds__(256) void gemm_hout(
    const float* __restrict__ attnout, const float* __restrict__ Whout,
    const float* __restrict__ bhout, const float* __restrict__ skip_p,
    const float* __restrict__ lng, const float* __restrict__ lnb,
    float* __restrict__ hbuf)
{
    __shared__ unsigned short Xb[64][72];
    __shared__ unsigned short Wt[64][72];
    __shared__ float hs[64][68];
    int b = blockIdx.x, tid = threadIdx.x;
    int type = (b >= PT);
    int tile = type ? (b - PT) : b;
    int N = type ? NA : NP;
    size_t base_off = type ? (size_t)NP * HID : 0;
    const float* X = attnout + base_off;
    const float* W = Whout + (size_t)type * HID * HID;
    const float* bias = bhout + type * HID;
    float* H = hbuf + base_off;
    int nb = tile * 64;

    {
        int row = tid >> 2, c0 = (tid & 3) * 16;
        int n = nb + row;
        unsigned short tmp[16];
        if (n < N) {
            const float* xr = X + (size_t)n * HID + c0;
            #pragma unroll
            for (int i = 0; i < 16; i += 4) {
                float4 v = *(const float4*)(xr + i);
                tmp[i]   = f2bf(gelu_exact(v.x)); tmp[i+1] = f2bf(gelu_exact(v.y));
                tmp[i+2] = f2bf(gelu_exact(v.z)); tmp[i+3] = f2bf(gelu_exact(v.w));
            }
        } else {
            #pragma unroll
            for (int i = 0; i < 16; i++) tmp[i] = 0;
        }
        #pragma unroll
        for (int i = 0; i < 16; i += 4)
            *(ushort4*)&Xb[row][c0 + i] = make_ushort4(tmp[i], tmp[i+1], tmp[i+2], tmp[i+3]);
    }
    #pragma unroll
    for (int it = 0; it < 4; it++) {
        int idx = it * 256 + tid;
        int k = idx & 63, c = (idx >> 6) * 4;
        float4 v = *(const float4*)(W + (size_t)k * HID + c);
        Wt[c + 0][k] = f2bf(v.x); Wt[c + 1][k] = f2bf(v.y);
        Wt[c + 2][k] = f2bf(v.z); Wt[c + 3][k] = f2bf(v.w);
    }
    __syncthreads();

    int w = tid >> 6, lane = tid & 63;
    int wr = (w >> 1) * 32, wc = (w & 1) * 32;
    int lrow = lane & 15, lgrp = lane >> 4;

    f32x4 acc00 = {0.f, 0.f, 0.f, 0.f};
    f32x4 acc01 = {0.f, 0.f, 0.f, 0.f};
    f32x4 acc10 = {0.f, 0.f, 0.f, 0.f};
    f32x4 acc11 = {0.f, 0.f, 0.f, 0.f};
    #pragma unroll
    for (int ks = 0; ks < 2; ks++) {
        int ko = ks * 32 + lgrp * 8;
        bf16x8 a0 = *(const bf16x8*)&Xb[wr + lrow][ko];
        bf16x8 a1 = *(const bf16x8*)&Xb[wr + 16 + lrow][ko];
        bf16x8 b0 = *(const bf16x8*)&Wt[wc + lrow][ko];
        bf16x8 b1 = *(const bf16x8*)&Wt[wc + 16 + lrow][ko];
        acc00 = __builtin_amdgcn_mfma_f32_16x16x32_bf16(a0, b0, acc00, 0, 0, 0);
        acc01 = __builtin_amdgcn_mfma_f32_16x16x32_bf16(a0, b1, acc01, 0, 0, 0);
        acc10 = __builtin_amdgcn_mfma_f32_16x16x32_bf16(a1, b0, acc10, 0, 0, 0);
        acc11 = __builtin_amdgcn_mfma_f32_16x16x32_bf16(a1, b1, acc11, 0, 0, 0);
    }

    float a = 1.0f / (1.0f + __expf(-skip_p[type]));
    float oma = 1.0f - a;
    float bias0 = bias[wc + lrow], bias1 = bias[wc + 16 + lrow];
    #pragma unroll
    for (int mi = 0; mi < 2; mi++) {
        const f32x4 accn0 = mi ? acc10 : acc00;
        const f32x4 accn1 = mi ? acc11 : acc01;
        int rbase = wr + mi * 16 + lgrp * 4;
        #pragma unroll
        for (int r = 0; r < 4; r++) {
            int row = rbase + r;
            int n = nb + row;
            if (n < N) {
                const float* hp = H + (size_t)n * HID;
                hs[row][wc + lrow]      = a * (accn0[r] + bias0) + oma * hp[wc + lrow];
                hs[row][wc + 16 + lrow] = a * (accn1[r] + bias1) + oma * hp[wc + 16 + lrow];
            } else {
                hs[row][wc + lrow] = 0.f;
                hs[row][wc + 16 + lrow] = 0.f;
            }
        }
    }
    __syncthreads();

    const int tr = tid >> 4, tc = tid & 15;
    const int tcj = tc * 4;
    float g0 = lng[type*HID+tcj], g1 = lng[type*HID+tcj+1],
          g2 = lng[type*HID+tcj+2], g3 = lng[type*HID+tcj+3];
    float l0 = lnb[type*HID+tcj], l1 = lnb[type*HID+tcj+1],
          l2 = lnb[type*HID+tcj+2], l3 = lnb[type*HID+tcj+3];
    #pragma unroll 1
    for (int m = 0; m < 4; m++) {
        int row = tr * 4 + m;
        int n = nb + row;
        float v0 = hs[row][tcj], v1 = hs[row][tcj+1], v2 = hs[row][tcj+2], v3 = hs[row][tcj+3];
        float sum = v0 + v1 + v2 + v3;
        sum += __shfl_xor(sum, 1, 64); sum += __shfl_xor(sum, 2, 64);
        sum += __shfl_xor(sum, 4, 64); sum += __shfl_xor(sum, 8, 64);
        float mean = sum * (1.0f / 64.0f);
        float d0 = v0 - mean, d1 = v1 - mean, d2 = v2 - mean, d3 = v3 - mean;
        float sq = d0*d0 + d1*d1 + d2*d2 + d3*d3;
        sq += __shfl_xor(sq, 1, 64); sq += __shfl_xor(sq, 2, 64);
        sq += __shfl_xor(sq, 4, 64); sq += __shfl_xor(sq, 8, 64);
        float rstd = rsqrtf(sq * (1.0f / 64.0f) + 1e-5f);
        if (n < N) {
            float* hp = H + (size_t)n * HID + tcj;
            hp[0] = gelu_exact(d0 * rstd * g0 + l0);
            hp[1] = gelu_exact(d1 * rstd * g1 + l1);
            hp[2] = gelu_exact(d2 * rstd * g2 + l2);
            hp[3] = gelu_exact(d3 * rstd * g3 + l3);
        }
    }
}

// ---------------- final linear via MFMA bf16 (K=64), paper+author merged ----------------
__global__ __launch_bounds__(256) void gemm_out(
    const float* __restrict__ hbuf, const float* __restrict__ W_out,
    const float* __restrict__ b_out, float* __restrict__ out)
{
    __shared__ unsigned short Xb[64][72];
    __shared__ unsigned short Wt[64][72];
    int b = blockIdx.x, tid = threadIdx.x;
    int type = (b >= PT);
    int tile = type ? (b - PT) : b;
    int N = type ? NA : NP;
    size_t base_off = type ? (size_t)NP * HID : 0;
    const float* X = hbuf + base_off;
    const float* W = W_out + (size_t)type * HID * HID;
    const float* bias = b_out + type * HID;
    float* O = out + base_off;
    int nb = tile * 64;

    {
        int row = tid >> 2, c0 = (tid & 3) * 16;
        int n = nb + row;
        unsigned short tmp[16];
        if (n < N) {
            const float* xr = X + (size_t)n * HID + c0;
            #pragma unroll
            for (int i = 0; i < 16; i += 4) {
                float4 v = *(const float4*)(xr + i);
                tmp[i] = f2bf(v.x); tmp[i+1] = f2bf(v.y);
                tmp[i+2] = f2bf(v.z); tmp[i+3] = f2bf(v.w);
            }
        } else {
            #pragma unroll
            for (int i = 0; i < 16; i++) tmp[i] = 0;
        }
        #pragma unroll
        for (int i = 0; i < 16; i += 4)
            *(ushort4*)&Xb[row][c0 + i] = make_ushort4(tmp[i], tmp[i+1], tmp[i+2], tmp[i+3]);
    }
    #pragma unroll
    for (int it = 0; it < 4; it++) {
        int idx = it * 256 + tid;
        int k = idx & 63, c = (idx >> 6) * 4;
        float4 v = *(const float4*)(W + (size_t)k * HID + c);
        Wt[c + 0][k] = f2bf(v.x); Wt[c + 1][k] = f2bf(v.y);
        Wt[c + 2][k] = f2bf(v.z); Wt[c + 3][k] = f2bf(v.w);
    }
    __syncthreads();

    int w = tid >> 6, lane = tid & 63;
    int wr = (w >> 1) * 32, wc = (w & 1) * 32;
    int lrow = lane & 15, lgrp = lane >> 4;

    f32x4 acc00 = {0.f, 0.f, 0.f, 0.f};
    f32x4 acc01 = {0.f, 0.f, 0.f, 0.f};
    f32x4 acc10 = {0.f, 0.f, 0.f, 0.f};
    f32x4 acc11 = {0.f, 0.f, 0.f, 0.f};
    #pragma unroll
    for (int ks = 0; ks < 2; ks++) {
        int ko = ks * 32 + lgrp * 8;
        bf16x8 a0 = *(const bf16x8*)&Xb[wr + lrow][ko];
        bf16x8 a1 = *(const bf16x8*)&Xb[wr + 16 + lrow][ko];
        bf16x8 b0 = *(const bf16x8*)&Wt[wc + lrow][ko];
        bf16x8 b1 = *(const bf16x8*)&Wt[wc + 16 + lrow][ko];
        acc00 = __builtin_amdgcn_mfma_f32_16x16x32_bf16(a0, b0, acc00, 0, 0, 0);
        acc01 = __builtin_amdgcn_mfma_f32_16x16x32_bf16(a0, b1, acc01, 0, 0, 0);
        acc10 = __builtin_amdgcn_mfma_f32_16x16x32_bf16(a1, b0, acc10, 0, 0, 0);
        acc11 = __builtin_amdgcn_mfma_f32_16x16x32_bf16(a1, b1, acc11, 0, 0, 0);
    }

    float bias0 = bias[wc + lrow], bias1 = bias[wc + 16 + lrow];
    #pragma unroll
    for (int mi = 0; mi < 2; mi++) {
        const f32x4 accn0 = mi ? acc10 : acc00;
        const f32x4 accn1 = mi ? acc11 : acc01;
        int rbase = wr + mi * 16 + lgrp * 4;
        #pragma unroll
        for (int r = 0; r < 4; r++) {
            int n = nb + rbase + r;
            if (n >= N) continue;
            O[(size_t)n * HID + wc + lrow]      = accn0[r] + bias0;
            O[(size_t)n * HID + wc + 16 + lrow] = accn1[r] + bias1;
        }
    }
}

extern "C" void kernel_launch(void* const* d_in, const int* in_sizes, int n_in,
                              void* d_out, int out_size, void* d_ws, size_t ws_size,
                              hipStream_t stream) {
    const float* x_paper  = (const float*)d_in[0];
    const float* x_author = (const float*)d_in[1];
    const int*   ei_ap    = (const int*)d_in[2];
    const int*   ei_pa    = (const int*)d_in[3];
    const int*   ei_pp    = (const int*)d_in[4];
    const float* W_in     = (const float*)d_in[5];
    const float* b_in     = (const float*)d_in[6];
    const float* W_kqv    = (const float*)d_in[7];
    const float* b_kqv    = (const float*)d_in[8];
    const float* W_krel   = (const float*)d_in[9];
    const float* W_vrel   = (const float*)d_in[10];
    const float* p_rel    = (const float*)d_in[11];
    const float* W_hout   = (const float*)d_in[12];
    const float* b_hout   = (const float*)d_in[13];
    const float* skip     = (const float*)d_in[14];
    const float* ln_g     = (const float*)d_in[15];
    const float* ln_b     = (const float*)d_in[16];
    const float* W_out    = (const float*)d_in[17];
    const float* b_out    = (const float*)d_in[18];
    float* out            = (float*)d_out;

    // ---- workspace layout (~146 MB) ----
    float* ws   = (float*)d_ws;
    float* hbuf = ws;                                   // NTOT*64 f32
    float* Q    = hbuf + (size_t)NTOT * HID;            // NTOT*64 f32 (attn out aliases Q)
    unsigned* KVb = (unsigned*)(Q + (size_t)NTOT * HID); // NSRC*64 dwords (f16 k/v pairs)
    float* Wfp  = (float*)(KVb + (size_t)NSRC * HID);   // 64*320
    float* bfp  = Wfp  + 64 * JP;                       // 320
    float* Wfa  = bfp  + JP;                            // 64*192
    float* bfa  = Wfa  + 64 * JA;                       // 192
    int* cnt      = (int*)(bfa + JA);                   // NTOT
    int* row_ptr  = cnt + NTOT;                         // NTOT+1 (pad 16)
    int* cursor   = row_ptr + NTOT + 16;                // NTOT
    int* edge_src = cursor + NTOT;                      // ETOT
    int* csum     = edge_src + ETOT;                    // 1024
    int* coff     = csum + 1024;                        // 1024

    dim3 blk(256);
    const int EB = (ETOT + 255) / 256;

    // ---- CSR build (edges are layer-invariant) ----
    zero_int_kernel<<<256, blk, 0, stream>>>(cnt, NTOT);
    csr_count_kernel<<<EB, blk, 0, stream>>>(ei_ap, ei_pa, ei_pp, cnt);
    scan_chunk_sums<<<NCH, blk, 0, stream>>>(cnt, csum);
    scan_offsets<<<1, 1024, 0, stream>>>(csum, coff, NCH);
    scan_final<<<NCH, blk, 0, stream>>>(cnt, coff, row_ptr, cursor);
    csr_fill_kernel<<<EB, blk, 0, stream>>>(ei_ap, ei_pa, ei_pp, cursor, edge_src);

    // ---- input projection ----
    gemm_in<<<PT + AT, blk, 0, stream>>>(x_paper, x_author, W_in, b_in, hbuf);

    for (int l = 0; l < LAYERS; l++) {
        fuse_weights_kernel<<<(65 * JP + 65 * JA + 255) / 256, blk, 0, stream>>>(
            W_kqv + (size_t)l * 2 * HID * KQV, b_kqv + (size_t)l * 2 * KQV,
            W_krel + (size_t)l * 3 * NH * HD * HD, W_vrel + (size_t)l * 3 * NH * HD * HD,
            Wfp, bfp, Wfa, bfa);
        gemm_kqv<<<PT * 5 + AT * 3, blk, 0, stream>>>(
            hbuf, Wfp, bfp, Wfa, bfa, Q, KVb);
        attn_kernel<<<(NTOT + 3) / 4, blk, 0, stream>>>(
            Q, KVb, p_rel + l * 3 * NH, row_ptr, edge_src, Q);
        gemm_hout<<<PT + AT, blk, 0, stream>>>(
            Q, W_hout + (size_t)l * 2 * HID * HID, b_hout + l * 2 * HID,
            skip + l * 2, ln_g + l * 2 * HID, ln_b + l * 2 * HID, hbuf);
    }

    gemm_out<<<PT + AT, blk, 0, stream>>>(hbuf, W_out, b_out, out);
}

// Round 12
// 445.421 us; speedup vs baseline: 4.2064x; 1.0838x over previous
//
#include <hip/hip_runtime.h>
#include <hip/hip_bf16.h>

// ---- problem constants (match reference) ----
#define NP 100000
#define NA 50000
#define NTOT 150000          // NP+NA
#define E0 300000
#define E1 300000
#define E2 200000
#define ETOT 800000
#define NH 4
#define HD 16
#define HID 64
#define IN_DIM 128
#define KQV 192
#define LAYERS 2
#define NSRC 250000          // NA + 2*NP
#define JP 320               // fused paper cols: q | k_et1 | k_et2 | v_et1 | v_et2
#define JA 192               // fused author cols: q | k_et0 | v_et0
#define NCH 586              // ceil(NTOT/256)
#define PT 1563              // ceil(NP/64)
#define AT 782               // ceil(NA/64)

typedef __attribute__((ext_vector_type(8))) short bf16x8;   // 8 bf16 (4 VGPRs)
typedef __attribute__((ext_vector_type(4))) float f32x4;    // MFMA C/D
typedef _Float16 h16x2 __attribute__((ext_vector_type(2)));

__device__ __forceinline__ float gelu_exact(float x) {
    return 0.5f * x * (1.0f + erff(x * 0.7071067811865475f));
}
// f32 -> bf16 bits, round-to-nearest-even (finite values)
__device__ __forceinline__ unsigned short f2bf(float f) {
    unsigned u = __float_as_uint(f);
    return (unsigned short)((u + 0x7fffu + ((u >> 16) & 1u)) >> 16);
}
// f32 -> f16 bits (RNE via hardware cvt)
__device__ __forceinline__ unsigned short f2h(float f) {
    union { _Float16 h; unsigned short u; } c;
    c.h = (_Float16)f;
    return c.u;
}

// decode global edge id -> (src in KV space, dst in node space)
__device__ __forceinline__ void edge_decode(int e, const int* __restrict__ ei_ap,
                                            const int* __restrict__ ei_pa,
                                            const int* __restrict__ ei_pp,
                                            int& src, int& dst) {
    if (e < E0)            { src = ei_ap[e];                 dst = ei_ap[E0 + e]; }
    else if (e < E0 + E1)  { int le = e - E0;
                             src = NA + ei_pa[le];           dst = NP + ei_pa[E1 + le]; }
    else                   { int le = e - E0 - E1;
                             src = NA + NP + ei_pp[le];      dst = ei_pp[E2 + le]; }
}

// ---------------- CSR build ----------------
__global__ void zero_int_kernel(int* __restrict__ p, int n) {
    int i = blockIdx.x * blockDim.x + threadIdx.x;
    int st = gridDim.x * blockDim.x;
    for (int j = i; j < n; j += st) p[j] = 0;
}

__global__ void csr_count_kernel(const int* __restrict__ ei_ap, const int* __restrict__ ei_pa,
                                 const int* __restrict__ ei_pp, int* __restrict__ cnt) {
    int e = blockIdx.x * 256 + threadIdx.x;
    if (e >= ETOT) return;
    int src, dst; edge_decode(e, ei_ap, ei_pa, ei_pp, src, dst);
    atomicAdd(&cnt[dst], 1);
}

__global__ void scan_chunk_sums(const int* __restrict__ cnt, int* __restrict__ csum) {
    __shared__ int sd[256];
    int c = blockIdx.x, t = threadIdx.x;
    int i = c * 256 + t;
    sd[t] = (i < NTOT) ? cnt[i] : 0;
    __syncthreads();
    for (int o = 128; o > 0; o >>= 1) { if (t < o) sd[t] += sd[t + o]; __syncthreads(); }
    if (t == 0) csum[c] = sd[0];
}

__global__ void scan_offsets(const int* __restrict__ csum, int* __restrict__ coff, int nch) {
    __shared__ int sd[1024];
    int t = threadIdx.x;
    int v = (t < nch) ? csum[t] : 0;
    sd[t] = v;
    __syncthreads();
    for (int o = 1; o < 1024; o <<= 1) {
        int x = (t >= o) ? sd[t - o] : 0;
        __syncthreads();
        sd[t] += x;
        __syncthreads();
    }
    if (t < nch) coff[t] = sd[t] - v;   // exclusive
}

__global__ void scan_final(const int* __restrict__ cnt, const int* __restrict__ coff,
                           int* __restrict__ row_ptr, int* __restrict__ cursor) {
    __shared__ int sd[256];
    int c = blockIdx.x, t = threadIdx.x, i = c * 256 + t;
    int v = (i < NTOT) ? cnt[i] : 0;
    sd[t] = v;
    __syncthreads();
    for (int o = 1; o < 256; o <<= 1) {
        int x = (t >= o) ? sd[t - o] : 0;
        __syncthreads();
        sd[t] += x;
        __syncthreads();
    }
    if (i < NTOT) { int ex = coff[c] + sd[t] - v; row_ptr[i] = ex; cursor[i] = ex; }
    if (i == 0) row_ptr[NTOT] = ETOT;
}

__global__ void csr_fill_kernel(const int* __restrict__ ei_ap, const int* __restrict__ ei_pa,
                                const int* __restrict__ ei_pp, int* __restrict__ cursor,
                                int* __restrict__ edge_src) {
    int e = blockIdx.x * 256 + threadIdx.x;
    if (e >= ETOT) return;
    int src, dst; edge_decode(e, ei_ap, ei_pa, ei_pp, src, dst);
    int pos = atomicAdd(&cursor[dst], 1);
    edge_src[pos] = src;
}

// ---------------- fused-weight build (per layer) ----------------
__global__ void fuse_weights_kernel(const float* __restrict__ Wkqv, const float* __restrict__ bkqv,
                                    const float* __restrict__ Wkrel, const float* __restrict__ Wvrel,
                                    float* __restrict__ Wfp, float* __restrict__ bfp,
                                    float* __restrict__ Wfa, float* __restrict__ bfa) {
    int idx = blockIdx.x * 256 + threadIdx.x;
    int type, i, j;
    if (idx < 65 * JP) { type = 0; i = idx / JP; j = idx % JP; }
    else {
        int r = idx - 65 * JP;
        if (r >= 65 * JA) return;
        type = 1; i = r / JA; j = r % JA;
    }
    int c = j >> 6, jj = j & 63, h = jj >> 4, e = jj & 15;
    const float* Wk = Wkqv + (size_t)type * HID * KQV;
    const float* bk = bkqv + type * KQV;
    float val;
    if (c == 0) {
        val = (i < 64) ? Wk[i * KQV + 64 + jj] : bk[64 + jj];
    } else {
        int et, isV;
        if (type == 0) { et = (c == 1 || c == 3) ? 1 : 2; isV = (c >= 3); }
        else           { et = 0; isV = (c == 2); }
        const float* Wr = (isV ? Wvrel : Wkrel) + (size_t)(et * NH + h) * HD * HD;
        int sb = (isV ? 128 : 0) + h * HD;
        val = 0.0f;
        #pragma unroll
        for (int d = 0; d < HD; d++) {
            float a = (i < 64) ? Wk[i * KQV + sb + d] : bk[sb + d];
            val += a * Wr[d * HD + e];
        }
    }
    if (i < 64) (type ? Wfa : Wfp)[i * (type ? JA : JP) + j] = val;
    else        (type ? bfa : bfp)[j] = val;
}

// ---------------- input projection via MFMA bf16 (K=128), paper+author merged ----------------
__global__ __launch_bounds__(256) void gemm_in(
    const float* __restrict__ xp, const float* __restrict__ xa,
    const float* __restrict__ W_in, const float* __restrict__ b_in,
    float* __restrict__ hbuf)
{
    __shared__ unsigned short Xb[64][136];   // 272B rows (16B-aligned)
    __shared__ unsigned short Wt[64][136];   // Wt[col][k]
    int b = blockIdx.x, tid = threadIdx.x;
    int type = (b >= PT);
    int tile = type ? (b - PT) : b;
    int N = type ? NA : NP;
    const float* X = type ? xa : xp;
    const float* W = W_in + (size_t)type * IN_DIM * HID;
    const float* bias = b_in + type * HID;
    float* H = hbuf + (type ? (size_t)NP * HID : 0);
    int nb = tile * 64;

    {
        int row = tid >> 2, c0 = (tid & 3) * 32;
        int n = nb + row;
        if (n < N) {
            const float* xr = X + (size_t)n * IN_DIM + c0;
            #pragma unroll
            for (int i = 0; i < 32; i += 4) {
                float4 v = *(const float4*)(xr + i);
                *(ushort4*)&Xb[row][c0 + i] =
                    make_ushort4(f2bf(v.x), f2bf(v.y), f2bf(v.z), f2bf(v.w));
            }
        } else {
            #pragma unroll
            for (int i = 0; i < 32; i += 4)
                *(ushort4*)&Xb[row][c0 + i] = make_ushort4(0, 0, 0, 0);
        }
    }
    #pragma unroll
    for (int it = 0; it < 8; it++) {
        int idx = it * 256 + tid;            // 0..2047
        int k = idx & 127, c = (idx >> 7) * 4;
        float4 v = *(const float4*)(W + (size_t)k * HID + c);
        Wt[c + 0][k] = f2bf(v.x); Wt[c + 1][k] = f2bf(v.y);
        Wt[c + 2][k] = f2bf(v.z); Wt[c + 3][k] = f2bf(v.w);
    }
    __syncthreads();

    int w = tid >> 6, lane = tid & 63;
    int wr = (w >> 1) * 32, wc = (w & 1) * 32;
    int lrow = lane & 15, lgrp = lane >> 4;

    f32x4 acc00 = {0.f, 0.f, 0.f, 0.f};
    f32x4 acc01 = {0.f, 0.f, 0.f, 0.f};
    f32x4 acc10 = {0.f, 0.f, 0.f, 0.f};
    f32x4 acc11 = {0.f, 0.f, 0.f, 0.f};
    #pragma unroll
    for (int ks = 0; ks < 4; ks++) {
        int ko = ks * 32 + lgrp * 8;
        bf16x8 a0 = *(const bf16x8*)&Xb[wr + lrow][ko];
        bf16x8 a1 = *(const bf16x8*)&Xb[wr + 16 + lrow][ko];
        bf16x8 b0 = *(const bf16x8*)&Wt[wc + lrow][ko];
        bf16x8 b1 = *(const bf16x8*)&Wt[wc + 16 + lrow][ko];
        acc00 = __builtin_amdgcn_mfma_f32_16x16x32_bf16(a0, b0, acc00, 0, 0, 0);
        acc01 = __builtin_amdgcn_mfma_f32_16x16x32_bf16(a0, b1, acc01, 0, 0, 0);
        acc10 = __builtin_amdgcn_mfma_f32_16x16x32_bf16(a1, b0, acc10, 0, 0, 0);
        acc11 = __builtin_amdgcn_mfma_f32_16x16x32_bf16(a1, b1, acc11, 0, 0, 0);
    }

    float bias0 = bias[wc + lrow], bias1 = bias[wc + 16 + lrow];
    #pragma unroll
    for (int mi = 0; mi < 2; mi++) {
        const f32x4 accn0 = mi ? acc10 : acc00;
        const f32x4 accn1 = mi ? acc11 : acc01;
        int rbase = wr + mi * 16 + lgrp * 4;
        #pragma unroll
        for (int r = 0; r < 4; r++) {
            int n = nb + rbase + r;
            if (n >= N) continue;
            H[(size_t)n * HID + wc + lrow]      = accn0[r] + bias0;
            H[(size_t)n * HID + wc + 16 + lrow] = accn1[r] + bias1;
        }
    }
}

// ---------------- KQV GEMM via MFMA bf16: K+V merged per block ----------------
// Block kinds: paper Q | paper KV(et1: K@64,V@192 -> dst NA) | paper KV(et2: K@128,V@256
// -> dst NA+NP) | author Q | author KV(K@64,V@128 -> dst 0).
// KV epilogue: lane holds (k,v) for its col; shfl_xor(1) partner exchange packs the
// attn pair-layout dwords (even col -> kpair, odd col -> vpair) => coalesced 4B
// stores, no 2-byte RMW (R11: scattered ushort writes cost +62MB WRITE amplification).
__global__ __launch_bounds__(256) void gemm_kqv(
    const float* __restrict__ hbuf,
    const float* __restrict__ Wfp, const float* __restrict__ bfp,
    const float* __restrict__ Wfa, const float* __restrict__ bfa,
    float* __restrict__ Q, unsigned* __restrict__ KVb)
{
    __shared__ unsigned short Xb[64][72];
    __shared__ unsigned short WtK[64][72];
    __shared__ unsigned short WtV[64][72];
    int b = blockIdx.x, tid = threadIdx.x;
    int type, tile, kind;
    if (b < PT)                { type = 0; kind = 0; tile = b; }
    else if (b < 2 * PT)       { type = 0; kind = 1; tile = b - PT; }
    else if (b < 3 * PT)       { type = 0; kind = 2; tile = b - 2 * PT; }
    else if (b < 3 * PT + AT)  { type = 1; kind = 0; tile = b - 3 * PT; }
    else                       { type = 1; kind = 1; tile = b - 3 * PT - AT; }
    int N = type ? NA : NP;
    const float* X = hbuf + (type ? (size_t)NP * HID : 0);
    const float* W = type ? Wfa : Wfp;
    const float* bias = type ? bfa : bfp;
    int ldw = type ? JA : JP;
    int nb = tile * 64;
    bool isQ = (kind == 0);
    int kcol = 0, vcol = 0, noff = 0;
    if (!isQ) {
        if (type == 0) {
            if (kind == 1) { kcol = 64;  vcol = 192; noff = NA; }
            else           { kcol = 128; vcol = 256; noff = NA + NP; }
        } else             { kcol = 64;  vcol = 128; noff = 0; }
    } else {
        noff = type ? NP : 0;
    }

    // stage X tile as bf16
    {
        int row = tid >> 2, c0 = (tid & 3) * 16;
        int n = nb + row;
        unsigned short tmp[16];
        if (n < N) {
            const float* xr = X + (size_t)n * HID + c0;
            #pragma unroll
            for (int i = 0; i < 16; i += 4) {
                float4 v = *(const float4*)(xr + i);
                tmp[i] = f2bf(v.x); tmp[i+1] = f2bf(v.y);
                tmp[i+2] = f2bf(v.z); tmp[i+3] = f2bf(v.w);
            }
        } else {
            #pragma unroll
            for (int i = 0; i < 16; i++) tmp[i] = 0;
        }
        #pragma unroll
        for (int i = 0; i < 16; i += 4)
            *(ushort4*)&Xb[row][c0 + i] = make_ushort4(tmp[i], tmp[i+1], tmp[i+2], tmp[i+3]);
    }
    // stage W transposed: WtK (Q cols or K cols) and WtV (V cols, KV blocks only)
    #pragma unroll
    for (int it = 0; it < 4; it++) {
        int idx = it * 256 + tid;           // 0..1023
        int k = idx & 63, c = (idx >> 6) * 4;
        float4 v = *(const float4*)(W + (size_t)k * ldw + kcol + c);
        WtK[c + 0][k] = f2bf(v.x); WtK[c + 1][k] = f2bf(v.y);
        WtK[c + 2][k] = f2bf(v.z); WtK[c + 3][k] = f2bf(v.w);
    }
    if (!isQ) {
        #pragma unroll
        for (int it = 0; it < 4; it++) {
            int idx = it * 256 + tid;
            int k = idx & 63, c = (idx >> 6) * 4;
            float4 v = *(const float4*)(W + (size_t)k * ldw + vcol + c);
            WtV[c + 0][k] = f2bf(v.x); WtV[c + 1][k] = f2bf(v.y);
            WtV[c + 2][k] = f2bf(v.z); WtV[c + 3][k] = f2bf(v.w);
        }
    }
    __syncthreads();

    int w = tid >> 6, lane = tid & 63;
    int wr = (w >> 1) * 32, wc = (w & 1) * 32;
    int lrow = lane & 15, lgrp = lane >> 4;

    f32x4 k00 = {0.f,0.f,0.f,0.f}, k01 = {0.f,0.f,0.f,0.f};
    f32x4 k10 = {0.f,0.f,0.f,0.f}, k11 = {0.f,0.f,0.f,0.f};
    f32x4 v00 = {0.f,0.f,0.f,0.f}, v01 = {0.f,0.f,0.f,0.f};
    f32x4 v10 = {0.f,0.f,0.f,0.f}, v11 = {0.f,0.f,0.f,0.f};
    #pragma unroll
    for (int ks = 0; ks < 2; ks++) {
        int ko = ks * 32 + lgrp * 8;
        bf16x8 a0 = *(const bf16x8*)&Xb[wr + lrow][ko];
        bf16x8 a1 = *(const bf16x8*)&Xb[wr + 16 + lrow][ko];
        bf16x8 bk0 = *(const bf16x8*)&WtK[wc + lrow][ko];
        bf16x8 bk1 = *(const bf16x8*)&WtK[wc + 16 + lrow][ko];
        k00 = __builtin_amdgcn_mfma_f32_16x16x32_bf16(a0, bk0, k00, 0, 0, 0);
        k01 = __builtin_amdgcn_mfma_f32_16x16x32_bf16(a0, bk1, k01, 0, 0, 0);
        k10 = __builtin_amdgcn_mfma_f32_16x16x32_bf16(a1, bk0, k10, 0, 0, 0);
        k11 = __builtin_amdgcn_mfma_f32_16x16x32_bf16(a1, bk1, k11, 0, 0, 0);
        if (!isQ) {
            bf16x8 bv0 = *(const bf16x8*)&WtV[wc + lrow][ko];
            bf16x8 bv1 = *(const bf16x8*)&WtV[wc + 16 + lrow][ko];
            v00 = __builtin_amdgcn_mfma_f32_16x16x32_bf16(a0, bv0, v00, 0, 0, 0);
            v01 = __builtin_amdgcn_mfma_f32_16x16x32_bf16(a0, bv1, v01, 0, 0, 0);
            v10 = __builtin_amdgcn_mfma_f32_16x16x32_bf16(a1, bv0, v10, 0, 0, 0);
            v11 = __builtin_amdgcn_mfma_f32_16x16x32_bf16(a1, bv1, v11, 0, 0, 0);
        }
    }

    int c0 = wc + lrow, c1 = wc + 16 + lrow;
    if (isQ) {
        float bias0 = bias[c0], bias1 = bias[c1];
        #pragma unroll
        for (int mi = 0; mi < 2; mi++) {
            const f32x4 a0 = mi ? k10 : k00;
            const f32x4 a1 = mi ? k11 : k01;
            int rbase = wr + mi * 16 + lgrp * 4;
            #pragma unroll
            for (int r = 0; r < 4; r++) {
                int n = nb + rbase + r;
                if (n >= N) continue;
                Q[(size_t)(noff + n) * HID + c0] = a0[r] + bias0;
                Q[(size_t)(noff + n) * HID + c1] = a1[r] + bias1;
            }
        }
    } else {
        float bk0 = bias[kcol + c0], bk1 = bias[kcol + c1];
        float bv0 = bias[vcol + c0], bv1 = bias[vcol + c1];
        bool even = ((lrow & 1) == 0);
        #pragma unroll
        for (int mi = 0; mi < 2; mi++) {
            const f32x4 ak0 = mi ? k10 : k00;
            const f32x4 ak1 = mi ? k11 : k01;
            const f32x4 av0 = mi ? v10 : v00;
            const f32x4 av1 = mi ? v11 : v01;
            int rbase = wr + mi * 16 + lgrp * 4;
            #pragma unroll
            for (int r = 0; r < 4; r++) {
                int n = nb + rbase + r;
                unsigned* dst = KVb + (((size_t)(noff + n)) << 6);
                // frag col 0 (c0)
                unsigned own0 = (unsigned)f2h(ak0[r] + bk0) | ((unsigned)f2h(av0[r] + bv0) << 16);
                unsigned oth0 = __shfl_xor(own0, 1, 64);
                // frag col 1 (c1)
                unsigned own1 = (unsigned)f2h(ak1[r] + bk1) | ((unsigned)f2h(av1[r] + bv1) << 16);
                unsigned oth1 = __shfl_xor(own1, 1, 64);
                if (n < N) {
                    unsigned w0 = even ? ((own0 & 0xffffu) | (oth0 << 16))
                                       : ((oth0 >> 16) | (own0 & 0xffff0000u));
                    unsigned w1 = even ? ((own1 & 0xffffu) | (oth1 << 16))
                                       : ((oth1 >> 16) | (own1 & 0xffff0000u));
                    dst[c0] = w0;
                    dst[c1] = w1;
                }
            }
        }
    }
}

// ---------------- fused attention: one wave per dst node, 4 edges/iter ----------------
// MLP-bound (R10/R11): 2 independent uint2 gathers in flight per iteration
// (4 edges via half-waves), exp2-domain softmax, cross-half exp via shfl,
// clamped unconditional loads.
__global__ __launch_bounds__(256) void attn_kernel(
    const float* Q, const unsigned* __restrict__ KVb,
    const float* __restrict__ p_rel, const int* __restrict__ row_ptr,
    const int* __restrict__ edge_src, float* attnout)
{
    int wid = threadIdx.x >> 6, lane = threadIdx.x & 63;
    int n = blockIdx.x * 4 + wid;
    if (n >= NTOT) return;
    int half = lane >> 5;
    int p = lane & 31;           // pair index: dims 2p, 2p+1
    int h = p >> 3;              // head
    float2 qp = *(const float2*)(Q + (size_t)n * HID + 2 * p);
    h16x2 qh; qh[0] = (_Float16)qp.x; qh[1] = (_Float16)qp.y;
    const float INV_LN2 = 1.4426950408889634f;
    float pr0 = p_rel[h] * 0.25f * INV_LN2;
    float pr1 = p_rel[4 + h] * 0.25f * INV_LN2;
    float pr2 = p_rel[8 + h] * 0.25f * INV_LN2;
    int beg = row_ptr[n], end = row_ptr[n + 1];
    float m = -INFINITY, s = 0.0f;
    float acc0 = 0.f, acc1 = 0.f;
    for (int e = beg; e < end; e += 4) {
        int e0 = e + half;           // edges e, e+1
        int e1 = e + 2 + half;       // edges e+2, e+3
        bool v0 = (e0 < end), v1 = (e1 < end);
        int s0 = edge_src[v0 ? e0 : beg];
        int s1 = edge_src[v1 ? e1 : beg];
        uint2 kv0 = *(const uint2*)(KVb + (((size_t)s0) << 6) + 2 * p);
        uint2 kv1 = *(const uint2*)(KVb + (((size_t)s1) << 6) + 2 * p);
        float d0, d1;
#if __has_builtin(__builtin_amdgcn_fdot2)
        {
            union { unsigned u; h16x2 v; } ck;
            ck.u = kv0.x; d0 = __builtin_amdgcn_fdot2(qh, ck.v, 0.0f, false);
            ck.u = kv1.x; d1 = __builtin_amdgcn_fdot2(qh, ck.v, 0.0f, false);
        }
#else
        {
            union { unsigned u; _Float16 f[2]; } ck;
            ck.u = kv0.x; d0 = qp.x * (float)ck.f[0] + qp.y * (float)ck.f[1];
            ck.u = kv1.x; d1 = qp.x * (float)ck.f[0] + qp.y * (float)ck.f[1];
        }
#endif
        d0 += __shfl_xor(d0, 1, 64);  d1 += __shfl_xor(d1, 1, 64);
        d0 += __shfl_xor(d0, 2, 64);  d1 += __shfl_xor(d1, 2, 64);
        d0 += __shfl_xor(d0, 4, 64);  d1 += __shfl_xor(d1, 4, 64);
        float pa = (s0 < NA) ? pr0 : ((s0 < NA + NP) ? pr1 : pr2);
        float pb = (s1 < NA) ? pr0 : ((s1 < NA + NP) ? pr1 : pr2);
        float a0 = v0 ? d0 * pa : -INFINITY;
        float a1 = v1 ? d1 * pb : -INFINITY;
        float a0x = __shfl_xor(a0, 32, 64);
        float a1x = __shfl_xor(a1, 32, 64);
        float mn = fmaxf(m, fmaxf(fmaxf(a0, a0x), fmaxf(a1, a1x)));
        float cc = exp2f(m - mn);
        float p0 = exp2f(a0 - mn);
        float p1 = exp2f(a1 - mn);
        float p0x = __shfl_xor(p0, 32, 64);
        float p1x = __shfl_xor(p1, 32, 64);
        s = s * cc + p0 + p1 + p0x + p1x;
        union { unsigned u; _Float16 f[2]; } cv0, cv1;
        cv0.u = kv0.y; cv1.u = kv1.y;
        acc0 = acc0 * cc + p0 * (float)cv0.f[0] + p1 * (float)cv1.f[0];
        acc1 = acc1 * cc + p0 * (float)cv0.f[1] + p1 * (float)cv1.f[1];
        m = mn;
    }
    acc0 += __shfl_xor(acc0, 32, 64);
    acc1 += __shfl_xor(acc1, 32, 64);
    if (half == 0) {
        float inv = 1.0f / (s + 1e-16f);
        float2 o; o.x = acc0 * inv; o.y = acc1 * inv;
        *(float2*)(attnout + (size_t)n * HID + 2 * p) = o;
    }
}

// ---------------- hout via MFMA bf16 + skip + LN + gelu, paper+author merged ----------------
__global__ __launch_bounds__(256) void gemm_hout(
    const float* __restrict__ attnout, const float* __restrict__ Whout,
    const float* __restrict__ bhout, const float* __restrict__ skip_p,
    const float* __restrict__ lng, const float* __restrict__ lnb,
    float* __restrict__ hbuf)
{
    __shared__ unsigned short Xb[64][72];
    __shared__ unsigned short Wt[64][72];
    __shared__ float hs[64][68];
    int b = blockIdx.x, tid = threadIdx.x;
    int type = (b >= PT);
    int tile = type ? (b - PT) : b;
    int N = type ? NA : NP;
    size_t base_off = type ? (size_t)NP * HID : 0;
    const float* X = attnout + base_off;
    const float* W = Whout + (size_t)type * HID * HID;
    const float* bias = bhout + type * HID;
    float* H = hbuf + base_off;
    int nb = tile * 64;

    {
        int row = tid >> 2, c0 = (tid & 3) * 16;
        int n = nb + row;
        unsigned short tmp[16];
        if (n < N) {
            const float* xr = X + (size_t)n * HID + c0;
            #pragma unroll
            for (int i = 0; i < 16; i += 4) {
                float4 v = *(const float4*)(xr + i);
                tmp[i]   = f2bf(gelu_exact(v.x)); tmp[i+1] = f2bf(gelu_exact(v.y));
                tmp[i+2] = f2bf(gelu_exact(v.z)); tmp[i+3] = f2bf(gelu_exact(v.w));
            }
        } else {
            #pragma unroll
            for (int i = 0; i < 16; i++) tmp[i] = 0;
        }
        #pragma unroll
        for (int i = 0; i < 16; i += 4)
            *(ushort4*)&Xb[row][c0 + i] = make_ushort4(tmp[i], tmp[i+1], tmp[i+2], tmp[i+3]);
    }
    #pragma unroll
    for (int it = 0; it < 4; it++) {
        int idx = it * 256 + tid;
        int k = idx & 63, c = (idx >> 6) * 4;
        float4 v = *(const float4*)(W + (size_t)k * HID + c);
        Wt[c + 0][k] = f2bf(v.x); Wt[c + 1][k] = f2bf(v.y);
        Wt[c + 2][k] = f2bf(v.z); Wt[c + 3][k] = f2bf(v.w);
    }
    __syncthreads();

    int w = tid >> 6, lane = tid & 63;
    int wr = (w >> 1) * 32, wc = (w & 1) * 32;
    int lrow = lane & 15, lgrp = lane >> 4;

    f32x4 acc00 = {0.f, 0.f, 0.f, 0.f};
    f32x4 acc01 = {0.f, 0.f, 0.f, 0.f};
    f32x4 acc10 = {0.f, 0.f, 0.f, 0.f};
    f32x4 acc11 = {0.f, 0.f, 0.f, 0.f};
    #pragma unroll
    for (int ks = 0; ks < 2; ks++) {
        int ko = ks * 32 + lgrp * 8;
        bf16x8 a0 = *(const bf16x8*)&Xb[wr + lrow][ko];
        bf16x8 a1 = *(const bf16x8*)&Xb[wr + 16 + lrow][ko];
        bf16x8 b0 = *(const bf16x8*)&Wt[wc + lrow][ko];
        bf16x8 b1 = *(const bf16x8*)&Wt[wc + 16 + lrow][ko];
        acc00 = __builtin_amdgcn_mfma_f32_16x16x32_bf16(a0, b0, acc00, 0, 0, 0);
        acc01 = __builtin_amdgcn_mfma_f32_16x16x32_bf16(a0, b1, acc01, 0, 0, 0);
        acc10 = __builtin_amdgcn_mfma_f32_16x16x32_bf16(a1, b0, acc10, 0, 0, 0);
        acc11 = __builtin_amdgcn_mfma_f32_16x16x32_bf16(a1, b1, acc11, 0, 0, 0);
    }

    float a = 1.0f / (1.0f + __expf(-skip_p[type]));
    float oma = 1.0f - a;
    float bias0 = bias[wc + lrow], bias1 = bias[wc + 16 + lrow];
    #pragma unroll
    for (int mi = 0; mi < 2; mi++) {
        const f32x4 accn0 = mi ? acc10 : acc00;
        const f32x4 accn1 = mi ? acc11 : acc01;
        int rbase = wr + mi * 16 + lgrp * 4;
        #pragma unroll
        for (int r = 0; r < 4; r++) {
            int row = rbase + r;
            int n = nb + row;
            if (n < N) {
                const float* hp = H + (size_t)n * HID;
                hs[row][wc + lrow]      = a * (accn0[r] + bias0) + oma * hp[wc + lrow];
                hs[row][wc + 16 + lrow] = a * (accn1[r] + bias1) + oma * hp[wc + 16 + lrow];
            } else {
                hs[row][wc + lrow] = 0.f;
                hs[row][wc + 16 + lrow] = 0.f;
            }
        }
    }
    __syncthreads();

    const int tr = tid >> 4, tc = tid & 15;
    const int tcj = tc * 4;
    float g0 = lng[type*HID+tcj], g1 = lng[type*HID+tcj+1],
          g2 = lng[type*HID+tcj+2], g3 = lng[type*HID+tcj+3];
    float l0 = lnb[type*HID+tcj], l1 = lnb[type*HID+tcj+1],
          l2 = lnb[type*HID+tcj+2], l3 = lnb[type*HID+tcj+3];
    #pragma unroll 1
    for (int m = 0; m < 4; m++) {
        int row = tr * 4 + m;
        int n = nb + row;
        float v0 = hs[row][tcj], v1 = hs[row][tcj+1], v2 = hs[row][tcj+2], v3 = hs[row][tcj+3];
        float sum = v0 + v1 + v2 + v3;
        sum += __shfl_xor(sum, 1, 64); sum += __shfl_xor(sum, 2, 64);
        sum += __shfl_xor(sum, 4, 64); sum += __shfl_xor(sum, 8, 64);
        float mean = sum * (1.0f / 64.0f);
        float d0 = v0 - mean, d1 = v1 - mean, d2 = v2 - mean, d3 = v3 - mean;
        float sq = d0*d0 + d1*d1 + d2*d2 + d3*d3;
        sq += __shfl_xor(sq, 1, 64); sq += __shfl_xor(sq, 2, 64);
        sq += __shfl_xor(sq, 4, 64); sq += __shfl_xor(sq, 8, 64);
        float rstd = rsqrtf(sq * (1.0f / 64.0f) + 1e-5f);
        if (n < N) {
            float* hp = H + (size_t)n * HID + tcj;
            hp[0] = gelu_exact(d0 * rstd * g0 + l0);
            hp[1] = gelu_exact(d1 * rstd * g1 + l1);
            hp[2] = gelu_exact(d2 * rstd * g2 + l2);
            hp[3] = gelu_exact(d3 * rstd * g3 + l3);
        }
    }
}

// ---------------- final linear via MFMA bf16 (K=64), paper+author merged ----------------
__global__ __launch_bounds__(256) void gemm_out(
    const float* __restrict__ hbuf, const float* __restrict__ W_out,
    const float* __restrict__ b_out, float* __restrict__ out)
{
    __shared__ unsigned short Xb[64][72];
    __shared__ unsigned short Wt[64][72];
    int b = blockIdx.x, tid = threadIdx.x;
    int type = (b >= PT);
    int tile = type ? (b - PT) : b;
    int N = type ? NA : NP;
    size_t base_off = type ? (size_t)NP * HID : 0;
    const float* X = hbuf + base_off;
    const float* W = W_out + (size_t)type * HID * HID;
    const float* bias = b_out + type * HID;
    float* O = out + base_off;
    int nb = tile * 64;

    {
        int row = tid >> 2, c0 = (tid & 3) * 16;
        int n = nb + row;
        unsigned short tmp[16];
        if (n < N) {
            const float* xr = X + (size_t)n * HID + c0;
            #pragma unroll
            for (int i = 0; i < 16; i += 4) {
                float4 v = *(const float4*)(xr + i);
                tmp[i] = f2bf(v.x); tmp[i+1] = f2bf(v.y);
                tmp[i+2] = f2bf(v.z); tmp[i+3] = f2bf(v.w);
            }
        } else {
            #pragma unroll
            for (int i = 0; i < 16; i++) tmp[i] = 0;
        }
        #pragma unroll
        for (int i = 0; i < 16; i += 4)
            *(ushort4*)&Xb[row][c0 + i] = make_ushort4(tmp[i], tmp[i+1], tmp[i+2], tmp[i+3]);
    }
    #pragma unroll
    for (int it = 0; it < 4; it++) {
        int idx = it * 256 + tid;
        int k = idx & 63, c = (idx >> 6) * 4;
        float4 v = *(const float4*)(W + (size_t)k * HID + c);
        Wt[c + 0][k] = f2bf(v.x); Wt[c + 1][k] = f2bf(v.y);
        Wt[c + 2][k] = f2bf(v.z); Wt[c + 3][k] = f2bf(v.w);
    }
    __syncthreads();

    int w = tid >> 6, lane = tid & 63;
    int wr = (w >> 1) * 32, wc = (w & 1) * 32;
    int lrow = lane & 15, lgrp = lane >> 4;

    f32x4 acc00 = {0.f, 0.f, 0.f, 0.f};
    f32x4 acc01 = {0.f, 0.f, 0.f, 0.f};
    f32x4 acc10 = {0.f, 0.f, 0.f, 0.f};
    f32x4 acc11 = {0.f, 0.f, 0.f, 0.f};
    #pragma unroll
    for (int ks = 0; ks < 2; ks++) {
        int ko = ks * 32 + lgrp * 8;
        bf16x8 a0 = *(const bf16x8*)&Xb[wr + lrow][ko];
        bf16x8 a1 = *(const bf16x8*)&Xb[wr + 16 + lrow][ko];
        bf16x8 b0 = *(const bf16x8*)&Wt[wc + lrow][ko];
        bf16x8 b1 = *(const bf16x8*)&Wt[wc + 16 + lrow][ko];
        acc00 = __builtin_amdgcn_mfma_f32_16x16x32_bf16(a0, b0, acc00, 0, 0, 0);
        acc01 = __builtin_amdgcn_mfma_f32_16x16x32_bf16(a0, b1, acc01, 0, 0, 0);
        acc10 = __builtin_amdgcn_mfma_f32_16x16x32_bf16(a1, b0, acc10, 0, 0, 0);
        acc11 = __builtin_amdgcn_mfma_f32_16x16x32_bf16(a1, b1, acc11, 0, 0, 0);
    }

    float bias0 = bias[wc + lrow], bias1 = bias[wc + 16 + lrow];
    #pragma unroll
    for (int mi = 0; mi < 2; mi++) {
        const f32x4 accn0 = mi ? acc10 : acc00;
        const f32x4 accn1 = mi ? acc11 : acc01;
        int rbase = wr + mi * 16 + lgrp * 4;
        #pragma unroll
        for (int r = 0; r < 4; r++) {
            int n = nb + rbase + r;
            if (n >= N) continue;
            O[(size_t)n * HID + wc + lrow]      = accn0[r] + bias0;
            O[(size_t)n * HID + wc + 16 + lrow] = accn1[r] + bias1;
        }
    }
}

extern "C" void kernel_launch(void* const* d_in, const int* in_sizes, int n_in,
                              void* d_out, int out_size, void* d_ws, size_t ws_size,
                              hipStream_t stream) {
    const float* x_paper  = (const float*)d_in[0];
    const float* x_author = (const float*)d_in[1];
    const int*   ei_ap    = (const int*)d_in[2];
    const int*   ei_pa    = (const int*)d_in[3];
    const int*   ei_pp    = (const int*)d_in[4];
    const float* W_in     = (const float*)d_in[5];
    const float* b_in     = (const float*)d_in[6];
    const float* W_kqv    = (const float*)d_in[7];
    const float* b_kqv    = (const float*)d_in[8];
    const float* W_krel   = (const float*)d_in[9];
    const float* W_vrel   = (const float*)d_in[10];
    const float* p_rel    = (const float*)d_in[11];
    const float* W_hout   = (const float*)d_in[12];
    const float* b_hout   = (const float*)d_in[13];
    const float* skip     = (const float*)d_in[14];
    const float* ln_g     = (const float*)d_in[15];
    const float* ln_b     = (const float*)d_in[16];
    const float* W_out    = (const float*)d_in[17];
    const float* b_out    = (const float*)d_in[18];
    float* out            = (float*)d_out;

    // ---- workspace layout (~146 MB) ----
    float* ws   = (float*)d_ws;
    float* hbuf = ws;                                   // NTOT*64 f32
    float* Q    = hbuf + (size_t)NTOT * HID;            // NTOT*64 f32 (attn out aliases Q)
    unsigned* KVb = (unsigned*)(Q + (size_t)NTOT * HID); // NSRC*64 dwords (f16 k/v pairs)
    float* Wfp  = (float*)(KVb + (size_t)NSRC * HID);   // 64*320
    float* bfp  = Wfp  + 64 * JP;                       // 320
    float* Wfa  = bfp  + JP;                            // 64*192
    float* bfa  = Wfa  + 64 * JA;                       // 192
    int* cnt      = (int*)(bfa + JA);                   // NTOT
    int* row_ptr  = cnt + NTOT;                         // NTOT+1 (pad 16)
    int* cursor   = row_ptr + NTOT + 16;                // NTOT
    int* edge_src = cursor + NTOT;                      // ETOT
    int* csum     = edge_src + ETOT;                    // 1024
    int* coff     = csum + 1024;                        // 1024

    dim3 blk(256);
    const int EB = (ETOT + 255) / 256;

    // ---- CSR build (edges are layer-invariant) ----
    zero_int_kernel<<<256, blk, 0, stream>>>(cnt, NTOT);
    csr_count_kernel<<<EB, blk, 0, stream>>>(ei_ap, ei_pa, ei_pp, cnt);
    scan_chunk_sums<<<NCH, blk, 0, stream>>>(cnt, csum);
    scan_offsets<<<1, 1024, 0, stream>>>(csum, coff, NCH);
    scan_final<<<NCH, blk, 0, stream>>>(cnt, coff, row_ptr, cursor);
    csr_fill_kernel<<<EB, blk, 0, stream>>>(ei_ap, ei_pa, ei_pp, cursor, edge_src);

    // ---- input projection ----
    gemm_in<<<PT + AT, blk, 0, stream>>>(x_paper, x_author, W_in, b_in, hbuf);

    for (int l = 0; l < LAYERS; l++) {
        fuse_weights_kernel<<<(65 * JP + 65 * JA + 255) / 256, blk, 0, stream>>>(
            W_kqv + (size_t)l * 2 * HID * KQV, b_kqv + (size_t)l * 2 * KQV,
            W_krel + (size_t)l * 3 * NH * HD * HD, W_vrel + (size_t)l * 3 * NH * HD * HD,
            Wfp, bfp, Wfa, bfa);
        gemm_kqv<<<3 * PT + 2 * AT, blk, 0, stream>>>(
            hbuf, Wfp, bfp, Wfa, bfa, Q, KVb);
        attn_kernel<<<(NTOT + 3) / 4, blk, 0, stream>>>(
            Q, KVb, p_rel + l * 3 * NH, row_ptr, edge_src, Q);
        gemm_hout<<<PT + AT, blk, 0, stream>>>(
            Q, W_hout + (size_t)l * 2 * HID * HID, b_hout + l * 2 * HID,
            skip + l * 2, ln_g + l * 2 * HID, ln_b + l * 2 * HID, hbuf);
    }

    gemm_out<<<PT + AT, blk, 0, stream>>>(hbuf, W_out, b_out, out);
}

// Round 13
// 431.034 us; speedup vs baseline: 4.3468x; 1.0334x over previous
//
#include <hip/hip_runtime.h>
#include <hip/hip_bf16.h>

// ---- problem constants (match reference) ----
#define NP 100000
#define NA 50000
#define NTOT 150000          // NP+NA
#define E0 300000
#define E1 300000
#define E2 200000
#define ETOT 800000
#define NH 4
#define HD 16
#define HID 64
#define IN_DIM 128
#define KQV 192
#define LAYERS 2
#define NSRC 250000          // NA + 2*NP
#define JP 320               // fused paper cols: q | k_et1 | k_et2 | v_et1 | v_et2
#define JA 192               // fused author cols: q | k_et0 | v_et0
#define NCH 586              // ceil(NTOT/256)
#define PT 1563              // ceil(NP/64)
#define AT 782               // ceil(NA/64)

typedef __attribute__((ext_vector_type(8))) short bf16x8;   // 8 bf16 (4 VGPRs)
typedef __attribute__((ext_vector_type(4))) float f32x4;    // MFMA C/D
typedef _Float16 h16x2 __attribute__((ext_vector_type(2)));

__device__ __forceinline__ float gelu_exact(float x) {
    return 0.5f * x * (1.0f + erff(x * 0.7071067811865475f));
}
// f32 -> bf16 bits, round-to-nearest-even (finite values)
__device__ __forceinline__ unsigned short f2bf(float f) {
    unsigned u = __float_as_uint(f);
    return (unsigned short)((u + 0x7fffu + ((u >> 16) & 1u)) >> 16);
}
// f32 -> f16 bits (RNE via hardware cvt)
__device__ __forceinline__ unsigned short f2h(float f) {
    union { _Float16 h; unsigned short u; } c;
    c.h = (_Float16)f;
    return c.u;
}

// decode global edge id -> (src in KV space, dst in node space)
__device__ __forceinline__ void edge_decode(int e, const int* __restrict__ ei_ap,
                                            const int* __restrict__ ei_pa,
                                            const int* __restrict__ ei_pp,
                                            int& src, int& dst) {
    if (e < E0)            { src = ei_ap[e];                 dst = ei_ap[E0 + e]; }
    else if (e < E0 + E1)  { int le = e - E0;
                             src = NA + ei_pa[le];           dst = NP + ei_pa[E1 + le]; }
    else                   { int le = e - E0 - E1;
                             src = NA + NP + ei_pp[le];      dst = ei_pp[E2 + le]; }
}

// ---------------- CSR build ----------------
__global__ void zero_int_kernel(int* __restrict__ p, int n) {
    int i = blockIdx.x * blockDim.x + threadIdx.x;
    int st = gridDim.x * blockDim.x;
    for (int j = i; j < n; j += st) p[j] = 0;
}

__global__ void csr_count_kernel(const int* __restrict__ ei_ap, const int* __restrict__ ei_pa,
                                 const int* __restrict__ ei_pp, int* __restrict__ cnt) {
    int e = blockIdx.x * 256 + threadIdx.x;
    if (e >= ETOT) return;
    int src, dst; edge_decode(e, ei_ap, ei_pa, ei_pp, src, dst);
    atomicAdd(&cnt[dst], 1);
}

__global__ void scan_chunk_sums(const int* __restrict__ cnt, int* __restrict__ csum) {
    __shared__ int sd[256];
    int c = blockIdx.x, t = threadIdx.x;
    int i = c * 256 + t;
    sd[t] = (i < NTOT) ? cnt[i] : 0;
    __syncthreads();
    for (int o = 128; o > 0; o >>= 1) { if (t < o) sd[t] += sd[t + o]; __syncthreads(); }
    if (t == 0) csum[c] = sd[0];
}

__global__ void scan_offsets(const int* __restrict__ csum, int* __restrict__ coff, int nch) {
    __shared__ int sd[1024];
    int t = threadIdx.x;
    int v = (t < nch) ? csum[t] : 0;
    sd[t] = v;
    __syncthreads();
    for (int o = 1; o < 1024; o <<= 1) {
        int x = (t >= o) ? sd[t - o] : 0;
        __syncthreads();
        sd[t] += x;
        __syncthreads();
    }
    if (t < nch) coff[t] = sd[t] - v;   // exclusive
}

__global__ void scan_final(const int* __restrict__ cnt, const int* __restrict__ coff,
                           int* __restrict__ row_ptr, int* __restrict__ cursor) {
    __shared__ int sd[256];
    int c = blockIdx.x, t = threadIdx.x, i = c * 256 + t;
    int v = (i < NTOT) ? cnt[i] : 0;
    sd[t] = v;
    __syncthreads();
    for (int o = 1; o < 256; o <<= 1) {
        int x = (t >= o) ? sd[t - o] : 0;
        __syncthreads();
        sd[t] += x;
        __syncthreads();
    }
    if (i < NTOT) { int ex = coff[c] + sd[t] - v; row_ptr[i] = ex; cursor[i] = ex; }
    if (i == 0) row_ptr[NTOT] = ETOT;
}

__global__ void csr_fill_kernel(const int* __restrict__ ei_ap, const int* __restrict__ ei_pa,
                                const int* __restrict__ ei_pp, int* __restrict__ cursor,
                                int* __restrict__ edge_src) {
    int e = blockIdx.x * 256 + threadIdx.x;
    if (e >= ETOT) return;
    int src, dst; edge_decode(e, ei_ap, ei_pa, ei_pp, src, dst);
    int pos = atomicAdd(&cursor[dst], 1);
    edge_src[pos] = src;
}

// ---------------- fused-weight build (per layer) ----------------
__global__ void fuse_weights_kernel(const float* __restrict__ Wkqv, const float* __restrict__ bkqv,
                                    const float* __restrict__ Wkrel, const float* __restrict__ Wvrel,
                                    float* __restrict__ Wfp, float* __restrict__ bfp,
                                    float* __restrict__ Wfa, float* __restrict__ bfa) {
    int idx = blockIdx.x * 256 + threadIdx.x;
    int type, i, j;
    if (idx < 65 * JP) { type = 0; i = idx / JP; j = idx % JP; }
    else {
        int r = idx - 65 * JP;
        if (r >= 65 * JA) return;
        type = 1; i = r / JA; j = r % JA;
    }
    int c = j >> 6, jj = j & 63, h = jj >> 4, e = jj & 15;
    const float* Wk = Wkqv + (size_t)type * HID * KQV;
    const float* bk = bkqv + type * KQV;
    float val;
    if (c == 0) {
        val = (i < 64) ? Wk[i * KQV + 64 + jj] : bk[64 + jj];
    } else {
        int et, isV;
        if (type == 0) { et = (c == 1 || c == 3) ? 1 : 2; isV = (c >= 3); }
        else           { et = 0; isV = (c == 2); }
        const float* Wr = (isV ? Wvrel : Wkrel) + (size_t)(et * NH + h) * HD * HD;
        int sb = (isV ? 128 : 0) + h * HD;
        val = 0.0f;
        #pragma unroll
        for (int d = 0; d < HD; d++) {
            float a = (i < 64) ? Wk[i * KQV + sb + d] : bk[sb + d];
            val += a * Wr[d * HD + e];
        }
    }
    if (i < 64) (type ? Wfa : Wfp)[i * (type ? JA : JP) + j] = val;
    else        (type ? bfa : bfp)[j] = val;
}

// ---------------- input projection via MFMA bf16 (K=128), paper+author merged ----------------
__global__ __launch_bounds__(256) void gemm_in(
    const float* __restrict__ xp, const float* __restrict__ xa,
    const float* __restrict__ W_in, const float* __restrict__ b_in,
    float* __restrict__ hbuf)
{
    __shared__ unsigned short Xb[64][136];   // 272B rows (16B-aligned)
    __shared__ unsigned short Wt[64][136];   // Wt[col][k]
    int b = blockIdx.x, tid = threadIdx.x;
    int type = (b >= PT);
    int tile = type ? (b - PT) : b;
    int N = type ? NA : NP;
    const float* X = type ? xa : xp;
    const float* W = W_in + (size_t)type * IN_DIM * HID;
    const float* bias = b_in + type * HID;
    float* H = hbuf + (type ? (size_t)NP * HID : 0);
    int nb = tile * 64;

    {
        int row = tid >> 2, c0 = (tid & 3) * 32;
        int n = nb + row;
        if (n < N) {
            const float* xr = X + (size_t)n * IN_DIM + c0;
            #pragma unroll
            for (int i = 0; i < 32; i += 4) {
                float4 v = *(const float4*)(xr + i);
                *(ushort4*)&Xb[row][c0 + i] =
                    make_ushort4(f2bf(v.x), f2bf(v.y), f2bf(v.z), f2bf(v.w));
            }
        } else {
            #pragma unroll
            for (int i = 0; i < 32; i += 4)
                *(ushort4*)&Xb[row][c0 + i] = make_ushort4(0, 0, 0, 0);
        }
    }
    #pragma unroll
    for (int it = 0; it < 8; it++) {
        int idx = it * 256 + tid;            // 0..2047
        int k = idx & 127, c = (idx >> 7) * 4;
        float4 v = *(const float4*)(W + (size_t)k * HID + c);
        Wt[c + 0][k] = f2bf(v.x); Wt[c + 1][k] = f2bf(v.y);
        Wt[c + 2][k] = f2bf(v.z); Wt[c + 3][k] = f2bf(v.w);
    }
    __syncthreads();

    int w = tid >> 6, lane = tid & 63;
    int wr = (w >> 1) * 32, wc = (w & 1) * 32;
    int lrow = lane & 15, lgrp = lane >> 4;

    f32x4 acc00 = {0.f, 0.f, 0.f, 0.f};
    f32x4 acc01 = {0.f, 0.f, 0.f, 0.f};
    f32x4 acc10 = {0.f, 0.f, 0.f, 0.f};
    f32x4 acc11 = {0.f, 0.f, 0.f, 0.f};
    #pragma unroll
    for (int ks = 0; ks < 4; ks++) {
        int ko = ks * 32 + lgrp * 8;
        bf16x8 a0 = *(const bf16x8*)&Xb[wr + lrow][ko];
        bf16x8 a1 = *(const bf16x8*)&Xb[wr + 16 + lrow][ko];
        bf16x8 b0 = *(const bf16x8*)&Wt[wc + lrow][ko];
        bf16x8 b1 = *(const bf16x8*)&Wt[wc + 16 + lrow][ko];
        acc00 = __builtin_amdgcn_mfma_f32_16x16x32_bf16(a0, b0, acc00, 0, 0, 0);
        acc01 = __builtin_amdgcn_mfma_f32_16x16x32_bf16(a0, b1, acc01, 0, 0, 0);
        acc10 = __builtin_amdgcn_mfma_f32_16x16x32_bf16(a1, b0, acc10, 0, 0, 0);
        acc11 = __builtin_amdgcn_mfma_f32_16x16x32_bf16(a1, b1, acc11, 0, 0, 0);
    }

    float bias0 = bias[wc + lrow], bias1 = bias[wc + 16 + lrow];
    #pragma unroll
    for (int mi = 0; mi < 2; mi++) {
        const f32x4 accn0 = mi ? acc10 : acc00;
        const f32x4 accn1 = mi ? acc11 : acc01;
        int rbase = wr + mi * 16 + lgrp * 4;
        #pragma unroll
        for (int r = 0; r < 4; r++) {
            int n = nb + rbase + r;
            if (n >= N) continue;
            H[(size_t)n * HID + wc + lrow]      = accn0[r] + bias0;
            H[(size_t)n * HID + wc + 16 + lrow] = accn1[r] + bias1;
        }
    }
}

// ---------------- KQV GEMM via MFMA bf16: K+V merged per block ----------------
// Block kinds: paper Q | paper KV(et1) | paper KV(et2) | author Q | author KV.
// KV epilogue: shfl_xor(1) partner exchange packs attn pair-layout dwords =>
// coalesced 4B stores, no 2-byte RMW.
__global__ __launch_bounds__(256) void gemm_kqv(
    const float* __restrict__ hbuf,
    const float* __restrict__ Wfp, const float* __restrict__ bfp,
    const float* __restrict__ Wfa, const float* __restrict__ bfa,
    float* __restrict__ Q, unsigned* __restrict__ KVb)
{
    __shared__ unsigned short Xb[64][72];
    __shared__ unsigned short WtK[64][72];
    __shared__ unsigned short WtV[64][72];
    int b = blockIdx.x, tid = threadIdx.x;
    int type, tile, kind;
    if (b < PT)                { type = 0; kind = 0; tile = b; }
    else if (b < 2 * PT)       { type = 0; kind = 1; tile = b - PT; }
    else if (b < 3 * PT)       { type = 0; kind = 2; tile = b - 2 * PT; }
    else if (b < 3 * PT + AT)  { type = 1; kind = 0; tile = b - 3 * PT; }
    else                       { type = 1; kind = 1; tile = b - 3 * PT - AT; }
    int N = type ? NA : NP;
    const float* X = hbuf + (type ? (size_t)NP * HID : 0);
    const float* W = type ? Wfa : Wfp;
    const float* bias = type ? bfa : bfp;
    int ldw = type ? JA : JP;
    int nb = tile * 64;
    bool isQ = (kind == 0);
    int kcol = 0, vcol = 0, noff = 0;
    if (!isQ) {
        if (type == 0) {
            if (kind == 1) { kcol = 64;  vcol = 192; noff = NA; }
            else           { kcol = 128; vcol = 256; noff = NA + NP; }
        } else             { kcol = 64;  vcol = 128; noff = 0; }
    } else {
        noff = type ? NP : 0;
    }

    {
        int row = tid >> 2, c0 = (tid & 3) * 16;
        int n = nb + row;
        unsigned short tmp[16];
        if (n < N) {
            const float* xr = X + (size_t)n * HID + c0;
            #pragma unroll
            for (int i = 0; i < 16; i += 4) {
                float4 v = *(const float4*)(xr + i);
                tmp[i] = f2bf(v.x); tmp[i+1] = f2bf(v.y);
                tmp[i+2] = f2bf(v.z); tmp[i+3] = f2bf(v.w);
            }
        } else {
            #pragma unroll
            for (int i = 0; i < 16; i++) tmp[i] = 0;
        }
        #pragma unroll
        for (int i = 0; i < 16; i += 4)
            *(ushort4*)&Xb[row][c0 + i] = make_ushort4(tmp[i], tmp[i+1], tmp[i+2], tmp[i+3]);
    }
    #pragma unroll
    for (int it = 0; it < 4; it++) {
        int idx = it * 256 + tid;           // 0..1023
        int k = idx & 63, c = (idx >> 6) * 4;
        float4 v = *(const float4*)(W + (size_t)k * ldw + kcol + c);
        WtK[c + 0][k] = f2bf(v.x); WtK[c + 1][k] = f2bf(v.y);
        WtK[c + 2][k] = f2bf(v.z); WtK[c + 3][k] = f2bf(v.w);
    }
    if (!isQ) {
        #pragma unroll
        for (int it = 0; it < 4; it++) {
            int idx = it * 256 + tid;
            int k = idx & 63, c = (idx >> 6) * 4;
            float4 v = *(const float4*)(W + (size_t)k * ldw + vcol + c);
            WtV[c + 0][k] = f2bf(v.x); WtV[c + 1][k] = f2bf(v.y);
            WtV[c + 2][k] = f2bf(v.z); WtV[c + 3][k] = f2bf(v.w);
        }
    }
    __syncthreads();

    int w = tid >> 6, lane = tid & 63;
    int wr = (w >> 1) * 32, wc = (w & 1) * 32;
    int lrow = lane & 15, lgrp = lane >> 4;

    f32x4 k00 = {0.f,0.f,0.f,0.f}, k01 = {0.f,0.f,0.f,0.f};
    f32x4 k10 = {0.f,0.f,0.f,0.f}, k11 = {0.f,0.f,0.f,0.f};
    f32x4 v00 = {0.f,0.f,0.f,0.f}, v01 = {0.f,0.f,0.f,0.f};
    f32x4 v10 = {0.f,0.f,0.f,0.f}, v11 = {0.f,0.f,0.f,0.f};
    #pragma unroll
    for (int ks = 0; ks < 2; ks++) {
        int ko = ks * 32 + lgrp * 8;
        bf16x8 a0 = *(const bf16x8*)&Xb[wr + lrow][ko];
        bf16x8 a1 = *(const bf16x8*)&Xb[wr + 16 + lrow][ko];
        bf16x8 bk0 = *(const bf16x8*)&WtK[wc + lrow][ko];
        bf16x8 bk1 = *(const bf16x8*)&WtK[wc + 16 + lrow][ko];
        k00 = __builtin_amdgcn_mfma_f32_16x16x32_bf16(a0, bk0, k00, 0, 0, 0);
        k01 = __builtin_amdgcn_mfma_f32_16x16x32_bf16(a0, bk1, k01, 0, 0, 0);
        k10 = __builtin_amdgcn_mfma_f32_16x16x32_bf16(a1, bk0, k10, 0, 0, 0);
        k11 = __builtin_amdgcn_mfma_f32_16x16x32_bf16(a1, bk1, k11, 0, 0, 0);
        if (!isQ) {
            bf16x8 bv0 = *(const bf16x8*)&WtV[wc + lrow][ko];
            bf16x8 bv1 = *(const bf16x8*)&WtV[wc + 16 + lrow][ko];
            v00 = __builtin_amdgcn_mfma_f32_16x16x32_bf16(a0, bv0, v00, 0, 0, 0);
            v01 = __builtin_amdgcn_mfma_f32_16x16x32_bf16(a0, bv1, v01, 0, 0, 0);
            v10 = __builtin_amdgcn_mfma_f32_16x16x32_bf16(a1, bv0, v10, 0, 0, 0);
            v11 = __builtin_amdgcn_mfma_f32_16x16x32_bf16(a1, bv1, v11, 0, 0, 0);
        }
    }

    int c0 = wc + lrow, c1 = wc + 16 + lrow;
    if (isQ) {
        float bias0 = bias[c0], bias1 = bias[c1];
        #pragma unroll
        for (int mi = 0; mi < 2; mi++) {
            const f32x4 a0 = mi ? k10 : k00;
            const f32x4 a1 = mi ? k11 : k01;
            int rbase = wr + mi * 16 + lgrp * 4;
            #pragma unroll
            for (int r = 0; r < 4; r++) {
                int n = nb + rbase + r;
                if (n >= N) continue;
                Q[(size_t)(noff + n) * HID + c0] = a0[r] + bias0;
                Q[(size_t)(noff + n) * HID + c1] = a1[r] + bias1;
            }
        }
    } else {
        float bk0 = bias[kcol + c0], bk1 = bias[kcol + c1];
        float bv0 = bias[vcol + c0], bv1 = bias[vcol + c1];
        bool even = ((lrow & 1) == 0);
        #pragma unroll
        for (int mi = 0; mi < 2; mi++) {
            const f32x4 ak0 = mi ? k10 : k00;
            const f32x4 ak1 = mi ? k11 : k01;
            const f32x4 av0 = mi ? v10 : v00;
            const f32x4 av1 = mi ? v11 : v01;
            int rbase = wr + mi * 16 + lgrp * 4;
            #pragma unroll
            for (int r = 0; r < 4; r++) {
                int n = nb + rbase + r;
                unsigned* dst = KVb + (((size_t)(noff + n)) << 6);
                unsigned own0 = (unsigned)f2h(ak0[r] + bk0) | ((unsigned)f2h(av0[r] + bv0) << 16);
                unsigned oth0 = __shfl_xor(own0, 1, 64);
                unsigned own1 = (unsigned)f2h(ak1[r] + bk1) | ((unsigned)f2h(av1[r] + bv1) << 16);
                unsigned oth1 = __shfl_xor(own1, 1, 64);
                if (n < N) {
                    unsigned w0 = even ? ((own0 & 0xffffu) | (oth0 << 16))
                                       : ((oth0 >> 16) | (own0 & 0xffff0000u));
                    unsigned w1 = even ? ((own1 & 0xffffu) | (oth1 << 16))
                                       : ((oth1 >> 16) | (own1 & 0xffff0000u));
                    dst[c0] = w0;
                    dst[c1] = w1;
                }
            }
        }
    }
}

// ---------------- fused attention: no-max softmax, 4 edges/iter ----------------
// R12 post-mortem: online-max machinery was ~1/3 of VALU and the whole
// loop-carried dep chain. Rows avg 5.3 edges, |alpha| small -> exact softmax
// without max subtraction (clamped at 80 in exp2 domain as overflow guard).
// Loop-carried state is now pure adds; 2 independent gathers in flight.
__global__ __launch_bounds__(256) void attn_kernel(
    const float* Q, const unsigned* __restrict__ KVb,
    const float* __restrict__ p_rel, const int* __restrict__ row_ptr,
    const int* __restrict__ edge_src, float* attnout)
{
    int wid = threadIdx.x >> 6, lane = threadIdx.x & 63;
    int n = blockIdx.x * 4 + wid;
    if (n >= NTOT) return;
    int half = lane >> 5;
    int p = lane & 31;           // pair index: dims 2p, 2p+1
    int h = p >> 3;              // head
    float2 qp = *(const float2*)(Q + (size_t)n * HID + 2 * p);
    h16x2 qh; qh[0] = (_Float16)qp.x; qh[1] = (_Float16)qp.y;
    const float INV_LN2 = 1.4426950408889634f;
    float pr0 = p_rel[h] * 0.25f * INV_LN2;
    float pr1 = p_rel[4 + h] * 0.25f * INV_LN2;
    float pr2 = p_rel[8 + h] * 0.25f * INV_LN2;
    int beg = row_ptr[n], end = row_ptr[n + 1];
    float s = 0.0f, acc0 = 0.f, acc1 = 0.f;
    for (int e = beg; e < end; e += 4) {
        int e0 = e + half;           // edges e, e+1
        int e1 = e + 2 + half;       // edges e+2, e+3
        bool v0 = (e0 < end), v1 = (e1 < end);
        int s0 = v0 ? edge_src[e0] : 0;
        int s1 = v1 ? edge_src[e1] : 0;
        uint2 kv0 = *(const uint2*)(KVb + (((size_t)s0) << 6) + 2 * p);
        uint2 kv1 = *(const uint2*)(KVb + (((size_t)s1) << 6) + 2 * p);
        float d0, d1;
#if __has_builtin(__builtin_amdgcn_fdot2)
        {
            union { unsigned u; h16x2 v; } ck;
            ck.u = kv0.x; d0 = __builtin_amdgcn_fdot2(qh, ck.v, 0.0f, false);
            ck.u = kv1.x; d1 = __builtin_amdgcn_fdot2(qh, ck.v, 0.0f, false);
        }
#else
        {
            union { unsigned u; _Float16 f[2]; } ck;
            ck.u = kv0.x; d0 = qp.x * (float)ck.f[0] + qp.y * (float)ck.f[1];
            ck.u = kv1.x; d1 = qp.x * (float)ck.f[0] + qp.y * (float)ck.f[1];
        }
#endif
        d0 += __shfl_xor(d0, 1, 64);  d1 += __shfl_xor(d1, 1, 64);
        d0 += __shfl_xor(d0, 2, 64);  d1 += __shfl_xor(d1, 2, 64);
        d0 += __shfl_xor(d0, 4, 64);  d1 += __shfl_xor(d1, 4, 64);
        float pa = (s0 < NA) ? pr0 : ((s0 < NA + NP) ? pr1 : pr2);
        float pb = (s1 < NA) ? pr0 : ((s1 < NA + NP) ? pr1 : pr2);
        float a0 = v0 ? fminf(d0 * pa, 80.0f) : -INFINITY;
        float a1 = v1 ? fminf(d1 * pb, 80.0f) : -INFINITY;
        float p0 = exp2f(a0);
        float p1 = exp2f(a1);
        s += p0 + p1;
        union { unsigned u; _Float16 f[2]; } cv0, cv1;
        cv0.u = kv0.y; cv1.u = kv1.y;
        acc0 += p0 * (float)cv0.f[0] + p1 * (float)cv1.f[0];
        acc1 += p0 * (float)cv0.f[1] + p1 * (float)cv1.f[1];
    }
    s    += __shfl_xor(s, 32, 64);
    acc0 += __shfl_xor(acc0, 32, 64);
    acc1 += __shfl_xor(acc1, 32, 64);
    if (half == 0) {
        float inv = 1.0f / (s + 1e-16f);
        float2 o; o.x = acc0 * inv; o.y = acc1 * inv;
        *(float2*)(attnout + (size_t)n * HID + 2 * p) = o;
    }
}

// ---------------- hout via MFMA bf16 + skip + LN + gelu, paper+author merged ----------------
__global__ __launch_bounds__(256) void gemm_hout(
    const float* __restrict__ attnout, const float* __restrict__ Whout,
    const float* __restrict__ bhout, const float* __restrict__ skip_p,
    const float* __restrict__ lng, const float* __restrict__ lnb,
    float* __restrict__ hbuf)
{
    __shared__ unsigned short Xb[64][72];
    __shared__ unsigned short Wt[64][72];
    __shared__ float hs[64][68];
    int b = blockIdx.x, tid = threadIdx.x;
    int type = (b >= PT);
    int tile = type ? (b - PT) : b;
    int N = type ? NA : NP;
    size_t base_off = type ? (size_t)NP * HID : 0;
    const float* X = attnout + base_off;
    const float* W = Whout + (size_t)type * HID * HID;
    const float* bias = bhout + type * HID;
    float* H = hbuf + base_off;
    int nb = tile * 64;

    {
        int row = tid >> 2, c0 = (tid & 3) * 16;
        int n = nb + row;
        unsigned short tmp[16];
        if (n < N) {
            const float* xr = X + (size_t)n * HID + c0;
            #pragma unroll
            for (int i = 0; i < 16; i += 4) {
                float4 v = *(const float4*)(xr + i);
                tmp[i]   = f2bf(gelu_exact(v.x)); tmp[i+1] = f2bf(gelu_exact(v.y));
                tmp[i+2] = f2bf(gelu_exact(v.z)); tmp[i+3] = f2bf(gelu_exact(v.w));
            }
        } else {
            #pragma unroll
            for (int i = 0; i < 16; i++) tmp[i] = 0;
        }
        #pragma unroll
        for (int i = 0; i < 16; i += 4)
            *(ushort4*)&Xb[row][c0 + i] = make_ushort4(tmp[i], tmp[i+1], tmp[i+2], tmp[i+3]);
    }
    #pragma unroll
    for (int it = 0; it < 4; it++) {
        int idx = it * 256 + tid;
        int k = idx & 63, c = (idx >> 6) * 4;
        float4 v = *(const float4*)(W + (size_t)k * HID + c);
        Wt[c + 0][k] = f2bf(v.x); Wt[c + 1][k] = f2bf(v.y);
        Wt[c + 2][k] = f2bf(v.z); Wt[c + 3][k] = f2bf(v.w);
    }
    __syncthreads();

    int w = tid >> 6, lane = tid & 63;
    int wr = (w >> 1) * 32, wc = (w & 1) * 32;
    int lrow = lane & 15, lgrp = lane >> 4;

    f32x4 acc00 = {0.f, 0.f, 0.f, 0.f};
    f32x4 acc01 = {0.f, 0.f, 0.f, 0.f};
    f32x4 acc10 = {0.f, 0.f, 0.f, 0.f};
    f32x4 acc11 = {0.f, 0.f, 0.f, 0.f};
    #pragma unroll
    for (int ks = 0; ks < 2; ks++) {
        int ko = ks * 32 + lgrp * 8;
        bf16x8 a0 = *(const bf16x8*)&Xb[wr + lrow][ko];
        bf16x8 a1 = *(const bf16x8*)&Xb[wr + 16 + lrow][ko];
        bf16x8 b0 = *(const bf16x8*)&Wt[wc + lrow][ko];
        bf16x8 b1 = *(const bf16x8*)&Wt[wc + 16 + lrow][ko];
        acc00 = __builtin_amdgcn_mfma_f32_16x16x32_bf16(a0, b0, acc00, 0, 0, 0);
        acc01 = __builtin_amdgcn_mfma_f32_16x16x32_bf16(a0, b1, acc01, 0, 0, 0);
        acc10 = __builtin_amdgcn_mfma_f32_16x16x32_bf16(a1, b0, acc10, 0, 0, 0);
        acc11 = __builtin_amdgcn_mfma_f32_16x16x32_bf16(a1, b1, acc11, 0, 0, 0);
    }

    float a = 1.0f / (1.0f + __expf(-skip_p[type]));
    float oma = 1.0f - a;
    float bias0 = bias[wc + lrow], bias1 = bias[wc + 16 + lrow];
    #pragma unroll
    for (int mi = 0; mi < 2; mi++) {
        const f32x4 accn0 = mi ? acc10 : acc00;
        const f32x4 accn1 = mi ? acc11 : acc01;
        int rbase = wr + mi * 16 + lgrp * 4;
        #pragma unroll
        for (int r = 0; r < 4; r++) {
            int row = rbase + r;
            int n = nb + row;
            if (n < N) {
                const float* hp = H + (size_t)n * HID;
                hs[row][wc + lrow]      = a * (accn0[r] + bias0) + oma * hp[wc + lrow];
                hs[row][wc + 16 + lrow] = a * (accn1[r] + bias1) + oma * hp[wc + 16 + lrow];
            } else {
                hs[row][wc + lrow] = 0.f;
                hs[row][wc + 16 + lrow] = 0.f;
            }
        }
    }
    __syncthreads();

    const int tr = tid >> 4, tc = tid & 15;
    const int tcj = tc * 4;
    float g0 = lng[type*HID+tcj], g1 = lng[type*HID+tcj+1],
          g2 = lng[type*HID+tcj+2], g3 = lng[type*HID+tcj+3];
    float l0 = lnb[type*HID+tcj], l1 = lnb[type*HID+tcj+1],
          l2 = lnb[type*HID+tcj+2], l3 = lnb[type*HID+tcj+3];
    #pragma unroll 1
    for (int m = 0; m < 4; m++) {
        int row = tr * 4 + m;
        int n = nb + row;
        float v0 = hs[row][tcj], v1 = hs[row][tcj+1], v2 = hs[row][tcj+2], v3 = hs[row][tcj+3];
        float sum = v0 + v1 + v2 + v3;
        sum += __shfl_xor(sum, 1, 64); sum += __shfl_xor(sum, 2, 64);
        sum += __shfl_xor(sum, 4, 64); sum += __shfl_xor(sum, 8, 64);
        float mean = sum * (1.0f / 64.0f);
        float d0 = v0 - mean, d1 = v1 - mean, d2 = v2 - mean, d3 = v3 - mean;
        float sq = d0*d0 + d1*d1 + d2*d2 + d3*d3;
        sq += __shfl_xor(sq, 1, 64); sq += __shfl_xor(sq, 2, 64);
        sq += __shfl_xor(sq, 4, 64); sq += __shfl_xor(sq, 8, 64);
        float rstd = rsqrtf(sq * (1.0f / 64.0f) + 1e-5f);
        if (n < N) {
            float* hp = H + (size_t)n * HID + tcj;
            hp[0] = gelu_exact(d0 * rstd * g0 + l0);
            hp[1] = gelu_exact(d1 * rstd * g1 + l1);
            hp[2] = gelu_exact(d2 * rstd * g2 + l2);
            hp[3] = gelu_exact(d3 * rstd * g3 + l3);
        }
    }
}

// ---------------- final linear via MFMA bf16 (K=64), paper+author merged ----------------
__global__ __launch_bounds__(256) void gemm_out(
    const float* __restrict__ hbuf, const float* __restrict__ W_out,
    const float* __restrict__ b_out, float* __restrict__ out)
{
    __shared__ unsigned short Xb[64][72];
    __shared__ unsigned short Wt[64][72];
    int b = blockIdx.x, tid = threadIdx.x;
    int type = (b >= PT);
    int tile = type ? (b - PT) : b;
    int N = type ? NA : NP;
    size_t base_off = type ? (size_t)NP * HID : 0;
    const float* X = hbuf + base_off;
    const float* W = W_out + (size_t)type * HID * HID;
    const float* bias = b_out + type * HID;
    float* O = out + base_off;
    int nb = tile * 64;

    {
        int row = tid >> 2, c0 = (tid & 3) * 16;
        int n = nb + row;
        unsigned short tmp[16];
        if (n < N) {
            const float* xr = X + (size_t)n * HID + c0;
            #pragma unroll
            for (int i = 0; i < 16; i += 4) {
                float4 v = *(const float4*)(xr + i);
                tmp[i] = f2bf(v.x); tmp[i+1] = f2bf(v.y);
                tmp[i+2] = f2bf(v.z); tmp[i+3] = f2bf(v.w);
            }
        } else {
            #pragma unroll
            for (int i = 0; i < 16; i++) tmp[i] = 0;
        }
        #pragma unroll
        for (int i = 0; i < 16; i += 4)
            *(ushort4*)&Xb[row][c0 + i] = make_ushort4(tmp[i], tmp[i+1], tmp[i+2], tmp[i+3]);
    }
    #pragma unroll
    for (int it = 0; it < 4; it++) {
        int idx = it * 256 + tid;
        int k = idx & 63, c = (idx >> 6) * 4;
        float4 v = *(const float4*)(W + (size_t)k * HID + c);
        Wt[c + 0][k] = f2bf(v.x); Wt[c + 1][k] = f2bf(v.y);
        Wt[c + 2][k] = f2bf(v.z); Wt[c + 3][k] = f2bf(v.w);
    }
    __syncthreads();

    int w = tid >> 6, lane = tid & 63;
    int wr = (w >> 1) * 32, wc = (w & 1) * 32;
    int lrow = lane & 15, lgrp = lane >> 4;

    f32x4 acc00 = {0.f, 0.f, 0.f, 0.f};
    f32x4 acc01 = {0.f, 0.f, 0.f, 0.f};
    f32x4 acc10 = {0.f, 0.f, 0.f, 0.f};
    f32x4 acc11 = {0.f, 0.f, 0.f, 0.f};
    #pragma unroll
    for (int ks = 0; ks < 2; ks++) {
        int ko = ks * 32 + lgrp * 8;
        bf16x8 a0 = *(const bf16x8*)&Xb[wr + lrow][ko];
        bf16x8 a1 = *(const bf16x8*)&Xb[wr + 16 + lrow][ko];
        bf16x8 b0 = *(const bf16x8*)&Wt[wc + lrow][ko];
        bf16x8 b1 = *(const bf16x8*)&Wt[wc + 16 + lrow][ko];
        acc00 = __builtin_amdgcn_mfma_f32_16x16x32_bf16(a0, b0, acc00, 0, 0, 0);
        acc01 = __builtin_amdgcn_mfma_f32_16x16x32_bf16(a0, b1, acc01, 0, 0, 0);
        acc10 = __builtin_amdgcn_mfma_f32_16x16x32_bf16(a1, b0, acc10, 0, 0, 0);
        acc11 = __builtin_amdgcn_mfma_f32_16x16x32_bf16(a1, b1, acc11, 0, 0, 0);
    }

    float bias0 = bias[wc + lrow], bias1 = bias[wc + 16 + lrow];
    #pragma unroll
    for (int mi = 0; mi < 2; mi++) {
        const f32x4 accn0 = mi ? acc10 : acc00;
        const f32x4 accn1 = mi ? acc11 : acc01;
        int rbase = wr + mi * 16 + lgrp * 4;
        #pragma unroll
        for (int r = 0; r < 4; r++) {
            int n = nb + rbase + r;
            if (n >= N) continue;
            O[(size_t)n * HID + wc + lrow]      = accn0[r] + bias0;
            O[(size_t)n * HID + wc + 16 + lrow] = accn1[r] + bias1;
        }
    }
}

extern "C" void kernel_launch(void* const* d_in, const int* in_sizes, int n_in,
                              void* d_out, int out_size, void* d_ws, size_t ws_size,
                              hipStream_t stream) {
    const float* x_paper  = (const float*)d_in[0];
    const float* x_author = (const float*)d_in[1];
    const int*   ei_ap    = (const int*)d_in[2];
    const int*   ei_pa    = (const int*)d_in[3];
    const int*   ei_pp    = (const int*)d_in[4];
    const float* W_in     = (const float*)d_in[5];
    const float* b_in     = (const float*)d_in[6];
    const float* W_kqv    = (const float*)d_in[7];
    const float* b_kqv    = (const float*)d_in[8];
    const float* W_krel   = (const float*)d_in[9];
    const float* W_vrel   = (const float*)d_in[10];
    const float* p_rel    = (const float*)d_in[11];
    const float* W_hout   = (const float*)d_in[12];
    const float* b_hout   = (const float*)d_in[13];
    const float* skip     = (const float*)d_in[14];
    const float* ln_g     = (const float*)d_in[15];
    const float* ln_b     = (const float*)d_in[16];
    const float* W_out    = (const float*)d_in[17];
    const float* b_out    = (const float*)d_in[18];
    float* out            = (float*)d_out;

    // ---- workspace layout (~146 MB) ----
    float* ws   = (float*)d_ws;
    float* hbuf = ws;                                   // NTOT*64 f32
    float* Q    = hbuf + (size_t)NTOT * HID;            // NTOT*64 f32 (attn out aliases Q)
    unsigned* KVb = (unsigned*)(Q + (size_t)NTOT * HID); // NSRC*64 dwords (f16 k/v pairs)
    float* Wfp  = (float*)(KVb + (size_t)NSRC * HID);   // 64*320
    float* bfp  = Wfp  + 64 * JP;                       // 320
    float* Wfa  = bfp  + JP;                            // 64*192
    float* bfa  = Wfa  + 64 * JA;                       // 192
    int* cnt      = (int*)(bfa + JA);                   // NTOT
    int* row_ptr  = cnt + NTOT;                         // NTOT+1 (pad 16)
    int* cursor   = row_ptr + NTOT + 16;                // NTOT
    int* edge_src = cursor + NTOT;                      // ETOT
    int* csum     = edge_src + ETOT;                    // 1024
    int* coff     = csum + 1024;                        // 1024

    dim3 blk(256);
    const int EB = (ETOT + 255) / 256;

    // ---- CSR build (edges are layer-invariant) ----
    zero_int_kernel<<<256, blk, 0, stream>>>(cnt, NTOT);
    csr_count_kernel<<<EB, blk, 0, stream>>>(ei_ap, ei_pa, ei_pp, cnt);
    scan_chunk_sums<<<NCH, blk, 0, stream>>>(cnt, csum);
    scan_offsets<<<1, 1024, 0, stream>>>(csum, coff, NCH);
    scan_final<<<NCH, blk, 0, stream>>>(cnt, coff, row_ptr, cursor);
    csr_fill_kernel<<<EB, blk, 0, stream>>>(ei_ap, ei_pa, ei_pp, cursor, edge_src);

    // ---- input projection ----
    gemm_in<<<PT + AT, blk, 0, stream>>>(x_paper, x_author, W_in, b_in, hbuf);

    for (int l = 0; l < LAYERS; l++) {
        fuse_weights_kernel<<<(65 * JP + 65 * JA + 255) / 256, blk, 0, stream>>>(
            W_kqv + (size_t)l * 2 * HID * KQV, b_kqv + (size_t)l * 2 * KQV,
            W_krel + (size_t)l * 3 * NH * HD * HD, W_vrel + (size_t)l * 3 * NH * HD * HD,
            Wfp, bfp, Wfa, bfa);
        gemm_kqv<<<3 * PT + 2 * AT, blk, 0, stream>>>(
            hbuf, Wfp, bfp, Wfa, bfa, Q, KVb);
        attn_kernel<<<(NTOT + 3) / 4, blk, 0, stream>>>(
            Q, KVb, p_rel + l * 3 * NH, row_ptr, edge_src, Q);
        gemm_hout<<<PT + AT, blk, 0, stream>>>(
            Q, W_hout + (size_t)l * 2 * HID * HID, b_hout + l * 2 * HID,
            skip + l * 2, ln_g + l * 2 * HID, ln_b + l * 2 * HID, hbuf);
    }

    gemm_out<<<PT + AT, blk, 0, stream>>>(hbuf, W_out, b_out, out);
}

// Round 14
// 424.299 us; speedup vs baseline: 4.4158x; 1.0159x over previous
//
#include <hip/hip_runtime.h>
#include <hip/hip_bf16.h>

// ---- problem constants (match reference) ----
#define NP 100000
#define NA 50000
#define NTOT 150000          // NP+NA
#define E0 300000
#define E1 300000
#define E2 200000
#define ETOT 800000
#define NH 4
#define HD 16
#define HID 64
#define IN_DIM 128
#define KQV 192
#define LAYERS 2
#define NSRC 250000          // NA + 2*NP
#define JP 320               // fused paper cols: q | k_et1 | k_et2 | v_et1 | v_et2
#define JA 192               // fused author cols: q | k_et0 | v_et0
#define NCH 586              // ceil(NTOT/256)
#define PT 1563              // ceil(NP/64)
#define AT 782               // ceil(NA/64)

typedef __attribute__((ext_vector_type(8))) short bf16x8;   // 8 bf16 (4 VGPRs)
typedef __attribute__((ext_vector_type(4))) float f32x4;    // MFMA C/D
typedef _Float16 h16x2 __attribute__((ext_vector_type(2)));

__device__ __forceinline__ float gelu_exact(float x) {
    return 0.5f * x * (1.0f + erff(x * 0.7071067811865475f));
}
// f32 -> bf16 bits, round-to-nearest-even (finite values)
__device__ __forceinline__ unsigned short f2bf(float f) {
    unsigned u = __float_as_uint(f);
    return (unsigned short)((u + 0x7fffu + ((u >> 16) & 1u)) >> 16);
}
__device__ __forceinline__ float bf2f(unsigned short b) {
    return __uint_as_float((unsigned)b << 16);
}
// f32 -> f16 bits (RNE via hardware cvt)
__device__ __forceinline__ unsigned short f2h(float f) {
    union { _Float16 h; unsigned short u; } c;
    c.h = (_Float16)f;
    return c.u;
}

// decode global edge id -> (src in KV space, dst in node space)
__device__ __forceinline__ void edge_decode(int e, const int* __restrict__ ei_ap,
                                            const int* __restrict__ ei_pa,
                                            const int* __restrict__ ei_pp,
                                            int& src, int& dst) {
    if (e < E0)            { src = ei_ap[e];                 dst = ei_ap[E0 + e]; }
    else if (e < E0 + E1)  { int le = e - E0;
                             src = NA + ei_pa[le];           dst = NP + ei_pa[E1 + le]; }
    else                   { int le = e - E0 - E1;
                             src = NA + NP + ei_pp[le];      dst = ei_pp[E2 + le]; }
}

// ---------------- CSR build ----------------
__global__ void zero_int_kernel(int* __restrict__ p, int n) {
    int i = blockIdx.x * blockDim.x + threadIdx.x;
    int st = gridDim.x * blockDim.x;
    for (int j = i; j < n; j += st) p[j] = 0;
}

__global__ void csr_count_kernel(const int* __restrict__ ei_ap, const int* __restrict__ ei_pa,
                                 const int* __restrict__ ei_pp, int* __restrict__ cnt) {
    int e = blockIdx.x * 256 + threadIdx.x;
    if (e >= ETOT) return;
    int src, dst; edge_decode(e, ei_ap, ei_pa, ei_pp, src, dst);
    atomicAdd(&cnt[dst], 1);
}

__global__ void scan_chunk_sums(const int* __restrict__ cnt, int* __restrict__ csum) {
    __shared__ int sd[256];
    int c = blockIdx.x, t = threadIdx.x;
    int i = c * 256 + t;
    sd[t] = (i < NTOT) ? cnt[i] : 0;
    __syncthreads();
    for (int o = 128; o > 0; o >>= 1) { if (t < o) sd[t] += sd[t + o]; __syncthreads(); }
    if (t == 0) csum[c] = sd[0];
}

__global__ void scan_offsets(const int* __restrict__ csum, int* __restrict__ coff, int nch) {
    __shared__ int sd[1024];
    int t = threadIdx.x;
    int v = (t < nch) ? csum[t] : 0;
    sd[t] = v;
    __syncthreads();
    for (int o = 1; o < 1024; o <<= 1) {
        int x = (t >= o) ? sd[t - o] : 0;
        __syncthreads();
        sd[t] += x;
        __syncthreads();
    }
    if (t < nch) coff[t] = sd[t] - v;   // exclusive
}

__global__ void scan_final(const int* __restrict__ cnt, const int* __restrict__ coff,
                           int* __restrict__ row_ptr, int* __restrict__ cursor) {
    __shared__ int sd[256];
    int c = blockIdx.x, t = threadIdx.x, i = c * 256 + t;
    int v = (i < NTOT) ? cnt[i] : 0;
    sd[t] = v;
    __syncthreads();
    for (int o = 1; o < 256; o <<= 1) {
        int x = (t >= o) ? sd[t - o] : 0;
        __syncthreads();
        sd[t] += x;
        __syncthreads();
    }
    if (i < NTOT) { int ex = coff[c] + sd[t] - v; row_ptr[i] = ex; cursor[i] = ex; }
    if (i == 0) row_ptr[NTOT] = ETOT;
}

__global__ void csr_fill_kernel(const int* __restrict__ ei_ap, const int* __restrict__ ei_pa,
                                const int* __restrict__ ei_pp, int* __restrict__ cursor,
                                int* __restrict__ edge_src) {
    int e = blockIdx.x * 256 + threadIdx.x;
    if (e >= ETOT) return;
    int src, dst; edge_decode(e, ei_ap, ei_pa, ei_pp, src, dst);
    int pos = atomicAdd(&cursor[dst], 1);
    edge_src[pos] = src;
}

// ---------------- fused-weight build (per layer) ----------------
__global__ void fuse_weights_kernel(const float* __restrict__ Wkqv, const float* __restrict__ bkqv,
                                    const float* __restrict__ Wkrel, const float* __restrict__ Wvrel,
                                    float* __restrict__ Wfp, float* __restrict__ bfp,
                                    float* __restrict__ Wfa, float* __restrict__ bfa) {
    int idx = blockIdx.x * 256 + threadIdx.x;
    int type, i, j;
    if (idx < 65 * JP) { type = 0; i = idx / JP; j = idx % JP; }
    else {
        int r = idx - 65 * JP;
        if (r >= 65 * JA) return;
        type = 1; i = r / JA; j = r % JA;
    }
    int c = j >> 6, jj = j & 63, h = jj >> 4, e = jj & 15;
    const float* Wk = Wkqv + (size_t)type * HID * KQV;
    const float* bk = bkqv + type * KQV;
    float val;
    if (c == 0) {
        val = (i < 64) ? Wk[i * KQV + 64 + jj] : bk[64 + jj];
    } else {
        int et, isV;
        if (type == 0) { et = (c == 1 || c == 3) ? 1 : 2; isV = (c >= 3); }
        else           { et = 0; isV = (c == 2); }
        const float* Wr = (isV ? Wvrel : Wkrel) + (size_t)(et * NH + h) * HD * HD;
        int sb = (isV ? 128 : 0) + h * HD;
        val = 0.0f;
        #pragma unroll
        for (int d = 0; d < HD; d++) {
            float a = (i < 64) ? Wk[i * KQV + sb + d] : bk[sb + d];
            val += a * Wr[d * HD + e];
        }
    }
    if (i < 64) (type ? Wfa : Wfp)[i * (type ? JA : JP) + j] = val;
    else        (type ? bfa : bfp)[j] = val;
}

// ---------------- input projection via MFMA bf16 (K=128), paper+author merged ----------------
__global__ __launch_bounds__(256) void gemm_in(
    const float* __restrict__ xp, const float* __restrict__ xa,
    const float* __restrict__ W_in, const float* __restrict__ b_in,
    float* __restrict__ hbuf)
{
    __shared__ unsigned short Xb[64][136];   // 272B rows (16B-aligned)
    __shared__ unsigned short Wt[64][136];   // Wt[col][k]
    int b = blockIdx.x, tid = threadIdx.x;
    int type = (b >= PT);
    int tile = type ? (b - PT) : b;
    int N = type ? NA : NP;
    const float* X = type ? xa : xp;
    const float* W = W_in + (size_t)type * IN_DIM * HID;
    const float* bias = b_in + type * HID;
    float* H = hbuf + (type ? (size_t)NP * HID : 0);
    int nb = tile * 64;

    {
        int row = tid >> 2, c0 = (tid & 3) * 32;
        int n = nb + row;
        if (n < N) {
            const float* xr = X + (size_t)n * IN_DIM + c0;
            #pragma unroll
            for (int i = 0; i < 32; i += 4) {
                float4 v = *(const float4*)(xr + i);
                *(ushort4*)&Xb[row][c0 + i] =
                    make_ushort4(f2bf(v.x), f2bf(v.y), f2bf(v.z), f2bf(v.w));
            }
        } else {
            #pragma unroll
            for (int i = 0; i < 32; i += 4)
                *(ushort4*)&Xb[row][c0 + i] = make_ushort4(0, 0, 0, 0);
        }
    }
    #pragma unroll
    for (int it = 0; it < 8; it++) {
        int idx = it * 256 + tid;            // 0..2047
        int k = idx & 127, c = (idx >> 7) * 4;
        float4 v = *(const float4*)(W + (size_t)k * HID + c);
        Wt[c + 0][k] = f2bf(v.x); Wt[c + 1][k] = f2bf(v.y);
        Wt[c + 2][k] = f2bf(v.z); Wt[c + 3][k] = f2bf(v.w);
    }
    __syncthreads();

    int w = tid >> 6, lane = tid & 63;
    int wr = (w >> 1) * 32, wc = (w & 1) * 32;
    int lrow = lane & 15, lgrp = lane >> 4;

    f32x4 acc00 = {0.f, 0.f, 0.f, 0.f};
    f32x4 acc01 = {0.f, 0.f, 0.f, 0.f};
    f32x4 acc10 = {0.f, 0.f, 0.f, 0.f};
    f32x4 acc11 = {0.f, 0.f, 0.f, 0.f};
    #pragma unroll
    for (int ks = 0; ks < 4; ks++) {
        int ko = ks * 32 + lgrp * 8;
        bf16x8 a0 = *(const bf16x8*)&Xb[wr + lrow][ko];
        bf16x8 a1 = *(const bf16x8*)&Xb[wr + 16 + lrow][ko];
        bf16x8 b0 = *(const bf16x8*)&Wt[wc + lrow][ko];
        bf16x8 b1 = *(const bf16x8*)&Wt[wc + 16 + lrow][ko];
        acc00 = __builtin_amdgcn_mfma_f32_16x16x32_bf16(a0, b0, acc00, 0, 0, 0);
        acc01 = __builtin_amdgcn_mfma_f32_16x16x32_bf16(a0, b1, acc01, 0, 0, 0);
        acc10 = __builtin_amdgcn_mfma_f32_16x16x32_bf16(a1, b0, acc10, 0, 0, 0);
        acc11 = __builtin_amdgcn_mfma_f32_16x16x32_bf16(a1, b1, acc11, 0, 0, 0);
    }

    float bias0 = bias[wc + lrow], bias1 = bias[wc + 16 + lrow];
    #pragma unroll
    for (int mi = 0; mi < 2; mi++) {
        const f32x4 accn0 = mi ? acc10 : acc00;
        const f32x4 accn1 = mi ? acc11 : acc01;
        int rbase = wr + mi * 16 + lgrp * 4;
        #pragma unroll
        for (int r = 0; r < 4; r++) {
            int n = nb + rbase + r;
            if (n >= N) continue;
            H[(size_t)n * HID + wc + lrow]      = accn0[r] + bias0;
            H[(size_t)n * HID + wc + 16 + lrow] = accn1[r] + bias1;
        }
    }
}

// ---------------- KQV GEMM via MFMA bf16: K+V merged per block ----------------
// Block kinds: paper Q | paper KV(et1) | paper KV(et2) | author Q | author KV.
// KV epilogue: shfl_xor(1) partner exchange packs attn pair-layout dwords =>
// coalesced 4B stores, no 2-byte RMW.
__global__ __launch_bounds__(256) void gemm_kqv(
    const float* __restrict__ hbuf,
    const float* __restrict__ Wfp, const float* __restrict__ bfp,
    const float* __restrict__ Wfa, const float* __restrict__ bfa,
    float* __restrict__ Q, unsigned* __restrict__ KVb)
{
    __shared__ unsigned short Xb[64][72];
    __shared__ unsigned short WtK[64][72];
    __shared__ unsigned short WtV[64][72];
    int b = blockIdx.x, tid = threadIdx.x;
    int type, tile, kind;
    if (b < PT)                { type = 0; kind = 0; tile = b; }
    else if (b < 2 * PT)       { type = 0; kind = 1; tile = b - PT; }
    else if (b < 3 * PT)       { type = 0; kind = 2; tile = b - 2 * PT; }
    else if (b < 3 * PT + AT)  { type = 1; kind = 0; tile = b - 3 * PT; }
    else                       { type = 1; kind = 1; tile = b - 3 * PT - AT; }
    int N = type ? NA : NP;
    const float* X = hbuf + (type ? (size_t)NP * HID : 0);
    const float* W = type ? Wfa : Wfp;
    const float* bias = type ? bfa : bfp;
    int ldw = type ? JA : JP;
    int nb = tile * 64;
    bool isQ = (kind == 0);
    int kcol = 0, vcol = 0, noff = 0;
    if (!isQ) {
        if (type == 0) {
            if (kind == 1) { kcol = 64;  vcol = 192; noff = NA; }
            else           { kcol = 128; vcol = 256; noff = NA + NP; }
        } else             { kcol = 64;  vcol = 128; noff = 0; }
    } else {
        noff = type ? NP : 0;
    }

    {
        int row = tid >> 2, c0 = (tid & 3) * 16;
        int n = nb + row;
        unsigned short tmp[16];
        if (n < N) {
            const float* xr = X + (size_t)n * HID + c0;
            #pragma unroll
            for (int i = 0; i < 16; i += 4) {
                float4 v = *(const float4*)(xr + i);
                tmp[i] = f2bf(v.x); tmp[i+1] = f2bf(v.y);
                tmp[i+2] = f2bf(v.z); tmp[i+3] = f2bf(v.w);
            }
        } else {
            #pragma unroll
            for (int i = 0; i < 16; i++) tmp[i] = 0;
        }
        #pragma unroll
        for (int i = 0; i < 16; i += 4)
            *(ushort4*)&Xb[row][c0 + i] = make_ushort4(tmp[i], tmp[i+1], tmp[i+2], tmp[i+3]);
    }
    #pragma unroll
    for (int it = 0; it < 4; it++) {
        int idx = it * 256 + tid;           // 0..1023
        int k = idx & 63, c = (idx >> 6) * 4;
        float4 v = *(const float4*)(W + (size_t)k * ldw + kcol + c);
        WtK[c + 0][k] = f2bf(v.x); WtK[c + 1][k] = f2bf(v.y);
        WtK[c + 2][k] = f2bf(v.z); WtK[c + 3][k] = f2bf(v.w);
    }
    if (!isQ) {
        #pragma unroll
        for (int it = 0; it < 4; it++) {
            int idx = it * 256 + tid;
            int k = idx & 63, c = (idx >> 6) * 4;
            float4 v = *(const float4*)(W + (size_t)k * ldw + vcol + c);
            WtV[c + 0][k] = f2bf(v.x); WtV[c + 1][k] = f2bf(v.y);
            WtV[c + 2][k] = f2bf(v.z); WtV[c + 3][k] = f2bf(v.w);
        }
    }
    __syncthreads();

    int w = tid >> 6, lane = tid & 63;
    int wr = (w >> 1) * 32, wc = (w & 1) * 32;
    int lrow = lane & 15, lgrp = lane >> 4;

    f32x4 k00 = {0.f,0.f,0.f,0.f}, k01 = {0.f,0.f,0.f,0.f};
    f32x4 k10 = {0.f,0.f,0.f,0.f}, k11 = {0.f,0.f,0.f,0.f};
    f32x4 v00 = {0.f,0.f,0.f,0.f}, v01 = {0.f,0.f,0.f,0.f};
    f32x4 v10 = {0.f,0.f,0.f,0.f}, v11 = {0.f,0.f,0.f,0.f};
    #pragma unroll
    for (int ks = 0; ks < 2; ks++) {
        int ko = ks * 32 + lgrp * 8;
        bf16x8 a0 = *(const bf16x8*)&Xb[wr + lrow][ko];
        bf16x8 a1 = *(const bf16x8*)&Xb[wr + 16 + lrow][ko];
        bf16x8 bk0 = *(const bf16x8*)&WtK[wc + lrow][ko];
        bf16x8 bk1 = *(const bf16x8*)&WtK[wc + 16 + lrow][ko];
        k00 = __builtin_amdgcn_mfma_f32_16x16x32_bf16(a0, bk0, k00, 0, 0, 0);
        k01 = __builtin_amdgcn_mfma_f32_16x16x32_bf16(a0, bk1, k01, 0, 0, 0);
        k10 = __builtin_amdgcn_mfma_f32_16x16x32_bf16(a1, bk0, k10, 0, 0, 0);
        k11 = __builtin_amdgcn_mfma_f32_16x16x32_bf16(a1, bk1, k11, 0, 0, 0);
        if (!isQ) {
            bf16x8 bv0 = *(const bf16x8*)&WtV[wc + lrow][ko];
            bf16x8 bv1 = *(const bf16x8*)&WtV[wc + 16 + lrow][ko];
            v00 = __builtin_amdgcn_mfma_f32_16x16x32_bf16(a0, bv0, v00, 0, 0, 0);
            v01 = __builtin_amdgcn_mfma_f32_16x16x32_bf16(a0, bv1, v01, 0, 0, 0);
            v10 = __builtin_amdgcn_mfma_f32_16x16x32_bf16(a1, bv0, v10, 0, 0, 0);
            v11 = __builtin_amdgcn_mfma_f32_16x16x32_bf16(a1, bv1, v11, 0, 0, 0);
        }
    }

    int c0 = wc + lrow, c1 = wc + 16 + lrow;
    if (isQ) {
        float bias0 = bias[c0], bias1 = bias[c1];
        #pragma unroll
        for (int mi = 0; mi < 2; mi++) {
            const f32x4 a0 = mi ? k10 : k00;
            const f32x4 a1 = mi ? k11 : k01;
            int rbase = wr + mi * 16 + lgrp * 4;
            #pragma unroll
            for (int r = 0; r < 4; r++) {
                int n = nb + rbase + r;
                if (n >= N) continue;
                Q[(size_t)(noff + n) * HID + c0] = a0[r] + bias0;
                Q[(size_t)(noff + n) * HID + c1] = a1[r] + bias1;
            }
        }
    } else {
        float bk0 = bias[kcol + c0], bk1 = bias[kcol + c1];
        float bv0 = bias[vcol + c0], bv1 = bias[vcol + c1];
        bool even = ((lrow & 1) == 0);
        #pragma unroll
        for (int mi = 0; mi < 2; mi++) {
            const f32x4 ak0 = mi ? k10 : k00;
            const f32x4 ak1 = mi ? k11 : k01;
            const f32x4 av0 = mi ? v10 : v00;
            const f32x4 av1 = mi ? v11 : v01;
            int rbase = wr + mi * 16 + lgrp * 4;
            #pragma unroll
            for (int r = 0; r < 4; r++) {
                int n = nb + rbase + r;
                unsigned* dst = KVb + (((size_t)(noff + n)) << 6);
                unsigned own0 = (unsigned)f2h(ak0[r] + bk0) | ((unsigned)f2h(av0[r] + bv0) << 16);
                unsigned oth0 = __shfl_xor(own0, 1, 64);
                unsigned own1 = (unsigned)f2h(ak1[r] + bk1) | ((unsigned)f2h(av1[r] + bv1) << 16);
                unsigned oth1 = __shfl_xor(own1, 1, 64);
                if (n < N) {
                    unsigned w0 = even ? ((own0 & 0xffffu) | (oth0 << 16))
                                       : ((oth0 >> 16) | (own0 & 0xffff0000u));
                    unsigned w1 = even ? ((own1 & 0xffffu) | (oth1 << 16))
                                       : ((oth1 >> 16) | (own1 & 0xffff0000u));
                    dst[c0] = w0;
                    dst[c1] = w1;
                }
            }
        }
    }
}

// ---------------- fused attention: no-max softmax, 4 edges/iter, bf16 output ----------------
__global__ __launch_bounds__(256) void attn_kernel(
    const float* __restrict__ Q, const unsigned* __restrict__ KVb,
    const float* __restrict__ p_rel, const int* __restrict__ row_ptr,
    const int* __restrict__ edge_src, unsigned short* __restrict__ ABf)
{
    int wid = threadIdx.x >> 6, lane = threadIdx.x & 63;
    int n = blockIdx.x * 4 + wid;
    if (n >= NTOT) return;
    int half = lane >> 5;
    int p = lane & 31;           // pair index: dims 2p, 2p+1
    int h = p >> 3;              // head
    float2 qp = *(const float2*)(Q + (size_t)n * HID + 2 * p);
    h16x2 qh; qh[0] = (_Float16)qp.x; qh[1] = (_Float16)qp.y;
    const float INV_LN2 = 1.4426950408889634f;
    float pr0 = p_rel[h] * 0.25f * INV_LN2;
    float pr1 = p_rel[4 + h] * 0.25f * INV_LN2;
    float pr2 = p_rel[8 + h] * 0.25f * INV_LN2;
    int beg = row_ptr[n], end = row_ptr[n + 1];
    float s = 0.0f, acc0 = 0.f, acc1 = 0.f;
    for (int e = beg; e < end; e += 4) {
        int e0 = e + half;           // edges e, e+1
        int e1 = e + 2 + half;       // edges e+2, e+3
        bool v0 = (e0 < end), v1 = (e1 < end);
        int s0 = v0 ? edge_src[e0] : 0;
        int s1 = v1 ? edge_src[e1] : 0;
        uint2 kv0 = *(const uint2*)(KVb + (((size_t)s0) << 6) + 2 * p);
        uint2 kv1 = *(const uint2*)(KVb + (((size_t)s1) << 6) + 2 * p);
        float d0, d1;
#if __has_builtin(__builtin_amdgcn_fdot2)
        {
            union { unsigned u; h16x2 v; } ck;
            ck.u = kv0.x; d0 = __builtin_amdgcn_fdot2(qh, ck.v, 0.0f, false);
            ck.u = kv1.x; d1 = __builtin_amdgcn_fdot2(qh, ck.v, 0.0f, false);
        }
#else
        {
            union { unsigned u; _Float16 f[2]; } ck;
            ck.u = kv0.x; d0 = qp.x * (float)ck.f[0] + qp.y * (float)ck.f[1];
            ck.u = kv1.x; d1 = qp.x * (float)ck.f[0] + qp.y * (float)ck.f[1];
        }
#endif
        d0 += __shfl_xor(d0, 1, 64);  d1 += __shfl_xor(d1, 1, 64);
        d0 += __shfl_xor(d0, 2, 64);  d1 += __shfl_xor(d1, 2, 64);
        d0 += __shfl_xor(d0, 4, 64);  d1 += __shfl_xor(d1, 4, 64);
        float pa = (s0 < NA) ? pr0 : ((s0 < NA + NP) ? pr1 : pr2);
        float pb = (s1 < NA) ? pr0 : ((s1 < NA + NP) ? pr1 : pr2);
        float a0 = v0 ? fminf(d0 * pa, 80.0f) : -INFINITY;
        float a1 = v1 ? fminf(d1 * pb, 80.0f) : -INFINITY;
        float p0 = exp2f(a0);
        float p1 = exp2f(a1);
        s += p0 + p1;
        union { unsigned u; _Float16 f[2]; } cv0, cv1;
        cv0.u = kv0.y; cv1.u = kv1.y;
        acc0 += p0 * (float)cv0.f[0] + p1 * (float)cv1.f[0];
        acc1 += p0 * (float)cv0.f[1] + p1 * (float)cv1.f[1];
    }
    s    += __shfl_xor(s, 32, 64);
    acc0 += __shfl_xor(acc0, 32, 64);
    acc1 += __shfl_xor(acc1, 32, 64);
    if (half == 0) {
        float inv = 1.0f / (s + 1e-16f);
        unsigned pack = (unsigned)f2bf(acc0 * inv) | ((unsigned)f2bf(acc1 * inv) << 16);
        *(unsigned*)(ABf + (((size_t)n) << 6) + 2 * p) = pack;
    }
}

// ---------------- hout via MFMA bf16 + skip + LN + gelu (+ optional fused W_out GEMM) ----------------
// Reads attn output as bf16 (ABf). When Wout != nullptr (last layer) the final
// LN+gelu tile in hs[] feeds a second MFMA against W_out and stores directly to
// outp, eliminating the separate gemm_out pass and layer-2's hbuf write.
__global__ __launch_bounds__(256) void gemm_hout(
    const unsigned short* __restrict__ ABf, const float* __restrict__ Whout,
    const float* __restrict__ bhout, const float* __restrict__ skip_p,
    const float* __restrict__ lng, const float* __restrict__ lnb,
    float* __restrict__ hbuf,
    const float* __restrict__ Wout, const float* __restrict__ bout,
    float* __restrict__ outp)
{
    __shared__ unsigned short Xb[64][72];
    __shared__ unsigned short Wt[64][72];
    __shared__ float hs[64][68];
    int b = blockIdx.x, tid = threadIdx.x;
    int type = (b >= PT);
    int tile = type ? (b - PT) : b;
    int N = type ? NA : NP;
    size_t base_off = type ? (size_t)NP * HID : 0;
    const unsigned short* X = ABf + base_off;
    const float* W = Whout + (size_t)type * HID * HID;
    const float* bias = bhout + type * HID;
    float* H = hbuf + base_off;
    int nb = tile * 64;
    bool fuse_out = (Wout != nullptr);

    {
        int row = tid >> 2, c0 = (tid & 3) * 16;
        int n = nb + row;
        unsigned short tmp[16];
        if (n < N) {
            const unsigned short* xr = X + (((size_t)n) << 6) + c0;
            #pragma unroll
            for (int i = 0; i < 16; i += 4) {
                ushort4 v = *(const ushort4*)(xr + i);
                tmp[i]   = f2bf(gelu_exact(bf2f(v.x)));
                tmp[i+1] = f2bf(gelu_exact(bf2f(v.y)));
                tmp[i+2] = f2bf(gelu_exact(bf2f(v.z)));
                tmp[i+3] = f2bf(gelu_exact(bf2f(v.w)));
            }
        } else {
            #pragma unroll
            for (int i = 0; i < 16; i++) tmp[i] = 0;
        }
        #pragma unroll
        for (int i = 0; i < 16; i += 4)
            *(ushort4*)&Xb[row][c0 + i] = make_ushort4(tmp[i], tmp[i+1], tmp[i+2], tmp[i+3]);
    }
    #pragma unroll
    for (int it = 0; it < 4; it++) {
        int idx = it * 256 + tid;
        int k = idx & 63, c = (idx >> 6) * 4;
        float4 v = *(const float4*)(W + (size_t)k * HID + c);
        Wt[c + 0][k] = f2bf(v.x); Wt[c + 1][k] = f2bf(v.y);
        Wt[c + 2][k] = f2bf(v.z); Wt[c + 3][k] = f2bf(v.w);
    }
    __syncthreads();

    int w = tid >> 6, lane = tid & 63;
    int wr = (w >> 1) * 32, wc = (w & 1) * 32;
    int lrow = lane & 15, lgrp = lane >> 4;

    f32x4 acc00 = {0.f, 0.f, 0.f, 0.f};
    f32x4 acc01 = {0.f, 0.f, 0.f, 0.f};
    f32x4 acc10 = {0.f, 0.f, 0.f, 0.f};
    f32x4 acc11 = {0.f, 0.f, 0.f, 0.f};
    #pragma unroll
    for (int ks = 0; ks < 2; ks++) {
        int ko = ks * 32 + lgrp * 8;
        bf16x8 a0 = *(const bf16x8*)&Xb[wr + lrow][ko];
        bf16x8 a1 = *(const bf16x8*)&Xb[wr + 16 + lrow][ko];
        bf16x8 b0 = *(const bf16x8*)&Wt[wc + lrow][ko];
        bf16x8 b1 = *(const bf16x8*)&Wt[wc + 16 + lrow][ko];
        acc00 = __builtin_amdgcn_mfma_f32_16x16x32_bf16(a0, b0, acc00, 0, 0, 0);
        acc01 = __builtin_amdgcn_mfma_f32_16x16x32_bf16(a0, b1, acc01, 0, 0, 0);
        acc10 = __builtin_amdgcn_mfma_f32_16x16x32_bf16(a1, b0, acc10, 0, 0, 0);
        acc11 = __builtin_amdgcn_mfma_f32_16x16x32_bf16(a1, b1, acc11, 0, 0, 0);
    }

    float a = 1.0f / (1.0f + __expf(-skip_p[type]));
    float oma = 1.0f - a;
    float bias0 = bias[wc + lrow], bias1 = bias[wc + 16 + lrow];
    #pragma unroll
    for (int mi = 0; mi < 2; mi++) {
        const f32x4 accn0 = mi ? acc10 : acc00;
        const f32x4 accn1 = mi ? acc11 : acc01;
        int rbase = wr + mi * 16 + lgrp * 4;
        #pragma unroll
        for (int r = 0; r < 4; r++) {
            int row = rbase + r;
            int n = nb + row;
            if (n < N) {
                const float* hp = H + (size_t)n * HID;
                hs[row][wc + lrow]      = a * (accn0[r] + bias0) + oma * hp[wc + lrow];
                hs[row][wc + 16 + lrow] = a * (accn1[r] + bias1) + oma * hp[wc + 16 + lrow];
            } else {
                hs[row][wc + lrow] = 0.f;
                hs[row][wc + 16 + lrow] = 0.f;
            }
        }
    }
    __syncthreads();

    const int tr = tid >> 4, tc = tid & 15;
    const int tcj = tc * 4;
    float g0 = lng[type*HID+tcj], g1 = lng[type*HID+tcj+1],
          g2 = lng[type*HID+tcj+2], g3 = lng[type*HID+tcj+3];
    float l0 = lnb[type*HID+tcj], l1 = lnb[type*HID+tcj+1],
          l2 = lnb[type*HID+tcj+2], l3 = lnb[type*HID+tcj+3];
    #pragma unroll 1
    for (int m = 0; m < 4; m++) {
        int row = tr * 4 + m;
        int n = nb + row;
        float v0 = hs[row][tcj], v1 = hs[row][tcj+1], v2 = hs[row][tcj+2], v3 = hs[row][tcj+3];
        float sum = v0 + v1 + v2 + v3;
        sum += __shfl_xor(sum, 1, 64); sum += __shfl_xor(sum, 2, 64);
        sum += __shfl_xor(sum, 4, 64); sum += __shfl_xor(sum, 8, 64);
        float mean = sum * (1.0f / 64.0f);
        float d0 = v0 - mean, d1 = v1 - mean, d2 = v2 - mean, d3 = v3 - mean;
        float sq = d0*d0 + d1*d1 + d2*d2 + d3*d3;
        sq += __shfl_xor(sq, 1, 64); sq += __shfl_xor(sq, 2, 64);
        sq += __shfl_xor(sq, 4, 64); sq += __shfl_xor(sq, 8, 64);
        float rstd = rsqrtf(sq * (1.0f / 64.0f) + 1e-5f);
        float r0 = gelu_exact(d0 * rstd * g0 + l0);
        float r1 = gelu_exact(d1 * rstd * g1 + l1);
        float r2 = gelu_exact(d2 * rstd * g2 + l2);
        float r3 = gelu_exact(d3 * rstd * g3 + l3);
        hs[row][tcj] = r0; hs[row][tcj+1] = r1;
        hs[row][tcj+2] = r2; hs[row][tcj+3] = r3;
        if (!fuse_out && n < N) {
            float* hp = H + (size_t)n * HID + tcj;
            hp[0] = r0; hp[1] = r1; hp[2] = r2; hp[3] = r3;
        }
    }

    if (fuse_out) {
        __syncthreads();
        // restage: Xb <- bf16(hs), Wt <- W_out^T
        {
            int row = tid >> 2, c0 = (tid & 3) * 16;
            #pragma unroll
            for (int i = 0; i < 16; i += 4) {
                *(ushort4*)&Xb[row][c0 + i] = make_ushort4(
                    f2bf(hs[row][c0 + i]),     f2bf(hs[row][c0 + i + 1]),
                    f2bf(hs[row][c0 + i + 2]), f2bf(hs[row][c0 + i + 3]));
            }
        }
        const float* W2 = Wout + (size_t)type * HID * HID;
        #pragma unroll
        for (int it = 0; it < 4; it++) {
            int idx = it * 256 + tid;
            int k = idx & 63, c = (idx >> 6) * 4;
            float4 v = *(const float4*)(W2 + (size_t)k * HID + c);
            Wt[c + 0][k] = f2bf(v.x); Wt[c + 1][k] = f2bf(v.y);
            Wt[c + 2][k] = f2bf(v.z); Wt[c + 3][k] = f2bf(v.w);
        }
        __syncthreads();

        f32x4 o00 = {0.f,0.f,0.f,0.f}, o01 = {0.f,0.f,0.f,0.f};
        f32x4 o10 = {0.f,0.f,0.f,0.f}, o11 = {0.f,0.f,0.f,0.f};
        #pragma unroll
        for (int ks = 0; ks < 2; ks++) {
            int ko = ks * 32 + lgrp * 8;
            bf16x8 a0 = *(const bf16x8*)&Xb[wr + lrow][ko];
            bf16x8 a1 = *(const bf16x8*)&Xb[wr + 16 + lrow][ko];
            bf16x8 b0 = *(const bf16x8*)&Wt[wc + lrow][ko];
            bf16x8 b1 = *(const bf16x8*)&Wt[wc + 16 + lrow][ko];
            o00 = __builtin_amdgcn_mfma_f32_16x16x32_bf16(a0, b0, o00, 0, 0, 0);
            o01 = __builtin_amdgcn_mfma_f32_16x16x32_bf16(a0, b1, o01, 0, 0, 0);
            o10 = __builtin_amdgcn_mfma_f32_16x16x32_bf16(a1, b0, o10, 0, 0, 0);
            o11 = __builtin_amdgcn_mfma_f32_16x16x32_bf16(a1, b1, o11, 0, 0, 0);
        }
        const float* b2 = bout + type * HID;
        float b20 = b2[wc + lrow], b21 = b2[wc + 16 + lrow];
        float* O = outp + base_off;
        #pragma unroll
        for (int mi = 0; mi < 2; mi++) {
            const f32x4 on0 = mi ? o10 : o00;
            const f32x4 on1 = mi ? o11 : o01;
            int rbase = wr + mi * 16 + lgrp * 4;
            #pragma unroll
            for (int r = 0; r < 4; r++) {
                int n = nb + rbase + r;
                if (n >= N) continue;
                O[(size_t)n * HID + wc + lrow]      = on0[r] + b20;
                O[(size_t)n * HID + wc + 16 + lrow] = on1[r] + b21;
            }
        }
    }
}

extern "C" void kernel_launch(void* const* d_in, const int* in_sizes, int n_in,
                              void* d_out, int out_size, void* d_ws, size_t ws_size,
                              hipStream_t stream) {
    const float* x_paper  = (const float*)d_in[0];
    const float* x_author = (const float*)d_in[1];
    const int*   ei_ap    = (const int*)d_in[2];
    const int*   ei_pa    = (const int*)d_in[3];
    const int*   ei_pp    = (const int*)d_in[4];
    const float* W_in     = (const float*)d_in[5];
    const float* b_in     = (const float*)d_in[6];
    const float* W_kqv    = (const float*)d_in[7];
    const float* b_kqv    = (const float*)d_in[8];
    const float* W_krel   = (const float*)d_in[9];
    const float* W_vrel   = (const float*)d_in[10];
    const float* p_rel    = (const float*)d_in[11];
    const float* W_hout   = (const float*)d_in[12];
    const float* b_hout   = (const float*)d_in[13];
    const float* skip     = (const float*)d_in[14];
    const float* ln_g     = (const float*)d_in[15];
    const float* ln_b     = (const float*)d_in[16];
    const float* W_out    = (const float*)d_in[17];
    const float* b_out    = (const float*)d_in[18];
    float* out            = (float*)d_out;

    // ---- workspace layout (~166 MB) ----
    float* ws   = (float*)d_ws;
    float* hbuf = ws;                                   // NTOT*64 f32
    float* Q    = hbuf + (size_t)NTOT * HID;            // NTOT*64 f32
    unsigned* KVb = (unsigned*)(Q + (size_t)NTOT * HID); // NSRC*64 dwords (f16 k/v pairs)
    unsigned short* ABf = (unsigned short*)(KVb + (size_t)NSRC * HID); // NTOT*64 bf16
    float* Wfp  = (float*)(ABf + (size_t)NTOT * HID);   // 64*320
    float* bfp  = Wfp  + 64 * JP;                       // 320
    float* Wfa  = bfp  + JP;                            // 64*192
    float* bfa  = Wfa  + 64 * JA;                       // 192
    int* cnt      = (int*)(bfa + JA);                   // NTOT
    int* row_ptr  = cnt + NTOT;                         // NTOT+1 (pad 16)
    int* cursor   = row_ptr + NTOT + 16;                // NTOT
    int* edge_src = cursor + NTOT;                      // ETOT
    int* csum     = edge_src + ETOT;                    // 1024
    int* coff     = csum + 1024;                        // 1024

    dim3 blk(256);
    const int EB = (ETOT + 255) / 256;

    // ---- CSR build (edges are layer-invariant) ----
    zero_int_kernel<<<256, blk, 0, stream>>>(cnt, NTOT);
    csr_count_kernel<<<EB, blk, 0, stream>>>(ei_ap, ei_pa, ei_pp, cnt);
    scan_chunk_sums<<<NCH, blk, 0, stream>>>(cnt, csum);
    scan_offsets<<<1, 1024, 0, stream>>>(csum, coff, NCH);
    scan_final<<<NCH, blk, 0, stream>>>(cnt, coff, row_ptr, cursor);
    csr_fill_kernel<<<EB, blk, 0, stream>>>(ei_ap, ei_pa, ei_pp, cursor, edge_src);

    // ---- input projection ----
    gemm_in<<<PT + AT, blk, 0, stream>>>(x_paper, x_author, W_in, b_in, hbuf);

    for (int l = 0; l < LAYERS; l++) {
        fuse_weights_kernel<<<(65 * JP + 65 * JA + 255) / 256, blk, 0, stream>>>(
            W_kqv + (size_t)l * 2 * HID * KQV, b_kqv + (size_t)l * 2 * KQV,
            W_krel + (size_t)l * 3 * NH * HD * HD, W_vrel + (size_t)l * 3 * NH * HD * HD,
            Wfp, bfp, Wfa, bfa);
        gemm_kqv<<<3 * PT + 2 * AT, blk, 0, stream>>>(
            hbuf, Wfp, bfp, Wfa, bfa, Q, KVb);
        attn_kernel<<<(NTOT + 3) / 4, blk, 0, stream>>>(
            Q, KVb, p_rel + l * 3 * NH, row_ptr, edge_src, ABf);
        bool last = (l == LAYERS - 1);
        gemm_hout<<<PT + AT, blk, 0, stream>>>(
            ABf, W_hout + (size_t)l * 2 * HID * HID, b_hout + l * 2 * HID,
            skip + l * 2, ln_g + l * 2 * HID, ln_b + l * 2 * HID, hbuf,
            last ? W_out : nullptr, last ? b_out : nullptr, last ? out : nullptr);
    }
}

// Round 15
// 390.251 us; speedup vs baseline: 4.8011x; 1.0872x over previous
//
#include <hip/hip_runtime.h>
#include <hip/hip_bf16.h>

// ---- problem constants (match reference) ----
#define NP 100000
#define NA 50000
#define NTOT 150000          // NP+NA
#define E0 300000
#define E1 300000
#define E2 200000
#define ETOT 800000
#define NH 4
#define HD 16
#define HID 64
#define IN_DIM 128
#define KQV 192
#define LAYERS 2
#define NSRC 250000          // NA + 2*NP
#define JP 320               // fused paper cols: q | k_et1 | k_et2 | v_et1 | v_et2
#define JA 192               // fused author cols: q | k_et0 | v_et0
#define NCH 586              // ceil(NTOT/256)
#define PT 1563              // ceil(NP/64)
#define AT 782               // ceil(NA/64)

typedef __attribute__((ext_vector_type(8))) short bf16x8;   // 8 bf16 (4 VGPRs)
typedef __attribute__((ext_vector_type(4))) float f32x4;    // MFMA C/D
typedef _Float16 h16x2 __attribute__((ext_vector_type(2)));

__device__ __forceinline__ float gelu_exact(float x) {
    return 0.5f * x * (1.0f + erff(x * 0.7071067811865475f));
}
// f32 -> bf16 bits, round-to-nearest-even (finite values)
__device__ __forceinline__ unsigned short f2bf(float f) {
    unsigned u = __float_as_uint(f);
    return (unsigned short)((u + 0x7fffu + ((u >> 16) & 1u)) >> 16);
}
__device__ __forceinline__ float bf2f(unsigned short b) {
    return __uint_as_float((unsigned)b << 16);
}
// f32 -> f16 bits (RNE via hardware cvt)
__device__ __forceinline__ unsigned short f2h(float f) {
    union { _Float16 h; unsigned short u; } c;
    c.h = (_Float16)f;
    return c.u;
}

// decode global edge id -> (src in KV space, dst in node space)
__device__ __forceinline__ void edge_decode(int e, const int* __restrict__ ei_ap,
                                            const int* __restrict__ ei_pa,
                                            const int* __restrict__ ei_pp,
                                            int& src, int& dst) {
    if (e < E0)            { src = ei_ap[e];                 dst = ei_ap[E0 + e]; }
    else if (e < E0 + E1)  { int le = e - E0;
                             src = NA + ei_pa[le];           dst = NP + ei_pa[E1 + le]; }
    else                   { int le = e - E0 - E1;
                             src = NA + NP + ei_pp[le];      dst = ei_pp[E2 + le]; }
}

// ---------------- CSR build ----------------
__global__ void zero_int_kernel(int* __restrict__ p, int n) {
    int i = blockIdx.x * blockDim.x + threadIdx.x;
    int st = gridDim.x * blockDim.x;
    for (int j = i; j < n; j += st) p[j] = 0;
}

__global__ void csr_count_kernel(const int* __restrict__ ei_ap, const int* __restrict__ ei_pa,
                                 const int* __restrict__ ei_pp, int* __restrict__ cnt) {
    int e = blockIdx.x * 256 + threadIdx.x;
    if (e >= ETOT) return;
    int src, dst; edge_decode(e, ei_ap, ei_pa, ei_pp, src, dst);
    atomicAdd(&cnt[dst], 1);
}

__global__ void scan_chunk_sums(const int* __restrict__ cnt, int* __restrict__ csum) {
    __shared__ int sd[256];
    int c = blockIdx.x, t = threadIdx.x;
    int i = c * 256 + t;
    sd[t] = (i < NTOT) ? cnt[i] : 0;
    __syncthreads();
    for (int o = 128; o > 0; o >>= 1) { if (t < o) sd[t] += sd[t + o]; __syncthreads(); }
    if (t == 0) csum[c] = sd[0];
}

__global__ void scan_offsets(const int* __restrict__ csum, int* __restrict__ coff, int nch) {
    __shared__ int sd[1024];
    int t = threadIdx.x;
    int v = (t < nch) ? csum[t] : 0;
    sd[t] = v;
    __syncthreads();
    for (int o = 1; o < 1024; o <<= 1) {
        int x = (t >= o) ? sd[t - o] : 0;
        __syncthreads();
        sd[t] += x;
        __syncthreads();
    }
    if (t < nch) coff[t] = sd[t] - v;   // exclusive
}

__global__ void scan_final(const int* __restrict__ cnt, const int* __restrict__ coff,
                           int* __restrict__ row_ptr, int* __restrict__ cursor) {
    __shared__ int sd[256];
    int c = blockIdx.x, t = threadIdx.x, i = c * 256 + t;
    int v = (i < NTOT) ? cnt[i] : 0;
    sd[t] = v;
    __syncthreads();
    for (int o = 1; o < 256; o <<= 1) {
        int x = (t >= o) ? sd[t - o] : 0;
        __syncthreads();
        sd[t] += x;
        __syncthreads();
    }
    if (i < NTOT) { int ex = coff[c] + sd[t] - v; row_ptr[i] = ex; cursor[i] = ex; }
    if (i == 0) row_ptr[NTOT] = ETOT;
}

__global__ void csr_fill_kernel(const int* __restrict__ ei_ap, const int* __restrict__ ei_pa,
                                const int* __restrict__ ei_pp, int* __restrict__ cursor,
                                int* __restrict__ edge_src) {
    int e = blockIdx.x * 256 + threadIdx.x;
    if (e >= ETOT) return;
    int src, dst; edge_decode(e, ei_ap, ei_pa, ei_pp, src, dst);
    int pos = atomicAdd(&cursor[dst], 1);
    edge_src[pos] = src;
}

// ---------------- fused-weight build (per layer) ----------------
__global__ void fuse_weights_kernel(const float* __restrict__ Wkqv, const float* __restrict__ bkqv,
                                    const float* __restrict__ Wkrel, const float* __restrict__ Wvrel,
                                    float* __restrict__ Wfp, float* __restrict__ bfp,
                                    float* __restrict__ Wfa, float* __restrict__ bfa) {
    int idx = blockIdx.x * 256 + threadIdx.x;
    int type, i, j;
    if (idx < 65 * JP) { type = 0; i = idx / JP; j = idx % JP; }
    else {
        int r = idx - 65 * JP;
        if (r >= 65 * JA) return;
        type = 1; i = r / JA; j = r % JA;
    }
    int c = j >> 6, jj = j & 63, h = jj >> 4, e = jj & 15;
    const float* Wk = Wkqv + (size_t)type * HID * KQV;
    const float* bk = bkqv + type * KQV;
    float val;
    if (c == 0) {
        val = (i < 64) ? Wk[i * KQV + 64 + jj] : bk[64 + jj];
    } else {
        int et, isV;
        if (type == 0) { et = (c == 1 || c == 3) ? 1 : 2; isV = (c >= 3); }
        else           { et = 0; isV = (c == 2); }
        const float* Wr = (isV ? Wvrel : Wkrel) + (size_t)(et * NH + h) * HD * HD;
        int sb = (isV ? 128 : 0) + h * HD;
        val = 0.0f;
        #pragma unroll
        for (int d = 0; d < HD; d++) {
            float a = (i < 64) ? Wk[i * KQV + sb + d] : bk[sb + d];
            val += a * Wr[d * HD + e];
        }
    }
    if (i < 64) (type ? Wfa : Wfp)[i * (type ? JA : JP) + j] = val;
    else        (type ? bfa : bfp)[j] = val;
}

// ---------------- input projection via MFMA bf16 (K=128) -> bf16 h ----------------
__global__ __launch_bounds__(256) void gemm_in(
    const float* __restrict__ xp, const float* __restrict__ xa,
    const float* __restrict__ W_in, const float* __restrict__ b_in,
    unsigned short* __restrict__ Hb)
{
    __shared__ unsigned short Xb[64][136];   // 272B rows (16B-aligned)
    __shared__ unsigned short Wt[64][136];   // Wt[col][k]
    int b = blockIdx.x, tid = threadIdx.x;
    int type = (b >= PT);
    int tile = type ? (b - PT) : b;
    int N = type ? NA : NP;
    const float* X = type ? xa : xp;
    const float* W = W_in + (size_t)type * IN_DIM * HID;
    const float* bias = b_in + type * HID;
    unsigned short* H = Hb + (type ? (size_t)NP * HID : 0);
    int nb = tile * 64;

    {
        int row = tid >> 2, c0 = (tid & 3) * 32;
        int n = nb + row;
        if (n < N) {
            const float* xr = X + (size_t)n * IN_DIM + c0;
            #pragma unroll
            for (int i = 0; i < 32; i += 4) {
                float4 v = *(const float4*)(xr + i);
                *(ushort4*)&Xb[row][c0 + i] =
                    make_ushort4(f2bf(v.x), f2bf(v.y), f2bf(v.z), f2bf(v.w));
            }
        } else {
            #pragma unroll
            for (int i = 0; i < 32; i += 4)
                *(ushort4*)&Xb[row][c0 + i] = make_ushort4(0, 0, 0, 0);
        }
    }
    #pragma unroll
    for (int it = 0; it < 8; it++) {
        int idx = it * 256 + tid;            // 0..2047
        int k = idx & 127, c = (idx >> 7) * 4;
        float4 v = *(const float4*)(W + (size_t)k * HID + c);
        Wt[c + 0][k] = f2bf(v.x); Wt[c + 1][k] = f2bf(v.y);
        Wt[c + 2][k] = f2bf(v.z); Wt[c + 3][k] = f2bf(v.w);
    }
    __syncthreads();

    int w = tid >> 6, lane = tid & 63;
    int wr = (w >> 1) * 32, wc = (w & 1) * 32;
    int lrow = lane & 15, lgrp = lane >> 4;

    f32x4 acc00 = {0.f, 0.f, 0.f, 0.f};
    f32x4 acc01 = {0.f, 0.f, 0.f, 0.f};
    f32x4 acc10 = {0.f, 0.f, 0.f, 0.f};
    f32x4 acc11 = {0.f, 0.f, 0.f, 0.f};
    #pragma unroll
    for (int ks = 0; ks < 4; ks++) {
        int ko = ks * 32 + lgrp * 8;
        bf16x8 a0 = *(const bf16x8*)&Xb[wr + lrow][ko];
        bf16x8 a1 = *(const bf16x8*)&Xb[wr + 16 + lrow][ko];
        bf16x8 b0 = *(const bf16x8*)&Wt[wc + lrow][ko];
        bf16x8 b1 = *(const bf16x8*)&Wt[wc + 16 + lrow][ko];
        acc00 = __builtin_amdgcn_mfma_f32_16x16x32_bf16(a0, b0, acc00, 0, 0, 0);
        acc01 = __builtin_amdgcn_mfma_f32_16x16x32_bf16(a0, b1, acc01, 0, 0, 0);
        acc10 = __builtin_amdgcn_mfma_f32_16x16x32_bf16(a1, b0, acc10, 0, 0, 0);
        acc11 = __builtin_amdgcn_mfma_f32_16x16x32_bf16(a1, b1, acc11, 0, 0, 0);
    }

    float bias0 = bias[wc + lrow], bias1 = bias[wc + 16 + lrow];
    int c0 = wc + lrow, c1 = wc + 16 + lrow;
    bool even = ((lrow & 1) == 0);
    #pragma unroll
    for (int mi = 0; mi < 2; mi++) {
        const f32x4 accn0 = mi ? acc10 : acc00;
        const f32x4 accn1 = mi ? acc11 : acc01;
        int rbase = wr + mi * 16 + lgrp * 4;
        #pragma unroll
        for (int r = 0; r < 4; r++) {
            int n = nb + rbase + r;
            unsigned own = (unsigned)f2bf(accn0[r] + bias0)
                         | ((unsigned)f2bf(accn1[r] + bias1) << 16);
            unsigned oth = __shfl_xor(own, 1, 64);
            if (even && n < N) {
                unsigned* hp = (unsigned*)(H + (size_t)n * HID);
                hp[c0 >> 1] = (own & 0xffffu) | (oth << 16);
                hp[c1 >> 1] = (own >> 16) | (oth & 0xffff0000u);
            }
        }
    }
}

// ---------------- KQV GEMM via MFMA bf16: K+V merged per block ----------------
// Reads bf16 h directly; Q written as f16 pair dwords; KV pair-packed dwords.
__global__ __launch_bounds__(256) void gemm_kqv(
    const unsigned short* __restrict__ Hb,
    const float* __restrict__ Wfp, const float* __restrict__ bfp,
    const float* __restrict__ Wfa, const float* __restrict__ bfa,
    unsigned short* __restrict__ Qh, unsigned* __restrict__ KVb)
{
    __shared__ unsigned short Xb[64][72];
    __shared__ unsigned short WtK[64][72];
    __shared__ unsigned short WtV[64][72];
    int b = blockIdx.x, tid = threadIdx.x;
    int type, tile, kind;
    if (b < PT)                { type = 0; kind = 0; tile = b; }
    else if (b < 2 * PT)       { type = 0; kind = 1; tile = b - PT; }
    else if (b < 3 * PT)       { type = 0; kind = 2; tile = b - 2 * PT; }
    else if (b < 3 * PT + AT)  { type = 1; kind = 0; tile = b - 3 * PT; }
    else                       { type = 1; kind = 1; tile = b - 3 * PT - AT; }
    int N = type ? NA : NP;
    const unsigned short* X = Hb + (type ? (size_t)NP * HID : 0);
    const float* W = type ? Wfa : Wfp;
    const float* bias = type ? bfa : bfp;
    int ldw = type ? JA : JP;
    int nb = tile * 64;
    bool isQ = (kind == 0);
    int kcol = 0, vcol = 0, noff = 0;
    if (!isQ) {
        if (type == 0) {
            if (kind == 1) { kcol = 64;  vcol = 192; noff = NA; }
            else           { kcol = 128; vcol = 256; noff = NA + NP; }
        } else             { kcol = 64;  vcol = 128; noff = 0; }
    } else {
        noff = type ? NP : 0;
    }

    // stage X tile (already bf16 — straight copy)
    {
        int row = tid >> 2, c0 = (tid & 3) * 16;
        int n = nb + row;
        if (n < N) {
            const unsigned short* xr = X + (size_t)n * HID + c0;
            *(ushort4*)&Xb[row][c0]      = *(const ushort4*)(xr);
            *(ushort4*)&Xb[row][c0 + 4]  = *(const ushort4*)(xr + 4);
            *(ushort4*)&Xb[row][c0 + 8]  = *(const ushort4*)(xr + 8);
            *(ushort4*)&Xb[row][c0 + 12] = *(const ushort4*)(xr + 12);
        } else {
            #pragma unroll
            for (int i = 0; i < 16; i += 4)
                *(ushort4*)&Xb[row][c0 + i] = make_ushort4(0, 0, 0, 0);
        }
    }
    #pragma unroll
    for (int it = 0; it < 4; it++) {
        int idx = it * 256 + tid;           // 0..1023
        int k = idx & 63, c = (idx >> 6) * 4;
        float4 v = *(const float4*)(W + (size_t)k * ldw + kcol + c);
        WtK[c + 0][k] = f2bf(v.x); WtK[c + 1][k] = f2bf(v.y);
        WtK[c + 2][k] = f2bf(v.z); WtK[c + 3][k] = f2bf(v.w);
    }
    if (!isQ) {
        #pragma unroll
        for (int it = 0; it < 4; it++) {
            int idx = it * 256 + tid;
            int k = idx & 63, c = (idx >> 6) * 4;
            float4 v = *(const float4*)(W + (size_t)k * ldw + vcol + c);
            WtV[c + 0][k] = f2bf(v.x); WtV[c + 1][k] = f2bf(v.y);
            WtV[c + 2][k] = f2bf(v.z); WtV[c + 3][k] = f2bf(v.w);
        }
    }
    __syncthreads();

    int w = tid >> 6, lane = tid & 63;
    int wr = (w >> 1) * 32, wc = (w & 1) * 32;
    int lrow = lane & 15, lgrp = lane >> 4;

    f32x4 k00 = {0.f,0.f,0.f,0.f}, k01 = {0.f,0.f,0.f,0.f};
    f32x4 k10 = {0.f,0.f,0.f,0.f}, k11 = {0.f,0.f,0.f,0.f};
    f32x4 v00 = {0.f,0.f,0.f,0.f}, v01 = {0.f,0.f,0.f,0.f};
    f32x4 v10 = {0.f,0.f,0.f,0.f}, v11 = {0.f,0.f,0.f,0.f};
    #pragma unroll
    for (int ks = 0; ks < 2; ks++) {
        int ko = ks * 32 + lgrp * 8;
        bf16x8 a0 = *(const bf16x8*)&Xb[wr + lrow][ko];
        bf16x8 a1 = *(const bf16x8*)&Xb[wr + 16 + lrow][ko];
        bf16x8 bk0 = *(const bf16x8*)&WtK[wc + lrow][ko];
        bf16x8 bk1 = *(const bf16x8*)&WtK[wc + 16 + lrow][ko];
        k00 = __builtin_amdgcn_mfma_f32_16x16x32_bf16(a0, bk0, k00, 0, 0, 0);
        k01 = __builtin_amdgcn_mfma_f32_16x16x32_bf16(a0, bk1, k01, 0, 0, 0);
        k10 = __builtin_amdgcn_mfma_f32_16x16x32_bf16(a1, bk0, k10, 0, 0, 0);
        k11 = __builtin_amdgcn_mfma_f32_16x16x32_bf16(a1, bk1, k11, 0, 0, 0);
        if (!isQ) {
            bf16x8 bv0 = *(const bf16x8*)&WtV[wc + lrow][ko];
            bf16x8 bv1 = *(const bf16x8*)&WtV[wc + 16 + lrow][ko];
            v00 = __builtin_amdgcn_mfma_f32_16x16x32_bf16(a0, bv0, v00, 0, 0, 0);
            v01 = __builtin_amdgcn_mfma_f32_16x16x32_bf16(a0, bv1, v01, 0, 0, 0);
            v10 = __builtin_amdgcn_mfma_f32_16x16x32_bf16(a1, bv0, v10, 0, 0, 0);
            v11 = __builtin_amdgcn_mfma_f32_16x16x32_bf16(a1, bv1, v11, 0, 0, 0);
        }
    }

    int c0 = wc + lrow, c1 = wc + 16 + lrow;
    bool even = ((lrow & 1) == 0);
    if (isQ) {
        float bias0 = bias[c0], bias1 = bias[c1];
        #pragma unroll
        for (int mi = 0; mi < 2; mi++) {
            const f32x4 a0 = mi ? k10 : k00;
            const f32x4 a1 = mi ? k11 : k01;
            int rbase = wr + mi * 16 + lgrp * 4;
            #pragma unroll
            for (int r = 0; r < 4; r++) {
                int n = nb + rbase + r;
                unsigned own = (unsigned)f2h(a0[r] + bias0)
                             | ((unsigned)f2h(a1[r] + bias1) << 16);
                unsigned oth = __shfl_xor(own, 1, 64);
                if (even && n < N) {
                    unsigned* qp = (unsigned*)(Qh + (size_t)(noff + n) * HID);
                    qp[c0 >> 1] = (own & 0xffffu) | (oth << 16);
                    qp[c1 >> 1] = (own >> 16) | (oth & 0xffff0000u);
                }
            }
        }
    } else {
        float bk0 = bias[kcol + c0], bk1 = bias[kcol + c1];
        float bv0 = bias[vcol + c0], bv1 = bias[vcol + c1];
        #pragma unroll
        for (int mi = 0; mi < 2; mi++) {
            const f32x4 ak0 = mi ? k10 : k00;
            const f32x4 ak1 = mi ? k11 : k01;
            const f32x4 av0 = mi ? v10 : v00;
            const f32x4 av1 = mi ? v11 : v01;
            int rbase = wr + mi * 16 + lgrp * 4;
            #pragma unroll
            for (int r = 0; r < 4; r++) {
                int n = nb + rbase + r;
                unsigned* dst = KVb + (((size_t)(noff + n)) << 6);
                unsigned own0 = (unsigned)f2h(ak0[r] + bk0) | ((unsigned)f2h(av0[r] + bv0) << 16);
                unsigned oth0 = __shfl_xor(own0, 1, 64);
                unsigned own1 = (unsigned)f2h(ak1[r] + bk1) | ((unsigned)f2h(av1[r] + bv1) << 16);
                unsigned oth1 = __shfl_xor(own1, 1, 64);
                if (n < N) {
                    unsigned w0 = even ? ((own0 & 0xffffu) | (oth0 << 16))
                                       : ((oth0 >> 16) | (own0 & 0xffff0000u));
                    unsigned w1 = even ? ((own1 & 0xffffu) | (oth1 << 16))
                                       : ((oth1 >> 16) | (own1 & 0xffff0000u));
                    dst[c0] = w0;
                    dst[c1] = w1;
                }
            }
        }
    }
}

// ---------------- fused attention: no-max softmax, 4 edges/iter, f16 Q, bf16 output ----------------
__global__ __launch_bounds__(256) void attn_kernel(
    const unsigned short* __restrict__ Qh, const unsigned* __restrict__ KVb,
    const float* __restrict__ p_rel, const int* __restrict__ row_ptr,
    const int* __restrict__ edge_src, unsigned short* __restrict__ ABf)
{
    int wid = threadIdx.x >> 6, lane = threadIdx.x & 63;
    int n = blockIdx.x * 4 + wid;
    if (n >= NTOT) return;
    int half = lane >> 5;
    int p = lane & 31;           // pair index: dims 2p, 2p+1
    int h = p >> 3;              // head
    unsigned qw = *(const unsigned*)(Qh + (((size_t)n) << 6) + 2 * p);
    union { unsigned u; h16x2 v; _Float16 f[2]; } qc; qc.u = qw;
    h16x2 qh = qc.v;
    const float INV_LN2 = 1.4426950408889634f;
    float pr0 = p_rel[h] * 0.25f * INV_LN2;
    float pr1 = p_rel[4 + h] * 0.25f * INV_LN2;
    float pr2 = p_rel[8 + h] * 0.25f * INV_LN2;
    int beg = row_ptr[n], end = row_ptr[n + 1];
    float s = 0.0f, acc0 = 0.f, acc1 = 0.f;
    for (int e = beg; e < end; e += 4) {
        int e0 = e + half;           // edges e, e+1
        int e1 = e + 2 + half;       // edges e+2, e+3
        bool v0 = (e0 < end), v1 = (e1 < end);
        int s0 = v0 ? edge_src[e0] : 0;
        int s1 = v1 ? edge_src[e1] : 0;
        uint2 kv0 = *(const uint2*)(KVb + (((size_t)s0) << 6) + 2 * p);
        uint2 kv1 = *(const uint2*)(KVb + (((size_t)s1) << 6) + 2 * p);
        float d0, d1;
#if __has_builtin(__builtin_amdgcn_fdot2)
        {
            union { unsigned u; h16x2 v; } ck;
            ck.u = kv0.x; d0 = __builtin_amdgcn_fdot2(qh, ck.v, 0.0f, false);
            ck.u = kv1.x; d1 = __builtin_amdgcn_fdot2(qh, ck.v, 0.0f, false);
        }
#else
        {
            union { unsigned u; _Float16 f[2]; } ck;
            float q0 = (float)qc.f[0], q1 = (float)qc.f[1];
            ck.u = kv0.x; d0 = q0 * (float)ck.f[0] + q1 * (float)ck.f[1];
            ck.u = kv1.x; d1 = q0 * (float)ck.f[0] + q1 * (float)ck.f[1];
        }
#endif
        d0 += __shfl_xor(d0, 1, 64);  d1 += __shfl_xor(d1, 1, 64);
        d0 += __shfl_xor(d0, 2, 64);  d1 += __shfl_xor(d1, 2, 64);
        d0 += __shfl_xor(d0, 4, 64);  d1 += __shfl_xor(d1, 4, 64);
        float pa = (s0 < NA) ? pr0 : ((s0 < NA + NP) ? pr1 : pr2);
        float pb = (s1 < NA) ? pr0 : ((s1 < NA + NP) ? pr1 : pr2);
        float a0 = v0 ? fminf(d0 * pa, 80.0f) : -INFINITY;
        float a1 = v1 ? fminf(d1 * pb, 80.0f) : -INFINITY;
        float p0 = exp2f(a0);
        float p1 = exp2f(a1);
        s += p0 + p1;
        union { unsigned u; _Float16 f[2]; } cv0, cv1;
        cv0.u = kv0.y; cv1.u = kv1.y;
        acc0 += p0 * (float)cv0.f[0] + p1 * (float)cv1.f[0];
        acc1 += p0 * (float)cv0.f[1] + p1 * (float)cv1.f[1];
    }
    s    += __shfl_xor(s, 32, 64);
    acc0 += __shfl_xor(acc0, 32, 64);
    acc1 += __shfl_xor(acc1, 32, 64);
    if (half == 0) {
        float inv = 1.0f / (s + 1e-16f);
        unsigned pack = (unsigned)f2bf(acc0 * inv) | ((unsigned)f2bf(acc1 * inv) << 16);
        *(unsigned*)(ABf + (((size_t)n) << 6) + 2 * p) = pack;
    }
}

// ---------------- hout via MFMA bf16 + skip + LN + gelu (+ optional fused W_out GEMM) ----------------
// Residual h read/written as bf16 (Hb). Last layer fuses W_out GEMM -> outp.
__global__ __launch_bounds__(256) void gemm_hout(
    const unsigned short* __restrict__ ABf, const float* __restrict__ Whout,
    const float* __restrict__ bhout, const float* __restrict__ skip_p,
    const float* __restrict__ lng, const float* __restrict__ lnb,
    unsigned short* __restrict__ Hb,
    const float* __restrict__ Wout, const float* __restrict__ bout,
    float* __restrict__ outp)
{
    __shared__ unsigned short Xb[64][72];
    __shared__ unsigned short Wt[64][72];
    __shared__ float hs[64][68];
    int b = blockIdx.x, tid = threadIdx.x;
    int type = (b >= PT);
    int tile = type ? (b - PT) : b;
    int N = type ? NA : NP;
    size_t base_off = type ? (size_t)NP * HID : 0;
    const unsigned short* X = ABf + base_off;
    const float* W = Whout + (size_t)type * HID * HID;
    const float* bias = bhout + type * HID;
    unsigned short* H = Hb + base_off;
    int nb = tile * 64;
    bool fuse_out = (Wout != nullptr);

    {
        int row = tid >> 2, c0 = (tid & 3) * 16;
        int n = nb + row;
        unsigned short tmp[16];
        if (n < N) {
            const unsigned short* xr = X + (((size_t)n) << 6) + c0;
            #pragma unroll
            for (int i = 0; i < 16; i += 4) {
                ushort4 v = *(const ushort4*)(xr + i);
                tmp[i]   = f2bf(gelu_exact(bf2f(v.x)));
                tmp[i+1] = f2bf(gelu_exact(bf2f(v.y)));
                tmp[i+2] = f2bf(gelu_exact(bf2f(v.z)));
                tmp[i+3] = f2bf(gelu_exact(bf2f(v.w)));
            }
        } else {
            #pragma unroll
            for (int i = 0; i < 16; i++) tmp[i] = 0;
        }
        #pragma unroll
        for (int i = 0; i < 16; i += 4)
            *(ushort4*)&Xb[row][c0 + i] = make_ushort4(tmp[i], tmp[i+1], tmp[i+2], tmp[i+3]);
    }
    #pragma unroll
    for (int it = 0; it < 4; it++) {
        int idx = it * 256 + tid;
        int k = idx & 63, c = (idx >> 6) * 4;
        float4 v = *(const float4*)(W + (size_t)k * HID + c);
        Wt[c + 0][k] = f2bf(v.x); Wt[c + 1][k] = f2bf(v.y);
        Wt[c + 2][k] = f2bf(v.z); Wt[c + 3][k] = f2bf(v.w);
    }
    __syncthreads();

    int w = tid >> 6, lane = tid & 63;
    int wr = (w >> 1) * 32, wc = (w & 1) * 32;
    int lrow = lane & 15, lgrp = lane >> 4;

    f32x4 acc00 = {0.f, 0.f, 0.f, 0.f};
    f32x4 acc01 = {0.f, 0.f, 0.f, 0.f};
    f32x4 acc10 = {0.f, 0.f, 0.f, 0.f};
    f32x4 acc11 = {0.f, 0.f, 0.f, 0.f};
    #pragma unroll
    for (int ks = 0; ks < 2; ks++) {
        int ko = ks * 32 + lgrp * 8;
        bf16x8 a0 = *(const bf16x8*)&Xb[wr + lrow][ko];
        bf16x8 a1 = *(const bf16x8*)&Xb[wr + 16 + lrow][ko];
        bf16x8 b0 = *(const bf16x8*)&Wt[wc + lrow][ko];
        bf16x8 b1 = *(const bf16x8*)&Wt[wc + 16 + lrow][ko];
        acc00 = __builtin_amdgcn_mfma_f32_16x16x32_bf16(a0, b0, acc00, 0, 0, 0);
        acc01 = __builtin_amdgcn_mfma_f32_16x16x32_bf16(a0, b1, acc01, 0, 0, 0);
        acc10 = __builtin_amdgcn_mfma_f32_16x16x32_bf16(a1, b0, acc10, 0, 0, 0);
        acc11 = __builtin_amdgcn_mfma_f32_16x16x32_bf16(a1, b1, acc11, 0, 0, 0);
    }

    float a = 1.0f / (1.0f + __expf(-skip_p[type]));
    float oma = 1.0f - a;
    float bias0 = bias[wc + lrow], bias1 = bias[wc + 16 + lrow];
    #pragma unroll
    for (int mi = 0; mi < 2; mi++) {
        const f32x4 accn0 = mi ? acc10 : acc00;
        const f32x4 accn1 = mi ? acc11 : acc01;
        int rbase = wr + mi * 16 + lgrp * 4;
        #pragma unroll
        for (int r = 0; r < 4; r++) {
            int row = rbase + r;
            int n = nb + row;
            if (n < N) {
                const unsigned short* hp = H + (size_t)n * HID;
                hs[row][wc + lrow]      = a * (accn0[r] + bias0) + oma * bf2f(hp[wc + lrow]);
                hs[row][wc + 16 + lrow] = a * (accn1[r] + bias1) + oma * bf2f(hp[wc + 16 + lrow]);
            } else {
                hs[row][wc + lrow] = 0.f;
                hs[row][wc + 16 + lrow] = 0.f;
            }
        }
    }
    __syncthreads();

    const int tr = tid >> 4, tc = tid & 15;
    const int tcj = tc * 4;
    float g0 = lng[type*HID+tcj], g1 = lng[type*HID+tcj+1],
          g2 = lng[type*HID+tcj+2], g3 = lng[type*HID+tcj+3];
    float l0 = lnb[type*HID+tcj], l1 = lnb[type*HID+tcj+1],
          l2 = lnb[type*HID+tcj+2], l3 = lnb[type*HID+tcj+3];
    #pragma unroll 1
    for (int m = 0; m < 4; m++) {
        int row = tr * 4 + m;
        int n = nb + row;
        float v0 = hs[row][tcj], v1 = hs[row][tcj+1], v2 = hs[row][tcj+2], v3 = hs[row][tcj+3];
        float sum = v0 + v1 + v2 + v3;
        sum += __shfl_xor(sum, 1, 64); sum += __shfl_xor(sum, 2, 64);
        sum += __shfl_xor(sum, 4, 64); sum += __shfl_xor(sum, 8, 64);
        float mean = sum * (1.0f / 64.0f);
        float d0 = v0 - mean, d1 = v1 - mean, d2 = v2 - mean, d3 = v3 - mean;
        float sq = d0*d0 + d1*d1 + d2*d2 + d3*d3;
        sq += __shfl_xor(sq, 1, 64); sq += __shfl_xor(sq, 2, 64);
        sq += __shfl_xor(sq, 4, 64); sq += __shfl_xor(sq, 8, 64);
        float rstd = rsqrtf(sq * (1.0f / 64.0f) + 1e-5f);
        float r0 = gelu_exact(d0 * rstd * g0 + l0);
        float r1 = gelu_exact(d1 * rstd * g1 + l1);
        float r2 = gelu_exact(d2 * rstd * g2 + l2);
        float r3 = gelu_exact(d3 * rstd * g3 + l3);
        hs[row][tcj] = r0; hs[row][tcj+1] = r1;
        hs[row][tcj+2] = r2; hs[row][tcj+3] = r3;
        if (!fuse_out && n < N) {
            // 4 consecutive cols -> 2 packed bf16 dwords (8B aligned)
            uint2 pk;
            pk.x = (unsigned)f2bf(r0) | ((unsigned)f2bf(r1) << 16);
            pk.y = (unsigned)f2bf(r2) | ((unsigned)f2bf(r3) << 16);
            *(uint2*)(H + (size_t)n * HID + tcj) = pk;
        }
    }

    if (fuse_out) {
        __syncthreads();
        // restage: Xb <- bf16(hs), Wt <- W_out^T
        {
            int row = tid >> 2, c0 = (tid & 3) * 16;
            #pragma unroll
            for (int i = 0; i < 16; i += 4) {
                *(ushort4*)&Xb[row][c0 + i] = make_ushort4(
                    f2bf(hs[row][c0 + i]),     f2bf(hs[row][c0 + i + 1]),
                    f2bf(hs[row][c0 + i + 2]), f2bf(hs[row][c0 + i + 3]));
            }
        }
        const float* W2 = Wout + (size_t)type * HID * HID;
        #pragma unroll
        for (int it = 0; it < 4; it++) {
            int idx = it * 256 + tid;
            int k = idx & 63, c = (idx >> 6) * 4;
            float4 v = *(const float4*)(W2 + (size_t)k * HID + c);
            Wt[c + 0][k] = f2bf(v.x); Wt[c + 1][k] = f2bf(v.y);
            Wt[c + 2][k] = f2bf(v.z); Wt[c + 3][k] = f2bf(v.w);
        }
        __syncthreads();

        f32x4 o00 = {0.f,0.f,0.f,0.f}, o01 = {0.f,0.f,0.f,0.f};
        f32x4 o10 = {0.f,0.f,0.f,0.f}, o11 = {0.f,0.f,0.f,0.f};
        #pragma unroll
        for (int ks = 0; ks < 2; ks++) {
            int ko = ks * 32 + lgrp * 8;
            bf16x8 a0 = *(const bf16x8*)&Xb[wr + lrow][ko];
            bf16x8 a1 = *(const bf16x8*)&Xb[wr + 16 + lrow][ko];
            bf16x8 b0 = *(const bf16x8*)&Wt[wc + lrow][ko];
            bf16x8 b1 = *(const bf16x8*)&Wt[wc + 16 + lrow][ko];
            o00 = __builtin_amdgcn_mfma_f32_16x16x32_bf16(a0, b0, o00, 0, 0, 0);
            o01 = __builtin_amdgcn_mfma_f32_16x16x32_bf16(a0, b1, o01, 0, 0, 0);
            o10 = __builtin_amdgcn_mfma_f32_16x16x32_bf16(a1, b0, o10, 0, 0, 0);
            o11 = __builtin_amdgcn_mfma_f32_16x16x32_bf16(a1, b1, o11, 0, 0, 0);
        }
        const float* b2 = bout + type * HID;
        float b20 = b2[wc + lrow], b21 = b2[wc + 16 + lrow];
        float* O = outp + base_off;
        #pragma unroll
        for (int mi = 0; mi < 2; mi++) {
            const f32x4 on0 = mi ? o10 : o00;
            const f32x4 on1 = mi ? o11 : o01;
            int rbase = wr + mi * 16 + lgrp * 4;
            #pragma unroll
            for (int r = 0; r < 4; r++) {
                int n = nb + rbase + r;
                if (n >= N) continue;
                O[(size_t)n * HID + wc + lrow]      = on0[r] + b20;
                O[(size_t)n * HID + wc + 16 + lrow] = on1[r] + b21;
            }
        }
    }
}

extern "C" void kernel_launch(void* const* d_in, const int* in_sizes, int n_in,
                              void* d_out, int out_size, void* d_ws, size_t ws_size,
                              hipStream_t stream) {
    const float* x_paper  = (const float*)d_in[0];
    const float* x_author = (const float*)d_in[1];
    const int*   ei_ap    = (const int*)d_in[2];
    const int*   ei_pa    = (const int*)d_in[3];
    const int*   ei_pp    = (const int*)d_in[4];
    const float* W_in     = (const float*)d_in[5];
    const float* b_in     = (const float*)d_in[6];
    const float* W_kqv    = (const float*)d_in[7];
    const float* b_kqv    = (const float*)d_in[8];
    const float* W_krel   = (const float*)d_in[9];
    const float* W_vrel   = (const float*)d_in[10];
    const float* p_rel    = (const float*)d_in[11];
    const float* W_hout   = (const float*)d_in[12];
    const float* b_hout   = (const float*)d_in[13];
    const float* skip     = (const float*)d_in[14];
    const float* ln_g     = (const float*)d_in[15];
    const float* ln_b     = (const float*)d_in[16];
    const float* W_out    = (const float*)d_in[17];
    const float* b_out    = (const float*)d_in[18];
    float* out            = (float*)d_out;

    // ---- workspace layout (~120 MB) ----
    char* ws = (char*)d_ws;
    unsigned short* Hb  = (unsigned short*)ws;                    // NTOT*64 bf16
    unsigned short* Qh  = Hb + (size_t)NTOT * HID;                // NTOT*64 f16 pairs
    unsigned* KVb       = (unsigned*)(Qh + (size_t)NTOT * HID);   // NSRC*64 dwords
    unsigned short* ABf = (unsigned short*)(KVb + (size_t)NSRC * HID); // NTOT*64 bf16
    float* Wfp  = (float*)(ABf + (size_t)NTOT * HID);   // 64*320
    float* bfp  = Wfp  + 64 * JP;                       // 320
    float* Wfa  = bfp  + JP;                            // 64*192
    float* bfa  = Wfa  + 64 * JA;                       // 192
    int* cnt      = (int*)(bfa + JA);                   // NTOT
    int* row_ptr  = cnt + NTOT;                         // NTOT+1 (pad 16)
    int* cursor   = row_ptr + NTOT + 16;                // NTOT
    int* edge_src = cursor + NTOT;                      // ETOT
    int* csum     = edge_src + ETOT;                    // 1024
    int* coff     = csum + 1024;                        // 1024

    dim3 blk(256);
    const int EB = (ETOT + 255) / 256;

    // ---- CSR build (edges are layer-invariant) ----
    zero_int_kernel<<<256, blk, 0, stream>>>(cnt, NTOT);
    csr_count_kernel<<<EB, blk, 0, stream>>>(ei_ap, ei_pa, ei_pp, cnt);
    scan_chunk_sums<<<NCH, blk, 0, stream>>>(cnt, csum);
    scan_offsets<<<1, 1024, 0, stream>>>(csum, coff, NCH);
    scan_final<<<NCH, blk, 0, stream>>>(cnt, coff, row_ptr, cursor);
    csr_fill_kernel<<<EB, blk, 0, stream>>>(ei_ap, ei_pa, ei_pp, cursor, edge_src);

    // ---- input projection ----
    gemm_in<<<PT + AT, blk, 0, stream>>>(x_paper, x_author, W_in, b_in, Hb);

    for (int l = 0; l < LAYERS; l++) {
        fuse_weights_kernel<<<(65 * JP + 65 * JA + 255) / 256, blk, 0, stream>>>(
            W_kqv + (size_t)l * 2 * HID * KQV, b_kqv + (size_t)l * 2 * KQV,
            W_krel + (size_t)l * 3 * NH * HD * HD, W_vrel + (size_t)l * 3 * NH * HD * HD,
            Wfp, bfp, Wfa, bfa);
        gemm_kqv<<<3 * PT + 2 * AT, blk, 0, stream>>>(
            Hb, Wfp, bfp, Wfa, bfa, Qh, KVb);
        attn_kernel<<<(NTOT + 3) / 4, blk, 0, stream>>>(
            Qh, KVb, p_rel + l * 3 * NH, row_ptr, edge_src, ABf);
        bool last = (l == LAYERS - 1);
        gemm_hout<<<PT + AT, blk, 0, stream>>>(
            ABf, W_hout + (size_t)l * 2 * HID * HID, b_hout + l * 2 * HID,
            skip + l * 2, ln_g + l * 2 * HID, ln_b + l * 2 * HID, Hb,
            last ? W_out : nullptr, last ? b_out : nullptr, last ? out : nullptr);
    }
}

// Round 16
// 365.366 us; speedup vs baseline: 5.1281x; 1.0681x over previous
//
#include <hip/hip_runtime.h>
#include <hip/hip_bf16.h>

// ---- problem constants (match reference) ----
#define NP 100000
#define NA 50000
#define NTOT 150000          // NP+NA
#define E0 300000
#define E1 300000
#define E2 200000
#define ETOT 800000
#define NH 4
#define HD 16
#define HID 64
#define IN_DIM 128
#define KQV 192
#define LAYERS 2
#define NSRC 250000          // NA + 2*NP
#define JP 320               // fused paper cols: q | k_et1 | k_et2 | v_et1 | v_et2
#define JA 192               // fused author cols: q | k_et0 | v_et0
#define NCH 586              // ceil(NTOT/256)
#define PT 1563              // ceil(NP/64)
#define AT 782               // ceil(NA/64)

typedef __attribute__((ext_vector_type(8))) short bf16x8;   // 8 bf16 (4 VGPRs)
typedef __attribute__((ext_vector_type(4))) float f32x4;    // MFMA C/D
typedef _Float16 h16x2 __attribute__((ext_vector_type(2)));

__device__ __forceinline__ float gelu_exact(float x) {
    return 0.5f * x * (1.0f + erff(x * 0.7071067811865475f));
}
__device__ __forceinline__ unsigned short f2bf(float f) {
    unsigned u = __float_as_uint(f);
    return (unsigned short)((u + 0x7fffu + ((u >> 16) & 1u)) >> 16);
}
__device__ __forceinline__ float bf2f(unsigned short b) {
    return __uint_as_float((unsigned)b << 16);
}
__device__ __forceinline__ unsigned short f2h(float f) {
    union { _Float16 h; unsigned short u; } c;
    c.h = (_Float16)f;
    return c.u;
}

__device__ __forceinline__ void edge_decode(int e, const int* __restrict__ ei_ap,
                                            const int* __restrict__ ei_pa,
                                            const int* __restrict__ ei_pp,
                                            int& src, int& dst) {
    if (e < E0)            { src = ei_ap[e];                 dst = ei_ap[E0 + e]; }
    else if (e < E0 + E1)  { int le = e - E0;
                             src = NA + ei_pa[le];           dst = NP + ei_pa[E1 + le]; }
    else                   { int le = e - E0 - E1;
                             src = NA + NP + ei_pp[le];      dst = ei_pp[E2 + le]; }
}

// ---------------- CSR build ----------------
__global__ void zero_int_kernel(int* __restrict__ p, int n) {
    int i = blockIdx.x * blockDim.x + threadIdx.x;
    int st = gridDim.x * blockDim.x;
    for (int j = i; j < n; j += st) p[j] = 0;
}

__global__ void csr_count_kernel(const int* __restrict__ ei_ap, const int* __restrict__ ei_pa,
                                 const int* __restrict__ ei_pp, int* __restrict__ cnt) {
    int e = blockIdx.x * 256 + threadIdx.x;
    if (e >= ETOT) return;
    int src, dst; edge_decode(e, ei_ap, ei_pa, ei_pp, src, dst);
    atomicAdd(&cnt[dst], 1);
}

__global__ void scan_chunk_sums(const int* __restrict__ cnt, int* __restrict__ csum) {
    __shared__ int sd[256];
    int c = blockIdx.x, t = threadIdx.x;
    int i = c * 256 + t;
    sd[t] = (i < NTOT) ? cnt[i] : 0;
    __syncthreads();
    for (int o = 128; o > 0; o >>= 1) { if (t < o) sd[t] += sd[t + o]; __syncthreads(); }
    if (t == 0) csum[c] = sd[0];
}

__global__ void scan_offsets(const int* __restrict__ csum, int* __restrict__ coff, int nch) {
    __shared__ int sd[1024];
    int t = threadIdx.x;
    int v = (t < nch) ? csum[t] : 0;
    sd[t] = v;
    __syncthreads();
    for (int o = 1; o < 1024; o <<= 1) {
        int x = (t >= o) ? sd[t - o] : 0;
        __syncthreads();
        sd[t] += x;
        __syncthreads();
    }
    if (t < nch) coff[t] = sd[t] - v;   // exclusive
}

__global__ void scan_final(const int* __restrict__ cnt, const int* __restrict__ coff,
                           int* __restrict__ row_ptr, int* __restrict__ cursor) {
    __shared__ int sd[256];
    int c = blockIdx.x, t = threadIdx.x, i = c * 256 + t;
    int v = (i < NTOT) ? cnt[i] : 0;
    sd[t] = v;
    __syncthreads();
    for (int o = 1; o < 256; o <<= 1) {
        int x = (t >= o) ? sd[t - o] : 0;
        __syncthreads();
        sd[t] += x;
        __syncthreads();
    }
    if (i < NTOT) { int ex = coff[c] + sd[t] - v; row_ptr[i] = ex; cursor[i] = ex; }
    if (i == 0) row_ptr[NTOT] = ETOT;
}

__global__ void csr_fill_kernel(const int* __restrict__ ei_ap, const int* __restrict__ ei_pa,
                                const int* __restrict__ ei_pp, int* __restrict__ cursor,
                                int* __restrict__ edge_src) {
    int e = blockIdx.x * 256 + threadIdx.x;
    if (e >= ETOT) return;
    int src, dst; edge_decode(e, ei_ap, ei_pa, ei_pp, src, dst);
    int pos = atomicAdd(&cursor[dst], 1);
    edge_src[pos] = src;
}

// ---------------- one-time weight prep: transposed bf16 panels ----------------
// WinT[type][c][k] (k<128), WhoutT[(l*2+t)][c][k], WoutT[t][c][k] (k<64)
__global__ void prep_weights(const float* __restrict__ W_in, const float* __restrict__ W_hout,
                             const float* __restrict__ W_out,
                             unsigned short* __restrict__ WinT,
                             unsigned short* __restrict__ WhoutT,
                             unsigned short* __restrict__ WoutT) {
    int idx = blockIdx.x * 256 + threadIdx.x;
    if (idx < 2 * 64 * IN_DIM) {
        int t = idx >> 13, r = idx & 8191;
        int c = r >> 7, k = r & 127;
        WinT[idx] = f2bf(W_in[(size_t)t * IN_DIM * HID + (size_t)k * HID + c]);
        return;
    }
    int i2 = idx - 2 * 64 * IN_DIM;
    if (i2 < LAYERS * 2 * 4096) {
        int p = i2 >> 12, r = i2 & 4095;
        int c = r >> 6, k = r & 63;
        WhoutT[i2] = f2bf(W_hout[(size_t)p * 4096 + (size_t)k * HID + c]);
        return;
    }
    int i3 = i2 - LAYERS * 2 * 4096;
    if (i3 < 2 * 4096) {
        int p = i3 >> 12, r = i3 & 4095;
        int c = r >> 6, k = r & 63;
        WoutT[i3] = f2bf(W_out[(size_t)p * 4096 + (size_t)k * HID + c]);
    }
}

// ---------------- fused-weight build (per layer) -> transposed bf16 ----------------
__global__ void fuse_weights_kernel(const float* __restrict__ Wkqv, const float* __restrict__ bkqv,
                                    const float* __restrict__ Wkrel, const float* __restrict__ Wvrel,
                                    unsigned short* __restrict__ WfpT, float* __restrict__ bfp,
                                    unsigned short* __restrict__ WfaT, float* __restrict__ bfa) {
    int idx = blockIdx.x * 256 + threadIdx.x;
    int type, i, j;
    if (idx < 65 * JP) { type = 0; i = idx / JP; j = idx % JP; }
    else {
        int r = idx - 65 * JP;
        if (r >= 65 * JA) return;
        type = 1; i = r / JA; j = r % JA;
    }
    int c = j >> 6, jj = j & 63, h = jj >> 4, e = jj & 15;
    const float* Wk = Wkqv + (size_t)type * HID * KQV;
    const float* bk = bkqv + type * KQV;
    float val;
    if (c == 0) {
        val = (i < 64) ? Wk[i * KQV + 64 + jj] : bk[64 + jj];
    } else {
        int et, isV;
        if (type == 0) { et = (c == 1 || c == 3) ? 1 : 2; isV = (c >= 3); }
        else           { et = 0; isV = (c == 2); }
        const float* Wr = (isV ? Wvrel : Wkrel) + (size_t)(et * NH + h) * HD * HD;
        int sb = (isV ? 128 : 0) + h * HD;
        val = 0.0f;
        #pragma unroll
        for (int d = 0; d < HD; d++) {
            float a = (i < 64) ? Wk[i * KQV + sb + d] : bk[sb + d];
            val += a * Wr[d * HD + e];
        }
    }
    if (i < 64) (type ? WfaT : WfpT)[(size_t)j * 64 + i] = f2bf(val);
    else        (type ? bfa : bfp)[j] = val;
}

// ---------------- input projection via MFMA bf16 (K=128) -> bf16 h ----------------
__global__ __launch_bounds__(256) void gemm_in(
    const float* __restrict__ xp, const float* __restrict__ xa,
    const unsigned short* __restrict__ WinT, const float* __restrict__ b_in,
    unsigned short* __restrict__ Hb)
{
    __shared__ unsigned short Xb[64][136];   // 272B rows (16B-aligned)
    __shared__ unsigned short Wt[64][136];   // Wt[col][k]
    int b = blockIdx.x, tid = threadIdx.x;
    int type = (b >= PT);
    int tile = type ? (b - PT) : b;
    int N = type ? NA : NP;
    const float* X = type ? xa : xp;
    const unsigned short* WT = WinT + (size_t)type * 64 * IN_DIM;
    const float* bias = b_in + type * HID;
    unsigned short* H = Hb + (type ? (size_t)NP * HID : 0);
    int nb = tile * 64;

    {
        int row = tid >> 2, c0 = (tid & 3) * 32;
        int n = nb + row;
        if (n < N) {
            const float* xr = X + (size_t)n * IN_DIM + c0;
            #pragma unroll
            for (int i = 0; i < 32; i += 4) {
                float4 v = *(const float4*)(xr + i);
                *(ushort4*)&Xb[row][c0 + i] =
                    make_ushort4(f2bf(v.x), f2bf(v.y), f2bf(v.z), f2bf(v.w));
            }
        } else {
            #pragma unroll
            for (int i = 0; i < 32; i += 4)
                *(ushort4*)&Xb[row][c0 + i] = make_ushort4(0, 0, 0, 0);
        }
    }
    #pragma unroll
    for (int it = 0; it < 8; it++) {
        int idx = it * 256 + tid;            // 0..2047 = 64c x 32 kgroups
        int c = idx >> 5, kg = (idx & 31) * 4;
        *(ushort4*)&Wt[c][kg] = *(const ushort4*)(WT + (size_t)c * IN_DIM + kg);
    }
    __syncthreads();

    int w = tid >> 6, lane = tid & 63;
    int wr = (w >> 1) * 32, wc = (w & 1) * 32;
    int lrow = lane & 15, lgrp = lane >> 4;

    f32x4 acc00 = {0.f, 0.f, 0.f, 0.f};
    f32x4 acc01 = {0.f, 0.f, 0.f, 0.f};
    f32x4 acc10 = {0.f, 0.f, 0.f, 0.f};
    f32x4 acc11 = {0.f, 0.f, 0.f, 0.f};
    #pragma unroll
    for (int ks = 0; ks < 4; ks++) {
        int ko = ks * 32 + lgrp * 8;
        bf16x8 a0 = *(const bf16x8*)&Xb[wr + lrow][ko];
        bf16x8 a1 = *(const bf16x8*)&Xb[wr + 16 + lrow][ko];
        bf16x8 b0 = *(const bf16x8*)&Wt[wc + lrow][ko];
        bf16x8 b1 = *(const bf16x8*)&Wt[wc + 16 + lrow][ko];
        acc00 = __builtin_amdgcn_mfma_f32_16x16x32_bf16(a0, b0, acc00, 0, 0, 0);
        acc01 = __builtin_amdgcn_mfma_f32_16x16x32_bf16(a0, b1, acc01, 0, 0, 0);
        acc10 = __builtin_amdgcn_mfma_f32_16x16x32_bf16(a1, b0, acc10, 0, 0, 0);
        acc11 = __builtin_amdgcn_mfma_f32_16x16x32_bf16(a1, b1, acc11, 0, 0, 0);
    }

    float bias0 = bias[wc + lrow], bias1 = bias[wc + 16 + lrow];
    int c0 = wc + lrow, c1 = wc + 16 + lrow;
    bool even = ((lrow & 1) == 0);
    #pragma unroll
    for (int mi = 0; mi < 2; mi++) {
        const f32x4 accn0 = mi ? acc10 : acc00;
        const f32x4 accn1 = mi ? acc11 : acc01;
        int rbase = wr + mi * 16 + lgrp * 4;
        #pragma unroll
        for (int r = 0; r < 4; r++) {
            int n = nb + rbase + r;
            unsigned own = (unsigned)f2bf(accn0[r] + bias0)
                         | ((unsigned)f2bf(accn1[r] + bias1) << 16);
            unsigned oth = __shfl_xor(own, 1, 64);
            if (even && n < N) {
                unsigned* hp = (unsigned*)(H + (size_t)n * HID);
                hp[c0 >> 1] = (own & 0xffffu) | (oth << 16);
                hp[c1 >> 1] = (own >> 16) | (oth & 0xffff0000u);
            }
        }
    }
}

// ---------------- KQV GEMM: Q merged into KV blocks ----------------
// paper kindA = {Q, K_et1, V_et1}; paper kindB = {K_et2, V_et2}; author = {Q, K, V}.
// Weights pre-transposed bf16 (WfT[col][k]) -> straight ushort4 LDS copies.
__global__ __launch_bounds__(256) void gemm_kqv(
    const unsigned short* __restrict__ Hb,
    const unsigned short* __restrict__ WfpT, const float* __restrict__ bfp,
    const unsigned short* __restrict__ WfaT, const float* __restrict__ bfa,
    unsigned short* __restrict__ Qh, unsigned* __restrict__ KVb)
{
    __shared__ unsigned short Xb[64][72];
    __shared__ unsigned short WtQ[64][72];
    __shared__ unsigned short WtK[64][72];
    __shared__ unsigned short WtV[64][72];
    int b = blockIdx.x, tid = threadIdx.x;
    int type, tile;
    bool hasQ;
    int kcol, vcol, noff;
    if (b < PT)        { type = 0; tile = b;          hasQ = true;
                         kcol = 64;  vcol = 192; noff = NA; }
    else if (b < 2*PT) { type = 0; tile = b - PT;     hasQ = false;
                         kcol = 128; vcol = 256; noff = NA + NP; }
    else               { type = 1; tile = b - 2*PT;   hasQ = true;
                         kcol = 64;  vcol = 128; noff = 0; }
    int N = type ? NA : NP;
    const unsigned short* X = Hb + (type ? (size_t)NP * HID : 0);
    const unsigned short* WT = type ? WfaT : WfpT;
    const float* bias = type ? bfa : bfp;
    int nb = tile * 64;
    int qnoff = type ? NP : 0;

    // stage X tile (already bf16)
    {
        int row = tid >> 2, c0 = (tid & 3) * 16;
        int n = nb + row;
        if (n < N) {
            const unsigned short* xr = X + (size_t)n * HID + c0;
            *(ushort4*)&Xb[row][c0]      = *(const ushort4*)(xr);
            *(ushort4*)&Xb[row][c0 + 4]  = *(const ushort4*)(xr + 4);
            *(ushort4*)&Xb[row][c0 + 8]  = *(const ushort4*)(xr + 8);
            *(ushort4*)&Xb[row][c0 + 12] = *(const ushort4*)(xr + 12);
        } else {
            #pragma unroll
            for (int i = 0; i < 16; i += 4)
                *(ushort4*)&Xb[row][c0 + i] = make_ushort4(0, 0, 0, 0);
        }
    }
    // stage weight panels (straight bf16 copies)
    #pragma unroll
    for (int it = 0; it < 4; it++) {
        int idx = it * 256 + tid;           // 0..1023 = 64c x 16 kgroups
        int c = idx >> 4, kg = (idx & 15) * 4;
        *(ushort4*)&WtK[c][kg] = *(const ushort4*)(WT + (size_t)(kcol + c) * 64 + kg);
        *(ushort4*)&WtV[c][kg] = *(const ushort4*)(WT + (size_t)(vcol + c) * 64 + kg);
        if (hasQ)
            *(ushort4*)&WtQ[c][kg] = *(const ushort4*)(WT + (size_t)c * 64 + kg);
    }
    __syncthreads();

    int w = tid >> 6, lane = tid & 63;
    int wr = (w >> 1) * 32, wc = (w & 1) * 32;
    int lrow = lane & 15, lgrp = lane >> 4;

    f32x4 q00 = {0.f,0.f,0.f,0.f}, q01 = {0.f,0.f,0.f,0.f};
    f32x4 q10 = {0.f,0.f,0.f,0.f}, q11 = {0.f,0.f,0.f,0.f};
    f32x4 k00 = {0.f,0.f,0.f,0.f}, k01 = {0.f,0.f,0.f,0.f};
    f32x4 k10 = {0.f,0.f,0.f,0.f}, k11 = {0.f,0.f,0.f,0.f};
    f32x4 v00 = {0.f,0.f,0.f,0.f}, v01 = {0.f,0.f,0.f,0.f};
    f32x4 v10 = {0.f,0.f,0.f,0.f}, v11 = {0.f,0.f,0.f,0.f};
    #pragma unroll
    for (int ks = 0; ks < 2; ks++) {
        int ko = ks * 32 + lgrp * 8;
        bf16x8 a0 = *(const bf16x8*)&Xb[wr + lrow][ko];
        bf16x8 a1 = *(const bf16x8*)&Xb[wr + 16 + lrow][ko];
        bf16x8 bk0 = *(const bf16x8*)&WtK[wc + lrow][ko];
        bf16x8 bk1 = *(const bf16x8*)&WtK[wc + 16 + lrow][ko];
        k00 = __builtin_amdgcn_mfma_f32_16x16x32_bf16(a0, bk0, k00, 0, 0, 0);
        k01 = __builtin_amdgcn_mfma_f32_16x16x32_bf16(a0, bk1, k01, 0, 0, 0);
        k10 = __builtin_amdgcn_mfma_f32_16x16x32_bf16(a1, bk0, k10, 0, 0, 0);
        k11 = __builtin_amdgcn_mfma_f32_16x16x32_bf16(a1, bk1, k11, 0, 0, 0);
        bf16x8 bv0 = *(const bf16x8*)&WtV[wc + lrow][ko];
        bf16x8 bv1 = *(const bf16x8*)&WtV[wc + 16 + lrow][ko];
        v00 = __builtin_amdgcn_mfma_f32_16x16x32_bf16(a0, bv0, v00, 0, 0, 0);
        v01 = __builtin_amdgcn_mfma_f32_16x16x32_bf16(a0, bv1, v01, 0, 0, 0);
        v10 = __builtin_amdgcn_mfma_f32_16x16x32_bf16(a1, bv0, v10, 0, 0, 0);
        v11 = __builtin_amdgcn_mfma_f32_16x16x32_bf16(a1, bv1, v11, 0, 0, 0);
        if (hasQ) {
            bf16x8 bq0 = *(const bf16x8*)&WtQ[wc + lrow][ko];
            bf16x8 bq1 = *(const bf16x8*)&WtQ[wc + 16 + lrow][ko];
            q00 = __builtin_amdgcn_mfma_f32_16x16x32_bf16(a0, bq0, q00, 0, 0, 0);
            q01 = __builtin_amdgcn_mfma_f32_16x16x32_bf16(a0, bq1, q01, 0, 0, 0);
            q10 = __builtin_amdgcn_mfma_f32_16x16x32_bf16(a1, bq0, q10, 0, 0, 0);
            q11 = __builtin_amdgcn_mfma_f32_16x16x32_bf16(a1, bq1, q11, 0, 0, 0);
        }
    }

    int c0 = wc + lrow, c1 = wc + 16 + lrow;
    bool even = ((lrow & 1) == 0);
    if (hasQ) {
        float bq0 = bias[c0], bq1 = bias[c1];
        #pragma unroll
        for (int mi = 0; mi < 2; mi++) {
            const f32x4 a0 = mi ? q10 : q00;
            const f32x4 a1 = mi ? q11 : q01;
            int rbase = wr + mi * 16 + lgrp * 4;
            #pragma unroll
            for (int r = 0; r < 4; r++) {
                int n = nb + rbase + r;
                unsigned own = (unsigned)f2h(a0[r] + bq0)
                             | ((unsigned)f2h(a1[r] + bq1) << 16);
                unsigned oth = __shfl_xor(own, 1, 64);
                if (even && n < N) {
                    unsigned* qp = (unsigned*)(Qh + (size_t)(qnoff + n) * HID);
                    qp[c0 >> 1] = (own & 0xffffu) | (oth << 16);
                    qp[c1 >> 1] = (own >> 16) | (oth & 0xffff0000u);
                }
            }
        }
    }
    {
        float bk0 = bias[kcol + c0], bk1 = bias[kcol + c1];
        float bv0 = bias[vcol + c0], bv1 = bias[vcol + c1];
        #pragma unroll
        for (int mi = 0; mi < 2; mi++) {
            const f32x4 ak0 = mi ? k10 : k00;
            const f32x4 ak1 = mi ? k11 : k01;
            const f32x4 av0 = mi ? v10 : v00;
            const f32x4 av1 = mi ? v11 : v01;
            int rbase = wr + mi * 16 + lgrp * 4;
            #pragma unroll
            for (int r = 0; r < 4; r++) {
                int n = nb + rbase + r;
                unsigned* dst = KVb + (((size_t)(noff + n)) << 6);
                unsigned own0 = (unsigned)f2h(ak0[r] + bk0) | ((unsigned)f2h(av0[r] + bv0) << 16);
                unsigned oth0 = __shfl_xor(own0, 1, 64);
                unsigned own1 = (unsigned)f2h(ak1[r] + bk1) | ((unsigned)f2h(av1[r] + bv1) << 16);
                unsigned oth1 = __shfl_xor(own1, 1, 64);
                if (n < N) {
                    unsigned w0 = even ? ((own0 & 0xffffu) | (oth0 << 16))
                                       : ((oth0 >> 16) | (own0 & 0xffff0000u));
                    unsigned w1 = even ? ((own1 & 0xffffu) | (oth1 << 16))
                                       : ((oth1 >> 16) | (own1 & 0xffff0000u));
                    dst[c0] = w0;
                    dst[c1] = w1;
                }
            }
        }
    }
}

// ---------------- fused attention: no-max softmax, 4 edges/iter, f16 Q, bf16 output ----------------
__global__ __launch_bounds__(256) void attn_kernel(
    const unsigned short* __restrict__ Qh, const unsigned* __restrict__ KVb,
    const float* __restrict__ p_rel, const int* __restrict__ row_ptr,
    const int* __restrict__ edge_src, unsigned short* __restrict__ ABf)
{
    int wid = threadIdx.x >> 6, lane = threadIdx.x & 63;
    int n = blockIdx.x * 4 + wid;
    if (n >= NTOT) return;
    int half = lane >> 5;
    int p = lane & 31;           // pair index: dims 2p, 2p+1
    int h = p >> 3;              // head
    unsigned qw = *(const unsigned*)(Qh + (((size_t)n) << 6) + 2 * p);
    union { unsigned u; h16x2 v; _Float16 f[2]; } qc; qc.u = qw;
    h16x2 qh = qc.v;
    const float INV_LN2 = 1.4426950408889634f;
    float pr0 = p_rel[h] * 0.25f * INV_LN2;
    float pr1 = p_rel[4 + h] * 0.25f * INV_LN2;
    float pr2 = p_rel[8 + h] * 0.25f * INV_LN2;
    int beg = row_ptr[n], end = row_ptr[n + 1];
    float s = 0.0f, acc0 = 0.f, acc1 = 0.f;
    for (int e = beg; e < end; e += 4) {
        int e0 = e + half;
        int e1 = e + 2 + half;
        bool v0 = (e0 < end), v1 = (e1 < end);
        int s0 = v0 ? edge_src[e0] : 0;
        int s1 = v1 ? edge_src[e1] : 0;
        uint2 kv0 = *(const uint2*)(KVb + (((size_t)s0) << 6) + 2 * p);
        uint2 kv1 = *(const uint2*)(KVb + (((size_t)s1) << 6) + 2 * p);
        float d0, d1;
#if __has_builtin(__builtin_amdgcn_fdot2)
        {
            union { unsigned u; h16x2 v; } ck;
            ck.u = kv0.x; d0 = __builtin_amdgcn_fdot2(qh, ck.v, 0.0f, false);
            ck.u = kv1.x; d1 = __builtin_amdgcn_fdot2(qh, ck.v, 0.0f, false);
        }
#else
        {
            union { unsigned u; _Float16 f[2]; } ck;
            float q0 = (float)qc.f[0], q1 = (float)qc.f[1];
            ck.u = kv0.x; d0 = q0 * (float)ck.f[0] + q1 * (float)ck.f[1];
            ck.u = kv1.x; d1 = q0 * (float)ck.f[0] + q1 * (float)ck.f[1];
        }
#endif
        d0 += __shfl_xor(d0, 1, 64);  d1 += __shfl_xor(d1, 1, 64);
        d0 += __shfl_xor(d0, 2, 64);  d1 += __shfl_xor(d1, 2, 64);
        d0 += __shfl_xor(d0, 4, 64);  d1 += __shfl_xor(d1, 4, 64);
        float pa = (s0 < NA) ? pr0 : ((s0 < NA + NP) ? pr1 : pr2);
        float pb = (s1 < NA) ? pr0 : ((s1 < NA + NP) ? pr1 : pr2);
        float a0 = v0 ? fminf(d0 * pa, 80.0f) : -INFINITY;
        float a1 = v1 ? fminf(d1 * pb, 80.0f) : -INFINITY;
        float p0 = exp2f(a0);
        float p1 = exp2f(a1);
        s += p0 + p1;
        union { unsigned u; _Float16 f[2]; } cv0, cv1;
        cv0.u = kv0.y; cv1.u = kv1.y;
        acc0 += p0 * (float)cv0.f[0] + p1 * (float)cv1.f[0];
        acc1 += p0 * (float)cv0.f[1] + p1 * (float)cv1.f[1];
    }
    s    += __shfl_xor(s, 32, 64);
    acc0 += __shfl_xor(acc0, 32, 64);
    acc1 += __shfl_xor(acc1, 32, 64);
    if (half == 0) {
        float inv = 1.0f / (s + 1e-16f);
        unsigned pack = (unsigned)f2bf(acc0 * inv) | ((unsigned)f2bf(acc1 * inv) << 16);
        *(unsigned*)(ABf + (((size_t)n) << 6) + 2 * p) = pack;
    }
}

// ---------------- hout via MFMA bf16 + skip + LN + gelu (+ optional fused W_out GEMM) ----------------
__global__ __launch_bounds__(256) void gemm_hout(
    const unsigned short* __restrict__ ABf, const unsigned short* __restrict__ WhT,
    const float* __restrict__ bhout, const float* __restrict__ skip_p,
    const float* __restrict__ lng, const float* __restrict__ lnb,
    unsigned short* __restrict__ Hb,
    const unsigned short* __restrict__ WoT, const float* __restrict__ bout,
    float* __restrict__ outp)
{
    __shared__ unsigned short Xb[64][72];
    __shared__ unsigned short Wt[64][72];
    __shared__ float hs[64][68];
    int b = blockIdx.x, tid = threadIdx.x;
    int type = (b >= PT);
    int tile = type ? (b - PT) : b;
    int N = type ? NA : NP;
    size_t base_off = type ? (size_t)NP * HID : 0;
    const unsigned short* X = ABf + base_off;
    const unsigned short* W = WhT + (size_t)type * 4096;
    const float* bias = bhout + type * HID;
    unsigned short* H = Hb + base_off;
    int nb = tile * 64;
    bool fuse_out = (WoT != nullptr);

    {
        int row = tid >> 2, c0 = (tid & 3) * 16;
        int n = nb + row;
        unsigned short tmp[16];
        if (n < N) {
            const unsigned short* xr = X + (((size_t)n) << 6) + c0;
            #pragma unroll
            for (int i = 0; i < 16; i += 4) {
                ushort4 v = *(const ushort4*)(xr + i);
                tmp[i]   = f2bf(gelu_exact(bf2f(v.x)));
                tmp[i+1] = f2bf(gelu_exact(bf2f(v.y)));
                tmp[i+2] = f2bf(gelu_exact(bf2f(v.z)));
                tmp[i+3] = f2bf(gelu_exact(bf2f(v.w)));
            }
        } else {
            #pragma unroll
            for (int i = 0; i < 16; i++) tmp[i] = 0;
        }
        #pragma unroll
        for (int i = 0; i < 16; i += 4)
            *(ushort4*)&Xb[row][c0 + i] = make_ushort4(tmp[i], tmp[i+1], tmp[i+2], tmp[i+3]);
    }
    #pragma unroll
    for (int it = 0; it < 4; it++) {
        int idx = it * 256 + tid;
        int c = idx >> 4, kg = (idx & 15) * 4;
        *(ushort4*)&Wt[c][kg] = *(const ushort4*)(W + (size_t)c * 64 + kg);
    }
    __syncthreads();

    int w = tid >> 6, lane = tid & 63;
    int wr = (w >> 1) * 32, wc = (w & 1) * 32;
    int lrow = lane & 15, lgrp = lane >> 4;

    f32x4 acc00 = {0.f, 0.f, 0.f, 0.f};
    f32x4 acc01 = {0.f, 0.f, 0.f, 0.f};
    f32x4 acc10 = {0.f, 0.f, 0.f, 0.f};
    f32x4 acc11 = {0.f, 0.f, 0.f, 0.f};
    #pragma unroll
    for (int ks = 0; ks < 2; ks++) {
        int ko = ks * 32 + lgrp * 8;
        bf16x8 a0 = *(const bf16x8*)&Xb[wr + lrow][ko];
        bf16x8 a1 = *(const bf16x8*)&Xb[wr + 16 + lrow][ko];
        bf16x8 b0 = *(const bf16x8*)&Wt[wc + lrow][ko];
        bf16x8 b1 = *(const bf16x8*)&Wt[wc + 16 + lrow][ko];
        acc00 = __builtin_amdgcn_mfma_f32_16x16x32_bf16(a0, b0, acc00, 0, 0, 0);
        acc01 = __builtin_amdgcn_mfma_f32_16x16x32_bf16(a0, b1, acc01, 0, 0, 0);
        acc10 = __builtin_amdgcn_mfma_f32_16x16x32_bf16(a1, b0, acc10, 0, 0, 0);
        acc11 = __builtin_amdgcn_mfma_f32_16x16x32_bf16(a1, b1, acc11, 0, 0, 0);
    }

    float a = 1.0f / (1.0f + __expf(-skip_p[type]));
    float oma = 1.0f - a;
    float bias0 = bias[wc + lrow], bias1 = bias[wc + 16 + lrow];
    #pragma unroll
    for (int mi = 0; mi < 2; mi++) {
        const f32x4 accn0 = mi ? acc10 : acc00;
        const f32x4 accn1 = mi ? acc11 : acc01;
        int rbase = wr + mi * 16 + lgrp * 4;
        #pragma unroll
        for (int r = 0; r < 4; r++) {
            int row = rbase + r;
            int n = nb + row;
            if (n < N) {
                const unsigned short* hp = H + (size_t)n * HID;
                hs[row][wc + lrow]      = a * (accn0[r] + bias0) + oma * bf2f(hp[wc + lrow]);
                hs[row][wc + 16 + lrow] = a * (accn1[r] + bias1) + oma * bf2f(hp[wc + 16 + lrow]);
            } else {
                hs[row][wc + lrow] = 0.f;
                hs[row][wc + 16 + lrow] = 0.f;
            }
        }
    }
    __syncthreads();

    const int tr = tid >> 4, tc = tid & 15;
    const int tcj = tc * 4;
    float g0 = lng[type*HID+tcj], g1 = lng[type*HID+tcj+1],
          g2 = lng[type*HID+tcj+2], g3 = lng[type*HID+tcj+3];
    float l0 = lnb[type*HID+tcj], l1 = lnb[type*HID+tcj+1],
          l2 = lnb[type*HID+tcj+2], l3 = lnb[type*HID+tcj+3];
    #pragma unroll 1
    for (int m = 0; m < 4; m++) {
        int row = tr * 4 + m;
        int n = nb + row;
        float v0 = hs[row][tcj], v1 = hs[row][tcj+1], v2 = hs[row][tcj+2], v3 = hs[row][tcj+3];
        float sum = v0 + v1 + v2 + v3;
        sum += __shfl_xor(sum, 1, 64); sum += __shfl_xor(sum, 2, 64);
        sum += __shfl_xor(sum, 4, 64); sum += __shfl_xor(sum, 8, 64);
        float mean = sum * (1.0f / 64.0f);
        float d0 = v0 - mean, d1 = v1 - mean, d2 = v2 - mean, d3 = v3 - mean;
        float sq = d0*d0 + d1*d1 + d2*d2 + d3*d3;
        sq += __shfl_xor(sq, 1, 64); sq += __shfl_xor(sq, 2, 64);
        sq += __shfl_xor(sq, 4, 64); sq += __shfl_xor(sq, 8, 64);
        float rstd = rsqrtf(sq * (1.0f / 64.0f) + 1e-5f);
        float r0 = gelu_exact(d0 * rstd * g0 + l0);
        float r1 = gelu_exact(d1 * rstd * g1 + l1);
        float r2 = gelu_exact(d2 * rstd * g2 + l2);
        float r3 = gelu_exact(d3 * rstd * g3 + l3);
        hs[row][tcj] = r0; hs[row][tcj+1] = r1;
        hs[row][tcj+2] = r2; hs[row][tcj+3] = r3;
        if (!fuse_out && n < N) {
            uint2 pk;
            pk.x = (unsigned)f2bf(r0) | ((unsigned)f2bf(r1) << 16);
            pk.y = (unsigned)f2bf(r2) | ((unsigned)f2bf(r3) << 16);
            *(uint2*)(H + (size_t)n * HID + tcj) = pk;
        }
    }

    if (fuse_out) {
        __syncthreads();
        {
            int row = tid >> 2, c0 = (tid & 3) * 16;
            #pragma unroll
            for (int i = 0; i < 16; i += 4) {
                *(ushort4*)&Xb[row][c0 + i] = make_ushort4(
                    f2bf(hs[row][c0 + i]),     f2bf(hs[row][c0 + i + 1]),
                    f2bf(hs[row][c0 + i + 2]), f2bf(hs[row][c0 + i + 3]));
            }
        }
        const unsigned short* W2 = WoT + (size_t)type * 4096;
        #pragma unroll
        for (int it = 0; it < 4; it++) {
            int idx = it * 256 + tid;
            int c = idx >> 4, kg = (idx & 15) * 4;
            *(ushort4*)&Wt[c][kg] = *(const ushort4*)(W2 + (size_t)c * 64 + kg);
        }
        __syncthreads();

        f32x4 o00 = {0.f,0.f,0.f,0.f}, o01 = {0.f,0.f,0.f,0.f};
        f32x4 o10 = {0.f,0.f,0.f,0.f}, o11 = {0.f,0.f,0.f,0.f};
        #pragma unroll
        for (int ks = 0; ks < 2; ks++) {
            int ko = ks * 32 + lgrp * 8;
            bf16x8 a0 = *(const bf16x8*)&Xb[wr + lrow][ko];
            bf16x8 a1 = *(const bf16x8*)&Xb[wr + 16 + lrow][ko];
            bf16x8 b0 = *(const bf16x8*)&Wt[wc + lrow][ko];
            bf16x8 b1 = *(const bf16x8*)&Wt[wc + 16 + lrow][ko];
            o00 = __builtin_amdgcn_mfma_f32_16x16x32_bf16(a0, b0, o00, 0, 0, 0);
            o01 = __builtin_amdgcn_mfma_f32_16x16x32_bf16(a0, b1, o01, 0, 0, 0);
            o10 = __builtin_amdgcn_mfma_f32_16x16x32_bf16(a1, b0, o10, 0, 0, 0);
            o11 = __builtin_amdgcn_mfma_f32_16x16x32_bf16(a1, b1, o11, 0, 0, 0);
        }
        const float* b2 = bout + type * HID;
        float b20 = b2[wc + lrow], b21 = b2[wc + 16 + lrow];
        float* O = outp + base_off;
        #pragma unroll
        for (int mi = 0; mi < 2; mi++) {
            const f32x4 on0 = mi ? o10 : o00;
            const f32x4 on1 = mi ? o11 : o01;
            int rbase = wr + mi * 16 + lgrp * 4;
            #pragma unroll
            for (int r = 0; r < 4; r++) {
                int n = nb + rbase + r;
                if (n >= N) continue;
                O[(size_t)n * HID + wc + lrow]      = on0[r] + b20;
                O[(size_t)n * HID + wc + 16 + lrow] = on1[r] + b21;
            }
        }
    }
}

extern "C" void kernel_launch(void* const* d_in, const int* in_sizes, int n_in,
                              void* d_out, int out_size, void* d_ws, size_t ws_size,
                              hipStream_t stream) {
    const float* x_paper  = (const float*)d_in[0];
    const float* x_author = (const float*)d_in[1];
    const int*   ei_ap    = (const int*)d_in[2];
    const int*   ei_pa    = (const int*)d_in[3];
    const int*   ei_pp    = (const int*)d_in[4];
    const float* W_in     = (const float*)d_in[5];
    const float* b_in     = (const float*)d_in[6];
    const float* W_kqv    = (const float*)d_in[7];
    const float* b_kqv    = (const float*)d_in[8];
    const float* W_krel   = (const float*)d_in[9];
    const float* W_vrel   = (const float*)d_in[10];
    const float* p_rel    = (const float*)d_in[11];
    const float* W_hout   = (const float*)d_in[12];
    const float* b_hout   = (const float*)d_in[13];
    const float* skip     = (const float*)d_in[14];
    const float* ln_g     = (const float*)d_in[15];
    const float* ln_b     = (const float*)d_in[16];
    const float* W_out    = (const float*)d_in[17];
    const float* b_out    = (const float*)d_in[18];
    float* out            = (float*)d_out;

    // ---- workspace layout (~122 MB) ----
    char* ws = (char*)d_ws;
    unsigned short* Hb  = (unsigned short*)ws;                    // NTOT*64 bf16
    unsigned short* Qh  = Hb + (size_t)NTOT * HID;                // NTOT*64 f16 pairs
    unsigned* KVb       = (unsigned*)(Qh + (size_t)NTOT * HID);   // NSRC*64 dwords
    unsigned short* ABf = (unsigned short*)(KVb + (size_t)NSRC * HID); // NTOT*64 bf16
    unsigned short* WfpT = ABf + (size_t)NTOT * HID;    // JP*64 bf16
    float* bfp  = (float*)(WfpT + (size_t)JP * 64);     // 320
    unsigned short* WfaT = (unsigned short*)(bfp + JP); // JA*64 bf16
    float* bfa  = (float*)(WfaT + (size_t)JA * 64);     // 192
    unsigned short* WinT   = (unsigned short*)(bfa + JA);         // 2*64*128
    unsigned short* WhoutT = WinT + 2 * 64 * IN_DIM;              // L*2*64*64
    unsigned short* WoutT  = WhoutT + LAYERS * 2 * 64 * 64;       // 2*64*64
    int* cnt      = (int*)(WoutT + 2 * 64 * 64);        // NTOT
    int* row_ptr  = cnt + NTOT;                         // NTOT+1 (pad 16)
    int* cursor   = row_ptr + NTOT + 16;                // NTOT
    int* edge_src = cursor + NTOT;                      // ETOT
    int* csum     = edge_src + ETOT;                    // 1024
    int* coff     = csum + 1024;                        // 1024

    dim3 blk(256);
    const int EB = (ETOT + 255) / 256;

    // ---- CSR build (edges are layer-invariant) ----
    zero_int_kernel<<<256, blk, 0, stream>>>(cnt, NTOT);
    csr_count_kernel<<<EB, blk, 0, stream>>>(ei_ap, ei_pa, ei_pp, cnt);
    scan_chunk_sums<<<NCH, blk, 0, stream>>>(cnt, csum);
    scan_offsets<<<1, 1024, 0, stream>>>(csum, coff, NCH);
    scan_final<<<NCH, blk, 0, stream>>>(cnt, coff, row_ptr, cursor);
    csr_fill_kernel<<<EB, blk, 0, stream>>>(ei_ap, ei_pa, ei_pp, cursor, edge_src);

    // ---- one-time weight prep (transposed bf16) ----
    prep_weights<<<(2*64*IN_DIM + LAYERS*2*4096 + 2*4096 + 255) / 256, blk, 0, stream>>>(
        W_in, W_hout, W_out, WinT, WhoutT, WoutT);

    // ---- input projection ----
    gemm_in<<<PT + AT, blk, 0, stream>>>(x_paper, x_author, WinT, b_in, Hb);

    for (int l = 0; l < LAYERS; l++) {
        fuse_weights_kernel<<<(65 * JP + 65 * JA + 255) / 256, blk, 0, stream>>>(
            W_kqv + (size_t)l * 2 * HID * KQV, b_kqv + (size_t)l * 2 * KQV,
            W_krel + (size_t)l * 3 * NH * HD * HD, W_vrel + (size_t)l * 3 * NH * HD * HD,
            WfpT, bfp, WfaT, bfa);
        gemm_kqv<<<2 * PT + AT, blk, 0, stream>>>(
            Hb, WfpT, bfp, WfaT, bfa, Qh, KVb);
        attn_kernel<<<(NTOT + 3) / 4, blk, 0, stream>>>(
            Qh, KVb, p_rel + l * 3 * NH, row_ptr, edge_src, ABf);
        bool last = (l == LAYERS - 1);
        gemm_hout<<<PT + AT, blk, 0, stream>>>(
            ABf, WhoutT + (size_t)l * 2 * 4096, b_hout + l * 2 * HID,
            skip + l * 2, ln_g + l * 2 * HID, ln_b + l * 2 * HID, Hb,
            last ? WoutT : nullptr, last ? b_out : nullptr, last ? out : nullptr);
    }
}